// Round 2
// baseline (5158.336 us; speedup 1.0000x reference)
//
#include <hip/hip_runtime.h>
#include <cstddef>
#include <cstdint>

#define D_MODEL 256
#define NHEAD   8
#define DHEAD   32
#define NLAYER  6
#define BATCH   4
#define QTOT    5440
#define MTOT    (BATCH*QTOT)   // 21760 = 340*64
#define MHALF   (MTOT/2)       // 10880 = 170*64
#define DFFN    1024

// ---------------------------------------------------------------------------
// Flatten + transpose: src [B, D, H*W] -> dst [B, Q, D] at query offset qoff.
// Optional level_embed add (for pos path).
// ---------------------------------------------------------------------------
__global__ __launch_bounds__(256) void flatten_tr(
    const float* __restrict__ src, const float* __restrict__ emb,
    float* __restrict__ dst, int HW, int qoff)
{
    __shared__ float tile[32][33];
    int tx = threadIdx.x, ty = threadIdx.y;
    int hw0 = blockIdx.x * 32, d0 = blockIdx.y * 32, b = blockIdx.z;
    const float* s = src + (size_t)b * D_MODEL * HW;
#pragma unroll
    for (int j = 0; j < 4; ++j) {
        int d = ty + j * 8;
        tile[d][tx] = s[(size_t)(d0 + d) * HW + hw0 + tx];
    }
    __syncthreads();
#pragma unroll
    for (int j = 0; j < 4; ++j) {
        int hw = ty + j * 8;
        float v = tile[tx][hw];
        if (emb) v += emb[d0 + tx];
        dst[((size_t)b * QTOT + qoff + hw0 + hw) * D_MODEL + d0 + tx] = v;
    }
}

// ---------------------------------------------------------------------------
// Tiled fp32 GEMM: C[M,N] = (A [+ A2])[M,K] @ W[K,N] + bias[N], optional ReLU.
// BM=BN=64, BK=16, 256 threads, 4x4 per thread. All dims divide evenly.
// ---------------------------------------------------------------------------
#define BM 64
#define BN 64
#define BK 16

__global__ __launch_bounds__(256) void gemm_bias(
    const float* __restrict__ A, const float* __restrict__ A2,
    const float* __restrict__ W, const float* __restrict__ bias,
    float* __restrict__ C, int N, int K, int relu)
{
    __shared__ float As[BK][BM];
    __shared__ float Bs[BK][BN];
    int tid = threadIdx.x;
    int row0 = blockIdx.y * BM, col0 = blockIdx.x * BN;
    int tx = tid & 15, ty = tid >> 4;          // 16x16 thread grid
    int am = tid >> 2, ak = (tid & 3) * 4;     // A-load: 64 rows x 16 k
    int bk = tid >> 4, bn = (tid & 15) * 4;    // B-load: 16 k x 64 n
    float acc[4][4] = {};

    for (int k0 = 0; k0 < K; k0 += BK) {
        size_t aoff = (size_t)(row0 + am) * K + k0 + ak;
        float4 av = *reinterpret_cast<const float4*>(&A[aoff]);
        if (A2) {
            float4 a2 = *reinterpret_cast<const float4*>(&A2[aoff]);
            av.x += a2.x; av.y += a2.y; av.z += a2.z; av.w += a2.w;
        }
        As[ak + 0][am] = av.x; As[ak + 1][am] = av.y;
        As[ak + 2][am] = av.z; As[ak + 3][am] = av.w;
        float4 bv = *reinterpret_cast<const float4*>(
            &W[(size_t)(k0 + bk) * N + col0 + bn]);
        *reinterpret_cast<float4*>(&Bs[bk][bn]) = bv;
        __syncthreads();
#pragma unroll
        for (int k = 0; k < BK; ++k) {
            float4 a = *reinterpret_cast<const float4*>(&As[k][ty * 4]);
            float4 b = *reinterpret_cast<const float4*>(&Bs[k][tx * 4]);
            acc[0][0] += a.x * b.x; acc[0][1] += a.x * b.y; acc[0][2] += a.x * b.z; acc[0][3] += a.x * b.w;
            acc[1][0] += a.y * b.x; acc[1][1] += a.y * b.y; acc[1][2] += a.y * b.z; acc[1][3] += a.y * b.w;
            acc[2][0] += a.z * b.x; acc[2][1] += a.z * b.y; acc[2][2] += a.z * b.z; acc[2][3] += a.z * b.w;
            acc[3][0] += a.w * b.x; acc[3][1] += a.w * b.y; acc[3][2] += a.w * b.z; acc[3][3] += a.w * b.w;
        }
        __syncthreads();
    }

    float4 bb = *reinterpret_cast<const float4*>(&bias[col0 + tx * 4]);
#pragma unroll
    for (int i = 0; i < 4; ++i) {
        float4 v = make_float4(acc[i][0] + bb.x, acc[i][1] + bb.y,
                               acc[i][2] + bb.z, acc[i][3] + bb.w);
        if (relu) {
            v.x = fmaxf(v.x, 0.f); v.y = fmaxf(v.y, 0.f);
            v.z = fmaxf(v.z, 0.f); v.w = fmaxf(v.w, 0.f);
        }
        *reinterpret_cast<float4*>(
            &C[(size_t)(row0 + ty * 4 + i) * N + col0 + tx * 4]) = v;
    }
}

// ---------------------------------------------------------------------------
// Softmax over 16 contiguous floats per thread (one (b,q,head) each).
// ---------------------------------------------------------------------------
__global__ __launch_bounds__(256) void softmax16(float* __restrict__ a, int total)
{
    int i = blockIdx.x * blockDim.x + threadIdx.x;
    if (i >= total) return;
    float* p = a + (size_t)i * 16;
    float v[16], mx = -1e30f;
#pragma unroll
    for (int j = 0; j < 16; ++j) { v[j] = p[j]; mx = fmaxf(mx, v[j]); }
    float s = 0.f;
#pragma unroll
    for (int j = 0; j < 16; ++j) { v[j] = expf(v[j] - mx); s += v[j]; }
    float r = 1.f / s;
#pragma unroll
    for (int j = 0; j < 16; ++j) p[j] = v[j] * r;
}

// ---------------------------------------------------------------------------
// MS-deformable attention sampling.
// One block per (b,q); 8 heads x 32 channels = 256 threads.
// ---------------------------------------------------------------------------
__global__ __launch_bounds__(256) void msda_sample(
    const float* __restrict__ value, const float* __restrict__ off,
    const float* __restrict__ aw, float* __restrict__ outp)
{
    const int lvl_off[4] = {0, 4096, 5120, 5376};
    const int lvl_hw[4]  = {64, 32, 16, 8};   // square levels

    int m = blockIdx.x;                // b*QTOT + q
    int b = m / QTOT, q = m - b * QTOT;
    int tid = threadIdx.x;
    int h = tid >> 5, dh = tid & 31;

    int lq, rem;
    if      (q < 4096) { lq = 0; rem = q; }
    else if (q < 5120) { lq = 1; rem = q - 4096; }
    else if (q < 5376) { lq = 2; rem = q - 5120; }
    else               { lq = 3; rem = q - 5376; }
    int Wq = lvl_hw[lq];
    int yq = rem / Wq, xq = rem - yq * Wq;
    float ref_x = (xq + 0.5f) / (float)Wq;
    float ref_y = (yq + 0.5f) / (float)Wq;

    const float* offp = off + (size_t)m * 256 + h * 32;   // ((h*4+l)*4+p)*2+c
    const float* awp  = aw  + (size_t)m * 128 + h * 16;

    float acc = 0.f;
#pragma unroll
    for (int l = 0; l < 4; ++l) {
        int HW = lvl_hw[l];
        float fHW = (float)HW;
        const float* vbase =
            value + ((size_t)(b * QTOT + lvl_off[l])) * D_MODEL + h * DHEAD + dh;
#pragma unroll
        for (int p = 0; p < 4; ++p) {
            float ox = offp[(l * 4 + p) * 2 + 0];
            float oy = offp[(l * 4 + p) * 2 + 1];
            float a  = awp[l * 4 + p];
            float x = (ref_x + ox / fHW) * fHW - 0.5f;
            float y = (ref_y + oy / fHW) * fHW - 0.5f;
            float x0f = floorf(x), y0f = floorf(y);
            int   x0 = (int)x0f,  y0 = (int)y0f;
            float wx = x - x0f,   wy = y - y0f;
            float w00 = (1.f - wx) * (1.f - wy), w01 = wx * (1.f - wy);
            float w10 = (1.f - wx) * wy,         w11 = wx * wy;
            bool xv0 = (x0 >= 0) && (x0 < HW);
            bool xv1 = (x0 + 1 >= 0) && (x0 + 1 < HW);
            bool yv0 = (y0 >= 0) && (y0 < HW);
            bool yv1 = (y0 + 1 >= 0) && (y0 + 1 < HW);
            float v00 = (xv0 && yv0) ? vbase[(size_t)(y0 * HW + x0) * D_MODEL] : 0.f;
            float v01 = (xv1 && yv0) ? vbase[(size_t)(y0 * HW + x0 + 1) * D_MODEL] : 0.f;
            float v10 = (xv0 && yv1) ? vbase[(size_t)((y0 + 1) * HW + x0) * D_MODEL] : 0.f;
            float v11 = (xv1 && yv1) ? vbase[(size_t)((y0 + 1) * HW + x0 + 1) * D_MODEL] : 0.f;
            acc += a * (w00 * v00 + w01 * v01 + w10 * v10 + w11 * v11);
        }
    }
    outp[(size_t)m * D_MODEL + h * DHEAD + dh] = acc;
}

// ---------------------------------------------------------------------------
// Fused residual-add + LayerNorm, in place on x: x = LN(x + t)*g + beta.
// One 64-lane wave per row of 256.
// ---------------------------------------------------------------------------
__global__ __launch_bounds__(64) void add_ln(
    const float* __restrict__ t, const float* __restrict__ g,
    const float* __restrict__ beta, float* __restrict__ x)
{
    int row = blockIdx.x;
    int lane = threadIdx.x;
    size_t base = (size_t)row * D_MODEL + lane * 4;
    float4 xv = *reinterpret_cast<const float4*>(&x[base]);
    float4 tv = *reinterpret_cast<const float4*>(&t[base]);
    float v0 = xv.x + tv.x, v1 = xv.y + tv.y, v2 = xv.z + tv.z, v3 = xv.w + tv.w;
    float s = v0 + v1 + v2 + v3;
#pragma unroll
    for (int o = 32; o > 0; o >>= 1) s += __shfl_xor(s, o);
    float mean = s * (1.f / D_MODEL);
    float d0 = v0 - mean, d1 = v1 - mean, d2 = v2 - mean, d3 = v3 - mean;
    float ss = d0 * d0 + d1 * d1 + d2 * d2 + d3 * d3;
#pragma unroll
    for (int o = 32; o > 0; o >>= 1) ss += __shfl_xor(ss, o);
    float rstd = rsqrtf(ss * (1.f / D_MODEL) + 1e-5f);
    float4 gv = *reinterpret_cast<const float4*>(&g[lane * 4]);
    float4 bv = *reinterpret_cast<const float4*>(&beta[lane * 4]);
    float4 ov = make_float4(d0 * rstd * gv.x + bv.x, d1 * rstd * gv.y + bv.y,
                            d2 * rstd * gv.z + bv.z, d3 * rstd * gv.w + bv.w);
    *reinterpret_cast<float4*>(&x[base]) = ov;
}

// ---------------------------------------------------------------------------
extern "C" void kernel_launch(void* const* d_in, const int* in_sizes, int n_in,
                              void* d_out, int out_size, void* d_ws, size_t ws_size,
                              hipStream_t stream)
{
    // setup_inputs() dict order is INTERLEAVED: src0,pos0,src1,pos1,...
    const float* src[4] = {(const float*)d_in[0], (const float*)d_in[2],
                           (const float*)d_in[4], (const float*)d_in[6]};
    const float* pos[4] = {(const float*)d_in[1], (const float*)d_in[3],
                           (const float*)d_in[5], (const float*)d_in[7]};
    const float* lvl   = (const float*)d_in[8];
    const float* W_off = (const float*)d_in[9];
    const float* b_off = (const float*)d_in[10];
    const float* W_att = (const float*)d_in[11];
    const float* b_att = (const float*)d_in[12];
    const float* W_val = (const float*)d_in[13];
    const float* b_val = (const float*)d_in[14];
    const float* W_out = (const float*)d_in[15];
    const float* b_out = (const float*)d_in[16];
    const float* ln1g  = (const float*)d_in[17];
    const float* ln1b  = (const float*)d_in[18];
    const float* W_ff1 = (const float*)d_in[19];
    const float* b_ff1 = (const float*)d_in[20];
    const float* W_ff2 = (const float*)d_in[21];
    const float* b_ff2 = (const float*)d_in[22];
    const float* ln2g  = (const float*)d_in[23];
    const float* ln2b  = (const float*)d_in[24];

    float* out = (float*)d_out;              // running [B,Q,D] activations
    float* ws  = (float*)d_ws;
    const size_t MD = (size_t)MTOT * D_MODEL;           // 5,570,560 floats
    // Workspace layout (total ~25.07M floats = ~95.6 MiB):
    float* posf  = ws;                                  // [M,256] persistent
    float* val   = posf + MD;                           // [M,256]
    float* attnb = val + MD;                            // [M,128]
    float* offb  = attnb + (size_t)MTOT * 128;          // [M,256]  (aliases tmp)
    float* ebuf  = offb + MD;                           // [M,256]  (msd / ffn2-out)
    float* hid   = val;   // FFN hidden (half-M chunks): spans val+attnb+part of offb
    float* tmp   = offb;  // out-proj result (offb dead by then)

    const int hws[4]  = {4096, 1024, 256, 64};
    const int qoff[4] = {0, 4096, 5120, 5376};

    // Flatten srcs into `out`, pos+level_embed into posf.
    for (int l = 0; l < 4; ++l) {
        dim3 g(hws[l] / 32, D_MODEL / 32, BATCH), blk(32, 8);
        flatten_tr<<<g, blk, 0, stream>>>(src[l], nullptr, out, hws[l], qoff[l]);
        flatten_tr<<<g, blk, 0, stream>>>(pos[l], lvl + l * D_MODEL, posf, hws[l], qoff[l]);
    }

    for (int i = 0; i < NLAYER; ++i) {
        // value = out @ W_val + b_val
        gemm_bias<<<dim3(4, MTOT / BM), 256, 0, stream>>>(
            out, nullptr, W_val + (size_t)i * 256 * 256, b_val + i * 256, val, 256, 256, 0);
        // offsets = (out+pos) @ W_off + b_off
        gemm_bias<<<dim3(4, MTOT / BM), 256, 0, stream>>>(
            out, posf, W_off + (size_t)i * 256 * 256, b_off + i * 256, offb, 256, 256, 0);
        // attn logits = (out+pos) @ W_attn + b_attn
        gemm_bias<<<dim3(2, MTOT / BM), 256, 0, stream>>>(
            out, posf, W_att + (size_t)i * 256 * 128, b_att + i * 128, attnb, 128, 256, 0);
        // softmax over 16 per (b,q,head)
        softmax16<<<(MTOT * NHEAD + 255) / 256, 256, 0, stream>>>(attnb, MTOT * NHEAD);
        // deformable sampling -> ebuf
        msda_sample<<<MTOT, 256, 0, stream>>>(val, offb, attnb, ebuf);
        // output projection: ebuf @ W_out -> tmp (aliases offb)
        gemm_bias<<<dim3(4, MTOT / BM), 256, 0, stream>>>(
            ebuf, nullptr, W_out + (size_t)i * 256 * 256, b_out + i * 256, tmp, 256, 256, 0);
        // out = LN(out + attn_out)
        add_ln<<<MTOT, 64, 0, stream>>>(tmp, ln1g + i * 256, ln1b + i * 256, out);
        // FFN in two half-M chunks (hid reuses val.. region; out -> ebuf)
        for (int h = 0; h < 2; ++h) {
            const float* arow = out + (size_t)h * MHALF * D_MODEL;
            gemm_bias<<<dim3(16, MHALF / BM), 256, 0, stream>>>(
                arow, nullptr, W_ff1 + (size_t)i * 256 * 1024, b_ff1 + i * 1024,
                hid, 1024, 256, 1);
            gemm_bias<<<dim3(4, MHALF / BM), 256, 0, stream>>>(
                hid, nullptr, W_ff2 + (size_t)i * 1024 * 256, b_ff2 + i * 256,
                ebuf + (size_t)h * MHALF * D_MODEL, 256, 1024, 0);
        }
        // out = LN(out + ff)
        add_ln<<<MTOT, 64, 0, stream>>>(ebuf, ln2g + i * 256, ln2b + i * 256, out);
    }
    (void)in_sizes; (void)n_in; (void)out_size; (void)ws_size;
}

// Round 3
// 2206.989 us; speedup vs baseline: 2.3373x; 2.3373x over previous
//
#include <hip/hip_runtime.h>
#include <cstddef>
#include <cstdint>

#define D_MODEL 256
#define NHEAD   8
#define NLAYER  6
#define BATCH   4
#define QTOT    5440
#define MTOT    (BATCH*QTOT)   // 21760 = 170*128
#define MHALF   (MTOT/2)       // 10880 = 85*128
#define DFFN    1024

typedef short  bf16x8 __attribute__((ext_vector_type(8)));
typedef float  f32x4  __attribute__((ext_vector_type(4)));

__device__ __forceinline__ unsigned short f2bf(float f) {
    uint32_t u = __float_as_uint(f);
    return (unsigned short)((u + 0x7fffu + ((u >> 16) & 1u)) >> 16);
}
__device__ __forceinline__ float bf2f(unsigned short s) {
    return __uint_as_float(((uint32_t)s) << 16);
}

// ---------------------------------------------------------------------------
// Flatten + transpose: src [B, D, H*W] -> dst [B, Q, D] at query offset qoff.
// ---------------------------------------------------------------------------
__global__ __launch_bounds__(256) void flatten_tr(
    const float* __restrict__ src, const float* __restrict__ emb,
    float* __restrict__ dst, int HW, int qoff)
{
    __shared__ float tile[32][33];
    int tx = threadIdx.x, ty = threadIdx.y;
    int hw0 = blockIdx.x * 32, d0 = blockIdx.y * 32, b = blockIdx.z;
    const float* s = src + (size_t)b * D_MODEL * HW;
#pragma unroll
    for (int j = 0; j < 4; ++j) {
        int d = ty + j * 8;
        tile[d][tx] = s[(size_t)(d0 + d) * HW + hw0 + tx];
    }
    __syncthreads();
#pragma unroll
    for (int j = 0; j < 4; ++j) {
        int hw = ty + j * 8;
        float v = tile[tx][hw];
        if (emb) v += emb[d0 + tx];
        dst[((size_t)b * QTOT + qoff + hw0 + hw) * D_MODEL + d0 + tx] = v;
    }
}

// ---------------------------------------------------------------------------
// Weight convert+transpose: W fp32 [L][K][N] -> Whi/Wlo bf16(short) [L][N][K]
// ---------------------------------------------------------------------------
__global__ __launch_bounds__(256) void wconv(
    const float* __restrict__ W, short* __restrict__ Whi,
    short* __restrict__ Wlo, int K, int N)
{
    __shared__ float t[32][33];
    int tx = threadIdx.x, ty = threadIdx.y;
    int n0 = blockIdx.x * 32, k0 = blockIdx.y * 32, l = blockIdx.z;
    const float* Wl = W + (size_t)l * K * N;
    short* Hl = Whi + (size_t)l * K * N;
    short* Ll = Wlo + (size_t)l * K * N;
#pragma unroll
    for (int j = 0; j < 4; ++j)
        t[ty + j * 8][tx] = Wl[(size_t)(k0 + ty + j * 8) * N + n0 + tx];
    __syncthreads();
#pragma unroll
    for (int j = 0; j < 4; ++j) {
        float v = t[tx][ty + j * 8];           // = W[k0+tx][n0+ty+8j]
        int n = n0 + ty + j * 8, k = k0 + tx;
        unsigned short h = f2bf(v);
        Hl[(size_t)n * K + k] = (short)h;
        Ll[(size_t)n * K + k] = (short)f2bf(v - bf2f(h));
    }
}

// ---------------------------------------------------------------------------
// MFMA GEMM: C[M,N] fp32 = split_bf16((A[+A2])[M,K]) @ (Whi+Wlo)[N,K]^T + bias
// BM=128, BN=64, BK=32. 256 thr = 4 waves (2x2), each wave 64x32 out.
// A staged fp32->bf16 hi/lo in-kernel; W pre-converted [N][K] bf16.
// LDS XOR-swizzled (seg ^ ((row>>1)&3)) -> 2-way (free) ds_read_b128.
// ---------------------------------------------------------------------------
template<int RELU, int HASA2>
__global__ __launch_bounds__(256) void gemm_mfma(
    const float* __restrict__ A, const float* __restrict__ A2,
    const short* __restrict__ Whi, const short* __restrict__ Wlo,
    const float* __restrict__ bias, float* __restrict__ C, int N, int K)
{
    // per buffer (shorts): Ahi 4096 | Alo 4096 | Bhi 2048 | Blo 2048 = 24KB
    __shared__ __align__(16) short lds[2 * 12288];

    int tid  = threadIdx.x;
    int lane = tid & 63, wid = tid >> 6;
    int wr = wid >> 1, wc = wid & 1;
    int row0 = blockIdx.y * 128, col0 = blockIdx.x * 64;

    // staging assignments
    int srow = tid >> 1, shalf = tid & 1;   // A: 128 rows x 2 halves(16 elem)
    int brow = tid >> 2, bseg = tid & 3;    // B: 64 rows x 4 segs(8 elem)
    const float* Arow  = A + (size_t)(row0 + srow) * K + shalf * 16;
    const float* A2row = HASA2 ? A2 + (size_t)(row0 + srow) * K + shalf * 16 : nullptr;
    const short* Whirow = Whi + (size_t)(col0 + brow) * K + bseg * 8;
    const short* Wlorow = Wlo + (size_t)(col0 + brow) * K + bseg * 8;
    int aswz = (srow >> 1) & 3;
    int a_wb0 = srow * 64 + ((2 * shalf + 0) ^ aswz) * 16;
    int a_wb1 = srow * 64 + ((2 * shalf + 1) ^ aswz) * 16;
    int b_wb  = brow * 64 + ((bseg ^ ((brow >> 1) & 3)) * 16);

    f32x4 acc[4][2];
#pragma unroll
    for (int i = 0; i < 4; ++i)
#pragma unroll
        for (int j = 0; j < 2; ++j) acc[i][j] = (f32x4){0.f, 0.f, 0.f, 0.f};

    float av[16];
    uint4 bhv, blv;

    auto load_stage = [&](int kt) {
        const float4* ap = reinterpret_cast<const float4*>(Arow + kt * 32);
#pragma unroll
        for (int i = 0; i < 4; ++i) {
            float4 v = ap[i];
            av[4 * i + 0] = v.x; av[4 * i + 1] = v.y;
            av[4 * i + 2] = v.z; av[4 * i + 3] = v.w;
        }
        if (HASA2) {
            const float4* a2p = reinterpret_cast<const float4*>(A2row + kt * 32);
#pragma unroll
            for (int i = 0; i < 4; ++i) {
                float4 v = a2p[i];
                av[4 * i + 0] += v.x; av[4 * i + 1] += v.y;
                av[4 * i + 2] += v.z; av[4 * i + 3] += v.w;
            }
        }
        bhv = *reinterpret_cast<const uint4*>(Whirow + kt * 32);
        blv = *reinterpret_cast<const uint4*>(Wlorow + kt * 32);
    };

    auto write_stage = [&](short* buf) {
        unsigned int hw[8], lw[8];
#pragma unroll
        for (int i = 0; i < 8; ++i) {
            unsigned short h0 = f2bf(av[2 * i]), h1 = f2bf(av[2 * i + 1]);
            unsigned short l0 = f2bf(av[2 * i] - bf2f(h0));
            unsigned short l1 = f2bf(av[2 * i + 1] - bf2f(h1));
            hw[i] = (unsigned int)h0 | ((unsigned int)h1 << 16);
            lw[i] = (unsigned int)l0 | ((unsigned int)l1 << 16);
        }
        char* Ahi = (char*)buf;
        char* Alo = (char*)(buf + 4096);
        *(uint4*)(Ahi + a_wb0) = make_uint4(hw[0], hw[1], hw[2], hw[3]);
        *(uint4*)(Ahi + a_wb1) = make_uint4(hw[4], hw[5], hw[6], hw[7]);
        *(uint4*)(Alo + a_wb0) = make_uint4(lw[0], lw[1], lw[2], lw[3]);
        *(uint4*)(Alo + a_wb1) = make_uint4(lw[4], lw[5], lw[6], lw[7]);
        *(uint4*)((char*)(buf + 8192)  + b_wb) = bhv;
        *(uint4*)((char*)(buf + 10240) + b_wb) = blv;
    };

    int l15 = lane & 15, l4 = lane >> 4;
    auto compute = [&](const short* buf) {
        const char* Ahi = (const char*)buf;
        const char* Alo = (const char*)(buf + 4096);
        const char* Bhi = (const char*)(buf + 8192);
        const char* Blo = (const char*)(buf + 10240);
        bf16x8 bh[2], bl[2];
#pragma unroll
        for (int nc = 0; nc < 2; ++nc) {
            int col = wc * 32 + nc * 16 + l15;
            int byt = col * 64 + ((l4 ^ ((col >> 1) & 3)) * 16);
            bh[nc] = *(const bf16x8*)(Bhi + byt);
            bl[nc] = *(const bf16x8*)(Blo + byt);
        }
#pragma unroll
        for (int mr = 0; mr < 4; ++mr) {
            int row = wr * 64 + mr * 16 + l15;
            int byt = row * 64 + ((l4 ^ ((row >> 1) & 3)) * 16);
            bf16x8 ah = *(const bf16x8*)(Ahi + byt);
            bf16x8 al = *(const bf16x8*)(Alo + byt);
#pragma unroll
            for (int nc = 0; nc < 2; ++nc) {
                acc[mr][nc] = __builtin_amdgcn_mfma_f32_16x16x32_bf16(ah, bh[nc], acc[mr][nc], 0, 0, 0);
                acc[mr][nc] = __builtin_amdgcn_mfma_f32_16x16x32_bf16(ah, bl[nc], acc[mr][nc], 0, 0, 0);
                acc[mr][nc] = __builtin_amdgcn_mfma_f32_16x16x32_bf16(al, bh[nc], acc[mr][nc], 0, 0, 0);
            }
        }
    };

    int nk = K >> 5;
    load_stage(0);
    write_stage(lds);
    __syncthreads();
    for (int kt = 0; kt < nk; ++kt) {
        short* cur = lds + (kt & 1) * 12288;
        short* nxt = lds + ((kt & 1) ^ 1) * 12288;
        if (kt + 1 < nk) load_stage(kt + 1);   // issue global loads early
        compute(cur);                           // MFMAs hide load latency
        if (kt + 1 < nk) write_stage(nxt);      // cvt + ds_write
        __syncthreads();
    }

#pragma unroll
    for (int nc = 0; nc < 2; ++nc) {
        int col = col0 + wc * 32 + nc * 16 + l15;
        float bv = bias[col];
#pragma unroll
        for (int mr = 0; mr < 4; ++mr) {
            int row = row0 + wr * 64 + mr * 16 + l4 * 4;
#pragma unroll
            for (int r = 0; r < 4; ++r) {
                float v = acc[mr][nc][r] + bv;
                if (RELU) v = fmaxf(v, 0.f);
                C[(size_t)(row + r) * N + col] = v;
            }
        }
    }
}

// ---------------------------------------------------------------------------
// Fallback fp32 GEMM (round-1): C = (A[+A2]) @ W + bias, optional ReLU.
// ---------------------------------------------------------------------------
__global__ __launch_bounds__(256) void gemm_bias(
    const float* __restrict__ A, const float* __restrict__ A2,
    const float* __restrict__ W, const float* __restrict__ bias,
    float* __restrict__ C, int N, int K, int relu)
{
    __shared__ float As[16][64];
    __shared__ float Bs[16][64];
    int tid = threadIdx.x;
    int row0 = blockIdx.y * 64, col0 = blockIdx.x * 64;
    int tx = tid & 15, ty = tid >> 4;
    int am = tid >> 2, ak = (tid & 3) * 4;
    int bk = tid >> 4, bn = (tid & 15) * 4;
    float acc[4][4] = {};

    for (int k0 = 0; k0 < K; k0 += 16) {
        size_t aoff = (size_t)(row0 + am) * K + k0 + ak;
        float4 avv = *reinterpret_cast<const float4*>(&A[aoff]);
        if (A2) {
            float4 a2 = *reinterpret_cast<const float4*>(&A2[aoff]);
            avv.x += a2.x; avv.y += a2.y; avv.z += a2.z; avv.w += a2.w;
        }
        As[ak + 0][am] = avv.x; As[ak + 1][am] = avv.y;
        As[ak + 2][am] = avv.z; As[ak + 3][am] = avv.w;
        float4 bvv = *reinterpret_cast<const float4*>(
            &W[(size_t)(k0 + bk) * N + col0 + bn]);
        *reinterpret_cast<float4*>(&Bs[bk][bn]) = bvv;
        __syncthreads();
#pragma unroll
        for (int k = 0; k < 16; ++k) {
            float4 a = *reinterpret_cast<const float4*>(&As[k][ty * 4]);
            float4 b = *reinterpret_cast<const float4*>(&Bs[k][tx * 4]);
            acc[0][0] += a.x * b.x; acc[0][1] += a.x * b.y; acc[0][2] += a.x * b.z; acc[0][3] += a.x * b.w;
            acc[1][0] += a.y * b.x; acc[1][1] += a.y * b.y; acc[1][2] += a.y * b.z; acc[1][3] += a.y * b.w;
            acc[2][0] += a.z * b.x; acc[2][1] += a.z * b.y; acc[2][2] += a.z * b.z; acc[2][3] += a.z * b.w;
            acc[3][0] += a.w * b.x; acc[3][1] += a.w * b.y; acc[3][2] += a.w * b.z; acc[3][3] += a.w * b.w;
        }
        __syncthreads();
    }
    float4 bb = *reinterpret_cast<const float4*>(&bias[col0 + tx * 4]);
#pragma unroll
    for (int i = 0; i < 4; ++i) {
        float4 v = make_float4(acc[i][0] + bb.x, acc[i][1] + bb.y,
                               acc[i][2] + bb.z, acc[i][3] + bb.w);
        if (relu) {
            v.x = fmaxf(v.x, 0.f); v.y = fmaxf(v.y, 0.f);
            v.z = fmaxf(v.z, 0.f); v.w = fmaxf(v.w, 0.f);
        }
        *reinterpret_cast<float4*>(
            &C[(size_t)(row0 + ty * 4 + i) * N + col0 + tx * 4]) = v;
    }
}

// ---------------------------------------------------------------------------
// MSDA sampling, one WAVE per query; 8 lanes/head, float4 channels.
// Softmax over 16 logits fused in-register.
// ---------------------------------------------------------------------------
__global__ __launch_bounds__(256) void msda2(
    const float* __restrict__ value, const float* __restrict__ off,
    const float* __restrict__ logits, float* __restrict__ outp)
{
    const int lvl_off[4] = {0, 4096, 5120, 5376};
    const int lvl_hw[4]  = {64, 32, 16, 8};

    int m = blockIdx.x * 4 + (threadIdx.x >> 6);
    int lane = threadIdx.x & 63;
    int h = lane >> 3, c = (lane & 7) * 4;
    int b = m / QTOT, q = m - b * QTOT;

    int lq, rem;
    if      (q < 4096) { lq = 0; rem = q; }
    else if (q < 5120) { lq = 1; rem = q - 4096; }
    else if (q < 5376) { lq = 2; rem = q - 5120; }
    else               { lq = 3; rem = q - 5376; }
    int Wq = lvl_hw[lq];
    int yq = rem / Wq, xq = rem - yq * Wq;
    float ref_x = (xq + 0.5f) / (float)Wq;
    float ref_y = (yq + 0.5f) / (float)Wq;

    // softmax over this head's 16 logits (8 lanes redundant -> broadcast loads)
    const float* lg = logits + (size_t)m * 128 + h * 16;
    float w[16];
    {
        float mx = -1e30f;
#pragma unroll
        for (int i = 0; i < 4; ++i) {
            float4 v = reinterpret_cast<const float4*>(lg)[i];
            w[4 * i] = v.x; w[4 * i + 1] = v.y; w[4 * i + 2] = v.z; w[4 * i + 3] = v.w;
        }
#pragma unroll
        for (int j = 0; j < 16; ++j) mx = fmaxf(mx, w[j]);
        float s = 0.f;
#pragma unroll
        for (int j = 0; j < 16; ++j) { w[j] = __expf(w[j] - mx); s += w[j]; }
        float rs = 1.f / s;
#pragma unroll
        for (int j = 0; j < 16; ++j) w[j] *= rs;
    }

    // offsets for this head: 32 floats
    float ofv[32];
    const float* op = off + (size_t)m * 256 + h * 32;
#pragma unroll
    for (int i = 0; i < 8; ++i) {
        float4 v = reinterpret_cast<const float4*>(op)[i];
        ofv[4 * i] = v.x; ofv[4 * i + 1] = v.y; ofv[4 * i + 2] = v.z; ofv[4 * i + 3] = v.w;
    }

    float a0 = 0.f, a1 = 0.f, a2 = 0.f, a3 = 0.f;
#pragma unroll
    for (int l = 0; l < 4; ++l) {
        int HW = lvl_hw[l];
        float fHW = (float)HW;
        const float* vbase =
            value + ((size_t)(b * QTOT + lvl_off[l])) * D_MODEL + h * 32 + c;
#pragma unroll
        for (int p = 0; p < 4; ++p) {
            float ox = ofv[(l * 4 + p) * 2 + 0];
            float oy = ofv[(l * 4 + p) * 2 + 1];
            float aw = w[l * 4 + p];
            float x = (ref_x + ox / fHW) * fHW - 0.5f;
            float y = (ref_y + oy / fHW) * fHW - 0.5f;
            float x0f = floorf(x), y0f = floorf(y);
            int   x0 = (int)x0f,  y0 = (int)y0f;
            float wx = x - x0f,   wy = y - y0f;
            float w00 = (1.f - wx) * (1.f - wy) * aw, w01 = wx * (1.f - wy) * aw;
            float w10 = (1.f - wx) * wy * aw,         w11 = wx * wy * aw;
            bool xv0 = (x0 >= 0) && (x0 < HW);
            bool xv1 = (x0 + 1 >= 0) && (x0 + 1 < HW);
            bool yv0 = (y0 >= 0) && (y0 < HW);
            bool yv1 = (y0 + 1 >= 0) && (y0 + 1 < HW);
#define GATH(cond, idx, wgt)                                                  \
            if (cond) {                                                       \
                float4 v = *reinterpret_cast<const float4*>(                  \
                    vbase + (size_t)(idx) * D_MODEL);                         \
                a0 += (wgt) * v.x; a1 += (wgt) * v.y;                         \
                a2 += (wgt) * v.z; a3 += (wgt) * v.w;                         \
            }
            GATH(xv0 && yv0, y0 * HW + x0,           w00)
            GATH(xv1 && yv0, y0 * HW + x0 + 1,       w01)
            GATH(xv0 && yv1, (y0 + 1) * HW + x0,     w10)
            GATH(xv1 && yv1, (y0 + 1) * HW + x0 + 1, w11)
#undef GATH
        }
    }
    float4 o = make_float4(a0, a1, a2, a3);
    *reinterpret_cast<float4*>(&outp[(size_t)m * D_MODEL + h * 32 + c]) = o;
}

// ---------------------------------------------------------------------------
// Fused residual-add + LayerNorm, in place: x = LN(x + t)*g + beta.
// ---------------------------------------------------------------------------
__global__ __launch_bounds__(64) void add_ln(
    const float* __restrict__ t, const float* __restrict__ g,
    const float* __restrict__ beta, float* __restrict__ x)
{
    int row = blockIdx.x;
    int lane = threadIdx.x;
    size_t base = (size_t)row * D_MODEL + lane * 4;
    float4 xv = *reinterpret_cast<const float4*>(&x[base]);
    float4 tv = *reinterpret_cast<const float4*>(&t[base]);
    float v0 = xv.x + tv.x, v1 = xv.y + tv.y, v2 = xv.z + tv.z, v3 = xv.w + tv.w;
    float s = v0 + v1 + v2 + v3;
#pragma unroll
    for (int o = 32; o > 0; o >>= 1) s += __shfl_xor(s, o);
    float mean = s * (1.f / D_MODEL);
    float d0 = v0 - mean, d1 = v1 - mean, d2 = v2 - mean, d3 = v3 - mean;
    float ss = d0 * d0 + d1 * d1 + d2 * d2 + d3 * d3;
#pragma unroll
    for (int o = 32; o > 0; o >>= 1) ss += __shfl_xor(ss, o);
    float rstd = rsqrtf(ss * (1.f / D_MODEL) + 1e-5f);
    float4 gv = *reinterpret_cast<const float4*>(&g[lane * 4]);
    float4 bv = *reinterpret_cast<const float4*>(&beta[lane * 4]);
    float4 ov = make_float4(d0 * rstd * gv.x + bv.x, d1 * rstd * gv.y + bv.y,
                            d2 * rstd * gv.z + bv.z, d3 * rstd * gv.w + bv.w);
    *reinterpret_cast<float4*>(&x[base]) = ov;
}

// ---------------------------------------------------------------------------
extern "C" void kernel_launch(void* const* d_in, const int* in_sizes, int n_in,
                              void* d_out, int out_size, void* d_ws, size_t ws_size,
                              hipStream_t stream)
{
    // setup_inputs() dict order is INTERLEAVED: src0,pos0,src1,pos1,...
    const float* src[4] = {(const float*)d_in[0], (const float*)d_in[2],
                           (const float*)d_in[4], (const float*)d_in[6]};
    const float* pos[4] = {(const float*)d_in[1], (const float*)d_in[3],
                           (const float*)d_in[5], (const float*)d_in[7]};
    const float* lvl   = (const float*)d_in[8];
    const float* W_off = (const float*)d_in[9];
    const float* b_off = (const float*)d_in[10];
    const float* W_att = (const float*)d_in[11];
    const float* b_att = (const float*)d_in[12];
    const float* W_val = (const float*)d_in[13];
    const float* b_val = (const float*)d_in[14];
    const float* W_out = (const float*)d_in[15];
    const float* b_out = (const float*)d_in[16];
    const float* ln1g  = (const float*)d_in[17];
    const float* ln1b  = (const float*)d_in[18];
    const float* W_ff1 = (const float*)d_in[19];
    const float* b_ff1 = (const float*)d_in[20];
    const float* W_ff2 = (const float*)d_in[21];
    const float* b_ff2 = (const float*)d_in[22];
    const float* ln2g  = (const float*)d_in[23];
    const float* ln2b  = (const float*)d_in[24];

    float* out = (float*)d_out;
    float* ws  = (float*)d_ws;
    const size_t MD = (size_t)MTOT * D_MODEL;    // 5,570,560
    // float region: posf | val | logits | offb | ebuf  (offb,ebuf adjacent!)
    float* posf   = ws;
    float* val    = posf + MD;
    float* logits = val + MD;
    float* offb   = logits + (size_t)MTOT * 128;
    float* ebuf   = offb + MD;
    float* tmp    = offb;                 // out-proj result (offb dead then)
    float* hid    = offb;                 // FFN hidden spans offb+ebuf (2*MD)
    const size_t FLOAT_BYTES = (4 * MD + (size_t)MTOT * 128) * 4; // 100.27 MB
    // weight region (bf16 shorts), per type across layers
    short* wbase = (short*)(ebuf + MD);
    short* wv_h = wbase;                 short* wv_l = wv_h + 6 * 65536;
    short* wo_h = wv_l + 6 * 65536;      short* wo_l = wo_h + 6 * 65536;
    short* wa_h = wo_l + 6 * 65536;      short* wa_l = wa_h + 6 * 32768;
    short* wu_h = wa_l + 6 * 32768;      short* wu_l = wu_h + 6 * 65536;
    short* wf1_h = wu_l + 6 * 65536;     short* wf1_l = wf1_h + 6 * 262144;
    short* wf2_h = wf1_l + 6 * 262144;   short* wf2_l = wf2_h + 6 * 262144;
    const size_t NEED = FLOAT_BYTES + (size_t)9043968 * 2;  // 118.36 MB
    const bool use_mfma = (ws_size >= NEED);

    const int hws[4]  = {4096, 1024, 256, 64};
    const int qoff[4] = {0, 4096, 5120, 5376};

    for (int l = 0; l < 4; ++l) {
        dim3 g(hws[l] / 32, D_MODEL / 32, BATCH), blk(32, 8);
        flatten_tr<<<g, blk, 0, stream>>>(src[l], nullptr, out, hws[l], qoff[l]);
        flatten_tr<<<g, blk, 0, stream>>>(pos[l], lvl + l * D_MODEL, posf, hws[l], qoff[l]);
    }

    if (use_mfma) {
        dim3 cb(32, 8);
        wconv<<<dim3(8, 8, 6),  cb, 0, stream>>>(W_val, wv_h, wv_l, 256, 256);
        wconv<<<dim3(8, 8, 6),  cb, 0, stream>>>(W_off, wo_h, wo_l, 256, 256);
        wconv<<<dim3(4, 8, 6),  cb, 0, stream>>>(W_att, wa_h, wa_l, 256, 128);
        wconv<<<dim3(8, 8, 6),  cb, 0, stream>>>(W_out, wu_h, wu_l, 256, 256);
        wconv<<<dim3(32, 8, 6), cb, 0, stream>>>(W_ff1, wf1_h, wf1_l, 256, 1024);
        wconv<<<dim3(8, 32, 6), cb, 0, stream>>>(W_ff2, wf2_h, wf2_l, 1024, 256);

        for (int i = 0; i < NLAYER; ++i) {
            gemm_mfma<0,0><<<dim3(4, 170), 256, 0, stream>>>(
                out, nullptr, wv_h + i * 65536, wv_l + i * 65536,
                b_val + i * 256, val, 256, 256);
            gemm_mfma<0,1><<<dim3(4, 170), 256, 0, stream>>>(
                out, posf, wo_h + i * 65536, wo_l + i * 65536,
                b_off + i * 256, offb, 256, 256);
            gemm_mfma<0,1><<<dim3(2, 170), 256, 0, stream>>>(
                out, posf, wa_h + i * 32768, wa_l + i * 32768,
                b_att + i * 128, logits, 128, 256);
            msda2<<<MTOT / 4, 256, 0, stream>>>(val, offb, logits, ebuf);
            gemm_mfma<0,0><<<dim3(4, 170), 256, 0, stream>>>(
                ebuf, nullptr, wu_h + i * 65536, wu_l + i * 65536,
                b_out + i * 256, tmp, 256, 256);
            add_ln<<<MTOT, 64, 0, stream>>>(tmp, ln1g + i * 256, ln1b + i * 256, out);
            for (int h = 0; h < 2; ++h) {
                gemm_mfma<1,0><<<dim3(16, 85), 256, 0, stream>>>(
                    out + (size_t)h * MHALF * 256, nullptr,
                    wf1_h + i * 262144, wf1_l + i * 262144,
                    b_ff1 + i * 1024, hid, 1024, 256);
                gemm_mfma<0,0><<<dim3(4, 85), 256, 0, stream>>>(
                    hid, nullptr, wf2_h + i * 262144, wf2_l + i * 262144,
                    b_ff2 + i * 256, val + (size_t)h * MHALF * 256, 256, 1024);
            }
            add_ln<<<MTOT, 64, 0, stream>>>(val, ln2g + i * 256, ln2b + i * 256, out);
        }
    } else {
        // fallback fp32 path (round-1 proven footprint)
        float* fhid = val;   // spans val..offb (needs 2*MD from val base)
        for (int i = 0; i < NLAYER; ++i) {
            gemm_bias<<<dim3(4, 340), 256, 0, stream>>>(
                out, nullptr, W_val + (size_t)i * 65536, b_val + i * 256, val, 256, 256, 0);
            gemm_bias<<<dim3(4, 340), 256, 0, stream>>>(
                out, posf, W_off + (size_t)i * 65536, b_off + i * 256, offb, 256, 256, 0);
            gemm_bias<<<dim3(2, 340), 256, 0, stream>>>(
                out, posf, W_att + (size_t)i * 32768, b_att + i * 128, logits, 128, 256, 0);
            msda2<<<MTOT / 4, 256, 0, stream>>>(val, offb, logits, ebuf);
            gemm_bias<<<dim3(4, 340), 256, 0, stream>>>(
                ebuf, nullptr, W_out + (size_t)i * 65536, b_out + i * 256, tmp, 256, 256, 0);
            add_ln<<<MTOT, 64, 0, stream>>>(tmp, ln1g + i * 256, ln1b + i * 256, out);
            for (int h = 0; h < 2; ++h) {
                gemm_bias<<<dim3(16, 170), 256, 0, stream>>>(
                    out + (size_t)h * MHALF * 256, nullptr, W_ff1 + (size_t)i * 262144,
                    b_ff1 + i * 1024, fhid, 1024, 256, 1);
                gemm_bias<<<dim3(4, 170), 256, 0, stream>>>(
                    fhid, nullptr, W_ff2 + (size_t)i * 262144, b_ff2 + i * 256,
                    ebuf + (size_t)h * MHALF * 256, 256, 1024, 0);
            }
            add_ln<<<MTOT, 64, 0, stream>>>(ebuf, ln2g + i * 256, ln2b + i * 256, out);
        }
    }
    (void)in_sizes; (void)n_in; (void)out_size;
}

// Round 4
// 2084.429 us; speedup vs baseline: 2.4747x; 1.0588x over previous
//
#include <hip/hip_runtime.h>
#include <cstddef>
#include <cstdint>

#define D_MODEL 256
#define NHEAD   8
#define NLAYER  6
#define BATCH   4
#define QTOT    5440
#define MTOT    (BATCH*QTOT)   // 21760 = 170*128
#define MHALF   (MTOT/2)
#define DFFN    1024

typedef short  bf16x8 __attribute__((ext_vector_type(8)));
typedef float  f32x4  __attribute__((ext_vector_type(4)));
typedef unsigned short u16;

__device__ __forceinline__ u16 f2bf(float f) {
    uint32_t u = __float_as_uint(f);
    return (u16)((u + 0x7fffu + ((u >> 16) & 1u)) >> 16);
}
__device__ __forceinline__ float bf2f(u16 s) {
    return __uint_as_float(((uint32_t)s) << 16);
}

// ---------------------------------------------------------------------------
// Flatten + transpose (fp32): src [B,D,HW] -> dst [B,Q,D], optional emb add.
// ---------------------------------------------------------------------------
__global__ __launch_bounds__(256) void flatten_tr(
    const float* __restrict__ src, const float* __restrict__ emb,
    float* __restrict__ dst, int HW, int qoff)
{
    __shared__ float tile[32][33];
    int tx = threadIdx.x, ty = threadIdx.y;
    int hw0 = blockIdx.x * 32, d0 = blockIdx.y * 32, b = blockIdx.z;
    const float* s = src + (size_t)b * D_MODEL * HW;
#pragma unroll
    for (int j = 0; j < 4; ++j)
        tile[ty + j * 8][tx] = s[(size_t)(d0 + ty + j * 8) * HW + hw0 + tx];
    __syncthreads();
#pragma unroll
    for (int j = 0; j < 4; ++j) {
        int hw = ty + j * 8;
        float v = tile[tx][hw];
        if (emb) v += emb[d0 + tx];
        dst[((size_t)b * QTOT + qoff + hw0 + hw) * D_MODEL + d0 + tx] = v;
    }
}

// ---------------------------------------------------------------------------
// Flatten src -> out bf16 pair + q=(src+posf) bf16 pair.
// ---------------------------------------------------------------------------
__global__ __launch_bounds__(256) void flatten_src_pair(
    const float* __restrict__ src, const float* __restrict__ posf,
    u16* __restrict__ oh, u16* __restrict__ ol,
    u16* __restrict__ qh, u16* __restrict__ ql, int HW, int qoff)
{
    __shared__ float tile[32][33];
    int tx = threadIdx.x, ty = threadIdx.y;
    int hw0 = blockIdx.x * 32, d0 = blockIdx.y * 32, b = blockIdx.z;
    const float* s = src + (size_t)b * D_MODEL * HW;
#pragma unroll
    for (int j = 0; j < 4; ++j)
        tile[ty + j * 8][tx] = s[(size_t)(d0 + ty + j * 8) * HW + hw0 + tx];
    __syncthreads();
#pragma unroll
    for (int j = 0; j < 4; ++j) {
        int hw = ty + j * 8;
        float v = tile[tx][hw];
        size_t idx = ((size_t)b * QTOT + qoff + hw0 + hw) * D_MODEL + d0 + tx;
        u16 h = f2bf(v);
        oh[idx] = h; ol[idx] = f2bf(v - bf2f(h));
        float q = v + posf[idx];
        u16 qhv = f2bf(q);
        qh[idx] = qhv; ql[idx] = f2bf(q - bf2f(qhv));
    }
}

// ---------------------------------------------------------------------------
// Weight convert+transpose: W fp32 [L][K][N] -> hi/lo bf16 [L(lstride)][N][K]
// ---------------------------------------------------------------------------
__global__ __launch_bounds__(256) void wconv(
    const float* __restrict__ W, u16* __restrict__ Whi,
    u16* __restrict__ Wlo, int K, int N, int lstride)
{
    __shared__ float t[32][33];
    int tx = threadIdx.x, ty = threadIdx.y;
    int n0 = blockIdx.x * 32, k0 = blockIdx.y * 32, l = blockIdx.z;
    const float* Wl = W + (size_t)l * K * N;
    u16* Hl = Whi + (size_t)l * lstride;
    u16* Ll = Wlo + (size_t)l * lstride;
#pragma unroll
    for (int j = 0; j < 4; ++j)
        t[ty + j * 8][tx] = Wl[(size_t)(k0 + ty + j * 8) * N + n0 + tx];
    __syncthreads();
#pragma unroll
    for (int j = 0; j < 4; ++j) {
        float v = t[tx][ty + j * 8];
        int n = n0 + ty + j * 8, k = k0 + tx;
        u16 h = f2bf(v);
        Hl[(size_t)n * K + k] = h;
        Ll[(size_t)n * K + k] = f2bf(v - bf2f(h));
    }
}

// ---------------------------------------------------------------------------
// MFMA GEMM with PRE-SPLIT bf16 A and B.
// C[M,N] = (Ah+Al)[M,K] @ (Bh+Bl)[N,K]^T + bias  (3-pass split product)
// BM=128 BN=64 BK=32, 256 thr (4 waves 2x2), XOR-swizzled LDS.
// CMODE 0: fp32 C.  CMODE 1: bf16 hi/lo pair C with ReLU.
// bias: col<nsplit -> bias[col], else bias2[col-nsplit].
// ---------------------------------------------------------------------------
template<int CMODE>
__global__ __launch_bounds__(256) void gemm_pre(
    const u16* __restrict__ Ah, const u16* __restrict__ Al,
    const u16* __restrict__ Bh, const u16* __restrict__ Bl,
    const float* __restrict__ bias, const float* __restrict__ bias2, int nsplit,
    float* __restrict__ Cf, u16* __restrict__ Ch, u16* __restrict__ Cl,
    int N, int K)
{
    __shared__ __align__(16) short lds[2 * 12288];   // 48 KB

    int tid  = threadIdx.x;
    int lane = tid & 63, wid = tid >> 6;
    int wr = wid >> 1, wc = wid & 1;
    int row0 = blockIdx.y * 128, col0 = blockIdx.x * 64;

    int srow = tid >> 1, shalf = tid & 1;
    int brow = tid >> 2, bseg = tid & 3;
    const u16* Ahr = Ah + (size_t)(row0 + srow) * K + shalf * 16;
    const u16* Alr = Al + (size_t)(row0 + srow) * K + shalf * 16;
    const u16* Bhr = Bh + (size_t)(col0 + brow) * K + bseg * 8;
    const u16* Blr = Bl + (size_t)(col0 + brow) * K + bseg * 8;
    int aswz = (srow >> 1) & 3;
    int a_wb0 = srow * 64 + ((2 * shalf + 0) ^ aswz) * 16;
    int a_wb1 = srow * 64 + ((2 * shalf + 1) ^ aswz) * 16;
    int b_wb  = brow * 64 + ((bseg ^ ((brow >> 1) & 3)) * 16);

    f32x4 acc[4][2];
#pragma unroll
    for (int i = 0; i < 4; ++i)
#pragma unroll
        for (int j = 0; j < 2; ++j) acc[i][j] = (f32x4){0.f, 0.f, 0.f, 0.f};

    uint4 rah0, rah1, ral0, ral1, rbh, rbl;
    auto load_stage = [&](int kt) {
        const u16* a = Ahr + kt * 32;
        rah0 = *reinterpret_cast<const uint4*>(a);
        rah1 = *reinterpret_cast<const uint4*>(a + 8);
        const u16* a2 = Alr + kt * 32;
        ral0 = *reinterpret_cast<const uint4*>(a2);
        ral1 = *reinterpret_cast<const uint4*>(a2 + 8);
        rbh = *reinterpret_cast<const uint4*>(Bhr + kt * 32);
        rbl = *reinterpret_cast<const uint4*>(Blr + kt * 32);
    };
    auto write_stage = [&](short* buf) {
        char* Ahi = (char*)buf;
        char* Alo = (char*)(buf + 4096);
        *(uint4*)(Ahi + a_wb0) = rah0;
        *(uint4*)(Ahi + a_wb1) = rah1;
        *(uint4*)(Alo + a_wb0) = ral0;
        *(uint4*)(Alo + a_wb1) = ral1;
        *(uint4*)((char*)(buf + 8192)  + b_wb) = rbh;
        *(uint4*)((char*)(buf + 10240) + b_wb) = rbl;
    };

    int l15 = lane & 15, l4 = lane >> 4;
    auto compute = [&](const short* buf) {
        const char* Ahi = (const char*)buf;
        const char* Alo = (const char*)(buf + 4096);
        const char* Bhi = (const char*)(buf + 8192);
        const char* Blo = (const char*)(buf + 10240);
        bf16x8 bh[2], bl[2];
#pragma unroll
        for (int nc = 0; nc < 2; ++nc) {
            int col = wc * 32 + nc * 16 + l15;
            int byt = col * 64 + ((l4 ^ ((col >> 1) & 3)) * 16);
            bh[nc] = *(const bf16x8*)(Bhi + byt);
            bl[nc] = *(const bf16x8*)(Blo + byt);
        }
#pragma unroll
        for (int mr = 0; mr < 4; ++mr) {
            int row = wr * 64 + mr * 16 + l15;
            int byt = row * 64 + ((l4 ^ ((row >> 1) & 3)) * 16);
            bf16x8 ah = *(const bf16x8*)(Ahi + byt);
            bf16x8 al = *(const bf16x8*)(Alo + byt);
#pragma unroll
            for (int nc = 0; nc < 2; ++nc) {
                acc[mr][nc] = __builtin_amdgcn_mfma_f32_16x16x32_bf16(ah, bh[nc], acc[mr][nc], 0, 0, 0);
                acc[mr][nc] = __builtin_amdgcn_mfma_f32_16x16x32_bf16(ah, bl[nc], acc[mr][nc], 0, 0, 0);
                acc[mr][nc] = __builtin_amdgcn_mfma_f32_16x16x32_bf16(al, bh[nc], acc[mr][nc], 0, 0, 0);
            }
        }
    };

    int nk = K >> 5;
    load_stage(0);
    write_stage(lds);
    __syncthreads();
    for (int kt = 0; kt < nk; ++kt) {
        short* cur = lds + (kt & 1) * 12288;
        short* nxt = lds + ((kt & 1) ^ 1) * 12288;
        if (kt + 1 < nk) load_stage(kt + 1);
        compute(cur);
        if (kt + 1 < nk) write_stage(nxt);
        __syncthreads();
    }

#pragma unroll
    for (int nc = 0; nc < 2; ++nc) {
        int col = col0 + wc * 32 + nc * 16 + l15;
        float bv = (col < nsplit) ? bias[col] : bias2[col - nsplit];
#pragma unroll
        for (int mr = 0; mr < 4; ++mr) {
            int row = row0 + wr * 64 + mr * 16 + l4 * 4;
#pragma unroll
            for (int r = 0; r < 4; ++r) {
                float v = acc[mr][nc][r] + bv;
                size_t idx = (size_t)(row + r) * N + col;
                if (CMODE == 0) {
                    Cf[idx] = v;
                } else {
                    v = fmaxf(v, 0.f);
                    u16 h = f2bf(v);
                    Ch[idx] = h;
                    Cl[idx] = f2bf(v - bf2f(h));
                }
            }
        }
    }
}

// ---------------------------------------------------------------------------
// OLD MFMA GEMM (fallback path, in-kernel fp32->bf16 split staging)
// ---------------------------------------------------------------------------
template<int RELU, int HASA2>
__global__ __launch_bounds__(256) void gemm_mfma(
    const float* __restrict__ A, const float* __restrict__ A2,
    const short* __restrict__ Whi, const short* __restrict__ Wlo,
    const float* __restrict__ bias, float* __restrict__ C, int N, int K)
{
    __shared__ __align__(16) short lds[2 * 12288];
    int tid  = threadIdx.x;
    int lane = tid & 63, wid = tid >> 6;
    int wr = wid >> 1, wc = wid & 1;
    int row0 = blockIdx.y * 128, col0 = blockIdx.x * 64;
    int srow = tid >> 1, shalf = tid & 1;
    int brow = tid >> 2, bseg = tid & 3;
    const float* Arow  = A + (size_t)(row0 + srow) * K + shalf * 16;
    const float* A2row = HASA2 ? A2 + (size_t)(row0 + srow) * K + shalf * 16 : nullptr;
    const short* Whirow = Whi + (size_t)(col0 + brow) * K + bseg * 8;
    const short* Wlorow = Wlo + (size_t)(col0 + brow) * K + bseg * 8;
    int aswz = (srow >> 1) & 3;
    int a_wb0 = srow * 64 + ((2 * shalf + 0) ^ aswz) * 16;
    int a_wb1 = srow * 64 + ((2 * shalf + 1) ^ aswz) * 16;
    int b_wb  = brow * 64 + ((bseg ^ ((brow >> 1) & 3)) * 16);
    f32x4 acc[4][2];
#pragma unroll
    for (int i = 0; i < 4; ++i)
#pragma unroll
        for (int j = 0; j < 2; ++j) acc[i][j] = (f32x4){0.f, 0.f, 0.f, 0.f};
    float av[16];
    uint4 bhv, blv;
    auto load_stage = [&](int kt) {
        const float4* ap = reinterpret_cast<const float4*>(Arow + kt * 32);
#pragma unroll
        for (int i = 0; i < 4; ++i) {
            float4 v = ap[i];
            av[4 * i + 0] = v.x; av[4 * i + 1] = v.y;
            av[4 * i + 2] = v.z; av[4 * i + 3] = v.w;
        }
        if (HASA2) {
            const float4* a2p = reinterpret_cast<const float4*>(A2row + kt * 32);
#pragma unroll
            for (int i = 0; i < 4; ++i) {
                float4 v = a2p[i];
                av[4 * i + 0] += v.x; av[4 * i + 1] += v.y;
                av[4 * i + 2] += v.z; av[4 * i + 3] += v.w;
            }
        }
        bhv = *reinterpret_cast<const uint4*>(Whirow + kt * 32);
        blv = *reinterpret_cast<const uint4*>(Wlorow + kt * 32);
    };
    auto write_stage = [&](short* buf) {
        unsigned int hw[8], lw[8];
#pragma unroll
        for (int i = 0; i < 8; ++i) {
            u16 h0 = f2bf(av[2 * i]), h1 = f2bf(av[2 * i + 1]);
            u16 l0 = f2bf(av[2 * i] - bf2f(h0));
            u16 l1 = f2bf(av[2 * i + 1] - bf2f(h1));
            hw[i] = (unsigned int)h0 | ((unsigned int)h1 << 16);
            lw[i] = (unsigned int)l0 | ((unsigned int)l1 << 16);
        }
        char* Ahi = (char*)buf;
        char* Alo = (char*)(buf + 4096);
        *(uint4*)(Ahi + a_wb0) = make_uint4(hw[0], hw[1], hw[2], hw[3]);
        *(uint4*)(Ahi + a_wb1) = make_uint4(hw[4], hw[5], hw[6], hw[7]);
        *(uint4*)(Alo + a_wb0) = make_uint4(lw[0], lw[1], lw[2], lw[3]);
        *(uint4*)(Alo + a_wb1) = make_uint4(lw[4], lw[5], lw[6], lw[7]);
        *(uint4*)((char*)(buf + 8192)  + b_wb) = bhv;
        *(uint4*)((char*)(buf + 10240) + b_wb) = blv;
    };
    int l15 = lane & 15, l4 = lane >> 4;
    auto compute = [&](const short* buf) {
        const char* Ahi = (const char*)buf;
        const char* Alo = (const char*)(buf + 4096);
        const char* Bhi = (const char*)(buf + 8192);
        const char* Blo = (const char*)(buf + 10240);
        bf16x8 bh[2], bl[2];
#pragma unroll
        for (int nc = 0; nc < 2; ++nc) {
            int col = wc * 32 + nc * 16 + l15;
            int byt = col * 64 + ((l4 ^ ((col >> 1) & 3)) * 16);
            bh[nc] = *(const bf16x8*)(Bhi + byt);
            bl[nc] = *(const bf16x8*)(Blo + byt);
        }
#pragma unroll
        for (int mr = 0; mr < 4; ++mr) {
            int row = wr * 64 + mr * 16 + l15;
            int byt = row * 64 + ((l4 ^ ((row >> 1) & 3)) * 16);
            bf16x8 ah = *(const bf16x8*)(Ahi + byt);
            bf16x8 al = *(const bf16x8*)(Alo + byt);
#pragma unroll
            for (int nc = 0; nc < 2; ++nc) {
                acc[mr][nc] = __builtin_amdgcn_mfma_f32_16x16x32_bf16(ah, bh[nc], acc[mr][nc], 0, 0, 0);
                acc[mr][nc] = __builtin_amdgcn_mfma_f32_16x16x32_bf16(ah, bl[nc], acc[mr][nc], 0, 0, 0);
                acc[mr][nc] = __builtin_amdgcn_mfma_f32_16x16x32_bf16(al, bh[nc], acc[mr][nc], 0, 0, 0);
            }
        }
    };
    int nk = K >> 5;
    load_stage(0);
    write_stage(lds);
    __syncthreads();
    for (int kt = 0; kt < nk; ++kt) {
        short* cur = lds + (kt & 1) * 12288;
        short* nxt = lds + ((kt & 1) ^ 1) * 12288;
        if (kt + 1 < nk) load_stage(kt + 1);
        compute(cur);
        if (kt + 1 < nk) write_stage(nxt);
        __syncthreads();
    }
#pragma unroll
    for (int nc = 0; nc < 2; ++nc) {
        int col = col0 + wc * 32 + nc * 16 + l15;
        float bv = bias[col];
#pragma unroll
        for (int mr = 0; mr < 4; ++mr) {
            int row = row0 + wr * 64 + mr * 16 + l4 * 4;
#pragma unroll
            for (int r = 0; r < 4; ++r) {
                float v = acc[mr][nc][r] + bv;
                if (RELU) v = fmaxf(v, 0.f);
                C[(size_t)(row + r) * N + col] = v;
            }
        }
    }
}

// ---------------------------------------------------------------------------
// MSDA sampling (new): off+logits combined [M,384]; output bf16 hi/lo pair.
// One wave per query; 8 lanes/head; fused softmax.
// ---------------------------------------------------------------------------
__global__ __launch_bounds__(256) void msda2n(
    const float* __restrict__ value, const float* __restrict__ offlog,
    u16* __restrict__ eh, u16* __restrict__ el)
{
    const int lvl_off[4] = {0, 4096, 5120, 5376};
    const int lvl_hw[4]  = {64, 32, 16, 8};

    int m = blockIdx.x * 4 + (threadIdx.x >> 6);
    int lane = threadIdx.x & 63;
    int h = lane >> 3, c = (lane & 7) * 4;
    int b = m / QTOT, q = m - b * QTOT;

    int lq, rem;
    if      (q < 4096) { lq = 0; rem = q; }
    else if (q < 5120) { lq = 1; rem = q - 4096; }
    else if (q < 5376) { lq = 2; rem = q - 5120; }
    else               { lq = 3; rem = q - 5376; }
    int Wq = lvl_hw[lq];
    int yq = rem / Wq, xq = rem - yq * Wq;
    float ref_x = (xq + 0.5f) / (float)Wq;
    float ref_y = (yq + 0.5f) / (float)Wq;

    const float* lg = offlog + (size_t)m * 384 + 256 + h * 16;
    float w[16];
    {
        float mx = -1e30f;
#pragma unroll
        for (int i = 0; i < 4; ++i) {
            float4 v = reinterpret_cast<const float4*>(lg)[i];
            w[4 * i] = v.x; w[4 * i + 1] = v.y; w[4 * i + 2] = v.z; w[4 * i + 3] = v.w;
        }
#pragma unroll
        for (int j = 0; j < 16; ++j) mx = fmaxf(mx, w[j]);
        float s = 0.f;
#pragma unroll
        for (int j = 0; j < 16; ++j) { w[j] = __expf(w[j] - mx); s += w[j]; }
        float rs = 1.f / s;
#pragma unroll
        for (int j = 0; j < 16; ++j) w[j] *= rs;
    }

    float ofv[32];
    const float* op = offlog + (size_t)m * 384 + h * 32;
#pragma unroll
    for (int i = 0; i < 8; ++i) {
        float4 v = reinterpret_cast<const float4*>(op)[i];
        ofv[4 * i] = v.x; ofv[4 * i + 1] = v.y; ofv[4 * i + 2] = v.z; ofv[4 * i + 3] = v.w;
    }

    float a0 = 0.f, a1 = 0.f, a2 = 0.f, a3 = 0.f;
#pragma unroll
    for (int l = 0; l < 4; ++l) {
        int HW = lvl_hw[l];
        float fHW = (float)HW;
        const float* vbase =
            value + ((size_t)(b * QTOT + lvl_off[l])) * D_MODEL + h * 32 + c;
#pragma unroll
        for (int p = 0; p < 4; ++p) {
            float ox = ofv[(l * 4 + p) * 2 + 0];
            float oy = ofv[(l * 4 + p) * 2 + 1];
            float aw = w[l * 4 + p];
            float x = (ref_x + ox / fHW) * fHW - 0.5f;
            float y = (ref_y + oy / fHW) * fHW - 0.5f;
            float x0f = floorf(x), y0f = floorf(y);
            int   x0 = (int)x0f,  y0 = (int)y0f;
            float wx = x - x0f,   wy = y - y0f;
            float w00 = (1.f - wx) * (1.f - wy) * aw, w01 = wx * (1.f - wy) * aw;
            float w10 = (1.f - wx) * wy * aw,         w11 = wx * wy * aw;
            bool xv0 = (x0 >= 0) && (x0 < HW);
            bool xv1 = (x0 + 1 >= 0) && (x0 + 1 < HW);
            bool yv0 = (y0 >= 0) && (y0 < HW);
            bool yv1 = (y0 + 1 >= 0) && (y0 + 1 < HW);
#define GATH(cond, idx, wgt)                                                  \
            if (cond) {                                                       \
                float4 v = *reinterpret_cast<const float4*>(                  \
                    vbase + (size_t)(idx) * D_MODEL);                         \
                a0 += (wgt) * v.x; a1 += (wgt) * v.y;                         \
                a2 += (wgt) * v.z; a3 += (wgt) * v.w;                         \
            }
            GATH(xv0 && yv0, y0 * HW + x0,           w00)
            GATH(xv1 && yv0, y0 * HW + x0 + 1,       w01)
            GATH(xv0 && yv1, (y0 + 1) * HW + x0,     w10)
            GATH(xv1 && yv1, (y0 + 1) * HW + x0 + 1, w11)
#undef GATH
        }
    }
    size_t oidx = (size_t)m * D_MODEL + h * 32 + c;
    ushort4 hv, lv;
    hv.x = f2bf(a0); lv.x = f2bf(a0 - bf2f(hv.x));
    hv.y = f2bf(a1); lv.y = f2bf(a1 - bf2f(hv.y));
    hv.z = f2bf(a2); lv.z = f2bf(a2 - bf2f(hv.z));
    hv.w = f2bf(a3); lv.w = f2bf(a3 - bf2f(hv.w));
    *reinterpret_cast<ushort4*>(eh + oidx) = hv;
    *reinterpret_cast<ushort4*>(el + oidx) = lv;
}

// msda (old, fallback): separate off/logits, fp32 out
__global__ __launch_bounds__(256) void msda2(
    const float* __restrict__ value, const float* __restrict__ off,
    const float* __restrict__ logits, float* __restrict__ outp)
{
    const int lvl_off[4] = {0, 4096, 5120, 5376};
    const int lvl_hw[4]  = {64, 32, 16, 8};
    int m = blockIdx.x * 4 + (threadIdx.x >> 6);
    int lane = threadIdx.x & 63;
    int h = lane >> 3, c = (lane & 7) * 4;
    int b = m / QTOT, q = m - b * QTOT;
    int lq, rem;
    if      (q < 4096) { lq = 0; rem = q; }
    else if (q < 5120) { lq = 1; rem = q - 4096; }
    else if (q < 5376) { lq = 2; rem = q - 5120; }
    else               { lq = 3; rem = q - 5376; }
    int Wq = lvl_hw[lq];
    int yq = rem / Wq, xq = rem - yq * Wq;
    float ref_x = (xq + 0.5f) / (float)Wq;
    float ref_y = (yq + 0.5f) / (float)Wq;
    const float* lg = logits + (size_t)m * 128 + h * 16;
    float w[16];
    {
        float mx = -1e30f;
#pragma unroll
        for (int i = 0; i < 4; ++i) {
            float4 v = reinterpret_cast<const float4*>(lg)[i];
            w[4 * i] = v.x; w[4 * i + 1] = v.y; w[4 * i + 2] = v.z; w[4 * i + 3] = v.w;
        }
#pragma unroll
        for (int j = 0; j < 16; ++j) mx = fmaxf(mx, w[j]);
        float s = 0.f;
#pragma unroll
        for (int j = 0; j < 16; ++j) { w[j] = __expf(w[j] - mx); s += w[j]; }
        float rs = 1.f / s;
#pragma unroll
        for (int j = 0; j < 16; ++j) w[j] *= rs;
    }
    float ofv[32];
    const float* op = off + (size_t)m * 256 + h * 32;
#pragma unroll
    for (int i = 0; i < 8; ++i) {
        float4 v = reinterpret_cast<const float4*>(op)[i];
        ofv[4 * i] = v.x; ofv[4 * i + 1] = v.y; ofv[4 * i + 2] = v.z; ofv[4 * i + 3] = v.w;
    }
    float a0 = 0.f, a1 = 0.f, a2 = 0.f, a3 = 0.f;
#pragma unroll
    for (int l = 0; l < 4; ++l) {
        int HW = lvl_hw[l];
        float fHW = (float)HW;
        const float* vbase =
            value + ((size_t)(b * QTOT + lvl_off[l])) * D_MODEL + h * 32 + c;
#pragma unroll
        for (int p = 0; p < 4; ++p) {
            float ox = ofv[(l * 4 + p) * 2 + 0];
            float oy = ofv[(l * 4 + p) * 2 + 1];
            float aw = w[l * 4 + p];
            float x = (ref_x + ox / fHW) * fHW - 0.5f;
            float y = (ref_y + oy / fHW) * fHW - 0.5f;
            float x0f = floorf(x), y0f = floorf(y);
            int   x0 = (int)x0f,  y0 = (int)y0f;
            float wx = x - x0f,   wy = y - y0f;
            float w00 = (1.f - wx) * (1.f - wy) * aw, w01 = wx * (1.f - wy) * aw;
            float w10 = (1.f - wx) * wy * aw,         w11 = wx * wy * aw;
            bool xv0 = (x0 >= 0) && (x0 < HW);
            bool xv1 = (x0 + 1 >= 0) && (x0 + 1 < HW);
            bool yv0 = (y0 >= 0) && (y0 < HW);
            bool yv1 = (y0 + 1 >= 0) && (y0 + 1 < HW);
#define GATH(cond, idx, wgt)                                                  \
            if (cond) {                                                       \
                float4 v = *reinterpret_cast<const float4*>(                  \
                    vbase + (size_t)(idx) * D_MODEL);                         \
                a0 += (wgt) * v.x; a1 += (wgt) * v.y;                         \
                a2 += (wgt) * v.z; a3 += (wgt) * v.w;                         \
            }
            GATH(xv0 && yv0, y0 * HW + x0,           w00)
            GATH(xv1 && yv0, y0 * HW + x0 + 1,       w01)
            GATH(xv0 && yv1, (y0 + 1) * HW + x0,     w10)
            GATH(xv1 && yv1, (y0 + 1) * HW + x0 + 1, w11)
#undef GATH
        }
    }
    float4 o = make_float4(a0, a1, a2, a3);
    *reinterpret_cast<float4*>(&outp[(size_t)m * D_MODEL + h * 32 + c]) = o;
}

// ---------------------------------------------------------------------------
// add+LN on pair-stored residual: y = LN((oh+ol) + t)*g + beta -> oh/ol.
// WRITEQ: also q = y + posf -> qh/ql.  WRITEF32: y -> f32out.
// ---------------------------------------------------------------------------
template<int WRITEQ, int WRITEF32>
__global__ __launch_bounds__(64) void add_ln_pair(
    const float* __restrict__ t, const float* __restrict__ g,
    const float* __restrict__ beta,
    u16* __restrict__ oh, u16* __restrict__ ol,
    const float* __restrict__ posf, u16* __restrict__ qh, u16* __restrict__ ql,
    float* __restrict__ f32out)
{
    int row = blockIdx.x;
    int lane = threadIdx.x;
    size_t base = (size_t)row * D_MODEL + lane * 4;
    ushort4 hv = *reinterpret_cast<const ushort4*>(oh + base);
    ushort4 lv = *reinterpret_cast<const ushort4*>(ol + base);
    float4 tv = *reinterpret_cast<const float4*>(t + base);
    float v0 = bf2f(hv.x) + bf2f(lv.x) + tv.x;
    float v1 = bf2f(hv.y) + bf2f(lv.y) + tv.y;
    float v2 = bf2f(hv.z) + bf2f(lv.z) + tv.z;
    float v3 = bf2f(hv.w) + bf2f(lv.w) + tv.w;
    float s = v0 + v1 + v2 + v3;
#pragma unroll
    for (int o = 32; o > 0; o >>= 1) s += __shfl_xor(s, o);
    float mean = s * (1.f / D_MODEL);
    float d0 = v0 - mean, d1 = v1 - mean, d2 = v2 - mean, d3 = v3 - mean;
    float ss = d0 * d0 + d1 * d1 + d2 * d2 + d3 * d3;
#pragma unroll
    for (int o = 32; o > 0; o >>= 1) ss += __shfl_xor(ss, o);
    float rstd = rsqrtf(ss * (1.f / D_MODEL) + 1e-5f);
    float4 gv = *reinterpret_cast<const float4*>(&g[lane * 4]);
    float4 bv = *reinterpret_cast<const float4*>(&beta[lane * 4]);
    float y0 = d0 * rstd * gv.x + bv.x;
    float y1 = d1 * rstd * gv.y + bv.y;
    float y2 = d2 * rstd * gv.z + bv.z;
    float y3 = d3 * rstd * gv.w + bv.w;
    ushort4 nh, nl;
    nh.x = f2bf(y0); nl.x = f2bf(y0 - bf2f(nh.x));
    nh.y = f2bf(y1); nl.y = f2bf(y1 - bf2f(nh.y));
    nh.z = f2bf(y2); nl.z = f2bf(y2 - bf2f(nh.z));
    nh.w = f2bf(y3); nl.w = f2bf(y3 - bf2f(nh.w));
    *reinterpret_cast<ushort4*>(oh + base) = nh;
    *reinterpret_cast<ushort4*>(ol + base) = nl;
    if (WRITEQ) {
        float4 pv = *reinterpret_cast<const float4*>(posf + base);
        float q0 = y0 + pv.x, q1 = y1 + pv.y, q2 = y2 + pv.z, q3 = y3 + pv.w;
        ushort4 qhv, qlv;
        qhv.x = f2bf(q0); qlv.x = f2bf(q0 - bf2f(qhv.x));
        qhv.y = f2bf(q1); qlv.y = f2bf(q1 - bf2f(qhv.y));
        qhv.z = f2bf(q2); qlv.z = f2bf(q2 - bf2f(qhv.z));
        qhv.w = f2bf(q3); qlv.w = f2bf(q3 - bf2f(qhv.w));
        *reinterpret_cast<ushort4*>(qh + base) = qhv;
        *reinterpret_cast<ushort4*>(ql + base) = qlv;
    }
    if (WRITEF32) {
        *reinterpret_cast<float4*>(f32out + base) = make_float4(y0, y1, y2, y3);
    }
}

// old add_ln (fallback): in-place fp32
__global__ __launch_bounds__(64) void add_ln(
    const float* __restrict__ t, const float* __restrict__ g,
    const float* __restrict__ beta, float* __restrict__ x)
{
    int row = blockIdx.x;
    int lane = threadIdx.x;
    size_t base = (size_t)row * D_MODEL + lane * 4;
    float4 xv = *reinterpret_cast<const float4*>(&x[base]);
    float4 tv = *reinterpret_cast<const float4*>(&t[base]);
    float v0 = xv.x + tv.x, v1 = xv.y + tv.y, v2 = xv.z + tv.z, v3 = xv.w + tv.w;
    float s = v0 + v1 + v2 + v3;
#pragma unroll
    for (int o = 32; o > 0; o >>= 1) s += __shfl_xor(s, o);
    float mean = s * (1.f / D_MODEL);
    float d0 = v0 - mean, d1 = v1 - mean, d2 = v2 - mean, d3 = v3 - mean;
    float ss = d0 * d0 + d1 * d1 + d2 * d2 + d3 * d3;
#pragma unroll
    for (int o = 32; o > 0; o >>= 1) ss += __shfl_xor(ss, o);
    float rstd = rsqrtf(ss * (1.f / D_MODEL) + 1e-5f);
    float4 gv = *reinterpret_cast<const float4*>(&g[lane * 4]);
    float4 bv = *reinterpret_cast<const float4*>(&beta[lane * 4]);
    float4 ov = make_float4(d0 * rstd * gv.x + bv.x, d1 * rstd * gv.y + bv.y,
                            d2 * rstd * gv.z + bv.z, d3 * rstd * gv.w + bv.w);
    *reinterpret_cast<float4*>(&x[base]) = ov;
}

// ---------------------------------------------------------------------------
extern "C" void kernel_launch(void* const* d_in, const int* in_sizes, int n_in,
                              void* d_out, int out_size, void* d_ws, size_t ws_size,
                              hipStream_t stream)
{
    // dict order is INTERLEAVED: src0,pos0,src1,pos1,...
    const float* src[4] = {(const float*)d_in[0], (const float*)d_in[2],
                           (const float*)d_in[4], (const float*)d_in[6]};
    const float* pos[4] = {(const float*)d_in[1], (const float*)d_in[3],
                           (const float*)d_in[5], (const float*)d_in[7]};
    const float* lvl   = (const float*)d_in[8];
    const float* W_off = (const float*)d_in[9];
    const float* b_off = (const float*)d_in[10];
    const float* W_att = (const float*)d_in[11];
    const float* b_att = (const float*)d_in[12];
    const float* W_val = (const float*)d_in[13];
    const float* b_val = (const float*)d_in[14];
    const float* W_out = (const float*)d_in[15];
    const float* b_out = (const float*)d_in[16];
    const float* ln1g  = (const float*)d_in[17];
    const float* ln1b  = (const float*)d_in[18];
    const float* W_ff1 = (const float*)d_in[19];
    const float* b_ff1 = (const float*)d_in[20];
    const float* W_ff2 = (const float*)d_in[21];
    const float* b_ff2 = (const float*)d_in[22];
    const float* ln2g  = (const float*)d_in[23];
    const float* ln2b  = (const float*)d_in[24];

    float* ws = (float*)d_ws;
    const size_t MD = (size_t)MTOT * D_MODEL;    // 5,570,560

    const int hws[4]  = {4096, 1024, 256, 64};
    const int qoff[4] = {0, 4096, 5120, 5376};

    // ---- NEW path layout ----
    float* posf = ws;                                    // fp32 [M,256]
    u16* oh = (u16*)(ws + MD);
    u16* ol = oh + MD;
    u16* qh = ol + MD;                                   // Q region (q|e)
    u16* ql = qh + MD;
    u16* eh = qh; u16* el = ql;
    float* val    = (float*)(ql + MD);                   // fp32 [M,256]; ffout
    float* ffout  = val;
    float* offlog = val + MD;                            // fp32 [M,384]; tmp/hid
    float* tmp    = offlog;
    u16* hid_h = (u16*)offlog;
    u16* hid_l = hid_h + (size_t)63 * 128 * 1024;
    u16* wb = (u16*)(offlog + (size_t)MTOT * 384);
    size_t o = 0;
    u16* wv_h = wb + o; o += 6 * 65536;  u16* wv_l = wb + o; o += 6 * 65536;
    u16* wc_h = wb + o; o += 6 * 98304;  u16* wc_l = wb + o; o += 6 * 98304;
    u16* wu_h = wb + o; o += 6 * 65536;  u16* wu_l = wb + o; o += 6 * 65536;
    u16* wf1_h = wb + o; o += 6 * 262144; u16* wf1_l = wb + o; o += 6 * 262144;
    u16* wf2_h = wb + o; o += 6 * 262144; u16* wf2_l = wb + o; o += 6 * 262144;
    const size_t NEED = (size_t)((char*)(wb + o) - (char*)ws);   // ~140.6 MB

    if (ws_size >= NEED) {
        dim3 cb(32, 8);
        for (int l = 0; l < 4; ++l) {
            dim3 g(hws[l] / 32, D_MODEL / 32, BATCH);
            flatten_tr<<<g, cb, 0, stream>>>(pos[l], lvl + l * D_MODEL, posf, hws[l], qoff[l]);
            flatten_src_pair<<<g, cb, 0, stream>>>(src[l], posf, oh, ol, qh, ql, hws[l], qoff[l]);
        }
        wconv<<<dim3(8, 8, 6),  cb, 0, stream>>>(W_val, wv_h, wv_l, 256, 256, 65536);
        wconv<<<dim3(8, 8, 6),  cb, 0, stream>>>(W_off, wc_h, wc_l, 256, 256, 98304);
        wconv<<<dim3(4, 8, 6),  cb, 0, stream>>>(W_att, wc_h + 65536, wc_l + 65536, 256, 128, 98304);
        wconv<<<dim3(8, 8, 6),  cb, 0, stream>>>(W_out, wu_h, wu_l, 256, 256, 65536);
        wconv<<<dim3(32, 8, 6), cb, 0, stream>>>(W_ff1, wf1_h, wf1_l, 256, 1024, 262144);
        wconv<<<dim3(8, 32, 6), cb, 0, stream>>>(W_ff2, wf2_h, wf2_l, 1024, 256, 262144);

        for (int i = 0; i < NLAYER; ++i) {
            gemm_pre<0><<<dim3(4, 170), 256, 0, stream>>>(
                oh, ol, wv_h + i * 65536, wv_l + i * 65536,
                b_val + i * 256, b_val + i * 256, 256, val, nullptr, nullptr, 256, 256);
            gemm_pre<0><<<dim3(6, 170), 256, 0, stream>>>(
                qh, ql, wc_h + i * 98304, wc_l + i * 98304,
                b_off + i * 256, b_att + i * 128, 256, offlog, nullptr, nullptr, 384, 256);
            msda2n<<<MTOT / 4, 256, 0, stream>>>(val, offlog, eh, el);
            gemm_pre<0><<<dim3(4, 170), 256, 0, stream>>>(
                eh, el, wu_h + i * 65536, wu_l + i * 65536,
                b_out + i * 256, b_out + i * 256, 256, tmp, nullptr, nullptr, 256, 256);
            add_ln_pair<0, 0><<<MTOT, 64, 0, stream>>>(
                tmp, ln1g + i * 256, ln1b + i * 256, oh, ol,
                nullptr, nullptr, nullptr, nullptr);
            const int nbs[3] = {63, 63, 44};
            int rb = 0;
            for (int c = 0; c < 3; ++c) {
                size_t r0 = (size_t)rb * 128 * 256;
                gemm_pre<1><<<dim3(16, nbs[c]), 256, 0, stream>>>(
                    oh + r0, ol + r0, wf1_h + i * 262144, wf1_l + i * 262144,
                    b_ff1 + i * 1024, b_ff1 + i * 1024, 1024,
                    nullptr, hid_h, hid_l, 1024, 256);
                gemm_pre<0><<<dim3(4, nbs[c]), 256, 0, stream>>>(
                    hid_h, hid_l, wf2_h + i * 262144, wf2_l + i * 262144,
                    b_ff2 + i * 256, b_ff2 + i * 256, 256,
                    ffout + r0, nullptr, nullptr, 256, 1024);
                rb += nbs[c];
            }
            if (i < NLAYER - 1)
                add_ln_pair<1, 0><<<MTOT, 64, 0, stream>>>(
                    ffout, ln2g + i * 256, ln2b + i * 256, oh, ol,
                    posf, qh, ql, nullptr);
            else
                add_ln_pair<0, 1><<<MTOT, 64, 0, stream>>>(
                    ffout, ln2g + i * 256, ln2b + i * 256, oh, ol,
                    nullptr, nullptr, nullptr, (float*)d_out);
        }
    } else {
        // ---- FALLBACK: round-3 proven path (~118.4 MB) ----
        float* out = (float*)d_out;
        float* posf2  = ws;
        float* val2   = posf2 + MD;
        float* logits = val2 + MD;
        float* offb   = logits + (size_t)MTOT * 128;
        float* ebuf   = offb + MD;
        float* tmp2   = offb;
        float* hid2   = offb;
        short* wbase = (short*)(ebuf + MD);
        short* v_h = wbase;               short* v_l = v_h + 6 * 65536;
        short* o_h = v_l + 6 * 65536;     short* o_l = o_h + 6 * 65536;
        short* a_h = o_l + 6 * 65536;     short* a_l = a_h + 6 * 32768;
        short* u_h = a_l + 6 * 32768;     short* u_l = u_h + 6 * 65536;
        short* f1h = u_l + 6 * 65536;     short* f1l = f1h + 6 * 262144;
        short* f2h = f1l + 6 * 262144;    short* f2l = f2h + 6 * 262144;
        dim3 cb(32, 8);
        for (int l = 0; l < 4; ++l) {
            dim3 g(hws[l] / 32, D_MODEL / 32, BATCH);
            flatten_tr<<<g, cb, 0, stream>>>(src[l], nullptr, out, hws[l], qoff[l]);
            flatten_tr<<<g, cb, 0, stream>>>(pos[l], lvl + l * D_MODEL, posf2, hws[l], qoff[l]);
        }
        wconv<<<dim3(8, 8, 6),  cb, 0, stream>>>(W_val, (u16*)v_h, (u16*)v_l, 256, 256, 65536);
        wconv<<<dim3(8, 8, 6),  cb, 0, stream>>>(W_off, (u16*)o_h, (u16*)o_l, 256, 256, 65536);
        wconv<<<dim3(4, 8, 6),  cb, 0, stream>>>(W_att, (u16*)a_h, (u16*)a_l, 256, 128, 32768);
        wconv<<<dim3(8, 8, 6),  cb, 0, stream>>>(W_out, (u16*)u_h, (u16*)u_l, 256, 256, 65536);
        wconv<<<dim3(32, 8, 6), cb, 0, stream>>>(W_ff1, (u16*)f1h, (u16*)f1l, 256, 1024, 262144);
        wconv<<<dim3(8, 32, 6), cb, 0, stream>>>(W_ff2, (u16*)f2h, (u16*)f2l, 1024, 256, 262144);
        for (int i = 0; i < NLAYER; ++i) {
            gemm_mfma<0,0><<<dim3(4, 170), 256, 0, stream>>>(
                out, nullptr, v_h + i * 65536, v_l + i * 65536,
                b_val + i * 256, val2, 256, 256);
            gemm_mfma<0,1><<<dim3(4, 170), 256, 0, stream>>>(
                out, posf2, o_h + i * 65536, o_l + i * 65536,
                b_off + i * 256, offb, 256, 256);
            gemm_mfma<0,1><<<dim3(2, 170), 256, 0, stream>>>(
                out, posf2, a_h + i * 32768, a_l + i * 32768,
                b_att + i * 128, logits, 128, 256);
            msda2<<<MTOT / 4, 256, 0, stream>>>(val2, offb, logits, ebuf);
            gemm_mfma<0,0><<<dim3(4, 170), 256, 0, stream>>>(
                ebuf, nullptr, u_h + i * 65536, u_l + i * 65536,
                b_out + i * 256, tmp2, 256, 256);
            add_ln<<<MTOT, 64, 0, stream>>>(tmp2, ln1g + i * 256, ln1b + i * 256, out);
            for (int h = 0; h < 2; ++h) {
                gemm_mfma<1,0><<<dim3(16, 85), 256, 0, stream>>>(
                    out + (size_t)h * MHALF * 256, nullptr,
                    f1h + i * 262144, f1l + i * 262144,
                    b_ff1 + i * 1024, hid2, 1024, 256);
                gemm_mfma<0,0><<<dim3(4, 85), 256, 0, stream>>>(
                    hid2, nullptr, f2h + i * 262144, f2l + i * 262144,
                    b_ff2 + i * 256, val2 + (size_t)h * MHALF * 256, 256, 1024);
            }
            add_ln<<<MTOT, 64, 0, stream>>>(val2, ln2g + i * 256, ln2b + i * 256, out);
        }
    }
    (void)in_sizes; (void)n_in; (void)out_size;
}

// Round 5
// 1845.727 us; speedup vs baseline: 2.7947x; 1.1293x over previous
//
#include <hip/hip_runtime.h>
#include <cstddef>
#include <cstdint>

#define D_MODEL 256
#define NHEAD   8
#define NLAYER  6
#define BATCH   4
#define QTOT    5440
#define MTOT    (BATCH*QTOT)   // 21760 = 170*128
#define MHALF   (MTOT/2)
#define DFFN    1024

typedef short  bf16x8 __attribute__((ext_vector_type(8)));
typedef float  f32x4  __attribute__((ext_vector_type(4)));
typedef unsigned short u16;

__device__ __forceinline__ u16 f2bf(float f) {
    uint32_t u = __float_as_uint(f);
    return (u16)((u + 0x7fffu + ((u >> 16) & 1u)) >> 16);
}
__device__ __forceinline__ float bf2f(u16 s) {
    return __uint_as_float(((uint32_t)s) << 16);
}

// ---------------------------------------------------------------------------
// Flatten + transpose (fp32): src [B,D,HW] -> dst [B,Q,D], optional emb add.
// ---------------------------------------------------------------------------
__global__ __launch_bounds__(256) void flatten_tr(
    const float* __restrict__ src, const float* __restrict__ emb,
    float* __restrict__ dst, int HW, int qoff)
{
    __shared__ float tile[32][33];
    int tx = threadIdx.x, ty = threadIdx.y;
    int hw0 = blockIdx.x * 32, d0 = blockIdx.y * 32, b = blockIdx.z;
    const float* s = src + (size_t)b * D_MODEL * HW;
#pragma unroll
    for (int j = 0; j < 4; ++j)
        tile[ty + j * 8][tx] = s[(size_t)(d0 + ty + j * 8) * HW + hw0 + tx];
    __syncthreads();
#pragma unroll
    for (int j = 0; j < 4; ++j) {
        int hw = ty + j * 8;
        float v = tile[tx][hw];
        if (emb) v += emb[d0 + tx];
        dst[((size_t)b * QTOT + qoff + hw0 + hw) * D_MODEL + d0 + tx] = v;
    }
}

// ---------------------------------------------------------------------------
// Flatten src -> out bf16 pair + q=(src+posf) bf16 pair.
// ---------------------------------------------------------------------------
__global__ __launch_bounds__(256) void flatten_src_pair(
    const float* __restrict__ src, const float* __restrict__ posf,
    u16* __restrict__ oh, u16* __restrict__ ol,
    u16* __restrict__ qh, u16* __restrict__ ql, int HW, int qoff)
{
    __shared__ float tile[32][33];
    int tx = threadIdx.x, ty = threadIdx.y;
    int hw0 = blockIdx.x * 32, d0 = blockIdx.y * 32, b = blockIdx.z;
    const float* s = src + (size_t)b * D_MODEL * HW;
#pragma unroll
    for (int j = 0; j < 4; ++j)
        tile[ty + j * 8][tx] = s[(size_t)(d0 + ty + j * 8) * HW + hw0 + tx];
    __syncthreads();
#pragma unroll
    for (int j = 0; j < 4; ++j) {
        int hw = ty + j * 8;
        float v = tile[tx][hw];
        size_t idx = ((size_t)b * QTOT + qoff + hw0 + hw) * D_MODEL + d0 + tx;
        u16 h = f2bf(v);
        oh[idx] = h; ol[idx] = f2bf(v - bf2f(h));
        float q = v + posf[idx];
        u16 qhv = f2bf(q);
        qh[idx] = qhv; ql[idx] = f2bf(q - bf2f(qhv));
    }
}

// ---------------------------------------------------------------------------
// Weight convert+transpose: W fp32 [L][K][N] -> hi/lo bf16 [L(lstride)][N][K]
// ---------------------------------------------------------------------------
__global__ __launch_bounds__(256) void wconv(
    const float* __restrict__ W, u16* __restrict__ Whi,
    u16* __restrict__ Wlo, int K, int N, int lstride)
{
    __shared__ float t[32][33];
    int tx = threadIdx.x, ty = threadIdx.y;
    int n0 = blockIdx.x * 32, k0 = blockIdx.y * 32, l = blockIdx.z;
    const float* Wl = W + (size_t)l * K * N;
    u16* Hl = Whi + (size_t)l * lstride;
    u16* Ll = Wlo + (size_t)l * lstride;
#pragma unroll
    for (int j = 0; j < 4; ++j)
        t[ty + j * 8][tx] = Wl[(size_t)(k0 + ty + j * 8) * N + n0 + tx];
    __syncthreads();
#pragma unroll
    for (int j = 0; j < 4; ++j) {
        float v = t[tx][ty + j * 8];
        int n = n0 + ty + j * 8, k = k0 + tx;
        u16 h = f2bf(v);
        Hl[(size_t)n * K + k] = h;
        Ll[(size_t)n * K + k] = f2bf(v - bf2f(h));
    }
}

// ---------------------------------------------------------------------------
// MFMA GEMM, pre-split bf16 A and B, BM=128 BN=128 BK=32.
// 256 thr = 4 waves (2x2); each wave computes 64x64 (acc[4][4]).
// Per K-step per wave: 48 MFMA vs 16 ds_read_b128 (3:1 density).
// CMODE 0: fp32 C.  CMODE 1: bf16 hi/lo pair C with ReLU.
// ---------------------------------------------------------------------------
template<int CMODE>
__global__ __launch_bounds__(256) void gemm_pre(
    const u16* __restrict__ Ah, const u16* __restrict__ Al,
    const u16* __restrict__ Bh, const u16* __restrict__ Bl,
    const float* __restrict__ bias, const float* __restrict__ bias2, int nsplit,
    float* __restrict__ Cf, u16* __restrict__ Ch, u16* __restrict__ Cl,
    int N, int K)
{
    // per buffer (bytes): Ahi 8192 | Alo 8192 | Bhi 8192 | Blo 8192 = 32 KB
    __shared__ __align__(16) short lds[2 * 16384];   // 64 KB

    int tid  = threadIdx.x;
    int lane = tid & 63, wid = tid >> 6;
    int wr = wid >> 1, wc = wid & 1;
    int row0 = blockIdx.y * 128, col0 = blockIdx.x * 128;

    // staging: thread -> (row 0..127, half 0..1); 32 B hi + 32 B lo each of A,B
    int srow = tid >> 1, shalf = tid & 1;
    const u16* Ahr = Ah + (size_t)(row0 + srow) * K + shalf * 16;
    const u16* Alr = Al + (size_t)(row0 + srow) * K + shalf * 16;
    const u16* Bhr = Bh + (size_t)(col0 + srow) * K + shalf * 16;
    const u16* Blr = Bl + (size_t)(col0 + srow) * K + shalf * 16;
    int swz = (srow >> 1) & 3;
    int wb0 = srow * 64 + ((2 * shalf + 0) ^ swz) * 16;
    int wb1 = srow * 64 + ((2 * shalf + 1) ^ swz) * 16;

    f32x4 acc[4][4];
#pragma unroll
    for (int i = 0; i < 4; ++i)
#pragma unroll
        for (int j = 0; j < 4; ++j) acc[i][j] = (f32x4){0.f, 0.f, 0.f, 0.f};

    uint4 rah0, rah1, ral0, ral1, rbh0, rbh1, rbl0, rbl1;
    auto load_stage = [&](int kt) {
        const u16* a = Ahr + kt * 32;
        rah0 = *reinterpret_cast<const uint4*>(a);
        rah1 = *reinterpret_cast<const uint4*>(a + 8);
        const u16* a2 = Alr + kt * 32;
        ral0 = *reinterpret_cast<const uint4*>(a2);
        ral1 = *reinterpret_cast<const uint4*>(a2 + 8);
        const u16* b = Bhr + kt * 32;
        rbh0 = *reinterpret_cast<const uint4*>(b);
        rbh1 = *reinterpret_cast<const uint4*>(b + 8);
        const u16* b2 = Blr + kt * 32;
        rbl0 = *reinterpret_cast<const uint4*>(b2);
        rbl1 = *reinterpret_cast<const uint4*>(b2 + 8);
    };
    auto write_stage = [&](short* buf) {
        char* Ahi = (char*)buf;
        char* Alo = (char*)(buf + 4096);
        char* Bhi = (char*)(buf + 8192);
        char* Blo = (char*)(buf + 12288);
        *(uint4*)(Ahi + wb0) = rah0;  *(uint4*)(Ahi + wb1) = rah1;
        *(uint4*)(Alo + wb0) = ral0;  *(uint4*)(Alo + wb1) = ral1;
        *(uint4*)(Bhi + wb0) = rbh0;  *(uint4*)(Bhi + wb1) = rbh1;
        *(uint4*)(Blo + wb0) = rbl0;  *(uint4*)(Blo + wb1) = rbl1;
    };

    int l15 = lane & 15, l4 = lane >> 4;
    auto compute = [&](const short* buf) {
        const char* Ahi = (const char*)buf;
        const char* Alo = (const char*)(buf + 4096);
        const char* Bhi = (const char*)(buf + 8192);
        const char* Blo = (const char*)(buf + 12288);
        bf16x8 bh[4], bl[4];
#pragma unroll
        for (int nc = 0; nc < 4; ++nc) {
            int col = wc * 64 + nc * 16 + l15;
            int byt = col * 64 + ((l4 ^ ((col >> 1) & 3)) * 16);
            bh[nc] = *(const bf16x8*)(Bhi + byt);
            bl[nc] = *(const bf16x8*)(Blo + byt);
        }
#pragma unroll
        for (int mr = 0; mr < 4; ++mr) {
            int row = wr * 64 + mr * 16 + l15;
            int byt = row * 64 + ((l4 ^ ((row >> 1) & 3)) * 16);
            bf16x8 ah = *(const bf16x8*)(Ahi + byt);
            bf16x8 al = *(const bf16x8*)(Alo + byt);
#pragma unroll
            for (int nc = 0; nc < 4; ++nc) {
                acc[mr][nc] = __builtin_amdgcn_mfma_f32_16x16x32_bf16(ah, bh[nc], acc[mr][nc], 0, 0, 0);
                acc[mr][nc] = __builtin_amdgcn_mfma_f32_16x16x32_bf16(ah, bl[nc], acc[mr][nc], 0, 0, 0);
                acc[mr][nc] = __builtin_amdgcn_mfma_f32_16x16x32_bf16(al, bh[nc], acc[mr][nc], 0, 0, 0);
            }
        }
    };

    int nk = K >> 5;
    load_stage(0);
    write_stage(lds);
    __syncthreads();
    for (int kt = 0; kt < nk; ++kt) {
        short* cur = lds + (kt & 1) * 16384;
        short* nxt = lds + ((kt & 1) ^ 1) * 16384;
        if (kt + 1 < nk) load_stage(kt + 1);
        compute(cur);
        if (kt + 1 < nk) write_stage(nxt);
        __syncthreads();
    }

#pragma unroll
    for (int nc = 0; nc < 4; ++nc) {
        int col = col0 + wc * 64 + nc * 16 + l15;
        float bv = (col < nsplit) ? bias[col] : bias2[col - nsplit];
#pragma unroll
        for (int mr = 0; mr < 4; ++mr) {
            int row = row0 + wr * 64 + mr * 16 + l4 * 4;
#pragma unroll
            for (int r = 0; r < 4; ++r) {
                float v = acc[mr][nc][r] + bv;
                size_t idx = (size_t)(row + r) * N + col;
                if (CMODE == 0) {
                    Cf[idx] = v;
                } else {
                    v = fmaxf(v, 0.f);
                    u16 h = f2bf(v);
                    Ch[idx] = h;
                    Cl[idx] = f2bf(v - bf2f(h));
                }
            }
        }
    }
}

// ---------------------------------------------------------------------------
// OLD MFMA GEMM (fallback path, in-kernel fp32->bf16 split staging)
// ---------------------------------------------------------------------------
template<int RELU, int HASA2>
__global__ __launch_bounds__(256) void gemm_mfma(
    const float* __restrict__ A, const float* __restrict__ A2,
    const short* __restrict__ Whi, const short* __restrict__ Wlo,
    const float* __restrict__ bias, float* __restrict__ C, int N, int K)
{
    __shared__ __align__(16) short lds[2 * 12288];
    int tid  = threadIdx.x;
    int lane = tid & 63, wid = tid >> 6;
    int wr = wid >> 1, wc = wid & 1;
    int row0 = blockIdx.y * 128, col0 = blockIdx.x * 64;
    int srow = tid >> 1, shalf = tid & 1;
    int brow = tid >> 2, bseg = tid & 3;
    const float* Arow  = A + (size_t)(row0 + srow) * K + shalf * 16;
    const float* A2row = HASA2 ? A2 + (size_t)(row0 + srow) * K + shalf * 16 : nullptr;
    const short* Whirow = Whi + (size_t)(col0 + brow) * K + bseg * 8;
    const short* Wlorow = Wlo + (size_t)(col0 + brow) * K + bseg * 8;
    int aswz = (srow >> 1) & 3;
    int a_wb0 = srow * 64 + ((2 * shalf + 0) ^ aswz) * 16;
    int a_wb1 = srow * 64 + ((2 * shalf + 1) ^ aswz) * 16;
    int b_wb  = brow * 64 + ((bseg ^ ((brow >> 1) & 3)) * 16);
    f32x4 acc[4][2];
#pragma unroll
    for (int i = 0; i < 4; ++i)
#pragma unroll
        for (int j = 0; j < 2; ++j) acc[i][j] = (f32x4){0.f, 0.f, 0.f, 0.f};
    float av[16];
    uint4 bhv, blv;
    auto load_stage = [&](int kt) {
        const float4* ap = reinterpret_cast<const float4*>(Arow + kt * 32);
#pragma unroll
        for (int i = 0; i < 4; ++i) {
            float4 v = ap[i];
            av[4 * i + 0] = v.x; av[4 * i + 1] = v.y;
            av[4 * i + 2] = v.z; av[4 * i + 3] = v.w;
        }
        if (HASA2) {
            const float4* a2p = reinterpret_cast<const float4*>(A2row + kt * 32);
#pragma unroll
            for (int i = 0; i < 4; ++i) {
                float4 v = a2p[i];
                av[4 * i + 0] += v.x; av[4 * i + 1] += v.y;
                av[4 * i + 2] += v.z; av[4 * i + 3] += v.w;
            }
        }
        bhv = *reinterpret_cast<const uint4*>(Whirow + kt * 32);
        blv = *reinterpret_cast<const uint4*>(Wlorow + kt * 32);
    };
    auto write_stage = [&](short* buf) {
        unsigned int hw[8], lw[8];
#pragma unroll
        for (int i = 0; i < 8; ++i) {
            u16 h0 = f2bf(av[2 * i]), h1 = f2bf(av[2 * i + 1]);
            u16 l0 = f2bf(av[2 * i] - bf2f(h0));
            u16 l1 = f2bf(av[2 * i + 1] - bf2f(h1));
            hw[i] = (unsigned int)h0 | ((unsigned int)h1 << 16);
            lw[i] = (unsigned int)l0 | ((unsigned int)l1 << 16);
        }
        char* Ahi = (char*)buf;
        char* Alo = (char*)(buf + 4096);
        *(uint4*)(Ahi + a_wb0) = make_uint4(hw[0], hw[1], hw[2], hw[3]);
        *(uint4*)(Ahi + a_wb1) = make_uint4(hw[4], hw[5], hw[6], hw[7]);
        *(uint4*)(Alo + a_wb0) = make_uint4(lw[0], lw[1], lw[2], lw[3]);
        *(uint4*)(Alo + a_wb1) = make_uint4(lw[4], lw[5], lw[6], lw[7]);
        *(uint4*)((char*)(buf + 8192)  + b_wb) = bhv;
        *(uint4*)((char*)(buf + 10240) + b_wb) = blv;
    };
    int l15 = lane & 15, l4 = lane >> 4;
    auto compute = [&](const short* buf) {
        const char* Ahi = (const char*)buf;
        const char* Alo = (const char*)(buf + 4096);
        const char* Bhi = (const char*)(buf + 8192);
        const char* Blo = (const char*)(buf + 10240);
        bf16x8 bh[2], bl[2];
#pragma unroll
        for (int nc = 0; nc < 2; ++nc) {
            int col = wc * 32 + nc * 16 + l15;
            int byt = col * 64 + ((l4 ^ ((col >> 1) & 3)) * 16);
            bh[nc] = *(const bf16x8*)(Bhi + byt);
            bl[nc] = *(const bf16x8*)(Blo + byt);
        }
#pragma unroll
        for (int mr = 0; mr < 4; ++mr) {
            int row = wr * 64 + mr * 16 + l15;
            int byt = row * 64 + ((l4 ^ ((row >> 1) & 3)) * 16);
            bf16x8 ah = *(const bf16x8*)(Ahi + byt);
            bf16x8 al = *(const bf16x8*)(Alo + byt);
#pragma unroll
            for (int nc = 0; nc < 2; ++nc) {
                acc[mr][nc] = __builtin_amdgcn_mfma_f32_16x16x32_bf16(ah, bh[nc], acc[mr][nc], 0, 0, 0);
                acc[mr][nc] = __builtin_amdgcn_mfma_f32_16x16x32_bf16(ah, bl[nc], acc[mr][nc], 0, 0, 0);
                acc[mr][nc] = __builtin_amdgcn_mfma_f32_16x16x32_bf16(al, bh[nc], acc[mr][nc], 0, 0, 0);
            }
        }
    };
    int nk = K >> 5;
    load_stage(0);
    write_stage(lds);
    __syncthreads();
    for (int kt = 0; kt < nk; ++kt) {
        short* cur = lds + (kt & 1) * 12288;
        short* nxt = lds + ((kt & 1) ^ 1) * 12288;
        if (kt + 1 < nk) load_stage(kt + 1);
        compute(cur);
        if (kt + 1 < nk) write_stage(nxt);
        __syncthreads();
    }
#pragma unroll
    for (int nc = 0; nc < 2; ++nc) {
        int col = col0 + wc * 32 + nc * 16 + l15;
        float bv = bias[col];
#pragma unroll
        for (int mr = 0; mr < 4; ++mr) {
            int row = row0 + wr * 64 + mr * 16 + l4 * 4;
#pragma unroll
            for (int r = 0; r < 4; ++r) {
                float v = acc[mr][nc][r] + bv;
                if (RELU) v = fmaxf(v, 0.f);
                C[(size_t)(row + r) * N + col] = v;
            }
        }
    }
}

// ---------------------------------------------------------------------------
// MSDA sampling, branchless gathers: clamp index, fold validity into weight.
// One wave per query; 8 lanes/head; fused softmax; bf16-pair output.
// ---------------------------------------------------------------------------
__global__ __launch_bounds__(256) void msda2n(
    const float* __restrict__ value, const float* __restrict__ offlog,
    u16* __restrict__ eh, u16* __restrict__ el)
{
    const int lvl_off[4] = {0, 4096, 5120, 5376};
    const int lvl_hw[4]  = {64, 32, 16, 8};

    int m = blockIdx.x * 4 + (threadIdx.x >> 6);
    int lane = threadIdx.x & 63;
    int h = lane >> 3, c = (lane & 7) * 4;
    int b = m / QTOT, q = m - b * QTOT;

    int lq, rem;
    if      (q < 4096) { lq = 0; rem = q; }
    else if (q < 5120) { lq = 1; rem = q - 4096; }
    else if (q < 5376) { lq = 2; rem = q - 5120; }
    else               { lq = 3; rem = q - 5376; }
    int Wq = lvl_hw[lq];
    int yq = rem / Wq, xq = rem - yq * Wq;
    float ref_x = (xq + 0.5f) / (float)Wq;
    float ref_y = (yq + 0.5f) / (float)Wq;

    const float* lg = offlog + (size_t)m * 384 + 256 + h * 16;
    float w[16];
    {
        float mx = -1e30f;
#pragma unroll
        for (int i = 0; i < 4; ++i) {
            float4 v = reinterpret_cast<const float4*>(lg)[i];
            w[4 * i] = v.x; w[4 * i + 1] = v.y; w[4 * i + 2] = v.z; w[4 * i + 3] = v.w;
        }
#pragma unroll
        for (int j = 0; j < 16; ++j) mx = fmaxf(mx, w[j]);
        float s = 0.f;
#pragma unroll
        for (int j = 0; j < 16; ++j) { w[j] = __expf(w[j] - mx); s += w[j]; }
        float rs = 1.f / s;
#pragma unroll
        for (int j = 0; j < 16; ++j) w[j] *= rs;
    }

    float ofv[32];
    const float* op = offlog + (size_t)m * 384 + h * 32;
#pragma unroll
    for (int i = 0; i < 8; ++i) {
        float4 v = reinterpret_cast<const float4*>(op)[i];
        ofv[4 * i] = v.x; ofv[4 * i + 1] = v.y; ofv[4 * i + 2] = v.z; ofv[4 * i + 3] = v.w;
    }

    float a0 = 0.f, a1 = 0.f, a2 = 0.f, a3 = 0.f;
#pragma unroll
    for (int l = 0; l < 4; ++l) {
        int HW = lvl_hw[l];
        float fHW = (float)HW;
        const float* vbase =
            value + ((size_t)(b * QTOT + lvl_off[l])) * D_MODEL + h * 32 + c;
#pragma unroll
        for (int p = 0; p < 4; ++p) {
            float ox = ofv[(l * 4 + p) * 2 + 0];
            float oy = ofv[(l * 4 + p) * 2 + 1];
            float aw = w[l * 4 + p];
            float x = (ref_x + ox / fHW) * fHW - 0.5f;
            float y = (ref_y + oy / fHW) * fHW - 0.5f;
            float x0f = floorf(x), y0f = floorf(y);
            int   x0 = (int)x0f,  y0 = (int)y0f;
            float wx = x - x0f,   wy = y - y0f;
            // validity folded into weights (branchless)
            float vx0 = (x0 >= 0 && x0 < HW) ? 1.f : 0.f;
            float vx1 = (x0 + 1 >= 0 && x0 + 1 < HW) ? 1.f : 0.f;
            float vy0 = (y0 >= 0 && y0 < HW) ? 1.f : 0.f;
            float vy1 = (y0 + 1 >= 0 && y0 + 1 < HW) ? 1.f : 0.f;
            float w00 = (1.f - wx) * (1.f - wy) * aw * vx0 * vy0;
            float w01 = wx * (1.f - wy) * aw * vx1 * vy0;
            float w10 = (1.f - wx) * wy * aw * vx0 * vy1;
            float w11 = wx * wy * aw * vx1 * vy1;
            int xc0 = min(max(x0, 0), HW - 1);
            int xc1 = min(max(x0 + 1, 0), HW - 1);
            int yc0 = min(max(y0, 0), HW - 1);
            int yc1 = min(max(y0 + 1, 0), HW - 1);
            const float* p00 = vbase + (size_t)(yc0 * HW + xc0) * D_MODEL;
            const float* p01 = vbase + (size_t)(yc0 * HW + xc1) * D_MODEL;
            const float* p10 = vbase + (size_t)(yc1 * HW + xc0) * D_MODEL;
            const float* p11 = vbase + (size_t)(yc1 * HW + xc1) * D_MODEL;
            float4 v00 = *reinterpret_cast<const float4*>(p00);
            float4 v01 = *reinterpret_cast<const float4*>(p01);
            float4 v10 = *reinterpret_cast<const float4*>(p10);
            float4 v11 = *reinterpret_cast<const float4*>(p11);
            a0 += w00 * v00.x + w01 * v01.x + w10 * v10.x + w11 * v11.x;
            a1 += w00 * v00.y + w01 * v01.y + w10 * v10.y + w11 * v11.y;
            a2 += w00 * v00.z + w01 * v01.z + w10 * v10.z + w11 * v11.z;
            a3 += w00 * v00.w + w01 * v01.w + w10 * v10.w + w11 * v11.w;
        }
    }
    size_t oidx = (size_t)m * D_MODEL + h * 32 + c;
    ushort4 hv, lv;
    hv.x = f2bf(a0); lv.x = f2bf(a0 - bf2f(hv.x));
    hv.y = f2bf(a1); lv.y = f2bf(a1 - bf2f(hv.y));
    hv.z = f2bf(a2); lv.z = f2bf(a2 - bf2f(hv.z));
    hv.w = f2bf(a3); lv.w = f2bf(a3 - bf2f(hv.w));
    *reinterpret_cast<ushort4*>(eh + oidx) = hv;
    *reinterpret_cast<ushort4*>(el + oidx) = lv;
}

// msda (old, fallback): separate off/logits, fp32 out
__global__ __launch_bounds__(256) void msda2(
    const float* __restrict__ value, const float* __restrict__ off,
    const float* __restrict__ logits, float* __restrict__ outp)
{
    const int lvl_off[4] = {0, 4096, 5120, 5376};
    const int lvl_hw[4]  = {64, 32, 16, 8};
    int m = blockIdx.x * 4 + (threadIdx.x >> 6);
    int lane = threadIdx.x & 63;
    int h = lane >> 3, c = (lane & 7) * 4;
    int b = m / QTOT, q = m - b * QTOT;
    int lq, rem;
    if      (q < 4096) { lq = 0; rem = q; }
    else if (q < 5120) { lq = 1; rem = q - 4096; }
    else if (q < 5376) { lq = 2; rem = q - 5120; }
    else               { lq = 3; rem = q - 5376; }
    int Wq = lvl_hw[lq];
    int yq = rem / Wq, xq = rem - yq * Wq;
    float ref_x = (xq + 0.5f) / (float)Wq;
    float ref_y = (yq + 0.5f) / (float)Wq;
    const float* lg = logits + (size_t)m * 128 + h * 16;
    float w[16];
    {
        float mx = -1e30f;
#pragma unroll
        for (int i = 0; i < 4; ++i) {
            float4 v = reinterpret_cast<const float4*>(lg)[i];
            w[4 * i] = v.x; w[4 * i + 1] = v.y; w[4 * i + 2] = v.z; w[4 * i + 3] = v.w;
        }
#pragma unroll
        for (int j = 0; j < 16; ++j) mx = fmaxf(mx, w[j]);
        float s = 0.f;
#pragma unroll
        for (int j = 0; j < 16; ++j) { w[j] = __expf(w[j] - mx); s += w[j]; }
        float rs = 1.f / s;
#pragma unroll
        for (int j = 0; j < 16; ++j) w[j] *= rs;
    }
    float ofv[32];
    const float* op = off + (size_t)m * 256 + h * 32;
#pragma unroll
    for (int i = 0; i < 8; ++i) {
        float4 v = reinterpret_cast<const float4*>(op)[i];
        ofv[4 * i] = v.x; ofv[4 * i + 1] = v.y; ofv[4 * i + 2] = v.z; ofv[4 * i + 3] = v.w;
    }
    float a0 = 0.f, a1 = 0.f, a2 = 0.f, a3 = 0.f;
#pragma unroll
    for (int l = 0; l < 4; ++l) {
        int HW = lvl_hw[l];
        float fHW = (float)HW;
        const float* vbase =
            value + ((size_t)(b * QTOT + lvl_off[l])) * D_MODEL + h * 32 + c;
#pragma unroll
        for (int p = 0; p < 4; ++p) {
            float ox = ofv[(l * 4 + p) * 2 + 0];
            float oy = ofv[(l * 4 + p) * 2 + 1];
            float aw = w[l * 4 + p];
            float x = (ref_x + ox / fHW) * fHW - 0.5f;
            float y = (ref_y + oy / fHW) * fHW - 0.5f;
            float x0f = floorf(x), y0f = floorf(y);
            int   x0 = (int)x0f,  y0 = (int)y0f;
            float wx = x - x0f,   wy = y - y0f;
            float w00 = (1.f - wx) * (1.f - wy) * aw, w01 = wx * (1.f - wy) * aw;
            float w10 = (1.f - wx) * wy * aw,         w11 = wx * wy * aw;
            bool xv0 = (x0 >= 0) && (x0 < HW);
            bool xv1 = (x0 + 1 >= 0) && (x0 + 1 < HW);
            bool yv0 = (y0 >= 0) && (y0 < HW);
            bool yv1 = (y0 + 1 >= 0) && (y0 + 1 < HW);
#define GATH(cond, idx, wgt)                                                  \
            if (cond) {                                                       \
                float4 v = *reinterpret_cast<const float4*>(                  \
                    vbase + (size_t)(idx) * D_MODEL);                         \
                a0 += (wgt) * v.x; a1 += (wgt) * v.y;                         \
                a2 += (wgt) * v.z; a3 += (wgt) * v.w;                         \
            }
            GATH(xv0 && yv0, y0 * HW + x0,           w00)
            GATH(xv1 && yv0, y0 * HW + x0 + 1,       w01)
            GATH(xv0 && yv1, (y0 + 1) * HW + x0,     w10)
            GATH(xv1 && yv1, (y0 + 1) * HW + x0 + 1, w11)
#undef GATH
        }
    }
    float4 o = make_float4(a0, a1, a2, a3);
    *reinterpret_cast<float4*>(&outp[(size_t)m * D_MODEL + h * 32 + c]) = o;
}

// ---------------------------------------------------------------------------
// add+LN on pair-stored residual: y = LN((oh+ol) + t)*g + beta -> oh/ol.
// WRITEQ: also q = y + posf -> qh/ql.  WRITEF32: y -> f32out.
// ---------------------------------------------------------------------------
template<int WRITEQ, int WRITEF32>
__global__ __launch_bounds__(64) void add_ln_pair(
    const float* __restrict__ t, const float* __restrict__ g,
    const float* __restrict__ beta,
    u16* __restrict__ oh, u16* __restrict__ ol,
    const float* __restrict__ posf, u16* __restrict__ qh, u16* __restrict__ ql,
    float* __restrict__ f32out)
{
    int row = blockIdx.x;
    int lane = threadIdx.x;
    size_t base = (size_t)row * D_MODEL + lane * 4;
    ushort4 hv = *reinterpret_cast<const ushort4*>(oh + base);
    ushort4 lv = *reinterpret_cast<const ushort4*>(ol + base);
    float4 tv = *reinterpret_cast<const float4*>(t + base);
    float v0 = bf2f(hv.x) + bf2f(lv.x) + tv.x;
    float v1 = bf2f(hv.y) + bf2f(lv.y) + tv.y;
    float v2 = bf2f(hv.z) + bf2f(lv.z) + tv.z;
    float v3 = bf2f(hv.w) + bf2f(lv.w) + tv.w;
    float s = v0 + v1 + v2 + v3;
#pragma unroll
    for (int o = 32; o > 0; o >>= 1) s += __shfl_xor(s, o);
    float mean = s * (1.f / D_MODEL);
    float d0 = v0 - mean, d1 = v1 - mean, d2 = v2 - mean, d3 = v3 - mean;
    float ss = d0 * d0 + d1 * d1 + d2 * d2 + d3 * d3;
#pragma unroll
    for (int o = 32; o > 0; o >>= 1) ss += __shfl_xor(ss, o);
    float rstd = rsqrtf(ss * (1.f / D_MODEL) + 1e-5f);
    float4 gv = *reinterpret_cast<const float4*>(&g[lane * 4]);
    float4 bv = *reinterpret_cast<const float4*>(&beta[lane * 4]);
    float y0 = d0 * rstd * gv.x + bv.x;
    float y1 = d1 * rstd * gv.y + bv.y;
    float y2 = d2 * rstd * gv.z + bv.z;
    float y3 = d3 * rstd * gv.w + bv.w;
    ushort4 nh, nl;
    nh.x = f2bf(y0); nl.x = f2bf(y0 - bf2f(nh.x));
    nh.y = f2bf(y1); nl.y = f2bf(y1 - bf2f(nh.y));
    nh.z = f2bf(y2); nl.z = f2bf(y2 - bf2f(nh.z));
    nh.w = f2bf(y3); nl.w = f2bf(y3 - bf2f(nh.w));
    *reinterpret_cast<ushort4*>(oh + base) = nh;
    *reinterpret_cast<ushort4*>(ol + base) = nl;
    if (WRITEQ) {
        float4 pv = *reinterpret_cast<const float4*>(posf + base);
        float q0 = y0 + pv.x, q1 = y1 + pv.y, q2 = y2 + pv.z, q3 = y3 + pv.w;
        ushort4 qhv, qlv;
        qhv.x = f2bf(q0); qlv.x = f2bf(q0 - bf2f(qhv.x));
        qhv.y = f2bf(q1); qlv.y = f2bf(q1 - bf2f(qhv.y));
        qhv.z = f2bf(q2); qlv.z = f2bf(q2 - bf2f(qhv.z));
        qhv.w = f2bf(q3); qlv.w = f2bf(q3 - bf2f(qhv.w));
        *reinterpret_cast<ushort4*>(qh + base) = qhv;
        *reinterpret_cast<ushort4*>(ql + base) = qlv;
    }
    if (WRITEF32) {
        *reinterpret_cast<float4*>(f32out + base) = make_float4(y0, y1, y2, y3);
    }
}

// old add_ln (fallback): in-place fp32
__global__ __launch_bounds__(64) void add_ln(
    const float* __restrict__ t, const float* __restrict__ g,
    const float* __restrict__ beta, float* __restrict__ x)
{
    int row = blockIdx.x;
    int lane = threadIdx.x;
    size_t base = (size_t)row * D_MODEL + lane * 4;
    float4 xv = *reinterpret_cast<const float4*>(&x[base]);
    float4 tv = *reinterpret_cast<const float4*>(&t[base]);
    float v0 = xv.x + tv.x, v1 = xv.y + tv.y, v2 = xv.z + tv.z, v3 = xv.w + tv.w;
    float s = v0 + v1 + v2 + v3;
#pragma unroll
    for (int o = 32; o > 0; o >>= 1) s += __shfl_xor(s, o);
    float mean = s * (1.f / D_MODEL);
    float d0 = v0 - mean, d1 = v1 - mean, d2 = v2 - mean, d3 = v3 - mean;
    float ss = d0 * d0 + d1 * d1 + d2 * d2 + d3 * d3;
#pragma unroll
    for (int o = 32; o > 0; o >>= 1) ss += __shfl_xor(ss, o);
    float rstd = rsqrtf(ss * (1.f / D_MODEL) + 1e-5f);
    float4 gv = *reinterpret_cast<const float4*>(&g[lane * 4]);
    float4 bv = *reinterpret_cast<const float4*>(&beta[lane * 4]);
    float4 ov = make_float4(d0 * rstd * gv.x + bv.x, d1 * rstd * gv.y + bv.y,
                            d2 * rstd * gv.z + bv.z, d3 * rstd * gv.w + bv.w);
    *reinterpret_cast<float4*>(&x[base]) = ov;
}

// ---------------------------------------------------------------------------
extern "C" void kernel_launch(void* const* d_in, const int* in_sizes, int n_in,
                              void* d_out, int out_size, void* d_ws, size_t ws_size,
                              hipStream_t stream)
{
    // dict order is INTERLEAVED: src0,pos0,src1,pos1,...
    const float* src[4] = {(const float*)d_in[0], (const float*)d_in[2],
                           (const float*)d_in[4], (const float*)d_in[6]};
    const float* pos[4] = {(const float*)d_in[1], (const float*)d_in[3],
                           (const float*)d_in[5], (const float*)d_in[7]};
    const float* lvl   = (const float*)d_in[8];
    const float* W_off = (const float*)d_in[9];
    const float* b_off = (const float*)d_in[10];
    const float* W_att = (const float*)d_in[11];
    const float* b_att = (const float*)d_in[12];
    const float* W_val = (const float*)d_in[13];
    const float* b_val = (const float*)d_in[14];
    const float* W_out = (const float*)d_in[15];
    const float* b_out = (const float*)d_in[16];
    const float* ln1g  = (const float*)d_in[17];
    const float* ln1b  = (const float*)d_in[18];
    const float* W_ff1 = (const float*)d_in[19];
    const float* b_ff1 = (const float*)d_in[20];
    const float* W_ff2 = (const float*)d_in[21];
    const float* b_ff2 = (const float*)d_in[22];
    const float* ln2g  = (const float*)d_in[23];
    const float* ln2b  = (const float*)d_in[24];

    float* ws = (float*)d_ws;
    const size_t MD = (size_t)MTOT * D_MODEL;    // 5,570,560

    const int hws[4]  = {4096, 1024, 256, 64};
    const int qoff[4] = {0, 4096, 5120, 5376};

    // ---- NEW path layout ----
    float* posf = ws;                                    // fp32 [M,256]
    u16* oh = (u16*)(ws + MD);
    u16* ol = oh + MD;
    u16* qh = ol + MD;                                   // Q region (q|e)
    u16* ql = qh + MD;
    u16* eh = qh; u16* el = ql;
    float* val    = (float*)(ql + MD);                   // fp32 [M,256]; ffout
    float* ffout  = val;
    float* offlog = val + MD;                            // fp32 [M,384]; tmp/hid
    float* tmp    = offlog;
    u16* hid_h = (u16*)offlog;
    u16* hid_l = hid_h + (size_t)63 * 128 * 1024;
    u16* wb = (u16*)(offlog + (size_t)MTOT * 384);
    size_t o = 0;
    u16* wv_h = wb + o; o += 6 * 65536;  u16* wv_l = wb + o; o += 6 * 65536;
    u16* wc_h = wb + o; o += 6 * 98304;  u16* wc_l = wb + o; o += 6 * 98304;
    u16* wu_h = wb + o; o += 6 * 65536;  u16* wu_l = wb + o; o += 6 * 65536;
    u16* wf1_h = wb + o; o += 6 * 262144; u16* wf1_l = wb + o; o += 6 * 262144;
    u16* wf2_h = wb + o; o += 6 * 262144; u16* wf2_l = wb + o; o += 6 * 262144;
    const size_t NEED = (size_t)((char*)(wb + o) - (char*)ws);   // ~140.6 MB

    if (ws_size >= NEED) {
        dim3 cb(32, 8);
        for (int l = 0; l < 4; ++l) {
            dim3 g(hws[l] / 32, D_MODEL / 32, BATCH);
            flatten_tr<<<g, cb, 0, stream>>>(pos[l], lvl + l * D_MODEL, posf, hws[l], qoff[l]);
            flatten_src_pair<<<g, cb, 0, stream>>>(src[l], posf, oh, ol, qh, ql, hws[l], qoff[l]);
        }
        wconv<<<dim3(8, 8, 6),  cb, 0, stream>>>(W_val, wv_h, wv_l, 256, 256, 65536);
        wconv<<<dim3(8, 8, 6),  cb, 0, stream>>>(W_off, wc_h, wc_l, 256, 256, 98304);
        wconv<<<dim3(4, 8, 6),  cb, 0, stream>>>(W_att, wc_h + 65536, wc_l + 65536, 256, 128, 98304);
        wconv<<<dim3(8, 8, 6),  cb, 0, stream>>>(W_out, wu_h, wu_l, 256, 256, 65536);
        wconv<<<dim3(32, 8, 6), cb, 0, stream>>>(W_ff1, wf1_h, wf1_l, 256, 1024, 262144);
        wconv<<<dim3(8, 32, 6), cb, 0, stream>>>(W_ff2, wf2_h, wf2_l, 1024, 256, 262144);

        for (int i = 0; i < NLAYER; ++i) {
            gemm_pre<0><<<dim3(2, 170), 256, 0, stream>>>(
                oh, ol, wv_h + i * 65536, wv_l + i * 65536,
                b_val + i * 256, b_val + i * 256, 256, val, nullptr, nullptr, 256, 256);
            gemm_pre<0><<<dim3(3, 170), 256, 0, stream>>>(
                qh, ql, wc_h + i * 98304, wc_l + i * 98304,
                b_off + i * 256, b_att + i * 128, 256, offlog, nullptr, nullptr, 384, 256);
            msda2n<<<MTOT / 4, 256, 0, stream>>>(val, offlog, eh, el);
            gemm_pre<0><<<dim3(2, 170), 256, 0, stream>>>(
                eh, el, wu_h + i * 65536, wu_l + i * 65536,
                b_out + i * 256, b_out + i * 256, 256, tmp, nullptr, nullptr, 256, 256);
            add_ln_pair<0, 0><<<MTOT, 64, 0, stream>>>(
                tmp, ln1g + i * 256, ln1b + i * 256, oh, ol,
                nullptr, nullptr, nullptr, nullptr);
            const int nbs[3] = {63, 63, 44};
            int rb = 0;
            for (int c = 0; c < 3; ++c) {
                size_t r0 = (size_t)rb * 128 * 256;
                gemm_pre<1><<<dim3(8, nbs[c]), 256, 0, stream>>>(
                    oh + r0, ol + r0, wf1_h + i * 262144, wf1_l + i * 262144,
                    b_ff1 + i * 1024, b_ff1 + i * 1024, 1024,
                    nullptr, hid_h, hid_l, 1024, 256);
                gemm_pre<0><<<dim3(2, nbs[c]), 256, 0, stream>>>(
                    hid_h, hid_l, wf2_h + i * 262144, wf2_l + i * 262144,
                    b_ff2 + i * 256, b_ff2 + i * 256, 256,
                    ffout + r0, nullptr, nullptr, 256, 1024);
                rb += nbs[c];
            }
            if (i < NLAYER - 1)
                add_ln_pair<1, 0><<<MTOT, 64, 0, stream>>>(
                    ffout, ln2g + i * 256, ln2b + i * 256, oh, ol,
                    posf, qh, ql, nullptr);
            else
                add_ln_pair<0, 1><<<MTOT, 64, 0, stream>>>(
                    ffout, ln2g + i * 256, ln2b + i * 256, oh, ol,
                    nullptr, nullptr, nullptr, (float*)d_out);
        }
    } else {
        // ---- FALLBACK: round-3 proven path (~118.4 MB) ----
        float* out = (float*)d_out;
        float* posf2  = ws;
        float* val2   = posf2 + MD;
        float* logits = val2 + MD;
        float* offb   = logits + (size_t)MTOT * 128;
        float* ebuf   = offb + MD;
        float* tmp2   = offb;
        float* hid2   = offb;
        short* wbase = (short*)(ebuf + MD);
        short* v_h = wbase;               short* v_l = v_h + 6 * 65536;
        short* o_h = v_l + 6 * 65536;     short* o_l = o_h + 6 * 65536;
        short* a_h = o_l + 6 * 65536;     short* a_l = a_h + 6 * 32768;
        short* u_h = a_l + 6 * 32768;     short* u_l = u_h + 6 * 65536;
        short* f1h = u_l + 6 * 65536;     short* f1l = f1h + 6 * 262144;
        short* f2h = f1l + 6 * 262144;    short* f2l = f2h + 6 * 262144;
        dim3 cb(32, 8);
        for (int l = 0; l < 4; ++l) {
            dim3 g(hws[l] / 32, D_MODEL / 32, BATCH);
            flatten_tr<<<g, cb, 0, stream>>>(src[l], nullptr, out, hws[l], qoff[l]);
            flatten_tr<<<g, cb, 0, stream>>>(pos[l], lvl + l * D_MODEL, posf2, hws[l], qoff[l]);
        }
        wconv<<<dim3(8, 8, 6),  cb, 0, stream>>>(W_val, (u16*)v_h, (u16*)v_l, 256, 256, 65536);
        wconv<<<dim3(8, 8, 6),  cb, 0, stream>>>(W_off, (u16*)o_h, (u16*)o_l, 256, 256, 65536);
        wconv<<<dim3(4, 8, 6),  cb, 0, stream>>>(W_att, (u16*)a_h, (u16*)a_l, 256, 128, 32768);
        wconv<<<dim3(8, 8, 6),  cb, 0, stream>>>(W_out, (u16*)u_h, (u16*)u_l, 256, 256, 65536);
        wconv<<<dim3(32, 8, 6), cb, 0, stream>>>(W_ff1, (u16*)f1h, (u16*)f1l, 256, 1024, 262144);
        wconv<<<dim3(8, 32, 6), cb, 0, stream>>>(W_ff2, (u16*)f2h, (u16*)f2l, 1024, 256, 262144);
        for (int i = 0; i < NLAYER; ++i) {
            gemm_mfma<0,0><<<dim3(4, 170), 256, 0, stream>>>(
                out, nullptr, v_h + i * 65536, v_l + i * 65536,
                b_val + i * 256, val2, 256, 256);
            gemm_mfma<0,1><<<dim3(4, 170), 256, 0, stream>>>(
                out, posf2, o_h + i * 65536, o_l + i * 65536,
                b_off + i * 256, offb, 256, 256);
            gemm_mfma<0,1><<<dim3(2, 170), 256, 0, stream>>>(
                out, posf2, a_h + i * 32768, a_l + i * 32768,
                b_att + i * 128, logits, 128, 256);
            msda2<<<MTOT / 4, 256, 0, stream>>>(val2, offb, logits, ebuf);
            gemm_mfma<0,0><<<dim3(4, 170), 256, 0, stream>>>(
                ebuf, nullptr, u_h + i * 65536, u_l + i * 65536,
                b_out + i * 256, tmp2, 256, 256);
            add_ln<<<MTOT, 64, 0, stream>>>(tmp2, ln1g + i * 256, ln1b + i * 256, out);
            for (int h = 0; h < 2; ++h) {
                gemm_mfma<1,0><<<dim3(16, 85), 256, 0, stream>>>(
                    out + (size_t)h * MHALF * 256, nullptr,
                    f1h + i * 262144, f1l + i * 262144,
                    b_ff1 + i * 1024, hid2, 1024, 256);
                gemm_mfma<0,0><<<dim3(4, 85), 256, 0, stream>>>(
                    hid2, nullptr, f2h + i * 262144, f2l + i * 262144,
                    b_ff2 + i * 256, val2 + (size_t)h * MHALF * 256, 256, 1024);
            }
            add_ln<<<MTOT, 64, 0, stream>>>(val2, ln2g + i * 256, ln2b + i * 256, out);
        }
    }
    (void)in_sizes; (void)n_in; (void)out_size;
}

// Round 6
// 1799.226 us; speedup vs baseline: 2.8670x; 1.0258x over previous
//
#include <hip/hip_runtime.h>
#include <cstddef>
#include <cstdint>

#define D_MODEL 256
#define NHEAD   8
#define NLAYER  6
#define BATCH   4
#define QTOT    5440
#define MTOT    (BATCH*QTOT)   // 21760 = 170*128
#define MHALF   (MTOT/2)
#define DFFN    1024

typedef short  bf16x8 __attribute__((ext_vector_type(8)));
typedef float  f32x4  __attribute__((ext_vector_type(4)));
typedef unsigned short u16;

typedef __attribute__((address_space(1))) const void g_as1;
typedef __attribute__((address_space(3))) void l_as3;

__device__ __forceinline__ u16 f2bf(float f) {
    uint32_t u = __float_as_uint(f);
    return (u16)((u + 0x7fffu + ((u >> 16) & 1u)) >> 16);
}
__device__ __forceinline__ float bf2f(u16 s) {
    return __uint_as_float(((uint32_t)s) << 16);
}

// ---------------------------------------------------------------------------
// Flatten + transpose (fp32): src [B,D,HW] -> dst [B,Q,D], optional emb add.
// ---------------------------------------------------------------------------
__global__ __launch_bounds__(256) void flatten_tr(
    const float* __restrict__ src, const float* __restrict__ emb,
    float* __restrict__ dst, int HW, int qoff)
{
    __shared__ float tile[32][33];
    int tx = threadIdx.x, ty = threadIdx.y;
    int hw0 = blockIdx.x * 32, d0 = blockIdx.y * 32, b = blockIdx.z;
    const float* s = src + (size_t)b * D_MODEL * HW;
#pragma unroll
    for (int j = 0; j < 4; ++j)
        tile[ty + j * 8][tx] = s[(size_t)(d0 + ty + j * 8) * HW + hw0 + tx];
    __syncthreads();
#pragma unroll
    for (int j = 0; j < 4; ++j) {
        int hw = ty + j * 8;
        float v = tile[tx][hw];
        if (emb) v += emb[d0 + tx];
        dst[((size_t)b * QTOT + qoff + hw0 + hw) * D_MODEL + d0 + tx] = v;
    }
}

// ---------------------------------------------------------------------------
// Flatten src -> out bf16 pair + q=(src+posf) bf16 pair.
// ---------------------------------------------------------------------------
__global__ __launch_bounds__(256) void flatten_src_pair(
    const float* __restrict__ src, const float* __restrict__ posf,
    u16* __restrict__ oh, u16* __restrict__ ol,
    u16* __restrict__ qh, u16* __restrict__ ql, int HW, int qoff)
{
    __shared__ float tile[32][33];
    int tx = threadIdx.x, ty = threadIdx.y;
    int hw0 = blockIdx.x * 32, d0 = blockIdx.y * 32, b = blockIdx.z;
    const float* s = src + (size_t)b * D_MODEL * HW;
#pragma unroll
    for (int j = 0; j < 4; ++j)
        tile[ty + j * 8][tx] = s[(size_t)(d0 + ty + j * 8) * HW + hw0 + tx];
    __syncthreads();
#pragma unroll
    for (int j = 0; j < 4; ++j) {
        int hw = ty + j * 8;
        float v = tile[tx][hw];
        size_t idx = ((size_t)b * QTOT + qoff + hw0 + hw) * D_MODEL + d0 + tx;
        u16 h = f2bf(v);
        oh[idx] = h; ol[idx] = f2bf(v - bf2f(h));
        float q = v + posf[idx];
        u16 qhv = f2bf(q);
        qh[idx] = qhv; ql[idx] = f2bf(q - bf2f(qhv));
    }
}

// ---------------------------------------------------------------------------
// Weight convert+transpose: W fp32 [L][K][N] -> hi/lo bf16 [L(lstride)][N][K]
// ---------------------------------------------------------------------------
__global__ __launch_bounds__(256) void wconv(
    const float* __restrict__ W, u16* __restrict__ Whi,
    u16* __restrict__ Wlo, int K, int N, int lstride)
{
    __shared__ float t[32][33];
    int tx = threadIdx.x, ty = threadIdx.y;
    int n0 = blockIdx.x * 32, k0 = blockIdx.y * 32, l = blockIdx.z;
    const float* Wl = W + (size_t)l * K * N;
    u16* Hl = Whi + (size_t)l * lstride;
    u16* Ll = Wlo + (size_t)l * lstride;
#pragma unroll
    for (int j = 0; j < 4; ++j)
        t[ty + j * 8][tx] = Wl[(size_t)(k0 + ty + j * 8) * N + n0 + tx];
    __syncthreads();
#pragma unroll
    for (int j = 0; j < 4; ++j) {
        float v = t[tx][ty + j * 8];
        int n = n0 + ty + j * 8, k = k0 + tx;
        u16 h = f2bf(v);
        Hl[(size_t)n * K + k] = h;
        Ll[(size_t)n * K + k] = f2bf(v - bf2f(h));
    }
}

// ---------------------------------------------------------------------------
// MFMA GEMM, pre-split bf16 A and B, BM=128 BN=128 BK=32.
// 256 thr = 4 waves (2x2); each wave computes 64x64 (acc[4][4]).
// Staging via global_load_lds (direct HBM->LDS DMA): linear LDS dest,
// inverse-swizzled per-lane GLOBAL source, swizzled ds_read (rule #21).
// Wave w stages region w: 0=A-hi 1=A-lo 2=B-hi 3=B-lo (8KB each, 8 calls).
// CMODE 0: fp32 C.  CMODE 1: bf16 hi/lo pair C with ReLU.
// ---------------------------------------------------------------------------
template<int CMODE>
__global__ __launch_bounds__(256) void gemm_pre(
    const u16* __restrict__ Ah, const u16* __restrict__ Al,
    const u16* __restrict__ Bh, const u16* __restrict__ Bl,
    const float* __restrict__ bias, const float* __restrict__ bias2, int nsplit,
    float* __restrict__ Cf, u16* __restrict__ Ch, u16* __restrict__ Cl,
    int N, int K)
{
    // per buffer (bytes): Ahi 8192 | Alo 8192 | Bhi 8192 | Blo 8192 = 32 KB
    __shared__ __align__(16) short lds[2 * 16384];   // 64 KB

    int tid  = threadIdx.x;
    int lane = tid & 63, wid = tid >> 6;
    int wr = wid >> 1, wc = wid & 1;
    int row0 = blockIdx.y * 128, col0 = blockIdx.x * 128;

    // ---- global_load_lds staging ----
    // lane -> (row = lane>>2 within 16-row chunk, seg = lane&3); linear LDS.
    // source K-seg = seg ^ swz(row), swz(row) = (row>>1)&3 = (lane>>3)&3.
    const u16* gsrc0 = (wid == 0) ? Ah : (wid == 1) ? Al : (wid == 2) ? Bh : Bl;
    int rbase = (wid < 2) ? row0 : col0;
    const u16* gsrc = gsrc0 + (size_t)(rbase + (lane >> 2)) * K
                            + (((lane & 3) ^ ((lane >> 3) & 3)) * 8);

    auto issue = [&](int kt, short* buf) {
        char* lbase = (char*)buf + wid * 8192;
        const u16* g = gsrc + kt * 32;
#pragma unroll
        for (int j = 0; j < 8; ++j) {
            __builtin_amdgcn_global_load_lds(
                (g_as1*)(g + (size_t)j * 16 * K),
                (l_as3*)(lbase + j * 1024), 16, 0, 0);
        }
    };

    f32x4 acc[4][4];
#pragma unroll
    for (int i = 0; i < 4; ++i)
#pragma unroll
        for (int j = 0; j < 4; ++j) acc[i][j] = (f32x4){0.f, 0.f, 0.f, 0.f};

    int l15 = lane & 15, l4 = lane >> 4;
    auto compute = [&](const short* buf) {
        const char* Ahi = (const char*)buf;
        const char* Alo = (const char*)(buf + 4096);
        const char* Bhi = (const char*)(buf + 8192);
        const char* Blo = (const char*)(buf + 12288);
        bf16x8 bh[4], bl[4];
#pragma unroll
        for (int nc = 0; nc < 4; ++nc) {
            int col = wc * 64 + nc * 16 + l15;
            int byt = col * 64 + ((l4 ^ ((col >> 1) & 3)) * 16);
            bh[nc] = *(const bf16x8*)(Bhi + byt);
            bl[nc] = *(const bf16x8*)(Blo + byt);
        }
#pragma unroll
        for (int mr = 0; mr < 4; ++mr) {
            int row = wr * 64 + mr * 16 + l15;
            int byt = row * 64 + ((l4 ^ ((row >> 1) & 3)) * 16);
            bf16x8 ah = *(const bf16x8*)(Ahi + byt);
            bf16x8 al = *(const bf16x8*)(Alo + byt);
#pragma unroll
            for (int nc = 0; nc < 4; ++nc) {
                acc[mr][nc] = __builtin_amdgcn_mfma_f32_16x16x32_bf16(ah, bh[nc], acc[mr][nc], 0, 0, 0);
                acc[mr][nc] = __builtin_amdgcn_mfma_f32_16x16x32_bf16(ah, bl[nc], acc[mr][nc], 0, 0, 0);
                acc[mr][nc] = __builtin_amdgcn_mfma_f32_16x16x32_bf16(al, bh[nc], acc[mr][nc], 0, 0, 0);
            }
        }
    };

    int nk = K >> 5;
    issue(0, lds);
    __syncthreads();                       // vmcnt(0) drain + barrier
    for (int kt = 0; kt < nk; ++kt) {
        short* cur = lds + (kt & 1) * 16384;
        short* nxt = lds + ((kt & 1) ^ 1) * 16384;
        if (kt + 1 < nk) issue(kt + 1, nxt);   // in flight across compute
        compute(cur);
        __syncthreads();                   // drains next-tile loads
    }

#pragma unroll
    for (int nc = 0; nc < 4; ++nc) {
        int col = col0 + wc * 64 + nc * 16 + l15;
        float bv = (col < nsplit) ? bias[col] : bias2[col - nsplit];
#pragma unroll
        for (int mr = 0; mr < 4; ++mr) {
            int row = row0 + wr * 64 + mr * 16 + l4 * 4;
#pragma unroll
            for (int r = 0; r < 4; ++r) {
                float v = acc[mr][nc][r] + bv;
                size_t idx = (size_t)(row + r) * N + col;
                if (CMODE == 0) {
                    Cf[idx] = v;
                } else {
                    v = fmaxf(v, 0.f);
                    u16 h = f2bf(v);
                    Ch[idx] = h;
                    Cl[idx] = f2bf(v - bf2f(h));
                }
            }
        }
    }
}

// ---------------------------------------------------------------------------
// OLD MFMA GEMM (fallback path, in-kernel fp32->bf16 split staging)
// ---------------------------------------------------------------------------
template<int RELU, int HASA2>
__global__ __launch_bounds__(256) void gemm_mfma(
    const float* __restrict__ A, const float* __restrict__ A2,
    const short* __restrict__ Whi, const short* __restrict__ Wlo,
    const float* __restrict__ bias, float* __restrict__ C, int N, int K)
{
    __shared__ __align__(16) short lds[2 * 12288];
    int tid  = threadIdx.x;
    int lane = tid & 63, wid = tid >> 6;
    int wr = wid >> 1, wc = wid & 1;
    int row0 = blockIdx.y * 128, col0 = blockIdx.x * 64;
    int srow = tid >> 1, shalf = tid & 1;
    int brow = tid >> 2, bseg = tid & 3;
    const float* Arow  = A + (size_t)(row0 + srow) * K + shalf * 16;
    const float* A2row = HASA2 ? A2 + (size_t)(row0 + srow) * K + shalf * 16 : nullptr;
    const short* Whirow = Whi + (size_t)(col0 + brow) * K + bseg * 8;
    const short* Wlorow = Wlo + (size_t)(col0 + brow) * K + bseg * 8;
    int aswz = (srow >> 1) & 3;
    int a_wb0 = srow * 64 + ((2 * shalf + 0) ^ aswz) * 16;
    int a_wb1 = srow * 64 + ((2 * shalf + 1) ^ aswz) * 16;
    int b_wb  = brow * 64 + ((bseg ^ ((brow >> 1) & 3)) * 16);
    f32x4 acc[4][2];
#pragma unroll
    for (int i = 0; i < 4; ++i)
#pragma unroll
        for (int j = 0; j < 2; ++j) acc[i][j] = (f32x4){0.f, 0.f, 0.f, 0.f};
    float av[16];
    uint4 bhv, blv;
    auto load_stage = [&](int kt) {
        const float4* ap = reinterpret_cast<const float4*>(Arow + kt * 32);
#pragma unroll
        for (int i = 0; i < 4; ++i) {
            float4 v = ap[i];
            av[4 * i + 0] = v.x; av[4 * i + 1] = v.y;
            av[4 * i + 2] = v.z; av[4 * i + 3] = v.w;
        }
        if (HASA2) {
            const float4* a2p = reinterpret_cast<const float4*>(A2row + kt * 32);
#pragma unroll
            for (int i = 0; i < 4; ++i) {
                float4 v = a2p[i];
                av[4 * i + 0] += v.x; av[4 * i + 1] += v.y;
                av[4 * i + 2] += v.z; av[4 * i + 3] += v.w;
            }
        }
        bhv = *reinterpret_cast<const uint4*>(Whirow + kt * 32);
        blv = *reinterpret_cast<const uint4*>(Wlorow + kt * 32);
    };
    auto write_stage = [&](short* buf) {
        unsigned int hw[8], lw[8];
#pragma unroll
        for (int i = 0; i < 8; ++i) {
            u16 h0 = f2bf(av[2 * i]), h1 = f2bf(av[2 * i + 1]);
            u16 l0 = f2bf(av[2 * i] - bf2f(h0));
            u16 l1 = f2bf(av[2 * i + 1] - bf2f(h1));
            hw[i] = (unsigned int)h0 | ((unsigned int)h1 << 16);
            lw[i] = (unsigned int)l0 | ((unsigned int)l1 << 16);
        }
        char* Ahi = (char*)buf;
        char* Alo = (char*)(buf + 4096);
        *(uint4*)(Ahi + a_wb0) = make_uint4(hw[0], hw[1], hw[2], hw[3]);
        *(uint4*)(Ahi + a_wb1) = make_uint4(hw[4], hw[5], hw[6], hw[7]);
        *(uint4*)(Alo + a_wb0) = make_uint4(lw[0], lw[1], lw[2], lw[3]);
        *(uint4*)(Alo + a_wb1) = make_uint4(lw[4], lw[5], lw[6], lw[7]);
        *(uint4*)((char*)(buf + 8192)  + b_wb) = bhv;
        *(uint4*)((char*)(buf + 10240) + b_wb) = blv;
    };
    int l15 = lane & 15, l4 = lane >> 4;
    auto compute = [&](const short* buf) {
        const char* Ahi = (const char*)buf;
        const char* Alo = (const char*)(buf + 4096);
        const char* Bhi = (const char*)(buf + 8192);
        const char* Blo = (const char*)(buf + 10240);
        bf16x8 bh[2], bl[2];
#pragma unroll
        for (int nc = 0; nc < 2; ++nc) {
            int col = wc * 32 + nc * 16 + l15;
            int byt = col * 64 + ((l4 ^ ((col >> 1) & 3)) * 16);
            bh[nc] = *(const bf16x8*)(Bhi + byt);
            bl[nc] = *(const bf16x8*)(Blo + byt);
        }
#pragma unroll
        for (int mr = 0; mr < 4; ++mr) {
            int row = wr * 64 + mr * 16 + l15;
            int byt = row * 64 + ((l4 ^ ((row >> 1) & 3)) * 16);
            bf16x8 ah = *(const bf16x8*)(Ahi + byt);
            bf16x8 al = *(const bf16x8*)(Alo + byt);
#pragma unroll
            for (int nc = 0; nc < 2; ++nc) {
                acc[mr][nc] = __builtin_amdgcn_mfma_f32_16x16x32_bf16(ah, bh[nc], acc[mr][nc], 0, 0, 0);
                acc[mr][nc] = __builtin_amdgcn_mfma_f32_16x16x32_bf16(ah, bl[nc], acc[mr][nc], 0, 0, 0);
                acc[mr][nc] = __builtin_amdgcn_mfma_f32_16x16x32_bf16(al, bh[nc], acc[mr][nc], 0, 0, 0);
            }
        }
    };
    int nk = K >> 5;
    load_stage(0);
    write_stage(lds);
    __syncthreads();
    for (int kt = 0; kt < nk; ++kt) {
        short* cur = lds + (kt & 1) * 12288;
        short* nxt = lds + ((kt & 1) ^ 1) * 12288;
        if (kt + 1 < nk) load_stage(kt + 1);
        compute(cur);
        if (kt + 1 < nk) write_stage(nxt);
        __syncthreads();
    }
#pragma unroll
    for (int nc = 0; nc < 2; ++nc) {
        int col = col0 + wc * 32 + nc * 16 + l15;
        float bv = bias[col];
#pragma unroll
        for (int mr = 0; mr < 4; ++mr) {
            int row = row0 + wr * 64 + mr * 16 + l4 * 4;
#pragma unroll
            for (int r = 0; r < 4; ++r) {
                float v = acc[mr][nc][r] + bv;
                if (RELU) v = fmaxf(v, 0.f);
                C[(size_t)(row + r) * N + col] = v;
            }
        }
    }
}

// ---------------------------------------------------------------------------
// MSDA sampling, branchless gathers: clamp index, fold validity into weight.
// One wave per query; 8 lanes/head; fused softmax; bf16-pair output.
// ---------------------------------------------------------------------------
__global__ __launch_bounds__(256) void msda2n(
    const float* __restrict__ value, const float* __restrict__ offlog,
    u16* __restrict__ eh, u16* __restrict__ el)
{
    const int lvl_off[4] = {0, 4096, 5120, 5376};
    const int lvl_hw[4]  = {64, 32, 16, 8};

    int m = blockIdx.x * 4 + (threadIdx.x >> 6);
    int lane = threadIdx.x & 63;
    int h = lane >> 3, c = (lane & 7) * 4;
    int b = m / QTOT, q = m - b * QTOT;

    int lq, rem;
    if      (q < 4096) { lq = 0; rem = q; }
    else if (q < 5120) { lq = 1; rem = q - 4096; }
    else if (q < 5376) { lq = 2; rem = q - 5120; }
    else               { lq = 3; rem = q - 5376; }
    int Wq = lvl_hw[lq];
    int yq = rem / Wq, xq = rem - yq * Wq;
    float ref_x = (xq + 0.5f) / (float)Wq;
    float ref_y = (yq + 0.5f) / (float)Wq;

    const float* lg = offlog + (size_t)m * 384 + 256 + h * 16;
    float w[16];
    {
        float mx = -1e30f;
#pragma unroll
        for (int i = 0; i < 4; ++i) {
            float4 v = reinterpret_cast<const float4*>(lg)[i];
            w[4 * i] = v.x; w[4 * i + 1] = v.y; w[4 * i + 2] = v.z; w[4 * i + 3] = v.w;
        }
#pragma unroll
        for (int j = 0; j < 16; ++j) mx = fmaxf(mx, w[j]);
        float s = 0.f;
#pragma unroll
        for (int j = 0; j < 16; ++j) { w[j] = __expf(w[j] - mx); s += w[j]; }
        float rs = 1.f / s;
#pragma unroll
        for (int j = 0; j < 16; ++j) w[j] *= rs;
    }

    float ofv[32];
    const float* op = offlog + (size_t)m * 384 + h * 32;
#pragma unroll
    for (int i = 0; i < 8; ++i) {
        float4 v = reinterpret_cast<const float4*>(op)[i];
        ofv[4 * i] = v.x; ofv[4 * i + 1] = v.y; ofv[4 * i + 2] = v.z; ofv[4 * i + 3] = v.w;
    }

    float a0 = 0.f, a1 = 0.f, a2 = 0.f, a3 = 0.f;
#pragma unroll
    for (int l = 0; l < 4; ++l) {
        int HW = lvl_hw[l];
        float fHW = (float)HW;
        const float* vbase =
            value + ((size_t)(b * QTOT + lvl_off[l])) * D_MODEL + h * 32 + c;
#pragma unroll
        for (int p = 0; p < 4; ++p) {
            float ox = ofv[(l * 4 + p) * 2 + 0];
            float oy = ofv[(l * 4 + p) * 2 + 1];
            float aw = w[l * 4 + p];
            float x = (ref_x + ox / fHW) * fHW - 0.5f;
            float y = (ref_y + oy / fHW) * fHW - 0.5f;
            float x0f = floorf(x), y0f = floorf(y);
            int   x0 = (int)x0f,  y0 = (int)y0f;
            float wx = x - x0f,   wy = y - y0f;
            float vx0 = (x0 >= 0 && x0 < HW) ? 1.f : 0.f;
            float vx1 = (x0 + 1 >= 0 && x0 + 1 < HW) ? 1.f : 0.f;
            float vy0 = (y0 >= 0 && y0 < HW) ? 1.f : 0.f;
            float vy1 = (y0 + 1 >= 0 && y0 + 1 < HW) ? 1.f : 0.f;
            float w00 = (1.f - wx) * (1.f - wy) * aw * vx0 * vy0;
            float w01 = wx * (1.f - wy) * aw * vx1 * vy0;
            float w10 = (1.f - wx) * wy * aw * vx0 * vy1;
            float w11 = wx * wy * aw * vx1 * vy1;
            int xc0 = min(max(x0, 0), HW - 1);
            int xc1 = min(max(x0 + 1, 0), HW - 1);
            int yc0 = min(max(y0, 0), HW - 1);
            int yc1 = min(max(y0 + 1, 0), HW - 1);
            const float* p00 = vbase + (size_t)(yc0 * HW + xc0) * D_MODEL;
            const float* p01 = vbase + (size_t)(yc0 * HW + xc1) * D_MODEL;
            const float* p10 = vbase + (size_t)(yc1 * HW + xc0) * D_MODEL;
            const float* p11 = vbase + (size_t)(yc1 * HW + xc1) * D_MODEL;
            float4 v00 = *reinterpret_cast<const float4*>(p00);
            float4 v01 = *reinterpret_cast<const float4*>(p01);
            float4 v10 = *reinterpret_cast<const float4*>(p10);
            float4 v11 = *reinterpret_cast<const float4*>(p11);
            a0 += w00 * v00.x + w01 * v01.x + w10 * v10.x + w11 * v11.x;
            a1 += w00 * v00.y + w01 * v01.y + w10 * v10.y + w11 * v11.y;
            a2 += w00 * v00.z + w01 * v01.z + w10 * v10.z + w11 * v11.z;
            a3 += w00 * v00.w + w01 * v01.w + w10 * v10.w + w11 * v11.w;
        }
    }
    size_t oidx = (size_t)m * D_MODEL + h * 32 + c;
    ushort4 hv, lv;
    hv.x = f2bf(a0); lv.x = f2bf(a0 - bf2f(hv.x));
    hv.y = f2bf(a1); lv.y = f2bf(a1 - bf2f(hv.y));
    hv.z = f2bf(a2); lv.z = f2bf(a2 - bf2f(hv.z));
    hv.w = f2bf(a3); lv.w = f2bf(a3 - bf2f(hv.w));
    *reinterpret_cast<ushort4*>(eh + oidx) = hv;
    *reinterpret_cast<ushort4*>(el + oidx) = lv;
}

// msda (old, fallback): separate off/logits, fp32 out
__global__ __launch_bounds__(256) void msda2(
    const float* __restrict__ value, const float* __restrict__ off,
    const float* __restrict__ logits, float* __restrict__ outp)
{
    const int lvl_off[4] = {0, 4096, 5120, 5376};
    const int lvl_hw[4]  = {64, 32, 16, 8};
    int m = blockIdx.x * 4 + (threadIdx.x >> 6);
    int lane = threadIdx.x & 63;
    int h = lane >> 3, c = (lane & 7) * 4;
    int b = m / QTOT, q = m - b * QTOT;
    int lq, rem;
    if      (q < 4096) { lq = 0; rem = q; }
    else if (q < 5120) { lq = 1; rem = q - 4096; }
    else if (q < 5376) { lq = 2; rem = q - 5120; }
    else               { lq = 3; rem = q - 5376; }
    int Wq = lvl_hw[lq];
    int yq = rem / Wq, xq = rem - yq * Wq;
    float ref_x = (xq + 0.5f) / (float)Wq;
    float ref_y = (yq + 0.5f) / (float)Wq;
    const float* lg = logits + (size_t)m * 128 + h * 16;
    float w[16];
    {
        float mx = -1e30f;
#pragma unroll
        for (int i = 0; i < 4; ++i) {
            float4 v = reinterpret_cast<const float4*>(lg)[i];
            w[4 * i] = v.x; w[4 * i + 1] = v.y; w[4 * i + 2] = v.z; w[4 * i + 3] = v.w;
        }
#pragma unroll
        for (int j = 0; j < 16; ++j) mx = fmaxf(mx, w[j]);
        float s = 0.f;
#pragma unroll
        for (int j = 0; j < 16; ++j) { w[j] = __expf(w[j] - mx); s += w[j]; }
        float rs = 1.f / s;
#pragma unroll
        for (int j = 0; j < 16; ++j) w[j] *= rs;
    }
    float ofv[32];
    const float* op = off + (size_t)m * 256 + h * 32;
#pragma unroll
    for (int i = 0; i < 8; ++i) {
        float4 v = reinterpret_cast<const float4*>(op)[i];
        ofv[4 * i] = v.x; ofv[4 * i + 1] = v.y; ofv[4 * i + 2] = v.z; ofv[4 * i + 3] = v.w;
    }
    float a0 = 0.f, a1 = 0.f, a2 = 0.f, a3 = 0.f;
#pragma unroll
    for (int l = 0; l < 4; ++l) {
        int HW = lvl_hw[l];
        float fHW = (float)HW;
        const float* vbase =
            value + ((size_t)(b * QTOT + lvl_off[l])) * D_MODEL + h * 32 + c;
#pragma unroll
        for (int p = 0; p < 4; ++p) {
            float ox = ofv[(l * 4 + p) * 2 + 0];
            float oy = ofv[(l * 4 + p) * 2 + 1];
            float aw = w[l * 4 + p];
            float x = (ref_x + ox / fHW) * fHW - 0.5f;
            float y = (ref_y + oy / fHW) * fHW - 0.5f;
            float x0f = floorf(x), y0f = floorf(y);
            int   x0 = (int)x0f,  y0 = (int)y0f;
            float wx = x - x0f,   wy = y - y0f;
            float w00 = (1.f - wx) * (1.f - wy) * aw, w01 = wx * (1.f - wy) * aw;
            float w10 = (1.f - wx) * wy * aw,         w11 = wx * wy * aw;
            bool xv0 = (x0 >= 0) && (x0 < HW);
            bool xv1 = (x0 + 1 >= 0) && (x0 + 1 < HW);
            bool yv0 = (y0 >= 0) && (y0 < HW);
            bool yv1 = (y0 + 1 >= 0) && (y0 + 1 < HW);
#define GATH(cond, idx, wgt)                                                  \
            if (cond) {                                                       \
                float4 v = *reinterpret_cast<const float4*>(                  \
                    vbase + (size_t)(idx) * D_MODEL);                         \
                a0 += (wgt) * v.x; a1 += (wgt) * v.y;                         \
                a2 += (wgt) * v.z; a3 += (wgt) * v.w;                         \
            }
            GATH(xv0 && yv0, y0 * HW + x0,           w00)
            GATH(xv1 && yv0, y0 * HW + x0 + 1,       w01)
            GATH(xv0 && yv1, (y0 + 1) * HW + x0,     w10)
            GATH(xv1 && yv1, (y0 + 1) * HW + x0 + 1, w11)
#undef GATH
        }
    }
    float4 o = make_float4(a0, a1, a2, a3);
    *reinterpret_cast<float4*>(&outp[(size_t)m * D_MODEL + h * 32 + c]) = o;
}

// ---------------------------------------------------------------------------
// add+LN on pair-stored residual: y = LN((oh+ol) + t)*g + beta -> oh/ol.
// WRITEQ: also q = y + posf -> qh/ql.  WRITEF32: y -> f32out.
// ---------------------------------------------------------------------------
template<int WRITEQ, int WRITEF32>
__global__ __launch_bounds__(64) void add_ln_pair(
    const float* __restrict__ t, const float* __restrict__ g,
    const float* __restrict__ beta,
    u16* __restrict__ oh, u16* __restrict__ ol,
    const float* __restrict__ posf, u16* __restrict__ qh, u16* __restrict__ ql,
    float* __restrict__ f32out)
{
    int row = blockIdx.x;
    int lane = threadIdx.x;
    size_t base = (size_t)row * D_MODEL + lane * 4;
    ushort4 hv = *reinterpret_cast<const ushort4*>(oh + base);
    ushort4 lv = *reinterpret_cast<const ushort4*>(ol + base);
    float4 tv = *reinterpret_cast<const float4*>(t + base);
    float v0 = bf2f(hv.x) + bf2f(lv.x) + tv.x;
    float v1 = bf2f(hv.y) + bf2f(lv.y) + tv.y;
    float v2 = bf2f(hv.z) + bf2f(lv.z) + tv.z;
    float v3 = bf2f(hv.w) + bf2f(lv.w) + tv.w;
    float s = v0 + v1 + v2 + v3;
#pragma unroll
    for (int o = 32; o > 0; o >>= 1) s += __shfl_xor(s, o);
    float mean = s * (1.f / D_MODEL);
    float d0 = v0 - mean, d1 = v1 - mean, d2 = v2 - mean, d3 = v3 - mean;
    float ss = d0 * d0 + d1 * d1 + d2 * d2 + d3 * d3;
#pragma unroll
    for (int o = 32; o > 0; o >>= 1) ss += __shfl_xor(ss, o);
    float rstd = rsqrtf(ss * (1.f / D_MODEL) + 1e-5f);
    float4 gv = *reinterpret_cast<const float4*>(&g[lane * 4]);
    float4 bv = *reinterpret_cast<const float4*>(&beta[lane * 4]);
    float y0 = d0 * rstd * gv.x + bv.x;
    float y1 = d1 * rstd * gv.y + bv.y;
    float y2 = d2 * rstd * gv.z + bv.z;
    float y3 = d3 * rstd * gv.w + bv.w;
    ushort4 nh, nl;
    nh.x = f2bf(y0); nl.x = f2bf(y0 - bf2f(nh.x));
    nh.y = f2bf(y1); nl.y = f2bf(y1 - bf2f(nh.y));
    nh.z = f2bf(y2); nl.z = f2bf(y2 - bf2f(nh.z));
    nh.w = f2bf(y3); nl.w = f2bf(y3 - bf2f(nh.w));
    *reinterpret_cast<ushort4*>(oh + base) = nh;
    *reinterpret_cast<ushort4*>(ol + base) = nl;
    if (WRITEQ) {
        float4 pv = *reinterpret_cast<const float4*>(posf + base);
        float q0 = y0 + pv.x, q1 = y1 + pv.y, q2 = y2 + pv.z, q3 = y3 + pv.w;
        ushort4 qhv, qlv;
        qhv.x = f2bf(q0); qlv.x = f2bf(q0 - bf2f(qhv.x));
        qhv.y = f2bf(q1); qlv.y = f2bf(q1 - bf2f(qhv.y));
        qhv.z = f2bf(q2); qlv.z = f2bf(q2 - bf2f(qhv.z));
        qhv.w = f2bf(q3); qlv.w = f2bf(q3 - bf2f(qhv.w));
        *reinterpret_cast<ushort4*>(qh + base) = qhv;
        *reinterpret_cast<ushort4*>(ql + base) = qlv;
    }
    if (WRITEF32) {
        *reinterpret_cast<float4*>(f32out + base) = make_float4(y0, y1, y2, y3);
    }
}

// old add_ln (fallback): in-place fp32
__global__ __launch_bounds__(64) void add_ln(
    const float* __restrict__ t, const float* __restrict__ g,
    const float* __restrict__ beta, float* __restrict__ x)
{
    int row = blockIdx.x;
    int lane = threadIdx.x;
    size_t base = (size_t)row * D_MODEL + lane * 4;
    float4 xv = *reinterpret_cast<const float4*>(&x[base]);
    float4 tv = *reinterpret_cast<const float4*>(&t[base]);
    float v0 = xv.x + tv.x, v1 = xv.y + tv.y, v2 = xv.z + tv.z, v3 = xv.w + tv.w;
    float s = v0 + v1 + v2 + v3;
#pragma unroll
    for (int o = 32; o > 0; o >>= 1) s += __shfl_xor(s, o);
    float mean = s * (1.f / D_MODEL);
    float d0 = v0 - mean, d1 = v1 - mean, d2 = v2 - mean, d3 = v3 - mean;
    float ss = d0 * d0 + d1 * d1 + d2 * d2 + d3 * d3;
#pragma unroll
    for (int o = 32; o > 0; o >>= 1) ss += __shfl_xor(ss, o);
    float rstd = rsqrtf(ss * (1.f / D_MODEL) + 1e-5f);
    float4 gv = *reinterpret_cast<const float4*>(&g[lane * 4]);
    float4 bv = *reinterpret_cast<const float4*>(&beta[lane * 4]);
    float4 ov = make_float4(d0 * rstd * gv.x + bv.x, d1 * rstd * gv.y + bv.y,
                            d2 * rstd * gv.z + bv.z, d3 * rstd * gv.w + bv.w);
    *reinterpret_cast<float4*>(&x[base]) = ov;
}

// ---------------------------------------------------------------------------
extern "C" void kernel_launch(void* const* d_in, const int* in_sizes, int n_in,
                              void* d_out, int out_size, void* d_ws, size_t ws_size,
                              hipStream_t stream)
{
    // dict order is INTERLEAVED: src0,pos0,src1,pos1,...
    const float* src[4] = {(const float*)d_in[0], (const float*)d_in[2],
                           (const float*)d_in[4], (const float*)d_in[6]};
    const float* pos[4] = {(const float*)d_in[1], (const float*)d_in[3],
                           (const float*)d_in[5], (const float*)d_in[7]};
    const float* lvl   = (const float*)d_in[8];
    const float* W_off = (const float*)d_in[9];
    const float* b_off = (const float*)d_in[10];
    const float* W_att = (const float*)d_in[11];
    const float* b_att = (const float*)d_in[12];
    const float* W_val = (const float*)d_in[13];
    const float* b_val = (const float*)d_in[14];
    const float* W_out = (const float*)d_in[15];
    const float* b_out = (const float*)d_in[16];
    const float* ln1g  = (const float*)d_in[17];
    const float* ln1b  = (const float*)d_in[18];
    const float* W_ff1 = (const float*)d_in[19];
    const float* b_ff1 = (const float*)d_in[20];
    const float* W_ff2 = (const float*)d_in[21];
    const float* b_ff2 = (const float*)d_in[22];
    const float* ln2g  = (const float*)d_in[23];
    const float* ln2b  = (const float*)d_in[24];

    float* ws = (float*)d_ws;
    const size_t MD = (size_t)MTOT * D_MODEL;    // 5,570,560

    const int hws[4]  = {4096, 1024, 256, 64};
    const int qoff[4] = {0, 4096, 5120, 5376};

    // ---- NEW path layout ----
    float* posf = ws;                                    // fp32 [M,256]
    u16* oh = (u16*)(ws + MD);
    u16* ol = oh + MD;
    u16* qh = ol + MD;                                   // Q region (q|e)
    u16* ql = qh + MD;
    u16* eh = qh; u16* el = ql;
    float* val    = (float*)(ql + MD);                   // fp32 [M,256]; ffout
    float* ffout  = val;
    float* offlog = val + MD;                            // fp32 [M,384]; tmp/hid
    float* tmp    = offlog;
    u16* hid_h = (u16*)offlog;
    u16* hid_l = hid_h + (size_t)63 * 128 * 1024;
    u16* wb = (u16*)(offlog + (size_t)MTOT * 384);
    size_t o = 0;
    u16* wv_h = wb + o; o += 6 * 65536;  u16* wv_l = wb + o; o += 6 * 65536;
    u16* wc_h = wb + o; o += 6 * 98304;  u16* wc_l = wb + o; o += 6 * 98304;
    u16* wu_h = wb + o; o += 6 * 65536;  u16* wu_l = wb + o; o += 6 * 65536;
    u16* wf1_h = wb + o; o += 6 * 262144; u16* wf1_l = wb + o; o += 6 * 262144;
    u16* wf2_h = wb + o; o += 6 * 262144; u16* wf2_l = wb + o; o += 6 * 262144;
    const size_t NEED = (size_t)((char*)(wb + o) - (char*)ws);   // ~140.6 MB

    if (ws_size >= NEED) {
        dim3 cb(32, 8);
        for (int l = 0; l < 4; ++l) {
            dim3 g(hws[l] / 32, D_MODEL / 32, BATCH);
            flatten_tr<<<g, cb, 0, stream>>>(pos[l], lvl + l * D_MODEL, posf, hws[l], qoff[l]);
            flatten_src_pair<<<g, cb, 0, stream>>>(src[l], posf, oh, ol, qh, ql, hws[l], qoff[l]);
        }
        wconv<<<dim3(8, 8, 6),  cb, 0, stream>>>(W_val, wv_h, wv_l, 256, 256, 65536);
        wconv<<<dim3(8, 8, 6),  cb, 0, stream>>>(W_off, wc_h, wc_l, 256, 256, 98304);
        wconv<<<dim3(4, 8, 6),  cb, 0, stream>>>(W_att, wc_h + 65536, wc_l + 65536, 256, 128, 98304);
        wconv<<<dim3(8, 8, 6),  cb, 0, stream>>>(W_out, wu_h, wu_l, 256, 256, 65536);
        wconv<<<dim3(32, 8, 6), cb, 0, stream>>>(W_ff1, wf1_h, wf1_l, 256, 1024, 262144);
        wconv<<<dim3(8, 32, 6), cb, 0, stream>>>(W_ff2, wf2_h, wf2_l, 1024, 256, 262144);

        for (int i = 0; i < NLAYER; ++i) {
            gemm_pre<0><<<dim3(2, 170), 256, 0, stream>>>(
                oh, ol, wv_h + i * 65536, wv_l + i * 65536,
                b_val + i * 256, b_val + i * 256, 256, val, nullptr, nullptr, 256, 256);
            gemm_pre<0><<<dim3(3, 170), 256, 0, stream>>>(
                qh, ql, wc_h + i * 98304, wc_l + i * 98304,
                b_off + i * 256, b_att + i * 128, 256, offlog, nullptr, nullptr, 384, 256);
            msda2n<<<MTOT / 4, 256, 0, stream>>>(val, offlog, eh, el);
            gemm_pre<0><<<dim3(2, 170), 256, 0, stream>>>(
                eh, el, wu_h + i * 65536, wu_l + i * 65536,
                b_out + i * 256, b_out + i * 256, 256, tmp, nullptr, nullptr, 256, 256);
            add_ln_pair<0, 0><<<MTOT, 64, 0, stream>>>(
                tmp, ln1g + i * 256, ln1b + i * 256, oh, ol,
                nullptr, nullptr, nullptr, nullptr);
            const int nbs[3] = {63, 63, 44};
            int rb = 0;
            for (int c = 0; c < 3; ++c) {
                size_t r0 = (size_t)rb * 128 * 256;
                gemm_pre<1><<<dim3(8, nbs[c]), 256, 0, stream>>>(
                    oh + r0, ol + r0, wf1_h + i * 262144, wf1_l + i * 262144,
                    b_ff1 + i * 1024, b_ff1 + i * 1024, 1024,
                    nullptr, hid_h, hid_l, 1024, 256);
                gemm_pre<0><<<dim3(2, nbs[c]), 256, 0, stream>>>(
                    hid_h, hid_l, wf2_h + i * 262144, wf2_l + i * 262144,
                    b_ff2 + i * 256, b_ff2 + i * 256, 256,
                    ffout + r0, nullptr, nullptr, 256, 1024);
                rb += nbs[c];
            }
            if (i < NLAYER - 1)
                add_ln_pair<1, 0><<<MTOT, 64, 0, stream>>>(
                    ffout, ln2g + i * 256, ln2b + i * 256, oh, ol,
                    posf, qh, ql, nullptr);
            else
                add_ln_pair<0, 1><<<MTOT, 64, 0, stream>>>(
                    ffout, ln2g + i * 256, ln2b + i * 256, oh, ol,
                    nullptr, nullptr, nullptr, (float*)d_out);
        }
    } else {
        // ---- FALLBACK: round-3 proven path (~118.4 MB) ----
        float* out = (float*)d_out;
        float* posf2  = ws;
        float* val2   = posf2 + MD;
        float* logits = val2 + MD;
        float* offb   = logits + (size_t)MTOT * 128;
        float* ebuf   = offb + MD;
        float* tmp2   = offb;
        float* hid2   = offb;
        short* wbase = (short*)(ebuf + MD);
        short* v_h = wbase;               short* v_l = v_h + 6 * 65536;
        short* o_h = v_l + 6 * 65536;     short* o_l = o_h + 6 * 65536;
        short* a_h = o_l + 6 * 65536;     short* a_l = a_h + 6 * 32768;
        short* u_h = a_l + 6 * 32768;     short* u_l = u_h + 6 * 65536;
        short* f1h = u_l + 6 * 65536;     short* f1l = f1h + 6 * 262144;
        short* f2h = f1l + 6 * 262144;    short* f2l = f2h + 6 * 262144;
        dim3 cb(32, 8);
        for (int l = 0; l < 4; ++l) {
            dim3 g(hws[l] / 32, D_MODEL / 32, BATCH);
            flatten_tr<<<g, cb, 0, stream>>>(src[l], nullptr, out, hws[l], qoff[l]);
            flatten_tr<<<g, cb, 0, stream>>>(pos[l], lvl + l * D_MODEL, posf2, hws[l], qoff[l]);
        }
        wconv<<<dim3(8, 8, 6),  cb, 0, stream>>>(W_val, (u16*)v_h, (u16*)v_l, 256, 256, 65536);
        wconv<<<dim3(8, 8, 6),  cb, 0, stream>>>(W_off, (u16*)o_h, (u16*)o_l, 256, 256, 65536);
        wconv<<<dim3(4, 8, 6),  cb, 0, stream>>>(W_att, (u16*)a_h, (u16*)a_l, 256, 128, 32768);
        wconv<<<dim3(8, 8, 6),  cb, 0, stream>>>(W_out, (u16*)u_h, (u16*)u_l, 256, 256, 65536);
        wconv<<<dim3(32, 8, 6), cb, 0, stream>>>(W_ff1, (u16*)f1h, (u16*)f1l, 256, 1024, 262144);
        wconv<<<dim3(8, 32, 6), cb, 0, stream>>>(W_ff2, (u16*)f2h, (u16*)f2l, 1024, 256, 262144);
        for (int i = 0; i < NLAYER; ++i) {
            gemm_mfma<0,0><<<dim3(4, 170), 256, 0, stream>>>(
                out, nullptr, v_h + i * 65536, v_l + i * 65536,
                b_val + i * 256, val2, 256, 256);
            gemm_mfma<0,1><<<dim3(4, 170), 256, 0, stream>>>(
                out, posf2, o_h + i * 65536, o_l + i * 65536,
                b_off + i * 256, offb, 256, 256);
            gemm_mfma<0,1><<<dim3(2, 170), 256, 0, stream>>>(
                out, posf2, a_h + i * 32768, a_l + i * 32768,
                b_att + i * 128, logits, 128, 256);
            msda2<<<MTOT / 4, 256, 0, stream>>>(val2, offb, logits, ebuf);
            gemm_mfma<0,0><<<dim3(4, 170), 256, 0, stream>>>(
                ebuf, nullptr, u_h + i * 65536, u_l + i * 65536,
                b_out + i * 256, tmp2, 256, 256);
            add_ln<<<MTOT, 64, 0, stream>>>(tmp2, ln1g + i * 256, ln1b + i * 256, out);
            for (int h = 0; h < 2; ++h) {
                gemm_mfma<1,0><<<dim3(16, 85), 256, 0, stream>>>(
                    out + (size_t)h * MHALF * 256, nullptr,
                    f1h + i * 262144, f1l + i * 262144,
                    b_ff1 + i * 1024, hid2, 1024, 256);
                gemm_mfma<0,0><<<dim3(4, 85), 256, 0, stream>>>(
                    hid2, nullptr, f2h + i * 262144, f2l + i * 262144,
                    b_ff2 + i * 256, val2 + (size_t)h * MHALF * 256, 256, 1024);
            }
            add_ln<<<MTOT, 64, 0, stream>>>(val2, ln2g + i * 256, ln2b + i * 256, out);
        }
    }
    (void)in_sizes; (void)n_in; (void)out_size;
}

// Round 7
// 1750.647 us; speedup vs baseline: 2.9465x; 1.0277x over previous
//
#include <hip/hip_runtime.h>
#include <cstddef>
#include <cstdint>

#define D_MODEL 256
#define NHEAD   8
#define NLAYER  6
#define BATCH   4
#define QTOT    5440
#define MTOT    (BATCH*QTOT)   // 21760 = 170*128
#define MHALF   (MTOT/2)
#define DFFN    1024

typedef short  bf16x8 __attribute__((ext_vector_type(8)));
typedef float  f32x4  __attribute__((ext_vector_type(4)));
typedef unsigned short u16;

typedef __attribute__((address_space(1))) const void g_as1;
typedef __attribute__((address_space(3))) void l_as3;

__device__ __forceinline__ u16 f2bf(float f) {
    uint32_t u = __float_as_uint(f);
    return (u16)((u + 0x7fffu + ((u >> 16) & 1u)) >> 16);
}
__device__ __forceinline__ float bf2f(u16 s) {
    return __uint_as_float(((uint32_t)s) << 16);
}

// ---------------------------------------------------------------------------
// Flatten + transpose (fp32): src [B,D,HW] -> dst [B,Q,D], optional emb add.
// ---------------------------------------------------------------------------
__global__ __launch_bounds__(256) void flatten_tr(
    const float* __restrict__ src, const float* __restrict__ emb,
    float* __restrict__ dst, int HW, int qoff)
{
    __shared__ float tile[32][33];
    int tx = threadIdx.x, ty = threadIdx.y;
    int hw0 = blockIdx.x * 32, d0 = blockIdx.y * 32, b = blockIdx.z;
    const float* s = src + (size_t)b * D_MODEL * HW;
#pragma unroll
    for (int j = 0; j < 4; ++j)
        tile[ty + j * 8][tx] = s[(size_t)(d0 + ty + j * 8) * HW + hw0 + tx];
    __syncthreads();
#pragma unroll
    for (int j = 0; j < 4; ++j) {
        int hw = ty + j * 8;
        float v = tile[tx][hw];
        if (emb) v += emb[d0 + tx];
        dst[((size_t)b * QTOT + qoff + hw0 + hw) * D_MODEL + d0 + tx] = v;
    }
}

// ---------------------------------------------------------------------------
// Flatten src -> out bf16 pair + q=(src+posf) bf16 pair.
// ---------------------------------------------------------------------------
__global__ __launch_bounds__(256) void flatten_src_pair(
    const float* __restrict__ src, const float* __restrict__ posf,
    u16* __restrict__ oh, u16* __restrict__ ol,
    u16* __restrict__ qh, u16* __restrict__ ql, int HW, int qoff)
{
    __shared__ float tile[32][33];
    int tx = threadIdx.x, ty = threadIdx.y;
    int hw0 = blockIdx.x * 32, d0 = blockIdx.y * 32, b = blockIdx.z;
    const float* s = src + (size_t)b * D_MODEL * HW;
#pragma unroll
    for (int j = 0; j < 4; ++j)
        tile[ty + j * 8][tx] = s[(size_t)(d0 + ty + j * 8) * HW + hw0 + tx];
    __syncthreads();
#pragma unroll
    for (int j = 0; j < 4; ++j) {
        int hw = ty + j * 8;
        float v = tile[tx][hw];
        size_t idx = ((size_t)b * QTOT + qoff + hw0 + hw) * D_MODEL + d0 + tx;
        u16 h = f2bf(v);
        oh[idx] = h; ol[idx] = f2bf(v - bf2f(h));
        float q = v + posf[idx];
        u16 qhv = f2bf(q);
        qh[idx] = qhv; ql[idx] = f2bf(q - bf2f(qhv));
    }
}

// ---------------------------------------------------------------------------
// Weight convert+transpose: W fp32 [L][K][N] -> hi/lo bf16 [L(lstride)][N][K]
// ---------------------------------------------------------------------------
__global__ __launch_bounds__(256) void wconv(
    const float* __restrict__ W, u16* __restrict__ Whi,
    u16* __restrict__ Wlo, int K, int N, int lstride)
{
    __shared__ float t[32][33];
    int tx = threadIdx.x, ty = threadIdx.y;
    int n0 = blockIdx.x * 32, k0 = blockIdx.y * 32, l = blockIdx.z;
    const float* Wl = W + (size_t)l * K * N;
    u16* Hl = Whi + (size_t)l * lstride;
    u16* Ll = Wlo + (size_t)l * lstride;
#pragma unroll
    for (int j = 0; j < 4; ++j)
        t[ty + j * 8][tx] = Wl[(size_t)(k0 + ty + j * 8) * N + n0 + tx];
    __syncthreads();
#pragma unroll
    for (int j = 0; j < 4; ++j) {
        float v = t[tx][ty + j * 8];
        int n = n0 + ty + j * 8, k = k0 + tx;
        u16 h = f2bf(v);
        Hl[(size_t)n * K + k] = h;
        Ll[(size_t)n * K + k] = f2bf(v - bf2f(h));
    }
}

// ---------------------------------------------------------------------------
// Shared GEMM body: BM=128 BN=128 BK=32, global_load_lds staging, 3-pass.
// ---------------------------------------------------------------------------
#define GEMM_BODY(AH, AL, BH, BL, KDIM, BIAS_EXPR, STORE_STMT)                 \
    __shared__ __align__(16) short lds[2 * 16384];                             \
    int tid  = threadIdx.x;                                                    \
    int lane = tid & 63, wid = tid >> 6;                                       \
    int wr = wid >> 1, wc = wid & 1;                                           \
    int row0 = blockIdx.y * 128;                                               \
    const u16* gsrc0 = (wid == 0) ? (AH) : (wid == 1) ? (AL)                   \
                     : (wid == 2) ? (BH) : (BL);                               \
    int rbase = (wid < 2) ? row0 : col0;                                       \
    const u16* gsrc = gsrc0 + (size_t)(rbase + (lane >> 2)) * (KDIM)           \
                            + (((lane & 3) ^ ((lane >> 3) & 3)) * 8);          \
    auto issue = [&](int kt, short* buf) {                                     \
        char* lbase = (char*)buf + wid * 8192;                                 \
        const u16* g = gsrc + kt * 32;                                         \
        _Pragma("unroll")                                                      \
        for (int j = 0; j < 8; ++j) {                                          \
            __builtin_amdgcn_global_load_lds(                                  \
                (g_as1*)(g + (size_t)j * 16 * (KDIM)),                         \
                (l_as3*)(lbase + j * 1024), 16, 0, 0);                         \
        }                                                                      \
    };                                                                         \
    f32x4 acc[4][4];                                                           \
    _Pragma("unroll")                                                          \
    for (int i = 0; i < 4; ++i)                                                \
        _Pragma("unroll")                                                      \
        for (int j = 0; j < 4; ++j) acc[i][j] = (f32x4){0.f, 0.f, 0.f, 0.f};   \
    int l15 = lane & 15, l4 = lane >> 4;                                       \
    auto compute = [&](const short* buf) {                                     \
        const char* Ahi = (const char*)buf;                                    \
        const char* Alo = (const char*)(buf + 4096);                           \
        const char* Bhi = (const char*)(buf + 8192);                           \
        const char* Blo = (const char*)(buf + 12288);                          \
        bf16x8 bh[4], bl[4];                                                   \
        _Pragma("unroll")                                                      \
        for (int nc = 0; nc < 4; ++nc) {                                       \
            int col = wc * 64 + nc * 16 + l15;                                 \
            int byt = col * 64 + ((l4 ^ ((col >> 1) & 3)) * 16);               \
            bh[nc] = *(const bf16x8*)(Bhi + byt);                              \
            bl[nc] = *(const bf16x8*)(Blo + byt);                              \
        }                                                                      \
        _Pragma("unroll")                                                      \
        for (int mr = 0; mr < 4; ++mr) {                                       \
            int row = wr * 64 + mr * 16 + l15;                                 \
            int byt = row * 64 + ((l4 ^ ((row >> 1) & 3)) * 16);               \
            bf16x8 ah = *(const bf16x8*)(Ahi + byt);                           \
            bf16x8 al = *(const bf16x8*)(Alo + byt);                           \
            _Pragma("unroll")                                                  \
            for (int nc = 0; nc < 4; ++nc) {                                   \
                acc[mr][nc] = __builtin_amdgcn_mfma_f32_16x16x32_bf16(ah, bh[nc], acc[mr][nc], 0, 0, 0); \
                acc[mr][nc] = __builtin_amdgcn_mfma_f32_16x16x32_bf16(ah, bl[nc], acc[mr][nc], 0, 0, 0); \
                acc[mr][nc] = __builtin_amdgcn_mfma_f32_16x16x32_bf16(al, bh[nc], acc[mr][nc], 0, 0, 0); \
            }                                                                  \
        }                                                                      \
    };                                                                         \
    int nk = (KDIM) >> 5;                                                      \
    issue(0, lds);                                                             \
    __syncthreads();                                                           \
    for (int kt = 0; kt < nk; ++kt) {                                          \
        short* cur = lds + (kt & 1) * 16384;                                   \
        short* nxt = lds + ((kt & 1) ^ 1) * 16384;                             \
        if (kt + 1 < nk) issue(kt + 1, nxt);                                   \
        compute(cur);                                                          \
        __syncthreads();                                                       \
    }                                                                          \
    _Pragma("unroll")                                                          \
    for (int nc = 0; nc < 4; ++nc) {                                           \
        int col = col0 + wc * 64 + nc * 16 + l15;                              \
        float bv = (BIAS_EXPR);                                                \
        _Pragma("unroll")                                                      \
        for (int mr = 0; mr < 4; ++mr) {                                       \
            int row = row0 + wr * 64 + mr * 16 + l4 * 4;                       \
            _Pragma("unroll")                                                  \
            for (int r = 0; r < 4; ++r) {                                      \
                float v = acc[mr][nc][r] + bv;                                 \
                size_t idx = (size_t)(row + r) * N + col;                      \
                STORE_STMT;                                                    \
            }                                                                  \
        }                                                                      \
    }

// GEMM: CMODE 0 fp32 C, CMODE 1 bf16 pair C + ReLU.
template<int CMODE>
__global__ __launch_bounds__(256) void gemm_pre(
    const u16* __restrict__ Ah, const u16* __restrict__ Al,
    const u16* __restrict__ Bh, const u16* __restrict__ Bl,
    const float* __restrict__ bias, const float* __restrict__ bias2, int nsplit,
    float* __restrict__ Cf, u16* __restrict__ Ch, u16* __restrict__ Cl,
    int N, int K)
{
    int col0 = blockIdx.x * 128;
    GEMM_BODY(Ah, Al, Bh, Bl, K,
        (col < nsplit) ? bias[col] : bias2[col - nsplit],
        {
            if (CMODE == 0) { Cf[idx] = v; }
            else {
                v = fmaxf(v, 0.f);
                u16 h = f2bf(v);
                Ch[idx] = h;
                Cl[idx] = f2bf(v - bf2f(h));
            }
        })
}

// Fused val + offlog GEMM: bx<2 -> val = oh@Wv; bx>=2 -> offlog = qh@Wc.
__global__ __launch_bounds__(256) void gemm_vo(
    const u16* __restrict__ oh, const u16* __restrict__ ol,
    const u16* __restrict__ qh, const u16* __restrict__ ql,
    const u16* __restrict__ wvh, const u16* __restrict__ wvl,
    const u16* __restrict__ wch, const u16* __restrict__ wcl,
    const float* __restrict__ b_val, const float* __restrict__ b_off,
    const float* __restrict__ b_att,
    float* __restrict__ val, float* __restrict__ offlog)
{
    int bx = blockIdx.x;
    bool isv = bx < 2;
    const u16* Ah = isv ? oh : qh;
    const u16* Al = isv ? ol : ql;
    const u16* Bh = isv ? wvh : wch;
    const u16* Bl = isv ? wvl : wcl;
    float* Cf = isv ? val : offlog;
    int N = isv ? 256 : 384;
    int col0 = isv ? bx * 128 : (bx - 2) * 128;
    GEMM_BODY(Ah, Al, Bh, Bl, 256,
        isv ? b_val[col] : (col < 256 ? b_off[col] : b_att[col - 256]),
        { Cf[idx] = v; })
}

// ---------------------------------------------------------------------------
// OLD MFMA GEMM (fallback path, in-kernel fp32->bf16 split staging)
// ---------------------------------------------------------------------------
template<int RELU, int HASA2>
__global__ __launch_bounds__(256) void gemm_mfma(
    const float* __restrict__ A, const float* __restrict__ A2,
    const short* __restrict__ Whi, const short* __restrict__ Wlo,
    const float* __restrict__ bias, float* __restrict__ C, int N, int K)
{
    __shared__ __align__(16) short lds[2 * 12288];
    int tid  = threadIdx.x;
    int lane = tid & 63, wid = tid >> 6;
    int wr = wid >> 1, wc = wid & 1;
    int row0 = blockIdx.y * 128, col0 = blockIdx.x * 64;
    int srow = tid >> 1, shalf = tid & 1;
    int brow = tid >> 2, bseg = tid & 3;
    const float* Arow  = A + (size_t)(row0 + srow) * K + shalf * 16;
    const float* A2row = HASA2 ? A2 + (size_t)(row0 + srow) * K + shalf * 16 : nullptr;
    const short* Whirow = Whi + (size_t)(col0 + brow) * K + bseg * 8;
    const short* Wlorow = Wlo + (size_t)(col0 + brow) * K + bseg * 8;
    int aswz = (srow >> 1) & 3;
    int a_wb0 = srow * 64 + ((2 * shalf + 0) ^ aswz) * 16;
    int a_wb1 = srow * 64 + ((2 * shalf + 1) ^ aswz) * 16;
    int b_wb  = brow * 64 + ((bseg ^ ((brow >> 1) & 3)) * 16);
    f32x4 acc[4][2];
#pragma unroll
    for (int i = 0; i < 4; ++i)
#pragma unroll
        for (int j = 0; j < 2; ++j) acc[i][j] = (f32x4){0.f, 0.f, 0.f, 0.f};
    float av[16];
    uint4 bhv, blv;
    auto load_stage = [&](int kt) {
        const float4* ap = reinterpret_cast<const float4*>(Arow + kt * 32);
#pragma unroll
        for (int i = 0; i < 4; ++i) {
            float4 v = ap[i];
            av[4 * i + 0] = v.x; av[4 * i + 1] = v.y;
            av[4 * i + 2] = v.z; av[4 * i + 3] = v.w;
        }
        if (HASA2) {
            const float4* a2p = reinterpret_cast<const float4*>(A2row + kt * 32);
#pragma unroll
            for (int i = 0; i < 4; ++i) {
                float4 v = a2p[i];
                av[4 * i + 0] += v.x; av[4 * i + 1] += v.y;
                av[4 * i + 2] += v.z; av[4 * i + 3] += v.w;
            }
        }
        bhv = *reinterpret_cast<const uint4*>(Whirow + kt * 32);
        blv = *reinterpret_cast<const uint4*>(Wlorow + kt * 32);
    };
    auto write_stage = [&](short* buf) {
        unsigned int hw[8], lw[8];
#pragma unroll
        for (int i = 0; i < 8; ++i) {
            u16 h0 = f2bf(av[2 * i]), h1 = f2bf(av[2 * i + 1]);
            u16 l0 = f2bf(av[2 * i] - bf2f(h0));
            u16 l1 = f2bf(av[2 * i + 1] - bf2f(h1));
            hw[i] = (unsigned int)h0 | ((unsigned int)h1 << 16);
            lw[i] = (unsigned int)l0 | ((unsigned int)l1 << 16);
        }
        char* Ahi = (char*)buf;
        char* Alo = (char*)(buf + 4096);
        *(uint4*)(Ahi + a_wb0) = make_uint4(hw[0], hw[1], hw[2], hw[3]);
        *(uint4*)(Ahi + a_wb1) = make_uint4(hw[4], hw[5], hw[6], hw[7]);
        *(uint4*)(Alo + a_wb0) = make_uint4(lw[0], lw[1], lw[2], lw[3]);
        *(uint4*)(Alo + a_wb1) = make_uint4(lw[4], lw[5], lw[6], lw[7]);
        *(uint4*)((char*)(buf + 8192)  + b_wb) = bhv;
        *(uint4*)((char*)(buf + 10240) + b_wb) = blv;
    };
    int l15 = lane & 15, l4 = lane >> 4;
    auto compute = [&](const short* buf) {
        const char* Ahi = (const char*)buf;
        const char* Alo = (const char*)(buf + 4096);
        const char* Bhi = (const char*)(buf + 8192);
        const char* Blo = (const char*)(buf + 10240);
        bf16x8 bh[2], bl[2];
#pragma unroll
        for (int nc = 0; nc < 2; ++nc) {
            int col = wc * 32 + nc * 16 + l15;
            int byt = col * 64 + ((l4 ^ ((col >> 1) & 3)) * 16);
            bh[nc] = *(const bf16x8*)(Bhi + byt);
            bl[nc] = *(const bf16x8*)(Blo + byt);
        }
#pragma unroll
        for (int mr = 0; mr < 4; ++mr) {
            int row = wr * 64 + mr * 16 + l15;
            int byt = row * 64 + ((l4 ^ ((row >> 1) & 3)) * 16);
            bf16x8 ah = *(const bf16x8*)(Ahi + byt);
            bf16x8 al = *(const bf16x8*)(Alo + byt);
#pragma unroll
            for (int nc = 0; nc < 2; ++nc) {
                acc[mr][nc] = __builtin_amdgcn_mfma_f32_16x16x32_bf16(ah, bh[nc], acc[mr][nc], 0, 0, 0);
                acc[mr][nc] = __builtin_amdgcn_mfma_f32_16x16x32_bf16(ah, bl[nc], acc[mr][nc], 0, 0, 0);
                acc[mr][nc] = __builtin_amdgcn_mfma_f32_16x16x32_bf16(al, bh[nc], acc[mr][nc], 0, 0, 0);
            }
        }
    };
    int nk = K >> 5;
    load_stage(0);
    write_stage(lds);
    __syncthreads();
    for (int kt = 0; kt < nk; ++kt) {
        short* cur = lds + (kt & 1) * 12288;
        short* nxt = lds + ((kt & 1) ^ 1) * 12288;
        if (kt + 1 < nk) load_stage(kt + 1);
        compute(cur);
        if (kt + 1 < nk) write_stage(nxt);
        __syncthreads();
    }
#pragma unroll
    for (int nc = 0; nc < 2; ++nc) {
        int col = col0 + wc * 32 + nc * 16 + l15;
        float bv = bias[col];
#pragma unroll
        for (int mr = 0; mr < 4; ++mr) {
            int row = row0 + wr * 64 + mr * 16 + l4 * 4;
#pragma unroll
            for (int r = 0; r < 4; ++r) {
                float v = acc[mr][nc][r] + bv;
                if (RELU) v = fmaxf(v, 0.f);
                C[(size_t)(row + r) * N + col] = v;
            }
        }
    }
}

// ---------------------------------------------------------------------------
// MSDA v3: LDS-shared weight precompute (dedup 8x geometry/softmax), then
// gather-only phase. One block = 4 queries (one wave each).
// ---------------------------------------------------------------------------
__global__ __launch_bounds__(256) void msda3(
    const float* __restrict__ value, const float* __restrict__ offlog,
    u16* __restrict__ eh, u16* __restrict__ el)
{
    __shared__ float aw_lds[32][16];                 // 2 KB
    __shared__ __align__(16) float wts[32 * 17 * 4]; // 8.5 KB, [qh][17] f4
    __shared__ __align__(16) int   idxs[32 * 17 * 4];// 8.5 KB

    int tid = threadIdx.x;
    int m0 = blockIdx.x * 4;

    // step A: softmax for 32 (q,h) pairs
    if (tid < 32) {
        int m = m0 + (tid >> 3);
        const float* lg = offlog + (size_t)m * 384 + 256 + (tid & 7) * 16;
        float w[16]; float mx = -1e30f;
#pragma unroll
        for (int i = 0; i < 4; ++i) {
            float4 v = reinterpret_cast<const float4*>(lg)[i];
            w[4 * i] = v.x; w[4 * i + 1] = v.y; w[4 * i + 2] = v.z; w[4 * i + 3] = v.w;
        }
#pragma unroll
        for (int j = 0; j < 16; ++j) mx = fmaxf(mx, w[j]);
        float s = 0.f;
#pragma unroll
        for (int j = 0; j < 16; ++j) { w[j] = __expf(w[j] - mx); s += w[j]; }
        float rs = 1.f / s;
#pragma unroll
        for (int j = 0; j < 16; ++j) aw_lds[tid][j] = w[j] * rs;
    }
    __syncthreads();

    // step B: 512 points, 2 per thread -> weights + byte offsets to LDS
#pragma unroll
    for (int pp = 0; pp < 2; ++pp) {
        int pi = tid * 2 + pp;
        int qi = pi >> 7, rem = pi & 127;
        int h = rem >> 4, j = rem & 15;
        int l = j >> 2;
        int m = m0 + qi;
        int b = m / QTOT, q = m - b * QTOT;
        int lq = (q < 4096) ? 0 : (q < 5120) ? 1 : (q < 5376) ? 2 : 3;
        int qbase = (lq == 0) ? 0 : (lq == 1) ? 4096 : (lq == 2) ? 5120 : 5376;
        int qrem = q - qbase;
        int shq = 6 - lq;
        int Wq = 1 << shq;
        int yq = qrem >> shq, xq = qrem & (Wq - 1);
        float invq = 1.0f / (float)Wq;       // pow2: exact
        float ref_x = (xq + 0.5f) * invq;
        float ref_y = (yq + 0.5f) * invq;
        int HW = 64 >> l;
        float fHW = (float)HW;
        float invl = 1.0f / fHW;             // pow2: exact
        int loff = (l == 0) ? 0 : (l == 1) ? 4096 : (l == 2) ? 5120 : 5376;
        float ox = offlog[(size_t)m * 384 + h * 32 + j * 2 + 0];
        float oy = offlog[(size_t)m * 384 + h * 32 + j * 2 + 1];
        float aw = aw_lds[qi * 8 + h][j];
        float x = (ref_x + ox * invl) * fHW - 0.5f;
        float y = (ref_y + oy * invl) * fHW - 0.5f;
        float x0f = floorf(x), y0f = floorf(y);
        int x0 = (int)x0f, y0 = (int)y0f;
        float wx = x - x0f, wy = y - y0f;
        float vx0 = (x0 >= 0 && x0 < HW) ? 1.f : 0.f;
        float vx1 = (x0 + 1 >= 0 && x0 + 1 < HW) ? 1.f : 0.f;
        float vy0 = (y0 >= 0 && y0 < HW) ? 1.f : 0.f;
        float vy1 = (y0 + 1 >= 0 && y0 + 1 < HW) ? 1.f : 0.f;
        float w00 = (1.f - wx) * (1.f - wy) * aw * vx0 * vy0;
        float w01 = wx * (1.f - wy) * aw * vx1 * vy0;
        float w10 = (1.f - wx) * wy * aw * vx0 * vy1;
        float w11 = wx * wy * aw * vx1 * vy1;
        int xc0 = min(max(x0, 0), HW - 1);
        int xc1 = min(max(x0 + 1, 0), HW - 1);
        int yc0 = min(max(y0, 0), HW - 1);
        int yc1 = min(max(y0 + 1, 0), HW - 1);
        int rbase = b * QTOT + loff;
        int i00 = (rbase + yc0 * HW + xc0) << 10;   // row * 1024 bytes
        int i01 = (rbase + yc0 * HW + xc1) << 10;
        int i10 = (rbase + yc1 * HW + xc0) << 10;
        int i11 = (rbase + yc1 * HW + xc1) << 10;
        int sl = (qi * 8 + h) * 17 + j;
        reinterpret_cast<float4*>(wts)[sl] = make_float4(w00, w01, w10, w11);
        reinterpret_cast<int4*>(idxs)[sl] = make_int4(i00, i01, i10, i11);
    }
    __syncthreads();

    // phase 2: gather + FMA only
    int lane = tid & 63;
    int qi = tid >> 6, h = lane >> 3, c8 = lane & 7;
    int m = m0 + qi;
    const char* vb = (const char*)value + h * 128 + c8 * 16;
    float a0 = 0.f, a1 = 0.f, a2 = 0.f, a3 = 0.f;
#pragma unroll
    for (int j = 0; j < 16; ++j) {
        int sl = (qi * 8 + h) * 17 + j;
        float4 w = reinterpret_cast<const float4*>(wts)[sl];
        int4  ix = reinterpret_cast<const int4*>(idxs)[sl];
        float4 v00 = *reinterpret_cast<const float4*>(vb + ix.x);
        float4 v01 = *reinterpret_cast<const float4*>(vb + ix.y);
        float4 v10 = *reinterpret_cast<const float4*>(vb + ix.z);
        float4 v11 = *reinterpret_cast<const float4*>(vb + ix.w);
        a0 += w.x * v00.x + w.y * v01.x + w.z * v10.x + w.w * v11.x;
        a1 += w.x * v00.y + w.y * v01.y + w.z * v10.y + w.w * v11.y;
        a2 += w.x * v00.z + w.y * v01.z + w.z * v10.z + w.w * v11.z;
        a3 += w.x * v00.w + w.y * v01.w + w.z * v10.w + w.w * v11.w;
    }
    size_t oidx = (size_t)m * D_MODEL + h * 32 + c8 * 4;
    ushort4 hv, lv;
    hv.x = f2bf(a0); lv.x = f2bf(a0 - bf2f(hv.x));
    hv.y = f2bf(a1); lv.y = f2bf(a1 - bf2f(hv.y));
    hv.z = f2bf(a2); lv.z = f2bf(a2 - bf2f(hv.z));
    hv.w = f2bf(a3); lv.w = f2bf(a3 - bf2f(hv.w));
    *reinterpret_cast<ushort4*>(eh + oidx) = hv;
    *reinterpret_cast<ushort4*>(el + oidx) = lv;
}

// msda (old, fallback): separate off/logits, fp32 out
__global__ __launch_bounds__(256) void msda2(
    const float* __restrict__ value, const float* __restrict__ off,
    const float* __restrict__ logits, float* __restrict__ outp)
{
    const int lvl_off[4] = {0, 4096, 5120, 5376};
    const int lvl_hw[4]  = {64, 32, 16, 8};
    int m = blockIdx.x * 4 + (threadIdx.x >> 6);
    int lane = threadIdx.x & 63;
    int h = lane >> 3, c = (lane & 7) * 4;
    int b = m / QTOT, q = m - b * QTOT;
    int lq, rem;
    if      (q < 4096) { lq = 0; rem = q; }
    else if (q < 5120) { lq = 1; rem = q - 4096; }
    else if (q < 5376) { lq = 2; rem = q - 5120; }
    else               { lq = 3; rem = q - 5376; }
    int Wq = lvl_hw[lq];
    int yq = rem / Wq, xq = rem - yq * Wq;
    float ref_x = (xq + 0.5f) / (float)Wq;
    float ref_y = (yq + 0.5f) / (float)Wq;
    const float* lg = logits + (size_t)m * 128 + h * 16;
    float w[16];
    {
        float mx = -1e30f;
#pragma unroll
        for (int i = 0; i < 4; ++i) {
            float4 v = reinterpret_cast<const float4*>(lg)[i];
            w[4 * i] = v.x; w[4 * i + 1] = v.y; w[4 * i + 2] = v.z; w[4 * i + 3] = v.w;
        }
#pragma unroll
        for (int j = 0; j < 16; ++j) mx = fmaxf(mx, w[j]);
        float s = 0.f;
#pragma unroll
        for (int j = 0; j < 16; ++j) { w[j] = __expf(w[j] - mx); s += w[j]; }
        float rs = 1.f / s;
#pragma unroll
        for (int j = 0; j < 16; ++j) w[j] *= rs;
    }
    float ofv[32];
    const float* op = off + (size_t)m * 256 + h * 32;
#pragma unroll
    for (int i = 0; i < 8; ++i) {
        float4 v = reinterpret_cast<const float4*>(op)[i];
        ofv[4 * i] = v.x; ofv[4 * i + 1] = v.y; ofv[4 * i + 2] = v.z; ofv[4 * i + 3] = v.w;
    }
    float a0 = 0.f, a1 = 0.f, a2 = 0.f, a3 = 0.f;
#pragma unroll
    for (int l = 0; l < 4; ++l) {
        int HW = lvl_hw[l];
        float fHW = (float)HW;
        const float* vbase =
            value + ((size_t)(b * QTOT + lvl_off[l])) * D_MODEL + h * 32 + c;
#pragma unroll
        for (int p = 0; p < 4; ++p) {
            float ox = ofv[(l * 4 + p) * 2 + 0];
            float oy = ofv[(l * 4 + p) * 2 + 1];
            float aw = w[l * 4 + p];
            float x = (ref_x + ox / fHW) * fHW - 0.5f;
            float y = (ref_y + oy / fHW) * fHW - 0.5f;
            float x0f = floorf(x), y0f = floorf(y);
            int   x0 = (int)x0f,  y0 = (int)y0f;
            float wx = x - x0f,   wy = y - y0f;
            float w00 = (1.f - wx) * (1.f - wy) * aw, w01 = wx * (1.f - wy) * aw;
            float w10 = (1.f - wx) * wy * aw,         w11 = wx * wy * aw;
            bool xv0 = (x0 >= 0) && (x0 < HW);
            bool xv1 = (x0 + 1 >= 0) && (x0 + 1 < HW);
            bool yv0 = (y0 >= 0) && (y0 < HW);
            bool yv1 = (y0 + 1 >= 0) && (y0 + 1 < HW);
#define GATH(cond, idx, wgt)                                                  \
            if (cond) {                                                       \
                float4 v = *reinterpret_cast<const float4*>(                  \
                    vbase + (size_t)(idx) * D_MODEL);                         \
                a0 += (wgt) * v.x; a1 += (wgt) * v.y;                         \
                a2 += (wgt) * v.z; a3 += (wgt) * v.w;                         \
            }
            GATH(xv0 && yv0, y0 * HW + x0,           w00)
            GATH(xv1 && yv0, y0 * HW + x0 + 1,       w01)
            GATH(xv0 && yv1, (y0 + 1) * HW + x0,     w10)
            GATH(xv1 && yv1, (y0 + 1) * HW + x0 + 1, w11)
#undef GATH
        }
    }
    float4 o = make_float4(a0, a1, a2, a3);
    *reinterpret_cast<float4*>(&outp[(size_t)m * D_MODEL + h * 32 + c]) = o;
}

// ---------------------------------------------------------------------------
// add+LN on pair-stored residual (v2: 4 rows/block, wave per row).
// WRITEQ: also q = y + posf -> qh/ql.  WRITEF32: y -> f32out.
// ---------------------------------------------------------------------------
template<int WRITEQ, int WRITEF32>
__global__ __launch_bounds__(256) void add_ln_pair(
    const float* __restrict__ t, const float* __restrict__ g,
    const float* __restrict__ beta,
    u16* __restrict__ oh, u16* __restrict__ ol,
    const float* __restrict__ posf, u16* __restrict__ qh, u16* __restrict__ ql,
    float* __restrict__ f32out)
{
    int row = blockIdx.x * 4 + (threadIdx.x >> 6);
    int lane = threadIdx.x & 63;
    size_t base = (size_t)row * D_MODEL + lane * 4;
    ushort4 hv = *reinterpret_cast<const ushort4*>(oh + base);
    ushort4 lv = *reinterpret_cast<const ushort4*>(ol + base);
    float4 tv = *reinterpret_cast<const float4*>(t + base);
    float v0 = bf2f(hv.x) + bf2f(lv.x) + tv.x;
    float v1 = bf2f(hv.y) + bf2f(lv.y) + tv.y;
    float v2 = bf2f(hv.z) + bf2f(lv.z) + tv.z;
    float v3 = bf2f(hv.w) + bf2f(lv.w) + tv.w;
    float s = v0 + v1 + v2 + v3;
#pragma unroll
    for (int o = 32; o > 0; o >>= 1) s += __shfl_xor(s, o);
    float mean = s * (1.f / D_MODEL);
    float d0 = v0 - mean, d1 = v1 - mean, d2 = v2 - mean, d3 = v3 - mean;
    float ss = d0 * d0 + d1 * d1 + d2 * d2 + d3 * d3;
#pragma unroll
    for (int o = 32; o > 0; o >>= 1) ss += __shfl_xor(ss, o);
    float rstd = rsqrtf(ss * (1.f / D_MODEL) + 1e-5f);
    float4 gv = *reinterpret_cast<const float4*>(&g[lane * 4]);
    float4 bv = *reinterpret_cast<const float4*>(&beta[lane * 4]);
    float y0 = d0 * rstd * gv.x + bv.x;
    float y1 = d1 * rstd * gv.y + bv.y;
    float y2 = d2 * rstd * gv.z + bv.z;
    float y3 = d3 * rstd * gv.w + bv.w;
    ushort4 nh, nl;
    nh.x = f2bf(y0); nl.x = f2bf(y0 - bf2f(nh.x));
    nh.y = f2bf(y1); nl.y = f2bf(y1 - bf2f(nh.y));
    nh.z = f2bf(y2); nl.z = f2bf(y2 - bf2f(nh.z));
    nh.w = f2bf(y3); nl.w = f2bf(y3 - bf2f(nh.w));
    *reinterpret_cast<ushort4*>(oh + base) = nh;
    *reinterpret_cast<ushort4*>(ol + base) = nl;
    if (WRITEQ) {
        float4 pv = *reinterpret_cast<const float4*>(posf + base);
        float q0 = y0 + pv.x, q1 = y1 + pv.y, q2 = y2 + pv.z, q3 = y3 + pv.w;
        ushort4 qhv, qlv;
        qhv.x = f2bf(q0); qlv.x = f2bf(q0 - bf2f(qhv.x));
        qhv.y = f2bf(q1); qlv.y = f2bf(q1 - bf2f(qhv.y));
        qhv.z = f2bf(q2); qlv.z = f2bf(q2 - bf2f(qhv.z));
        qhv.w = f2bf(q3); qlv.w = f2bf(q3 - bf2f(qhv.w));
        *reinterpret_cast<ushort4*>(qh + base) = qhv;
        *reinterpret_cast<ushort4*>(ql + base) = qlv;
    }
    if (WRITEF32) {
        *reinterpret_cast<float4*>(f32out + base) = make_float4(y0, y1, y2, y3);
    }
}

// old add_ln (fallback): in-place fp32
__global__ __launch_bounds__(64) void add_ln(
    const float* __restrict__ t, const float* __restrict__ g,
    const float* __restrict__ beta, float* __restrict__ x)
{
    int row = blockIdx.x;
    int lane = threadIdx.x;
    size_t base = (size_t)row * D_MODEL + lane * 4;
    float4 xv = *reinterpret_cast<const float4*>(&x[base]);
    float4 tv = *reinterpret_cast<const float4*>(&t[base]);
    float v0 = xv.x + tv.x, v1 = xv.y + tv.y, v2 = xv.z + tv.z, v3 = xv.w + tv.w;
    float s = v0 + v1 + v2 + v3;
#pragma unroll
    for (int o = 32; o > 0; o >>= 1) s += __shfl_xor(s, o);
    float mean = s * (1.f / D_MODEL);
    float d0 = v0 - mean, d1 = v1 - mean, d2 = v2 - mean, d3 = v3 - mean;
    float ss = d0 * d0 + d1 * d1 + d2 * d2 + d3 * d3;
#pragma unroll
    for (int o = 32; o > 0; o >>= 1) ss += __shfl_xor(ss, o);
    float rstd = rsqrtf(ss * (1.f / D_MODEL) + 1e-5f);
    float4 gv = *reinterpret_cast<const float4*>(&g[lane * 4]);
    float4 bv = *reinterpret_cast<const float4*>(&beta[lane * 4]);
    float4 ov = make_float4(d0 * rstd * gv.x + bv.x, d1 * rstd * gv.y + bv.y,
                            d2 * rstd * gv.z + bv.z, d3 * rstd * gv.w + bv.w);
    *reinterpret_cast<float4*>(&x[base]) = ov;
}

// ---------------------------------------------------------------------------
extern "C" void kernel_launch(void* const* d_in, const int* in_sizes, int n_in,
                              void* d_out, int out_size, void* d_ws, size_t ws_size,
                              hipStream_t stream)
{
    // dict order is INTERLEAVED: src0,pos0,src1,pos1,...
    const float* src[4] = {(const float*)d_in[0], (const float*)d_in[2],
                           (const float*)d_in[4], (const float*)d_in[6]};
    const float* pos[4] = {(const float*)d_in[1], (const float*)d_in[3],
                           (const float*)d_in[5], (const float*)d_in[7]};
    const float* lvl   = (const float*)d_in[8];
    const float* W_off = (const float*)d_in[9];
    const float* b_off = (const float*)d_in[10];
    const float* W_att = (const float*)d_in[11];
    const float* b_att = (const float*)d_in[12];
    const float* W_val = (const float*)d_in[13];
    const float* b_val = (const float*)d_in[14];
    const float* W_out = (const float*)d_in[15];
    const float* b_out = (const float*)d_in[16];
    const float* ln1g  = (const float*)d_in[17];
    const float* ln1b  = (const float*)d_in[18];
    const float* W_ff1 = (const float*)d_in[19];
    const float* b_ff1 = (const float*)d_in[20];
    const float* W_ff2 = (const float*)d_in[21];
    const float* b_ff2 = (const float*)d_in[22];
    const float* ln2g  = (const float*)d_in[23];
    const float* ln2b  = (const float*)d_in[24];

    float* ws = (float*)d_ws;
    const size_t MD = (size_t)MTOT * D_MODEL;    // 5,570,560

    const int hws[4]  = {4096, 1024, 256, 64};
    const int qoff[4] = {0, 4096, 5120, 5376};

    // ---- NEW path layout ----
    float* posf = ws;                                    // fp32 [M,256]
    u16* oh = (u16*)(ws + MD);
    u16* ol = oh + MD;
    u16* qh = ol + MD;                                   // Q region (q|e)
    u16* ql = qh + MD;
    u16* eh = qh; u16* el = ql;
    float* val    = (float*)(ql + MD);                   // fp32 [M,256]; ffout
    float* ffout  = val;
    float* offlog = val + MD;                            // fp32 [M,384]; tmp/hid
    float* tmp    = offlog;
    u16* hid_h = (u16*)offlog;
    u16* hid_l = hid_h + (size_t)63 * 128 * 1024;
    u16* wb = (u16*)(offlog + (size_t)MTOT * 384);
    size_t o = 0;
    u16* wv_h = wb + o; o += 6 * 65536;  u16* wv_l = wb + o; o += 6 * 65536;
    u16* wc_h = wb + o; o += 6 * 98304;  u16* wc_l = wb + o; o += 6 * 98304;
    u16* wu_h = wb + o; o += 6 * 65536;  u16* wu_l = wb + o; o += 6 * 65536;
    u16* wf1_h = wb + o; o += 6 * 262144; u16* wf1_l = wb + o; o += 6 * 262144;
    u16* wf2_h = wb + o; o += 6 * 262144; u16* wf2_l = wb + o; o += 6 * 262144;
    const size_t NEED = (size_t)((char*)(wb + o) - (char*)ws);   // ~140.6 MB

    if (ws_size >= NEED) {
        dim3 cb(32, 8);
        for (int l = 0; l < 4; ++l) {
            dim3 g(hws[l] / 32, D_MODEL / 32, BATCH);
            flatten_tr<<<g, cb, 0, stream>>>(pos[l], lvl + l * D_MODEL, posf, hws[l], qoff[l]);
            flatten_src_pair<<<g, cb, 0, stream>>>(src[l], posf, oh, ol, qh, ql, hws[l], qoff[l]);
        }
        wconv<<<dim3(8, 8, 6),  cb, 0, stream>>>(W_val, wv_h, wv_l, 256, 256, 65536);
        wconv<<<dim3(8, 8, 6),  cb, 0, stream>>>(W_off, wc_h, wc_l, 256, 256, 98304);
        wconv<<<dim3(4, 8, 6),  cb, 0, stream>>>(W_att, wc_h + 65536, wc_l + 65536, 256, 128, 98304);
        wconv<<<dim3(8, 8, 6),  cb, 0, stream>>>(W_out, wu_h, wu_l, 256, 256, 65536);
        wconv<<<dim3(32, 8, 6), cb, 0, stream>>>(W_ff1, wf1_h, wf1_l, 256, 1024, 262144);
        wconv<<<dim3(8, 32, 6), cb, 0, stream>>>(W_ff2, wf2_h, wf2_l, 1024, 256, 262144);

        for (int i = 0; i < NLAYER; ++i) {
            // fused: val = oh@Wv ; offlog = qh@[Woff|Watt]
            gemm_vo<<<dim3(5, 170), 256, 0, stream>>>(
                oh, ol, qh, ql,
                wv_h + i * 65536, wv_l + i * 65536,
                wc_h + i * 98304, wc_l + i * 98304,
                b_val + i * 256, b_off + i * 256, b_att + i * 128,
                val, offlog);
            msda3<<<MTOT / 4, 256, 0, stream>>>(val, offlog, eh, el);
            gemm_pre<0><<<dim3(2, 170), 256, 0, stream>>>(
                eh, el, wu_h + i * 65536, wu_l + i * 65536,
                b_out + i * 256, b_out + i * 256, 256, tmp, nullptr, nullptr, 256, 256);
            add_ln_pair<0, 0><<<MTOT / 4, 256, 0, stream>>>(
                tmp, ln1g + i * 256, ln1b + i * 256, oh, ol,
                nullptr, nullptr, nullptr, nullptr);
            const int nbs[3] = {63, 63, 44};
            int rb = 0;
            for (int c = 0; c < 3; ++c) {
                size_t r0 = (size_t)rb * 128 * 256;
                gemm_pre<1><<<dim3(8, nbs[c]), 256, 0, stream>>>(
                    oh + r0, ol + r0, wf1_h + i * 262144, wf1_l + i * 262144,
                    b_ff1 + i * 1024, b_ff1 + i * 1024, 1024,
                    nullptr, hid_h, hid_l, 1024, 256);
                gemm_pre<0><<<dim3(2, nbs[c]), 256, 0, stream>>>(
                    hid_h, hid_l, wf2_h + i * 262144, wf2_l + i * 262144,
                    b_ff2 + i * 256, b_ff2 + i * 256, 256,
                    ffout + r0, nullptr, nullptr, 256, 1024);
                rb += nbs[c];
            }
            if (i < NLAYER - 1)
                add_ln_pair<1, 0><<<MTOT / 4, 256, 0, stream>>>(
                    ffout, ln2g + i * 256, ln2b + i * 256, oh, ol,
                    posf, qh, ql, nullptr);
            else
                add_ln_pair<0, 1><<<MTOT / 4, 256, 0, stream>>>(
                    ffout, ln2g + i * 256, ln2b + i * 256, oh, ol,
                    nullptr, nullptr, nullptr, (float*)d_out);
        }
    } else {
        // ---- FALLBACK: round-3 proven path (~118.4 MB) ----
        float* out = (float*)d_out;
        float* posf2  = ws;
        float* val2   = posf2 + MD;
        float* logits = val2 + MD;
        float* offb   = logits + (size_t)MTOT * 128;
        float* ebuf   = offb + MD;
        float* tmp2   = offb;
        float* hid2   = offb;
        short* wbase = (short*)(ebuf + MD);
        short* v_h = wbase;               short* v_l = v_h + 6 * 65536;
        short* o_h = v_l + 6 * 65536;     short* o_l = o_h + 6 * 65536;
        short* a_h = o_l + 6 * 65536;     short* a_l = a_h + 6 * 32768;
        short* u_h = a_l + 6 * 32768;     short* u_l = u_h + 6 * 65536;
        short* f1h = u_l + 6 * 65536;     short* f1l = f1h + 6 * 262144;
        short* f2h = f1l + 6 * 262144;    short* f2l = f2h + 6 * 262144;
        dim3 cb(32, 8);
        for (int l = 0; l < 4; ++l) {
            dim3 g(hws[l] / 32, D_MODEL / 32, BATCH);
            flatten_tr<<<g, cb, 0, stream>>>(src[l], nullptr, out, hws[l], qoff[l]);
            flatten_tr<<<g, cb, 0, stream>>>(pos[l], lvl + l * D_MODEL, posf2, hws[l], qoff[l]);
        }
        wconv<<<dim3(8, 8, 6),  cb, 0, stream>>>(W_val, (u16*)v_h, (u16*)v_l, 256, 256, 65536);
        wconv<<<dim3(8, 8, 6),  cb, 0, stream>>>(W_off, (u16*)o_h, (u16*)o_l, 256, 256, 65536);
        wconv<<<dim3(4, 8, 6),  cb, 0, stream>>>(W_att, (u16*)a_h, (u16*)a_l, 256, 128, 32768);
        wconv<<<dim3(8, 8, 6),  cb, 0, stream>>>(W_out, (u16*)u_h, (u16*)u_l, 256, 256, 65536);
        wconv<<<dim3(32, 8, 6), cb, 0, stream>>>(W_ff1, (u16*)f1h, (u16*)f1l, 256, 1024, 262144);
        wconv<<<dim3(8, 32, 6), cb, 0, stream>>>(W_ff2, (u16*)f2h, (u16*)f2l, 1024, 256, 262144);
        for (int i = 0; i < NLAYER; ++i) {
            gemm_mfma<0,0><<<dim3(4, 170), 256, 0, stream>>>(
                out, nullptr, v_h + i * 65536, v_l + i * 65536,
                b_val + i * 256, val2, 256, 256);
            gemm_mfma<0,1><<<dim3(4, 170), 256, 0, stream>>>(
                out, posf2, o_h + i * 65536, o_l + i * 65536,
                b_off + i * 256, offb, 256, 256);
            gemm_mfma<0,1><<<dim3(2, 170), 256, 0, stream>>>(
                out, posf2, a_h + i * 32768, a_l + i * 32768,
                b_att + i * 128, logits, 128, 256);
            msda2<<<MTOT / 4, 256, 0, stream>>>(val2, offb, logits, ebuf);
            gemm_mfma<0,0><<<dim3(4, 170), 256, 0, stream>>>(
                ebuf, nullptr, u_h + i * 65536, u_l + i * 65536,
                b_out + i * 256, tmp2, 256, 256);
            add_ln<<<MTOT, 64, 0, stream>>>(tmp2, ln1g + i * 256, ln1b + i * 256, out);
            for (int h = 0; h < 2; ++h) {
                gemm_mfma<1,0><<<dim3(16, 85), 256, 0, stream>>>(
                    out + (size_t)h * MHALF * 256, nullptr,
                    f1h + i * 262144, f1l + i * 262144,
                    b_ff1 + i * 1024, hid2, 1024, 256);
                gemm_mfma<0,0><<<dim3(4, 85), 256, 0, stream>>>(
                    hid2, nullptr, f2h + i * 262144, f2l + i * 262144,
                    b_ff2 + i * 256, val2 + (size_t)h * MHALF * 256, 256, 1024);
            }
            add_ln<<<MTOT, 64, 0, stream>>>(val2, ln2g + i * 256, ln2b + i * 256, out);
        }
    }
    (void)in_sizes; (void)n_in; (void)out_size;
}

// Round 8
// 1719.600 us; speedup vs baseline: 2.9997x; 1.0181x over previous
//
#include <hip/hip_runtime.h>
#include <cstddef>
#include <cstdint>

#define D_MODEL 256
#define NHEAD   8
#define NLAYER  6
#define BATCH   4
#define QTOT    5440
#define MTOT    (BATCH*QTOT)   // 21760 = 170*128
#define MHALF   (MTOT/2)       // 10880 = 85*128
#define DFFN    1024

typedef short  bf16x8 __attribute__((ext_vector_type(8)));
typedef float  f32x4  __attribute__((ext_vector_type(4)));
typedef unsigned short u16;

typedef __attribute__((address_space(1))) const void g_as1;
typedef __attribute__((address_space(3))) void l_as3;

__device__ __forceinline__ u16 f2bf(float f) {
    uint32_t u = __float_as_uint(f);
    return (u16)((u + 0x7fffu + ((u >> 16) & 1u)) >> 16);
}
__device__ __forceinline__ float bf2f(u16 s) {
    return __uint_as_float(((uint32_t)s) << 16);
}

// ---------------------------------------------------------------------------
// Flatten + transpose (fp32): src [B,D,HW] -> dst [B,Q,D], optional emb add.
// ---------------------------------------------------------------------------
__global__ __launch_bounds__(256) void flatten_tr(
    const float* __restrict__ src, const float* __restrict__ emb,
    float* __restrict__ dst, int HW, int qoff)
{
    __shared__ float tile[32][33];
    int tx = threadIdx.x, ty = threadIdx.y;
    int hw0 = blockIdx.x * 32, d0 = blockIdx.y * 32, b = blockIdx.z;
    const float* s = src + (size_t)b * D_MODEL * HW;
#pragma unroll
    for (int j = 0; j < 4; ++j)
        tile[ty + j * 8][tx] = s[(size_t)(d0 + ty + j * 8) * HW + hw0 + tx];
    __syncthreads();
#pragma unroll
    for (int j = 0; j < 4; ++j) {
        int hw = ty + j * 8;
        float v = tile[tx][hw];
        if (emb) v += emb[d0 + tx];
        dst[((size_t)b * QTOT + qoff + hw0 + hw) * D_MODEL + d0 + tx] = v;
    }
}

// ---------------------------------------------------------------------------
// Flatten src -> out bf16 pair + q=(src+posf) bf16 pair.
// ---------------------------------------------------------------------------
__global__ __launch_bounds__(256) void flatten_src_pair(
    const float* __restrict__ src, const float* __restrict__ posf,
    u16* __restrict__ oh, u16* __restrict__ ol,
    u16* __restrict__ qh, u16* __restrict__ ql, int HW, int qoff)
{
    __shared__ float tile[32][33];
    int tx = threadIdx.x, ty = threadIdx.y;
    int hw0 = blockIdx.x * 32, d0 = blockIdx.y * 32, b = blockIdx.z;
    const float* s = src + (size_t)b * D_MODEL * HW;
#pragma unroll
    for (int j = 0; j < 4; ++j)
        tile[ty + j * 8][tx] = s[(size_t)(d0 + ty + j * 8) * HW + hw0 + tx];
    __syncthreads();
#pragma unroll
    for (int j = 0; j < 4; ++j) {
        int hw = ty + j * 8;
        float v = tile[tx][hw];
        size_t idx = ((size_t)b * QTOT + qoff + hw0 + hw) * D_MODEL + d0 + tx;
        u16 h = f2bf(v);
        oh[idx] = h; ol[idx] = f2bf(v - bf2f(h));
        float q = v + posf[idx];
        u16 qhv = f2bf(q);
        qh[idx] = qhv; ql[idx] = f2bf(q - bf2f(qhv));
    }
}

// ---------------------------------------------------------------------------
// Weight convert+transpose: W fp32 [L][K][N] -> hi/lo bf16 [L(lstride)][N][K]
// ---------------------------------------------------------------------------
__global__ __launch_bounds__(256) void wconv(
    const float* __restrict__ W, u16* __restrict__ Whi,
    u16* __restrict__ Wlo, int K, int N, int lstride)
{
    __shared__ float t[32][33];
    int tx = threadIdx.x, ty = threadIdx.y;
    int n0 = blockIdx.x * 32, k0 = blockIdx.y * 32, l = blockIdx.z;
    const float* Wl = W + (size_t)l * K * N;
    u16* Hl = Whi + (size_t)l * lstride;
    u16* Ll = Wlo + (size_t)l * lstride;
#pragma unroll
    for (int j = 0; j < 4; ++j)
        t[ty + j * 8][tx] = Wl[(size_t)(k0 + ty + j * 8) * N + n0 + tx];
    __syncthreads();
#pragma unroll
    for (int j = 0; j < 4; ++j) {
        float v = t[tx][ty + j * 8];
        int n = n0 + ty + j * 8, k = k0 + tx;
        u16 h = f2bf(v);
        Hl[(size_t)n * K + k] = h;
        Ll[(size_t)n * K + k] = f2bf(v - bf2f(h));
    }
}

// ---------------------------------------------------------------------------
// Shared GEMM body v2: BM=128 BN=128 BK=32.
// LDS (48 KB dbuf): Ahi | Bhi | Blo via global_load_lds (3 of 4 waves stage).
// A-lo: direct per-lane global loads in MFMA fragment layout, prefetched
// one K-step ahead in registers (used only in the al*bh pass).
// ---------------------------------------------------------------------------
#define GEMM_BODY(AH, AL, BH, BL, KDIM, BIAS_EXPR, STORE_STMT)                 \
    __shared__ __align__(16) short lds[2 * 12288];  /* 2 x 24 KB */            \
    int tid  = threadIdx.x;                                                    \
    int lane = tid & 63, wid = tid >> 6;                                       \
    int wr = wid >> 1, wc = wid & 1;                                           \
    int row0 = blockIdx.y * 128;                                               \
    const u16* gsrc0 = (wid == 0) ? (AH) : (wid == 1) ? (BH) : (BL);           \
    int rbase = (wid == 0) ? row0 : col0;                                      \
    const u16* gsrc = gsrc0 + (size_t)(rbase + (lane >> 2)) * (KDIM)           \
                            + (((lane & 3) ^ ((lane >> 3) & 3)) * 8);          \
    auto issue = [&](int kt, short* buf) {                                     \
        if (wid < 3) {                                                         \
            char* lbase = (char*)buf + wid * 8192;                             \
            const u16* g = gsrc + kt * 32;                                     \
            _Pragma("unroll")                                                  \
            for (int j = 0; j < 8; ++j) {                                      \
                __builtin_amdgcn_global_load_lds(                              \
                    (g_as1*)(g + (size_t)j * 16 * (KDIM)),                     \
                    (l_as3*)(lbase + j * 1024), 16, 0, 0);                     \
            }                                                                  \
        }                                                                      \
    };                                                                         \
    int l15 = lane & 15, l4 = lane >> 4;                                       \
    const u16* alp0 = (AL) + (size_t)(row0 + wr * 64 + l15) * (KDIM) + l4 * 8; \
    const u16* alp1 = alp0 + (size_t)16 * (KDIM);                              \
    const u16* alp2 = alp0 + (size_t)32 * (KDIM);                              \
    const u16* alp3 = alp0 + (size_t)48 * (KDIM);                              \
    f32x4 acc[4][4];                                                           \
    _Pragma("unroll")                                                          \
    for (int i = 0; i < 4; ++i)                                                \
        _Pragma("unroll")                                                      \
        for (int j = 0; j < 4; ++j) acc[i][j] = (f32x4){0.f, 0.f, 0.f, 0.f};   \
    auto compute = [&](const short* buf,                                       \
                       bf16x8 al0, bf16x8 al1, bf16x8 al2, bf16x8 al3) {       \
        const char* Ahi = (const char*)buf;                                    \
        const char* Bhi = (const char*)(buf + 4096);                           \
        const char* Blo = (const char*)(buf + 8192);                           \
        bf16x8 bh[4], bl[4];                                                   \
        _Pragma("unroll")                                                      \
        for (int nc = 0; nc < 4; ++nc) {                                       \
            int col = wc * 64 + nc * 16 + l15;                                 \
            int byt = col * 64 + ((l4 ^ ((col >> 1) & 3)) * 16);               \
            bh[nc] = *(const bf16x8*)(Bhi + byt);                              \
            bl[nc] = *(const bf16x8*)(Blo + byt);                              \
        }                                                                      \
        _Pragma("unroll")                                                      \
        for (int mr = 0; mr < 4; ++mr) {                                       \
            int row = wr * 64 + mr * 16 + l15;                                 \
            int byt = row * 64 + ((l4 ^ ((row >> 1) & 3)) * 16);               \
            bf16x8 ah = *(const bf16x8*)(Ahi + byt);                           \
            bf16x8 al = (mr == 0) ? al0 : (mr == 1) ? al1                      \
                       : (mr == 2) ? al2 : al3;                                \
            _Pragma("unroll")                                                  \
            for (int nc = 0; nc < 4; ++nc) {                                   \
                acc[mr][nc] = __builtin_amdgcn_mfma_f32_16x16x32_bf16(ah, bh[nc], acc[mr][nc], 0, 0, 0); \
                acc[mr][nc] = __builtin_amdgcn_mfma_f32_16x16x32_bf16(ah, bl[nc], acc[mr][nc], 0, 0, 0); \
                acc[mr][nc] = __builtin_amdgcn_mfma_f32_16x16x32_bf16(al, bh[nc], acc[mr][nc], 0, 0, 0); \
            }                                                                  \
        }                                                                      \
    };                                                                         \
    int nk = (KDIM) >> 5;                                                      \
    short* lds0 = lds;                                                         \
    short* lds1 = lds + 12288;                                                 \
    bf16x8 a0A, a1A, a2A, a3A, a0B, a1B, a2B, a3B;                             \
    issue(0, lds0);                                                            \
    a0A = *(const bf16x8*)(alp0); a1A = *(const bf16x8*)(alp1);                \
    a2A = *(const bf16x8*)(alp2); a3A = *(const bf16x8*)(alp3);                \
    __syncthreads();                                                           \
    for (int kt = 0; kt < nk; kt += 2) {                                       \
        if (kt + 1 < nk) {                                                     \
            issue(kt + 1, lds1);                                               \
            const int o1 = (kt + 1) * 32;                                      \
            a0B = *(const bf16x8*)(alp0 + o1); a1B = *(const bf16x8*)(alp1 + o1); \
            a2B = *(const bf16x8*)(alp2 + o1); a3B = *(const bf16x8*)(alp3 + o1); \
        }                                                                      \
        compute(lds0, a0A, a1A, a2A, a3A);                                     \
        __syncthreads();                                                       \
        if (kt + 1 < nk) {                                                     \
            if (kt + 2 < nk) {                                                 \
                issue(kt + 2, lds0);                                           \
                const int o2 = (kt + 2) * 32;                                  \
                a0A = *(const bf16x8*)(alp0 + o2); a1A = *(const bf16x8*)(alp1 + o2); \
                a2A = *(const bf16x8*)(alp2 + o2); a3A = *(const bf16x8*)(alp3 + o2); \
            }                                                                  \
            compute(lds1, a0B, a1B, a2B, a3B);                                 \
            __syncthreads();                                                   \
        }                                                                      \
    }                                                                          \
    _Pragma("unroll")                                                          \
    for (int nc = 0; nc < 4; ++nc) {                                           \
        int col = col0 + wc * 64 + nc * 16 + l15;                              \
        float bv = (BIAS_EXPR);                                                \
        _Pragma("unroll")                                                      \
        for (int mr = 0; mr < 4; ++mr) {                                       \
            int row = row0 + wr * 64 + mr * 16 + l4 * 4;                       \
            _Pragma("unroll")                                                  \
            for (int r = 0; r < 4; ++r) {                                      \
                float v = acc[mr][nc][r] + bv;                                 \
                size_t idx = (size_t)(row + r) * N + col;                      \
                STORE_STMT;                                                    \
            }                                                                  \
        }                                                                      \
    }

// GEMM: CMODE 0 fp32 C; CMODE 1 bf16 pair + ReLU; CMODE 2 bf16 pair no ReLU.
template<int CMODE>
__global__ __launch_bounds__(256, 3) void gemm_pre(
    const u16* __restrict__ Ah, const u16* __restrict__ Al,
    const u16* __restrict__ Bh, const u16* __restrict__ Bl,
    const float* __restrict__ bias, const float* __restrict__ bias2, int nsplit,
    float* __restrict__ Cf, u16* __restrict__ Ch, u16* __restrict__ Cl,
    int N, int K)
{
    int col0 = blockIdx.x * 128;
    GEMM_BODY(Ah, Al, Bh, Bl, K,
        (col < nsplit) ? bias[col] : bias2[col - nsplit],
        {
            if (CMODE == 0) { Cf[idx] = v; }
            else {
                if (CMODE == 1) v = fmaxf(v, 0.f);
                u16 h = f2bf(v);
                Ch[idx] = h;
                Cl[idx] = f2bf(v - bf2f(h));
            }
        })
}

// Fused val + offlog GEMM: bx<2 -> val = oh@Wv; bx>=2 -> offlog = qh@Wc.
__global__ __launch_bounds__(256, 3) void gemm_vo(
    const u16* __restrict__ oh, const u16* __restrict__ ol,
    const u16* __restrict__ qh, const u16* __restrict__ ql,
    const u16* __restrict__ wvh, const u16* __restrict__ wvl,
    const u16* __restrict__ wch, const u16* __restrict__ wcl,
    const float* __restrict__ b_val, const float* __restrict__ b_off,
    const float* __restrict__ b_att,
    float* __restrict__ val, float* __restrict__ offlog)
{
    int bx = blockIdx.x;
    bool isv = bx < 2;
    const u16* Ah = isv ? oh : qh;
    const u16* Al = isv ? ol : ql;
    const u16* Bh = isv ? wvh : wch;
    const u16* Bl = isv ? wvl : wcl;
    float* Cf = isv ? val : offlog;
    int N = isv ? 256 : 384;
    int col0 = isv ? bx * 128 : (bx - 2) * 128;
    GEMM_BODY(Ah, Al, Bh, Bl, 256,
        isv ? b_val[col] : (col < 256 ? b_off[col] : b_att[col - 256]),
        { Cf[idx] = v; })
}

// ---------------------------------------------------------------------------
// OLD MFMA GEMM (fallback path, in-kernel fp32->bf16 split staging)
// ---------------------------------------------------------------------------
template<int RELU, int HASA2>
__global__ __launch_bounds__(256) void gemm_mfma(
    const float* __restrict__ A, const float* __restrict__ A2,
    const short* __restrict__ Whi, const short* __restrict__ Wlo,
    const float* __restrict__ bias, float* __restrict__ C, int N, int K)
{
    __shared__ __align__(16) short lds[2 * 12288];
    int tid  = threadIdx.x;
    int lane = tid & 63, wid = tid >> 6;
    int wr = wid >> 1, wc = wid & 1;
    int row0 = blockIdx.y * 128, col0 = blockIdx.x * 64;
    int srow = tid >> 1, shalf = tid & 1;
    int brow = tid >> 2, bseg = tid & 3;
    const float* Arow  = A + (size_t)(row0 + srow) * K + shalf * 16;
    const float* A2row = HASA2 ? A2 + (size_t)(row0 + srow) * K + shalf * 16 : nullptr;
    const short* Whirow = Whi + (size_t)(col0 + brow) * K + bseg * 8;
    const short* Wlorow = Wlo + (size_t)(col0 + brow) * K + bseg * 8;
    int aswz = (srow >> 1) & 3;
    int a_wb0 = srow * 64 + ((2 * shalf + 0) ^ aswz) * 16;
    int a_wb1 = srow * 64 + ((2 * shalf + 1) ^ aswz) * 16;
    int b_wb  = brow * 64 + ((bseg ^ ((brow >> 1) & 3)) * 16);
    f32x4 acc[4][2];
#pragma unroll
    for (int i = 0; i < 4; ++i)
#pragma unroll
        for (int j = 0; j < 2; ++j) acc[i][j] = (f32x4){0.f, 0.f, 0.f, 0.f};
    float av[16];
    uint4 bhv, blv;
    auto load_stage = [&](int kt) {
        const float4* ap = reinterpret_cast<const float4*>(Arow + kt * 32);
#pragma unroll
        for (int i = 0; i < 4; ++i) {
            float4 v = ap[i];
            av[4 * i + 0] = v.x; av[4 * i + 1] = v.y;
            av[4 * i + 2] = v.z; av[4 * i + 3] = v.w;
        }
        if (HASA2) {
            const float4* a2p = reinterpret_cast<const float4*>(A2row + kt * 32);
#pragma unroll
            for (int i = 0; i < 4; ++i) {
                float4 v = a2p[i];
                av[4 * i + 0] += v.x; av[4 * i + 1] += v.y;
                av[4 * i + 2] += v.z; av[4 * i + 3] += v.w;
            }
        }
        bhv = *reinterpret_cast<const uint4*>(Whirow + kt * 32);
        blv = *reinterpret_cast<const uint4*>(Wlorow + kt * 32);
    };
    auto write_stage = [&](short* buf) {
        unsigned int hw[8], lw[8];
#pragma unroll
        for (int i = 0; i < 8; ++i) {
            u16 h0 = f2bf(av[2 * i]), h1 = f2bf(av[2 * i + 1]);
            u16 l0 = f2bf(av[2 * i] - bf2f(h0));
            u16 l1 = f2bf(av[2 * i + 1] - bf2f(h1));
            hw[i] = (unsigned int)h0 | ((unsigned int)h1 << 16);
            lw[i] = (unsigned int)l0 | ((unsigned int)l1 << 16);
        }
        char* Ahi = (char*)buf;
        char* Alo = (char*)(buf + 4096);
        *(uint4*)(Ahi + a_wb0) = make_uint4(hw[0], hw[1], hw[2], hw[3]);
        *(uint4*)(Ahi + a_wb1) = make_uint4(hw[4], hw[5], hw[6], hw[7]);
        *(uint4*)(Alo + a_wb0) = make_uint4(lw[0], lw[1], lw[2], lw[3]);
        *(uint4*)(Alo + a_wb1) = make_uint4(lw[4], lw[5], lw[6], lw[7]);
        *(uint4*)((char*)(buf + 8192)  + b_wb) = bhv;
        *(uint4*)((char*)(buf + 10240) + b_wb) = blv;
    };
    int l15 = lane & 15, l4 = lane >> 4;
    auto compute = [&](const short* buf) {
        const char* Ahi = (const char*)buf;
        const char* Alo = (const char*)(buf + 4096);
        const char* Bhi = (const char*)(buf + 8192);
        const char* Blo = (const char*)(buf + 10240);
        bf16x8 bh[2], bl[2];
#pragma unroll
        for (int nc = 0; nc < 2; ++nc) {
            int col = wc * 32 + nc * 16 + l15;
            int byt = col * 64 + ((l4 ^ ((col >> 1) & 3)) * 16);
            bh[nc] = *(const bf16x8*)(Bhi + byt);
            bl[nc] = *(const bf16x8*)(Blo + byt);
        }
#pragma unroll
        for (int mr = 0; mr < 4; ++mr) {
            int row = wr * 64 + mr * 16 + l15;
            int byt = row * 64 + ((l4 ^ ((row >> 1) & 3)) * 16);
            bf16x8 ah = *(const bf16x8*)(Ahi + byt);
            bf16x8 al = *(const bf16x8*)(Alo + byt);
#pragma unroll
            for (int nc = 0; nc < 2; ++nc) {
                acc[mr][nc] = __builtin_amdgcn_mfma_f32_16x16x32_bf16(ah, bh[nc], acc[mr][nc], 0, 0, 0);
                acc[mr][nc] = __builtin_amdgcn_mfma_f32_16x16x32_bf16(ah, bl[nc], acc[mr][nc], 0, 0, 0);
                acc[mr][nc] = __builtin_amdgcn_mfma_f32_16x16x32_bf16(al, bh[nc], acc[mr][nc], 0, 0, 0);
            }
        }
    };
    int nk = K >> 5;
    load_stage(0);
    write_stage(lds);
    __syncthreads();
    for (int kt = 0; kt < nk; ++kt) {
        short* cur = lds + (kt & 1) * 12288;
        short* nxt = lds + ((kt & 1) ^ 1) * 12288;
        if (kt + 1 < nk) load_stage(kt + 1);
        compute(cur);
        if (kt + 1 < nk) write_stage(nxt);
        __syncthreads();
    }
#pragma unroll
    for (int nc = 0; nc < 2; ++nc) {
        int col = col0 + wc * 32 + nc * 16 + l15;
        float bv = bias[col];
#pragma unroll
        for (int mr = 0; mr < 4; ++mr) {
            int row = row0 + wr * 64 + mr * 16 + l4 * 4;
#pragma unroll
            for (int r = 0; r < 4; ++r) {
                float v = acc[mr][nc][r] + bv;
                if (RELU) v = fmaxf(v, 0.f);
                C[(size_t)(row + r) * N + col] = v;
            }
        }
    }
}

// ---------------------------------------------------------------------------
// MSDA v3: LDS-shared weight precompute, then gather-only phase.
// ---------------------------------------------------------------------------
__global__ __launch_bounds__(256) void msda3(
    const float* __restrict__ value, const float* __restrict__ offlog,
    u16* __restrict__ eh, u16* __restrict__ el)
{
    __shared__ float aw_lds[32][16];
    __shared__ __align__(16) float wts[32 * 17 * 4];
    __shared__ __align__(16) int   idxs[32 * 17 * 4];

    int tid = threadIdx.x;
    int m0 = blockIdx.x * 4;

    if (tid < 32) {
        int m = m0 + (tid >> 3);
        const float* lg = offlog + (size_t)m * 384 + 256 + (tid & 7) * 16;
        float w[16]; float mx = -1e30f;
#pragma unroll
        for (int i = 0; i < 4; ++i) {
            float4 v = reinterpret_cast<const float4*>(lg)[i];
            w[4 * i] = v.x; w[4 * i + 1] = v.y; w[4 * i + 2] = v.z; w[4 * i + 3] = v.w;
        }
#pragma unroll
        for (int j = 0; j < 16; ++j) mx = fmaxf(mx, w[j]);
        float s = 0.f;
#pragma unroll
        for (int j = 0; j < 16; ++j) { w[j] = __expf(w[j] - mx); s += w[j]; }
        float rs = 1.f / s;
#pragma unroll
        for (int j = 0; j < 16; ++j) aw_lds[tid][j] = w[j] * rs;
    }
    __syncthreads();

#pragma unroll
    for (int pp = 0; pp < 2; ++pp) {
        int pi = tid * 2 + pp;
        int qi = pi >> 7, rem = pi & 127;
        int h = rem >> 4, j = rem & 15;
        int l = j >> 2;
        int m = m0 + qi;
        int b = m / QTOT, q = m - b * QTOT;
        int lq = (q < 4096) ? 0 : (q < 5120) ? 1 : (q < 5376) ? 2 : 3;
        int qbase = (lq == 0) ? 0 : (lq == 1) ? 4096 : (lq == 2) ? 5120 : 5376;
        int qrem = q - qbase;
        int shq = 6 - lq;
        int Wq = 1 << shq;
        int yq = qrem >> shq, xq = qrem & (Wq - 1);
        float invq = 1.0f / (float)Wq;
        float ref_x = (xq + 0.5f) * invq;
        float ref_y = (yq + 0.5f) * invq;
        int HW = 64 >> l;
        float fHW = (float)HW;
        float invl = 1.0f / fHW;
        int loff = (l == 0) ? 0 : (l == 1) ? 4096 : (l == 2) ? 5120 : 5376;
        float ox = offlog[(size_t)m * 384 + h * 32 + j * 2 + 0];
        float oy = offlog[(size_t)m * 384 + h * 32 + j * 2 + 1];
        float aw = aw_lds[qi * 8 + h][j];
        float x = (ref_x + ox * invl) * fHW - 0.5f;
        float y = (ref_y + oy * invl) * fHW - 0.5f;
        float x0f = floorf(x), y0f = floorf(y);
        int x0 = (int)x0f, y0 = (int)y0f;
        float wx = x - x0f, wy = y - y0f;
        float vx0 = (x0 >= 0 && x0 < HW) ? 1.f : 0.f;
        float vx1 = (x0 + 1 >= 0 && x0 + 1 < HW) ? 1.f : 0.f;
        float vy0 = (y0 >= 0 && y0 < HW) ? 1.f : 0.f;
        float vy1 = (y0 + 1 >= 0 && y0 + 1 < HW) ? 1.f : 0.f;
        float w00 = (1.f - wx) * (1.f - wy) * aw * vx0 * vy0;
        float w01 = wx * (1.f - wy) * aw * vx1 * vy0;
        float w10 = (1.f - wx) * wy * aw * vx0 * vy1;
        float w11 = wx * wy * aw * vx1 * vy1;
        int xc0 = min(max(x0, 0), HW - 1);
        int xc1 = min(max(x0 + 1, 0), HW - 1);
        int yc0 = min(max(y0, 0), HW - 1);
        int yc1 = min(max(y0 + 1, 0), HW - 1);
        int rbase = b * QTOT + loff;
        int i00 = (rbase + yc0 * HW + xc0) << 10;
        int i01 = (rbase + yc0 * HW + xc1) << 10;
        int i10 = (rbase + yc1 * HW + xc0) << 10;
        int i11 = (rbase + yc1 * HW + xc1) << 10;
        int sl = (qi * 8 + h) * 17 + j;
        reinterpret_cast<float4*>(wts)[sl] = make_float4(w00, w01, w10, w11);
        reinterpret_cast<int4*>(idxs)[sl] = make_int4(i00, i01, i10, i11);
    }
    __syncthreads();

    int lane = tid & 63;
    int qi = tid >> 6, h = lane >> 3, c8 = lane & 7;
    int m = m0 + qi;
    const char* vb = (const char*)value + h * 128 + c8 * 16;
    float a0 = 0.f, a1 = 0.f, a2 = 0.f, a3 = 0.f;
#pragma unroll
    for (int j = 0; j < 16; ++j) {
        int sl = (qi * 8 + h) * 17 + j;
        float4 w = reinterpret_cast<const float4*>(wts)[sl];
        int4  ix = reinterpret_cast<const int4*>(idxs)[sl];
        float4 v00 = *reinterpret_cast<const float4*>(vb + ix.x);
        float4 v01 = *reinterpret_cast<const float4*>(vb + ix.y);
        float4 v10 = *reinterpret_cast<const float4*>(vb + ix.z);
        float4 v11 = *reinterpret_cast<const float4*>(vb + ix.w);
        a0 += w.x * v00.x + w.y * v01.x + w.z * v10.x + w.w * v11.x;
        a1 += w.x * v00.y + w.y * v01.y + w.z * v10.y + w.w * v11.y;
        a2 += w.x * v00.z + w.y * v01.z + w.z * v10.z + w.w * v11.z;
        a3 += w.x * v00.w + w.y * v01.w + w.z * v10.w + w.w * v11.w;
    }
    size_t oidx = (size_t)m * D_MODEL + h * 32 + c8 * 4;
    ushort4 hv, lv;
    hv.x = f2bf(a0); lv.x = f2bf(a0 - bf2f(hv.x));
    hv.y = f2bf(a1); lv.y = f2bf(a1 - bf2f(hv.y));
    hv.z = f2bf(a2); lv.z = f2bf(a2 - bf2f(hv.z));
    hv.w = f2bf(a3); lv.w = f2bf(a3 - bf2f(hv.w));
    *reinterpret_cast<ushort4*>(eh + oidx) = hv;
    *reinterpret_cast<ushort4*>(el + oidx) = lv;
}

// msda (old, fallback): separate off/logits, fp32 out
__global__ __launch_bounds__(256) void msda2(
    const float* __restrict__ value, const float* __restrict__ off,
    const float* __restrict__ logits, float* __restrict__ outp)
{
    const int lvl_off[4] = {0, 4096, 5120, 5376};
    const int lvl_hw[4]  = {64, 32, 16, 8};
    int m = blockIdx.x * 4 + (threadIdx.x >> 6);
    int lane = threadIdx.x & 63;
    int h = lane >> 3, c = (lane & 7) * 4;
    int b = m / QTOT, q = m - b * QTOT;
    int lq, rem;
    if      (q < 4096) { lq = 0; rem = q; }
    else if (q < 5120) { lq = 1; rem = q - 4096; }
    else if (q < 5376) { lq = 2; rem = q - 5120; }
    else               { lq = 3; rem = q - 5376; }
    int Wq = lvl_hw[lq];
    int yq = rem / Wq, xq = rem - yq * Wq;
    float ref_x = (xq + 0.5f) / (float)Wq;
    float ref_y = (yq + 0.5f) / (float)Wq;
    const float* lg = logits + (size_t)m * 128 + h * 16;
    float w[16];
    {
        float mx = -1e30f;
#pragma unroll
        for (int i = 0; i < 4; ++i) {
            float4 v = reinterpret_cast<const float4*>(lg)[i];
            w[4 * i] = v.x; w[4 * i + 1] = v.y; w[4 * i + 2] = v.z; w[4 * i + 3] = v.w;
        }
#pragma unroll
        for (int j = 0; j < 16; ++j) mx = fmaxf(mx, w[j]);
        float s = 0.f;
#pragma unroll
        for (int j = 0; j < 16; ++j) { w[j] = __expf(w[j] - mx); s += w[j]; }
        float rs = 1.f / s;
#pragma unroll
        for (int j = 0; j < 16; ++j) w[j] *= rs;
    }
    float ofv[32];
    const float* op = off + (size_t)m * 256 + h * 32;
#pragma unroll
    for (int i = 0; i < 8; ++i) {
        float4 v = reinterpret_cast<const float4*>(op)[i];
        ofv[4 * i] = v.x; ofv[4 * i + 1] = v.y; ofv[4 * i + 2] = v.z; ofv[4 * i + 3] = v.w;
    }
    float a0 = 0.f, a1 = 0.f, a2 = 0.f, a3 = 0.f;
#pragma unroll
    for (int l = 0; l < 4; ++l) {
        int HW = lvl_hw[l];
        float fHW = (float)HW;
        const float* vbase =
            value + ((size_t)(b * QTOT + lvl_off[l])) * D_MODEL + h * 32 + c;
#pragma unroll
        for (int p = 0; p < 4; ++p) {
            float ox = ofv[(l * 4 + p) * 2 + 0];
            float oy = ofv[(l * 4 + p) * 2 + 1];
            float aw = w[l * 4 + p];
            float x = (ref_x + ox / fHW) * fHW - 0.5f;
            float y = (ref_y + oy / fHW) * fHW - 0.5f;
            float x0f = floorf(x), y0f = floorf(y);
            int   x0 = (int)x0f,  y0 = (int)y0f;
            float wx = x - x0f,   wy = y - y0f;
            float w00 = (1.f - wx) * (1.f - wy) * aw, w01 = wx * (1.f - wy) * aw;
            float w10 = (1.f - wx) * wy * aw,         w11 = wx * wy * aw;
            bool xv0 = (x0 >= 0) && (x0 < HW);
            bool xv1 = (x0 + 1 >= 0) && (x0 + 1 < HW);
            bool yv0 = (y0 >= 0) && (y0 < HW);
            bool yv1 = (y0 + 1 >= 0) && (y0 + 1 < HW);
#define GATH(cond, idx, wgt)                                                  \
            if (cond) {                                                       \
                float4 v = *reinterpret_cast<const float4*>(                  \
                    vbase + (size_t)(idx) * D_MODEL);                         \
                a0 += (wgt) * v.x; a1 += (wgt) * v.y;                         \
                a2 += (wgt) * v.z; a3 += (wgt) * v.w;                         \
            }
            GATH(xv0 && yv0, y0 * HW + x0,           w00)
            GATH(xv1 && yv0, y0 * HW + x0 + 1,       w01)
            GATH(xv0 && yv1, (y0 + 1) * HW + x0,     w10)
            GATH(xv1 && yv1, (y0 + 1) * HW + x0 + 1, w11)
#undef GATH
        }
    }
    float4 o = make_float4(a0, a1, a2, a3);
    *reinterpret_cast<float4*>(&outp[(size_t)m * D_MODEL + h * 32 + c]) = o;
}

// ---------------------------------------------------------------------------
// add+LN on pair-stored residual (4 rows/block, wave per row).
// TMODE 0: t fp32.  TMODE 1: t bf16 pair (th, tl).
// WRITEQ: also q = y + posf -> qh/ql.  WRITEF32: y -> f32out.
// ---------------------------------------------------------------------------
template<int TMODE, int WRITEQ, int WRITEF32>
__global__ __launch_bounds__(256) void add_ln_pair(
    const float* __restrict__ t, const u16* __restrict__ th,
    const u16* __restrict__ tl,
    const float* __restrict__ g, const float* __restrict__ beta,
    u16* __restrict__ oh, u16* __restrict__ ol,
    const float* __restrict__ posf, u16* __restrict__ qh, u16* __restrict__ ql,
    float* __restrict__ f32out)
{
    int row = blockIdx.x * 4 + (threadIdx.x >> 6);
    int lane = threadIdx.x & 63;
    size_t base = (size_t)row * D_MODEL + lane * 4;
    ushort4 hv = *reinterpret_cast<const ushort4*>(oh + base);
    ushort4 lv = *reinterpret_cast<const ushort4*>(ol + base);
    float t0, t1, t2, t3;
    if (TMODE == 0) {
        float4 tv = *reinterpret_cast<const float4*>(t + base);
        t0 = tv.x; t1 = tv.y; t2 = tv.z; t3 = tv.w;
    } else {
        ushort4 thv = *reinterpret_cast<const ushort4*>(th + base);
        ushort4 tlv = *reinterpret_cast<const ushort4*>(tl + base);
        t0 = bf2f(thv.x) + bf2f(tlv.x);
        t1 = bf2f(thv.y) + bf2f(tlv.y);
        t2 = bf2f(thv.z) + bf2f(tlv.z);
        t3 = bf2f(thv.w) + bf2f(tlv.w);
    }
    float v0 = bf2f(hv.x) + bf2f(lv.x) + t0;
    float v1 = bf2f(hv.y) + bf2f(lv.y) + t1;
    float v2 = bf2f(hv.z) + bf2f(lv.z) + t2;
    float v3 = bf2f(hv.w) + bf2f(lv.w) + t3;
    float s = v0 + v1 + v2 + v3;
#pragma unroll
    for (int o = 32; o > 0; o >>= 1) s += __shfl_xor(s, o);
    float mean = s * (1.f / D_MODEL);
    float d0 = v0 - mean, d1 = v1 - mean, d2 = v2 - mean, d3 = v3 - mean;
    float ss = d0 * d0 + d1 * d1 + d2 * d2 + d3 * d3;
#pragma unroll
    for (int o = 32; o > 0; o >>= 1) ss += __shfl_xor(ss, o);
    float rstd = rsqrtf(ss * (1.f / D_MODEL) + 1e-5f);
    float4 gv = *reinterpret_cast<const float4*>(&g[lane * 4]);
    float4 bv = *reinterpret_cast<const float4*>(&beta[lane * 4]);
    float y0 = d0 * rstd * gv.x + bv.x;
    float y1 = d1 * rstd * gv.y + bv.y;
    float y2 = d2 * rstd * gv.z + bv.z;
    float y3 = d3 * rstd * gv.w + bv.w;
    ushort4 nh, nl;
    nh.x = f2bf(y0); nl.x = f2bf(y0 - bf2f(nh.x));
    nh.y = f2bf(y1); nl.y = f2bf(y1 - bf2f(nh.y));
    nh.z = f2bf(y2); nl.z = f2bf(y2 - bf2f(nh.z));
    nh.w = f2bf(y3); nl.w = f2bf(y3 - bf2f(nh.w));
    *reinterpret_cast<ushort4*>(oh + base) = nh;
    *reinterpret_cast<ushort4*>(ol + base) = nl;
    if (WRITEQ) {
        float4 pv = *reinterpret_cast<const float4*>(posf + base);
        float q0 = y0 + pv.x, q1 = y1 + pv.y, q2 = y2 + pv.z, q3 = y3 + pv.w;
        ushort4 qhv, qlv;
        qhv.x = f2bf(q0); qlv.x = f2bf(q0 - bf2f(qhv.x));
        qhv.y = f2bf(q1); qlv.y = f2bf(q1 - bf2f(qhv.y));
        qhv.z = f2bf(q2); qlv.z = f2bf(q2 - bf2f(qhv.z));
        qhv.w = f2bf(q3); qlv.w = f2bf(q3 - bf2f(qhv.w));
        *reinterpret_cast<ushort4*>(qh + base) = qhv;
        *reinterpret_cast<ushort4*>(ql + base) = qlv;
    }
    if (WRITEF32) {
        *reinterpret_cast<float4*>(f32out + base) = make_float4(y0, y1, y2, y3);
    }
}

// old add_ln (fallback): in-place fp32
__global__ __launch_bounds__(64) void add_ln(
    const float* __restrict__ t, const float* __restrict__ g,
    const float* __restrict__ beta, float* __restrict__ x)
{
    int row = blockIdx.x;
    int lane = threadIdx.x;
    size_t base = (size_t)row * D_MODEL + lane * 4;
    float4 xv = *reinterpret_cast<const float4*>(&x[base]);
    float4 tv = *reinterpret_cast<const float4*>(&t[base]);
    float v0 = xv.x + tv.x, v1 = xv.y + tv.y, v2 = xv.z + tv.z, v3 = xv.w + tv.w;
    float s = v0 + v1 + v2 + v3;
#pragma unroll
    for (int o = 32; o > 0; o >>= 1) s += __shfl_xor(s, o);
    float mean = s * (1.f / D_MODEL);
    float d0 = v0 - mean, d1 = v1 - mean, d2 = v2 - mean, d3 = v3 - mean;
    float ss = d0 * d0 + d1 * d1 + d2 * d2 + d3 * d3;
#pragma unroll
    for (int o = 32; o > 0; o >>= 1) ss += __shfl_xor(ss, o);
    float rstd = rsqrtf(ss * (1.f / D_MODEL) + 1e-5f);
    float4 gv = *reinterpret_cast<const float4*>(&g[lane * 4]);
    float4 bv = *reinterpret_cast<const float4*>(&beta[lane * 4]);
    float4 ov = make_float4(d0 * rstd * gv.x + bv.x, d1 * rstd * gv.y + bv.y,
                            d2 * rstd * gv.z + bv.z, d3 * rstd * gv.w + bv.w);
    *reinterpret_cast<float4*>(&x[base]) = ov;
}

// ---------------------------------------------------------------------------
extern "C" void kernel_launch(void* const* d_in, const int* in_sizes, int n_in,
                              void* d_out, int out_size, void* d_ws, size_t ws_size,
                              hipStream_t stream)
{
    // dict order is INTERLEAVED: src0,pos0,src1,pos1,...
    const float* src[4] = {(const float*)d_in[0], (const float*)d_in[2],
                           (const float*)d_in[4], (const float*)d_in[6]};
    const float* pos[4] = {(const float*)d_in[1], (const float*)d_in[3],
                           (const float*)d_in[5], (const float*)d_in[7]};
    const float* lvl   = (const float*)d_in[8];
    const float* W_off = (const float*)d_in[9];
    const float* b_off = (const float*)d_in[10];
    const float* W_att = (const float*)d_in[11];
    const float* b_att = (const float*)d_in[12];
    const float* W_val = (const float*)d_in[13];
    const float* b_val = (const float*)d_in[14];
    const float* W_out = (const float*)d_in[15];
    const float* b_out = (const float*)d_in[16];
    const float* ln1g  = (const float*)d_in[17];
    const float* ln1b  = (const float*)d_in[18];
    const float* W_ff1 = (const float*)d_in[19];
    const float* b_ff1 = (const float*)d_in[20];
    const float* W_ff2 = (const float*)d_in[21];
    const float* b_ff2 = (const float*)d_in[22];
    const float* ln2g  = (const float*)d_in[23];
    const float* ln2b  = (const float*)d_in[24];

    float* ws = (float*)d_ws;
    const size_t MD = (size_t)MTOT * D_MODEL;    // 5,570,560

    const int hws[4]  = {4096, 1024, 256, 64};
    const int qoff[4] = {0, 4096, 5120, 5376};

    // ---- NEW path layout ----
    float* posf = ws;                                    // fp32 [M,256]
    u16* oh = (u16*)(ws + MD);
    u16* ol = oh + MD;
    u16* qh = ol + MD;                                   // q / e / ff2-out pair
    u16* ql = qh + MD;
    u16* eh = qh; u16* el = ql;
    float* val    = (float*)(ql + MD);                   // fp32 [M,256]
    float* offlog = val + MD;                            // fp32 [M,384]; tmp
    float* tmp    = offlog;
    u16* hid_h = (u16*)val;                              // FFN hid spans val+offlog
    u16* hid_l = hid_h + (size_t)MHALF * DFFN;
    u16* wb = (u16*)(offlog + (size_t)MTOT * 384);
    size_t o = 0;
    u16* wv_h = wb + o; o += 6 * 65536;  u16* wv_l = wb + o; o += 6 * 65536;
    u16* wc_h = wb + o; o += 6 * 98304;  u16* wc_l = wb + o; o += 6 * 98304;
    u16* wu_h = wb + o; o += 6 * 65536;  u16* wu_l = wb + o; o += 6 * 65536;
    u16* wf1_h = wb + o; o += 6 * 262144; u16* wf1_l = wb + o; o += 6 * 262144;
    u16* wf2_h = wb + o; o += 6 * 262144; u16* wf2_l = wb + o; o += 6 * 262144;
    const size_t NEED = (size_t)((char*)(wb + o) - (char*)ws);   // ~140.6 MB

    if (ws_size >= NEED) {
        dim3 cb(32, 8);
        for (int l = 0; l < 4; ++l) {
            dim3 g(hws[l] / 32, D_MODEL / 32, BATCH);
            flatten_tr<<<g, cb, 0, stream>>>(pos[l], lvl + l * D_MODEL, posf, hws[l], qoff[l]);
            flatten_src_pair<<<g, cb, 0, stream>>>(src[l], posf, oh, ol, qh, ql, hws[l], qoff[l]);
        }
        wconv<<<dim3(8, 8, 6),  cb, 0, stream>>>(W_val, wv_h, wv_l, 256, 256, 65536);
        wconv<<<dim3(8, 8, 6),  cb, 0, stream>>>(W_off, wc_h, wc_l, 256, 256, 98304);
        wconv<<<dim3(4, 8, 6),  cb, 0, stream>>>(W_att, wc_h + 65536, wc_l + 65536, 256, 128, 98304);
        wconv<<<dim3(8, 8, 6),  cb, 0, stream>>>(W_out, wu_h, wu_l, 256, 256, 65536);
        wconv<<<dim3(32, 8, 6), cb, 0, stream>>>(W_ff1, wf1_h, wf1_l, 256, 1024, 262144);
        wconv<<<dim3(8, 32, 6), cb, 0, stream>>>(W_ff2, wf2_h, wf2_l, 1024, 256, 262144);

        for (int i = 0; i < NLAYER; ++i) {
            gemm_vo<<<dim3(5, 170), 256, 0, stream>>>(
                oh, ol, qh, ql,
                wv_h + i * 65536, wv_l + i * 65536,
                wc_h + i * 98304, wc_l + i * 98304,
                b_val + i * 256, b_off + i * 256, b_att + i * 128,
                val, offlog);
            msda3<<<MTOT / 4, 256, 0, stream>>>(val, offlog, eh, el);
            gemm_pre<0><<<dim3(2, 170), 256, 0, stream>>>(
                eh, el, wu_h + i * 65536, wu_l + i * 65536,
                b_out + i * 256, b_out + i * 256, 256, tmp, nullptr, nullptr, 256, 256);
            add_ln_pair<0, 0, 0><<<MTOT / 4, 256, 0, stream>>>(
                tmp, nullptr, nullptr, ln1g + i * 256, ln1b + i * 256, oh, ol,
                nullptr, nullptr, nullptr, nullptr);
            // FFN: 2 chunks of 85 row-blocks; hid spans val+offlog (freed).
            for (int c = 0; c < 2; ++c) {
                size_t r0 = (size_t)c * MHALF * 256;
                gemm_pre<1><<<dim3(8, 85), 256, 0, stream>>>(
                    oh + r0, ol + r0, wf1_h + i * 262144, wf1_l + i * 262144,
                    b_ff1 + i * 1024, b_ff1 + i * 1024, 1024,
                    nullptr, hid_h, hid_l, 1024, 256);
                gemm_pre<2><<<dim3(2, 85), 256, 0, stream>>>(
                    hid_h, hid_l, wf2_h + i * 262144, wf2_l + i * 262144,
                    b_ff2 + i * 256, b_ff2 + i * 256, 256,
                    nullptr, eh + r0, el + r0, 256, 1024);
            }
            if (i < NLAYER - 1)
                add_ln_pair<1, 1, 0><<<MTOT / 4, 256, 0, stream>>>(
                    nullptr, eh, el, ln2g + i * 256, ln2b + i * 256, oh, ol,
                    posf, qh, ql, nullptr);
            else
                add_ln_pair<1, 0, 1><<<MTOT / 4, 256, 0, stream>>>(
                    nullptr, eh, el, ln2g + i * 256, ln2b + i * 256, oh, ol,
                    nullptr, nullptr, nullptr, (float*)d_out);
        }
    } else {
        // ---- FALLBACK: round-3 proven path (~118.4 MB) ----
        float* out = (float*)d_out;
        float* posf2  = ws;
        float* val2   = posf2 + MD;
        float* logits = val2 + MD;
        float* offb   = logits + (size_t)MTOT * 128;
        float* ebuf   = offb + MD;
        float* tmp2   = offb;
        float* hid2   = offb;
        short* wbase = (short*)(ebuf + MD);
        short* v_h = wbase;               short* v_l = v_h + 6 * 65536;
        short* o_h = v_l + 6 * 65536;     short* o_l = o_h + 6 * 65536;
        short* a_h = o_l + 6 * 65536;     short* a_l = a_h + 6 * 32768;
        short* u_h = a_l + 6 * 32768;     short* u_l = u_h + 6 * 65536;
        short* f1h = u_l + 6 * 65536;     short* f1l = f1h + 6 * 262144;
        short* f2h = f1l + 6 * 262144;    short* f2l = f2h + 6 * 262144;
        dim3 cb(32, 8);
        for (int l = 0; l < 4; ++l) {
            dim3 g(hws[l] / 32, D_MODEL / 32, BATCH);
            flatten_tr<<<g, cb, 0, stream>>>(src[l], nullptr, out, hws[l], qoff[l]);
            flatten_tr<<<g, cb, 0, stream>>>(pos[l], lvl + l * D_MODEL, posf2, hws[l], qoff[l]);
        }
        wconv<<<dim3(8, 8, 6),  cb, 0, stream>>>(W_val, (u16*)v_h, (u16*)v_l, 256, 256, 65536);
        wconv<<<dim3(8, 8, 6),  cb, 0, stream>>>(W_off, (u16*)o_h, (u16*)o_l, 256, 256, 65536);
        wconv<<<dim3(4, 8, 6),  cb, 0, stream>>>(W_att, (u16*)a_h, (u16*)a_l, 256, 128, 32768);
        wconv<<<dim3(8, 8, 6),  cb, 0, stream>>>(W_out, (u16*)u_h, (u16*)u_l, 256, 256, 65536);
        wconv<<<dim3(32, 8, 6), cb, 0, stream>>>(W_ff1, (u16*)f1h, (u16*)f1l, 256, 1024, 262144);
        wconv<<<dim3(8, 32, 6), cb, 0, stream>>>(W_ff2, (u16*)f2h, (u16*)f2l, 1024, 256, 262144);
        for (int i = 0; i < NLAYER; ++i) {
            gemm_mfma<0,0><<<dim3(4, 170), 256, 0, stream>>>(
                out, nullptr, v_h + i * 65536, v_l + i * 65536,
                b_val + i * 256, val2, 256, 256);
            gemm_mfma<0,1><<<dim3(4, 170), 256, 0, stream>>>(
                out, posf2, o_h + i * 65536, o_l + i * 65536,
                b_off + i * 256, offb, 256, 256);
            gemm_mfma<0,1><<<dim3(2, 170), 256, 0, stream>>>(
                out, posf2, a_h + i * 32768, a_l + i * 32768,
                b_att + i * 128, logits, 128, 256);
            msda2<<<MTOT / 4, 256, 0, stream>>>(val2, offb, logits, ebuf);
            gemm_mfma<0,0><<<dim3(4, 170), 256, 0, stream>>>(
                ebuf, nullptr, u_h + i * 65536, u_l + i * 65536,
                b_out + i * 256, tmp2, 256, 256);
            add_ln<<<MTOT, 64, 0, stream>>>(tmp2, ln1g + i * 256, ln1b + i * 256, out);
            for (int h = 0; h < 2; ++h) {
                gemm_mfma<1,0><<<dim3(16, 85), 256, 0, stream>>>(
                    out + (size_t)h * MHALF * 256, nullptr,
                    f1h + i * 262144, f1l + i * 262144,
                    b_ff1 + i * 1024, hid2, 1024, 256);
                gemm_mfma<0,0><<<dim3(4, 85), 256, 0, stream>>>(
                    hid2, nullptr, f2h + i * 262144, f2l + i * 262144,
                    b_ff2 + i * 256, val2 + (size_t)h * MHALF * 256, 256, 1024);
            }
            add_ln<<<MTOT, 64, 0, stream>>>(val2, ln2g + i * 256, ln2b + i * 256, out);
        }
    }
    (void)in_sizes; (void)n_in; (void)out_size;
}

// Round 9
// 1690.126 us; speedup vs baseline: 3.0520x; 1.0174x over previous
//
#include <hip/hip_runtime.h>
#include <cstddef>
#include <cstdint>

#define D_MODEL 256
#define NHEAD   8
#define NLAYER  6
#define BATCH   4
#define QTOT    5440
#define MTOT    (BATCH*QTOT)   // 21760 = 170*128
#define MHALF   (MTOT/2)       // 10880 = 85*128
#define DFFN    1024

typedef short  bf16x8 __attribute__((ext_vector_type(8)));
typedef float  f32x4  __attribute__((ext_vector_type(4)));
typedef unsigned short u16;

typedef __attribute__((address_space(1))) const void g_as1;
typedef __attribute__((address_space(3))) void l_as3;

__device__ __forceinline__ u16 f2bf(float f) {
    uint32_t u = __float_as_uint(f);
    return (u16)((u + 0x7fffu + ((u >> 16) & 1u)) >> 16);
}
__device__ __forceinline__ float bf2f(u16 s) {
    return __uint_as_float(((uint32_t)s) << 16);
}

// ---------------------------------------------------------------------------
// Flatten + transpose (fp32): src [B,D,HW] -> dst [B,Q,D]  (fallback only)
// ---------------------------------------------------------------------------
__global__ __launch_bounds__(256) void flatten_tr(
    const float* __restrict__ src, const float* __restrict__ emb,
    float* __restrict__ dst, int HW, int qoff)
{
    __shared__ float tile[32][33];
    int tx = threadIdx.x, ty = threadIdx.y;
    int hw0 = blockIdx.x * 32, d0 = blockIdx.y * 32, b = blockIdx.z;
    const float* s = src + (size_t)b * D_MODEL * HW;
#pragma unroll
    for (int j = 0; j < 4; ++j)
        tile[ty + j * 8][tx] = s[(size_t)(d0 + ty + j * 8) * HW + hw0 + tx];
    __syncthreads();
#pragma unroll
    for (int j = 0; j < 4; ++j) {
        int hw = ty + j * 8;
        float v = tile[tx][hw];
        if (emb) v += emb[d0 + tx];
        dst[((size_t)b * QTOT + qoff + hw0 + hw) * D_MODEL + d0 + tx] = v;
    }
}

// ---------------------------------------------------------------------------
// FUSED flatten: all 4 levels, src+pos in one pass.
// Writes posf (fp32), oh/ol (out pair), qh/ql (q pair).
// Grid: (170, 8, BATCH), block (32,8).
// ---------------------------------------------------------------------------
__global__ __launch_bounds__(256) void flatten_all(
    const float* __restrict__ s0, const float* __restrict__ s1,
    const float* __restrict__ s2, const float* __restrict__ s3,
    const float* __restrict__ p0, const float* __restrict__ p1,
    const float* __restrict__ p2, const float* __restrict__ p3,
    const float* __restrict__ lvl, float* __restrict__ posf,
    u16* __restrict__ oh, u16* __restrict__ ol,
    u16* __restrict__ qh, u16* __restrict__ ql)
{
    __shared__ float ts[32][33];
    __shared__ float tp[32][33];
    int bx = blockIdx.x;
    int l, hw0, qoff, HW;
    if (bx < 128)      { l = 0; hw0 = bx * 32;         qoff = 0;    HW = 4096; }
    else if (bx < 160) { l = 1; hw0 = (bx - 128) * 32; qoff = 4096; HW = 1024; }
    else if (bx < 168) { l = 2; hw0 = (bx - 160) * 32; qoff = 5120; HW = 256;  }
    else               { l = 3; hw0 = (bx - 168) * 32; qoff = 5376; HW = 64;   }
    const float* src = (l == 0) ? s0 : (l == 1) ? s1 : (l == 2) ? s2 : s3;
    const float* pos = (l == 0) ? p0 : (l == 1) ? p1 : (l == 2) ? p2 : p3;
    int tx = threadIdx.x, ty = threadIdx.y;
    int d0 = blockIdx.y * 32, b = blockIdx.z;
    const float* sp = src + (size_t)b * D_MODEL * HW;
    const float* pp = pos + (size_t)b * D_MODEL * HW;
#pragma unroll
    for (int j = 0; j < 4; ++j) {
        size_t off = (size_t)(d0 + ty + j * 8) * HW + hw0 + tx;
        ts[ty + j * 8][tx] = sp[off];
        tp[ty + j * 8][tx] = pp[off];
    }
    __syncthreads();
    float emb = lvl[l * D_MODEL + d0 + tx];
#pragma unroll
    for (int j = 0; j < 4; ++j) {
        int hw = ty + j * 8;
        float v = ts[tx][hw];
        float pv = tp[tx][hw] + emb;
        size_t idx = ((size_t)b * QTOT + qoff + hw0 + hw) * D_MODEL + d0 + tx;
        posf[idx] = pv;
        u16 h = f2bf(v);
        oh[idx] = h; ol[idx] = f2bf(v - bf2f(h));
        float q = v + pv;
        u16 qhv = f2bf(q);
        qh[idx] = qhv; ql[idx] = f2bf(q - bf2f(qhv));
    }
}

// ---------------------------------------------------------------------------
// Weight convert+transpose (fallback): W fp32 [L][K][N] -> hi/lo [L][N][K]
// ---------------------------------------------------------------------------
__global__ __launch_bounds__(256) void wconv(
    const float* __restrict__ W, u16* __restrict__ Whi,
    u16* __restrict__ Wlo, int K, int N, int lstride)
{
    __shared__ float t[32][33];
    int tx = threadIdx.x, ty = threadIdx.y;
    int n0 = blockIdx.x * 32, k0 = blockIdx.y * 32, l = blockIdx.z;
    const float* Wl = W + (size_t)l * K * N;
    u16* Hl = Whi + (size_t)l * lstride;
    u16* Ll = Wlo + (size_t)l * lstride;
#pragma unroll
    for (int j = 0; j < 4; ++j)
        t[ty + j * 8][tx] = Wl[(size_t)(k0 + ty + j * 8) * N + n0 + tx];
    __syncthreads();
#pragma unroll
    for (int j = 0; j < 4; ++j) {
        float v = t[tx][ty + j * 8];
        int n = n0 + ty + j * 8, k = k0 + tx;
        u16 h = f2bf(v);
        Hl[(size_t)n * K + k] = h;
        Ll[(size_t)n * K + k] = f2bf(v - bf2f(h));
    }
}

// ---------------------------------------------------------------------------
// FUSED weight convert: all 6 weight types x 6 layers in one dispatch.
// blockIdx.x linear over 6 layers x 736 tile-slots.
// ---------------------------------------------------------------------------
__global__ __launch_bounds__(256) void wconv_all(
    const float* __restrict__ Wv, const float* __restrict__ Wo,
    const float* __restrict__ Wa, const float* __restrict__ Wu,
    const float* __restrict__ Wf1, const float* __restrict__ Wf2,
    u16* __restrict__ wv_h, u16* __restrict__ wv_l,
    u16* __restrict__ wc_h, u16* __restrict__ wc_l,
    u16* __restrict__ wu_h, u16* __restrict__ wu_l,
    u16* __restrict__ wf1_h, u16* __restrict__ wf1_l,
    u16* __restrict__ wf2_h, u16* __restrict__ wf2_l)
{
    __shared__ float t[32][33];
    int id = blockIdx.x;
    int layer = id / 736, r = id - layer * 736;
    const float* W; u16* Hl; u16* Ll; int K, N, n0, k0;
    if (r < 64) {
        W = Wv + (size_t)layer * 65536;
        Hl = wv_h + (size_t)layer * 65536; Ll = wv_l + (size_t)layer * 65536;
        K = 256; N = 256; n0 = (r & 7) * 32; k0 = (r >> 3) * 32;
    } else if (r < 128) {
        r -= 64;
        W = Wo + (size_t)layer * 65536;
        Hl = wc_h + (size_t)layer * 98304; Ll = wc_l + (size_t)layer * 98304;
        K = 256; N = 256; n0 = (r & 7) * 32; k0 = (r >> 3) * 32;
    } else if (r < 160) {
        r -= 128;
        W = Wa + (size_t)layer * 32768;
        Hl = wc_h + (size_t)layer * 98304 + 65536;
        Ll = wc_l + (size_t)layer * 98304 + 65536;
        K = 256; N = 128; n0 = (r & 3) * 32; k0 = (r >> 2) * 32;
    } else if (r < 224) {
        r -= 160;
        W = Wu + (size_t)layer * 65536;
        Hl = wu_h + (size_t)layer * 65536; Ll = wu_l + (size_t)layer * 65536;
        K = 256; N = 256; n0 = (r & 7) * 32; k0 = (r >> 3) * 32;
    } else if (r < 480) {
        r -= 224;
        W = Wf1 + (size_t)layer * 262144;
        Hl = wf1_h + (size_t)layer * 262144; Ll = wf1_l + (size_t)layer * 262144;
        K = 256; N = 1024; n0 = (r & 31) * 32; k0 = (r >> 5) * 32;
    } else {
        r -= 480;
        W = Wf2 + (size_t)layer * 262144;
        Hl = wf2_h + (size_t)layer * 262144; Ll = wf2_l + (size_t)layer * 262144;
        K = 1024; N = 256; n0 = (r & 7) * 32; k0 = (r >> 3) * 32;
    }
    int tx = threadIdx.x, ty = threadIdx.y;
#pragma unroll
    for (int j = 0; j < 4; ++j)
        t[ty + j * 8][tx] = W[(size_t)(k0 + ty + j * 8) * N + n0 + tx];
    __syncthreads();
#pragma unroll
    for (int j = 0; j < 4; ++j) {
        float v = t[tx][ty + j * 8];
        int n = n0 + ty + j * 8, k = k0 + tx;
        u16 h = f2bf(v);
        Hl[(size_t)n * K + k] = h;
        Ll[(size_t)n * K + k] = f2bf(v - bf2f(h));
    }
}

// ---------------------------------------------------------------------------
// Shared GEMM body v2: BM=128 BN=128 BK=32.
// LDS (48 KB dbuf): Ahi | Bhi | Blo via global_load_lds (3 of 4 waves stage).
// A-lo: direct per-lane global loads in MFMA fragment layout, prefetched.
// ---------------------------------------------------------------------------
#define GEMM_BODY(AH, AL, BH, BL, KDIM, BIAS_EXPR, STORE_STMT)                 \
    __shared__ __align__(16) short lds[2 * 12288];  /* 2 x 24 KB */            \
    int tid  = threadIdx.x;                                                    \
    int lane = tid & 63, wid = tid >> 6;                                       \
    int wr = wid >> 1, wc = wid & 1;                                           \
    int row0 = blockIdx.y * 128;                                               \
    const u16* gsrc0 = (wid == 0) ? (AH) : (wid == 1) ? (BH) : (BL);           \
    int rbase = (wid == 0) ? row0 : col0;                                      \
    const u16* gsrc = gsrc0 + (size_t)(rbase + (lane >> 2)) * (KDIM)           \
                            + (((lane & 3) ^ ((lane >> 3) & 3)) * 8);          \
    auto issue = [&](int kt, short* buf) {                                     \
        if (wid < 3) {                                                         \
            char* lbase = (char*)buf + wid * 8192;                             \
            const u16* g = gsrc + kt * 32;                                     \
            _Pragma("unroll")                                                  \
            for (int j = 0; j < 8; ++j) {                                      \
                __builtin_amdgcn_global_load_lds(                              \
                    (g_as1*)(g + (size_t)j * 16 * (KDIM)),                     \
                    (l_as3*)(lbase + j * 1024), 16, 0, 0);                     \
            }                                                                  \
        }                                                                      \
    };                                                                         \
    int l15 = lane & 15, l4 = lane >> 4;                                       \
    const u16* alp0 = (AL) + (size_t)(row0 + wr * 64 + l15) * (KDIM) + l4 * 8; \
    const u16* alp1 = alp0 + (size_t)16 * (KDIM);                              \
    const u16* alp2 = alp0 + (size_t)32 * (KDIM);                              \
    const u16* alp3 = alp0 + (size_t)48 * (KDIM);                              \
    f32x4 acc[4][4];                                                           \
    _Pragma("unroll")                                                          \
    for (int i = 0; i < 4; ++i)                                                \
        _Pragma("unroll")                                                      \
        for (int j = 0; j < 4; ++j) acc[i][j] = (f32x4){0.f, 0.f, 0.f, 0.f};   \
    auto compute = [&](const short* buf,                                       \
                       bf16x8 al0, bf16x8 al1, bf16x8 al2, bf16x8 al3) {       \
        const char* Ahi = (const char*)buf;                                    \
        const char* Bhi = (const char*)(buf + 4096);                           \
        const char* Blo = (const char*)(buf + 8192);                           \
        bf16x8 bh[4], bl[4];                                                   \
        _Pragma("unroll")                                                      \
        for (int nc = 0; nc < 4; ++nc) {                                       \
            int col = wc * 64 + nc * 16 + l15;                                 \
            int byt = col * 64 + ((l4 ^ ((col >> 1) & 3)) * 16);               \
            bh[nc] = *(const bf16x8*)(Bhi + byt);                              \
            bl[nc] = *(const bf16x8*)(Blo + byt);                              \
        }                                                                      \
        _Pragma("unroll")                                                      \
        for (int mr = 0; mr < 4; ++mr) {                                       \
            int row = wr * 64 + mr * 16 + l15;                                 \
            int byt = row * 64 + ((l4 ^ ((row >> 1) & 3)) * 16);               \
            bf16x8 ah = *(const bf16x8*)(Ahi + byt);                           \
            bf16x8 al = (mr == 0) ? al0 : (mr == 1) ? al1                      \
                       : (mr == 2) ? al2 : al3;                                \
            _Pragma("unroll")                                                  \
            for (int nc = 0; nc < 4; ++nc) {                                   \
                acc[mr][nc] = __builtin_amdgcn_mfma_f32_16x16x32_bf16(ah, bh[nc], acc[mr][nc], 0, 0, 0); \
                acc[mr][nc] = __builtin_amdgcn_mfma_f32_16x16x32_bf16(ah, bl[nc], acc[mr][nc], 0, 0, 0); \
                acc[mr][nc] = __builtin_amdgcn_mfma_f32_16x16x32_bf16(al, bh[nc], acc[mr][nc], 0, 0, 0); \
            }                                                                  \
        }                                                                      \
    };                                                                         \
    int nk = (KDIM) >> 5;                                                      \
    short* lds0 = lds;                                                         \
    short* lds1 = lds + 12288;                                                 \
    bf16x8 a0A, a1A, a2A, a3A, a0B, a1B, a2B, a3B;                             \
    issue(0, lds0);                                                            \
    a0A = *(const bf16x8*)(alp0); a1A = *(const bf16x8*)(alp1);                \
    a2A = *(const bf16x8*)(alp2); a3A = *(const bf16x8*)(alp3);                \
    __syncthreads();                                                           \
    for (int kt = 0; kt < nk; kt += 2) {                                       \
        if (kt + 1 < nk) {                                                     \
            issue(kt + 1, lds1);                                               \
            const int o1 = (kt + 1) * 32;                                      \
            a0B = *(const bf16x8*)(alp0 + o1); a1B = *(const bf16x8*)(alp1 + o1); \
            a2B = *(const bf16x8*)(alp2 + o1); a3B = *(const bf16x8*)(alp3 + o1); \
        }                                                                      \
        compute(lds0, a0A, a1A, a2A, a3A);                                     \
        __syncthreads();                                                       \
        if (kt + 1 < nk) {                                                     \
            if (kt + 2 < nk) {                                                 \
                issue(kt + 2, lds0);                                           \
                const int o2 = (kt + 2) * 32;                                  \
                a0A = *(const bf16x8*)(alp0 + o2); a1A = *(const bf16x8*)(alp1 + o2); \
                a2A = *(const bf16x8*)(alp2 + o2); a3A = *(const bf16x8*)(alp3 + o2); \
            }                                                                  \
            compute(lds1, a0B, a1B, a2B, a3B);                                 \
            __syncthreads();                                                   \
        }                                                                      \
    }                                                                          \
    _Pragma("unroll")                                                          \
    for (int nc = 0; nc < 4; ++nc) {                                           \
        int col = col0 + wc * 64 + nc * 16 + l15;                              \
        float bv = (BIAS_EXPR);                                                \
        _Pragma("unroll")                                                      \
        for (int mr = 0; mr < 4; ++mr) {                                       \
            int row = row0 + wr * 64 + mr * 16 + l4 * 4;                       \
            _Pragma("unroll")                                                  \
            for (int r = 0; r < 4; ++r) {                                      \
                float v = acc[mr][nc][r] + bv;                                 \
                size_t idx = (size_t)(row + r) * N + col;                      \
                STORE_STMT;                                                    \
            }                                                                  \
        }                                                                      \
    }

// GEMM: CMODE 0 fp32 C; CMODE 1 bf16 pair + ReLU; CMODE 2 bf16 pair no ReLU.
template<int CMODE>
__global__ __launch_bounds__(256, 3) void gemm_pre(
    const u16* __restrict__ Ah, const u16* __restrict__ Al,
    const u16* __restrict__ Bh, const u16* __restrict__ Bl,
    const float* __restrict__ bias, const float* __restrict__ bias2, int nsplit,
    float* __restrict__ Cf, u16* __restrict__ Ch, u16* __restrict__ Cl,
    int N, int K)
{
    int col0 = blockIdx.x * 128;
    GEMM_BODY(Ah, Al, Bh, Bl, K,
        (col < nsplit) ? bias[col] : bias2[col - nsplit],
        {
            if (CMODE == 0) { Cf[idx] = v; }
            else {
                if (CMODE == 1) v = fmaxf(v, 0.f);
                u16 h = f2bf(v);
                Ch[idx] = h;
                Cl[idx] = f2bf(v - bf2f(h));
            }
        })
}

// Fused val + offlog GEMM: bx<2 -> val = oh@Wv; bx>=2 -> offlog = qh@Wc.
__global__ __launch_bounds__(256, 3) void gemm_vo(
    const u16* __restrict__ oh, const u16* __restrict__ ol,
    const u16* __restrict__ qh, const u16* __restrict__ ql,
    const u16* __restrict__ wvh, const u16* __restrict__ wvl,
    const u16* __restrict__ wch, const u16* __restrict__ wcl,
    const float* __restrict__ b_val, const float* __restrict__ b_off,
    const float* __restrict__ b_att,
    float* __restrict__ val, float* __restrict__ offlog)
{
    int bx = blockIdx.x;
    bool isv = bx < 2;
    const u16* Ah = isv ? oh : qh;
    const u16* Al = isv ? ol : ql;
    const u16* Bh = isv ? wvh : wch;
    const u16* Bl = isv ? wvl : wcl;
    float* Cf = isv ? val : offlog;
    int N = isv ? 256 : 384;
    int col0 = isv ? bx * 128 : (bx - 2) * 128;
    GEMM_BODY(Ah, Al, Bh, Bl, 256,
        isv ? b_val[col] : (col < 256 ? b_off[col] : b_att[col - 256]),
        { Cf[idx] = v; })
}

// ---------------------------------------------------------------------------
// OLD MFMA GEMM (fallback path, in-kernel fp32->bf16 split staging)
// ---------------------------------------------------------------------------
template<int RELU, int HASA2>
__global__ __launch_bounds__(256) void gemm_mfma(
    const float* __restrict__ A, const float* __restrict__ A2,
    const short* __restrict__ Whi, const short* __restrict__ Wlo,
    const float* __restrict__ bias, float* __restrict__ C, int N, int K)
{
    __shared__ __align__(16) short lds[2 * 12288];
    int tid  = threadIdx.x;
    int lane = tid & 63, wid = tid >> 6;
    int wr = wid >> 1, wc = wid & 1;
    int row0 = blockIdx.y * 128, col0 = blockIdx.x * 64;
    int srow = tid >> 1, shalf = tid & 1;
    int brow = tid >> 2, bseg = tid & 3;
    const float* Arow  = A + (size_t)(row0 + srow) * K + shalf * 16;
    const float* A2row = HASA2 ? A2 + (size_t)(row0 + srow) * K + shalf * 16 : nullptr;
    const short* Whirow = Whi + (size_t)(col0 + brow) * K + bseg * 8;
    const short* Wlorow = Wlo + (size_t)(col0 + brow) * K + bseg * 8;
    int aswz = (srow >> 1) & 3;
    int a_wb0 = srow * 64 + ((2 * shalf + 0) ^ aswz) * 16;
    int a_wb1 = srow * 64 + ((2 * shalf + 1) ^ aswz) * 16;
    int b_wb  = brow * 64 + ((bseg ^ ((brow >> 1) & 3)) * 16);
    f32x4 acc[4][2];
#pragma unroll
    for (int i = 0; i < 4; ++i)
#pragma unroll
        for (int j = 0; j < 2; ++j) acc[i][j] = (f32x4){0.f, 0.f, 0.f, 0.f};
    float av[16];
    uint4 bhv, blv;
    auto load_stage = [&](int kt) {
        const float4* ap = reinterpret_cast<const float4*>(Arow + kt * 32);
#pragma unroll
        for (int i = 0; i < 4; ++i) {
            float4 v = ap[i];
            av[4 * i + 0] = v.x; av[4 * i + 1] = v.y;
            av[4 * i + 2] = v.z; av[4 * i + 3] = v.w;
        }
        if (HASA2) {
            const float4* a2p = reinterpret_cast<const float4*>(A2row + kt * 32);
#pragma unroll
            for (int i = 0; i < 4; ++i) {
                float4 v = a2p[i];
                av[4 * i + 0] += v.x; av[4 * i + 1] += v.y;
                av[4 * i + 2] += v.z; av[4 * i + 3] += v.w;
            }
        }
        bhv = *reinterpret_cast<const uint4*>(Whirow + kt * 32);
        blv = *reinterpret_cast<const uint4*>(Wlorow + kt * 32);
    };
    auto write_stage = [&](short* buf) {
        unsigned int hw[8], lw[8];
#pragma unroll
        for (int i = 0; i < 8; ++i) {
            u16 h0 = f2bf(av[2 * i]), h1 = f2bf(av[2 * i + 1]);
            u16 l0 = f2bf(av[2 * i] - bf2f(h0));
            u16 l1 = f2bf(av[2 * i + 1] - bf2f(h1));
            hw[i] = (unsigned int)h0 | ((unsigned int)h1 << 16);
            lw[i] = (unsigned int)l0 | ((unsigned int)l1 << 16);
        }
        char* Ahi = (char*)buf;
        char* Alo = (char*)(buf + 4096);
        *(uint4*)(Ahi + a_wb0) = make_uint4(hw[0], hw[1], hw[2], hw[3]);
        *(uint4*)(Ahi + a_wb1) = make_uint4(hw[4], hw[5], hw[6], hw[7]);
        *(uint4*)(Alo + a_wb0) = make_uint4(lw[0], lw[1], lw[2], lw[3]);
        *(uint4*)(Alo + a_wb1) = make_uint4(lw[4], lw[5], lw[6], lw[7]);
        *(uint4*)((char*)(buf + 8192)  + b_wb) = bhv;
        *(uint4*)((char*)(buf + 10240) + b_wb) = blv;
    };
    int l15 = lane & 15, l4 = lane >> 4;
    auto compute = [&](const short* buf) {
        const char* Ahi = (const char*)buf;
        const char* Alo = (const char*)(buf + 4096);
        const char* Bhi = (const char*)(buf + 8192);
        const char* Blo = (const char*)(buf + 10240);
        bf16x8 bh[2], bl[2];
#pragma unroll
        for (int nc = 0; nc < 2; ++nc) {
            int col = wc * 32 + nc * 16 + l15;
            int byt = col * 64 + ((l4 ^ ((col >> 1) & 3)) * 16);
            bh[nc] = *(const bf16x8*)(Bhi + byt);
            bl[nc] = *(const bf16x8*)(Blo + byt);
        }
#pragma unroll
        for (int mr = 0; mr < 4; ++mr) {
            int row = wr * 64 + mr * 16 + l15;
            int byt = row * 64 + ((l4 ^ ((row >> 1) & 3)) * 16);
            bf16x8 ah = *(const bf16x8*)(Ahi + byt);
            bf16x8 al = *(const bf16x8*)(Alo + byt);
#pragma unroll
            for (int nc = 0; nc < 2; ++nc) {
                acc[mr][nc] = __builtin_amdgcn_mfma_f32_16x16x32_bf16(ah, bh[nc], acc[mr][nc], 0, 0, 0);
                acc[mr][nc] = __builtin_amdgcn_mfma_f32_16x16x32_bf16(ah, bl[nc], acc[mr][nc], 0, 0, 0);
                acc[mr][nc] = __builtin_amdgcn_mfma_f32_16x16x32_bf16(al, bh[nc], acc[mr][nc], 0, 0, 0);
            }
        }
    };
    int nk = K >> 5;
    load_stage(0);
    write_stage(lds);
    __syncthreads();
    for (int kt = 0; kt < nk; ++kt) {
        short* cur = lds + (kt & 1) * 12288;
        short* nxt = lds + ((kt & 1) ^ 1) * 12288;
        if (kt + 1 < nk) load_stage(kt + 1);
        compute(cur);
        if (kt + 1 < nk) write_stage(nxt);
        __syncthreads();
    }
#pragma unroll
    for (int nc = 0; nc < 2; ++nc) {
        int col = col0 + wc * 32 + nc * 16 + l15;
        float bv = bias[col];
#pragma unroll
        for (int mr = 0; mr < 4; ++mr) {
            int row = row0 + wr * 64 + mr * 16 + l4 * 4;
#pragma unroll
            for (int r = 0; r < 4; ++r) {
                float v = acc[mr][nc][r] + bv;
                if (RELU) v = fmaxf(v, 0.f);
                C[(size_t)(row + r) * N + col] = v;
            }
        }
    }
}

// ---------------------------------------------------------------------------
// MSDA v3b: LDS-shared weight precompute, gather phase with dual FMA chains.
// Step-B point mapping pi = tid + 256*pp so adjacent lanes write adjacent
// LDS slots (reduces write bank conflicts).
// ---------------------------------------------------------------------------
__global__ __launch_bounds__(256) void msda3(
    const float* __restrict__ value, const float* __restrict__ offlog,
    u16* __restrict__ eh, u16* __restrict__ el)
{
    __shared__ float aw_lds[32][16];
    __shared__ __align__(16) float wts[32 * 17 * 4];
    __shared__ __align__(16) int   idxs[32 * 17 * 4];

    int tid = threadIdx.x;
    int m0 = blockIdx.x * 4;

    if (tid < 32) {
        int m = m0 + (tid >> 3);
        const float* lg = offlog + (size_t)m * 384 + 256 + (tid & 7) * 16;
        float w[16]; float mx = -1e30f;
#pragma unroll
        for (int i = 0; i < 4; ++i) {
            float4 v = reinterpret_cast<const float4*>(lg)[i];
            w[4 * i] = v.x; w[4 * i + 1] = v.y; w[4 * i + 2] = v.z; w[4 * i + 3] = v.w;
        }
#pragma unroll
        for (int j = 0; j < 16; ++j) mx = fmaxf(mx, w[j]);
        float s = 0.f;
#pragma unroll
        for (int j = 0; j < 16; ++j) { w[j] = __expf(w[j] - mx); s += w[j]; }
        float rs = 1.f / s;
#pragma unroll
        for (int j = 0; j < 16; ++j) aw_lds[tid][j] = w[j] * rs;
    }
    __syncthreads();

#pragma unroll
    for (int pp = 0; pp < 2; ++pp) {
        int pi = tid + 256 * pp;
        int qi = pi >> 7, rem = pi & 127;
        int h = rem >> 4, j = rem & 15;
        int l = j >> 2;
        int m = m0 + qi;
        int b = m / QTOT, q = m - b * QTOT;
        int lq = (q < 4096) ? 0 : (q < 5120) ? 1 : (q < 5376) ? 2 : 3;
        int qbase = (lq == 0) ? 0 : (lq == 1) ? 4096 : (lq == 2) ? 5120 : 5376;
        int qrem = q - qbase;
        int shq = 6 - lq;
        int Wq = 1 << shq;
        int yq = qrem >> shq, xq = qrem & (Wq - 1);
        float invq = 1.0f / (float)Wq;
        float ref_x = (xq + 0.5f) * invq;
        float ref_y = (yq + 0.5f) * invq;
        int HW = 64 >> l;
        float fHW = (float)HW;
        float invl = 1.0f / fHW;
        int loff = (l == 0) ? 0 : (l == 1) ? 4096 : (l == 2) ? 5120 : 5376;
        float ox = offlog[(size_t)m * 384 + h * 32 + j * 2 + 0];
        float oy = offlog[(size_t)m * 384 + h * 32 + j * 2 + 1];
        float aw = aw_lds[qi * 8 + h][j];
        float x = (ref_x + ox * invl) * fHW - 0.5f;
        float y = (ref_y + oy * invl) * fHW - 0.5f;
        float x0f = floorf(x), y0f = floorf(y);
        int x0 = (int)x0f, y0 = (int)y0f;
        float wx = x - x0f, wy = y - y0f;
        float vx0 = (x0 >= 0 && x0 < HW) ? 1.f : 0.f;
        float vx1 = (x0 + 1 >= 0 && x0 + 1 < HW) ? 1.f : 0.f;
        float vy0 = (y0 >= 0 && y0 < HW) ? 1.f : 0.f;
        float vy1 = (y0 + 1 >= 0 && y0 + 1 < HW) ? 1.f : 0.f;
        float w00 = (1.f - wx) * (1.f - wy) * aw * vx0 * vy0;
        float w01 = wx * (1.f - wy) * aw * vx1 * vy0;
        float w10 = (1.f - wx) * wy * aw * vx0 * vy1;
        float w11 = wx * wy * aw * vx1 * vy1;
        int xc0 = min(max(x0, 0), HW - 1);
        int xc1 = min(max(x0 + 1, 0), HW - 1);
        int yc0 = min(max(y0, 0), HW - 1);
        int yc1 = min(max(y0 + 1, 0), HW - 1);
        int rbase = b * QTOT + loff;
        int i00 = (rbase + yc0 * HW + xc0) << 10;
        int i01 = (rbase + yc0 * HW + xc1) << 10;
        int i10 = (rbase + yc1 * HW + xc0) << 10;
        int i11 = (rbase + yc1 * HW + xc1) << 10;
        int sl = (qi * 8 + h) * 17 + j;
        reinterpret_cast<float4*>(wts)[sl] = make_float4(w00, w01, w10, w11);
        reinterpret_cast<int4*>(idxs)[sl] = make_int4(i00, i01, i10, i11);
    }
    __syncthreads();

    int lane = tid & 63;
    int qi = tid >> 6, h = lane >> 3, c8 = lane & 7;
    int m = m0 + qi;
    const char* vb = (const char*)value + h * 128 + c8 * 16;
    int base = (qi * 8 + h) * 17;
    float a0 = 0.f, a1 = 0.f, a2 = 0.f, a3 = 0.f;
    float b0 = 0.f, b1 = 0.f, b2 = 0.f, b3 = 0.f;
#pragma unroll
    for (int j = 0; j < 16; j += 2) {
        float4 w0 = reinterpret_cast<const float4*>(wts)[base + j];
        int4  x0 = reinterpret_cast<const int4*>(idxs)[base + j];
        float4 w1 = reinterpret_cast<const float4*>(wts)[base + j + 1];
        int4  x1 = reinterpret_cast<const int4*>(idxs)[base + j + 1];
        float4 v00 = *reinterpret_cast<const float4*>(vb + x0.x);
        float4 v01 = *reinterpret_cast<const float4*>(vb + x0.y);
        float4 v10 = *reinterpret_cast<const float4*>(vb + x0.z);
        float4 v11 = *reinterpret_cast<const float4*>(vb + x0.w);
        float4 u00 = *reinterpret_cast<const float4*>(vb + x1.x);
        float4 u01 = *reinterpret_cast<const float4*>(vb + x1.y);
        float4 u10 = *reinterpret_cast<const float4*>(vb + x1.z);
        float4 u11 = *reinterpret_cast<const float4*>(vb + x1.w);
        a0 += w0.x * v00.x + w0.y * v01.x + w0.z * v10.x + w0.w * v11.x;
        a1 += w0.x * v00.y + w0.y * v01.y + w0.z * v10.y + w0.w * v11.y;
        a2 += w0.x * v00.z + w0.y * v01.z + w0.z * v10.z + w0.w * v11.z;
        a3 += w0.x * v00.w + w0.y * v01.w + w0.z * v10.w + w0.w * v11.w;
        b0 += w1.x * u00.x + w1.y * u01.x + w1.z * u10.x + w1.w * u11.x;
        b1 += w1.x * u00.y + w1.y * u01.y + w1.z * u10.y + w1.w * u11.y;
        b2 += w1.x * u00.z + w1.y * u01.z + w1.z * u10.z + w1.w * u11.z;
        b3 += w1.x * u00.w + w1.y * u01.w + w1.z * u10.w + w1.w * u11.w;
    }
    a0 += b0; a1 += b1; a2 += b2; a3 += b3;
    size_t oidx = (size_t)m * D_MODEL + h * 32 + c8 * 4;
    ushort4 hv, lv;
    hv.x = f2bf(a0); lv.x = f2bf(a0 - bf2f(hv.x));
    hv.y = f2bf(a1); lv.y = f2bf(a1 - bf2f(hv.y));
    hv.z = f2bf(a2); lv.z = f2bf(a2 - bf2f(hv.z));
    hv.w = f2bf(a3); lv.w = f2bf(a3 - bf2f(hv.w));
    *reinterpret_cast<ushort4*>(eh + oidx) = hv;
    *reinterpret_cast<ushort4*>(el + oidx) = lv;
}

// msda (old, fallback): separate off/logits, fp32 out
__global__ __launch_bounds__(256) void msda2(
    const float* __restrict__ value, const float* __restrict__ off,
    const float* __restrict__ logits, float* __restrict__ outp)
{
    const int lvl_off[4] = {0, 4096, 5120, 5376};
    const int lvl_hw[4]  = {64, 32, 16, 8};
    int m = blockIdx.x * 4 + (threadIdx.x >> 6);
    int lane = threadIdx.x & 63;
    int h = lane >> 3, c = (lane & 7) * 4;
    int b = m / QTOT, q = m - b * QTOT;
    int lq, rem;
    if      (q < 4096) { lq = 0; rem = q; }
    else if (q < 5120) { lq = 1; rem = q - 4096; }
    else if (q < 5376) { lq = 2; rem = q - 5120; }
    else               { lq = 3; rem = q - 5376; }
    int Wq = lvl_hw[lq];
    int yq = rem / Wq, xq = rem - yq * Wq;
    float ref_x = (xq + 0.5f) / (float)Wq;
    float ref_y = (yq + 0.5f) / (float)Wq;
    const float* lg = logits + (size_t)m * 128 + h * 16;
    float w[16];
    {
        float mx = -1e30f;
#pragma unroll
        for (int i = 0; i < 4; ++i) {
            float4 v = reinterpret_cast<const float4*>(lg)[i];
            w[4 * i] = v.x; w[4 * i + 1] = v.y; w[4 * i + 2] = v.z; w[4 * i + 3] = v.w;
        }
#pragma unroll
        for (int j = 0; j < 16; ++j) mx = fmaxf(mx, w[j]);
        float s = 0.f;
#pragma unroll
        for (int j = 0; j < 16; ++j) { w[j] = __expf(w[j] - mx); s += w[j]; }
        float rs = 1.f / s;
#pragma unroll
        for (int j = 0; j < 16; ++j) w[j] *= rs;
    }
    float ofv[32];
    const float* op = off + (size_t)m * 256 + h * 32;
#pragma unroll
    for (int i = 0; i < 8; ++i) {
        float4 v = reinterpret_cast<const float4*>(op)[i];
        ofv[4 * i] = v.x; ofv[4 * i + 1] = v.y; ofv[4 * i + 2] = v.z; ofv[4 * i + 3] = v.w;
    }
    float a0 = 0.f, a1 = 0.f, a2 = 0.f, a3 = 0.f;
#pragma unroll
    for (int l = 0; l < 4; ++l) {
        int HW = lvl_hw[l];
        float fHW = (float)HW;
        const float* vbase =
            value + ((size_t)(b * QTOT + lvl_off[l])) * D_MODEL + h * 32 + c;
#pragma unroll
        for (int p = 0; p < 4; ++p) {
            float ox = ofv[(l * 4 + p) * 2 + 0];
            float oy = ofv[(l * 4 + p) * 2 + 1];
            float aw = w[l * 4 + p];
            float x = (ref_x + ox / fHW) * fHW - 0.5f;
            float y = (ref_y + oy / fHW) * fHW - 0.5f;
            float x0f = floorf(x), y0f = floorf(y);
            int   x0 = (int)x0f,  y0 = (int)y0f;
            float wx = x - x0f,   wy = y - y0f;
            float w00 = (1.f - wx) * (1.f - wy) * aw, w01 = wx * (1.f - wy) * aw;
            float w10 = (1.f - wx) * wy * aw,         w11 = wx * wy * aw;
            bool xv0 = (x0 >= 0) && (x0 < HW);
            bool xv1 = (x0 + 1 >= 0) && (x0 + 1 < HW);
            bool yv0 = (y0 >= 0) && (y0 < HW);
            bool yv1 = (y0 + 1 >= 0) && (y0 + 1 < HW);
#define GATH(cond, idx, wgt)                                                  \
            if (cond) {                                                       \
                float4 v = *reinterpret_cast<const float4*>(                  \
                    vbase + (size_t)(idx) * D_MODEL);                         \
                a0 += (wgt) * v.x; a1 += (wgt) * v.y;                         \
                a2 += (wgt) * v.z; a3 += (wgt) * v.w;                         \
            }
            GATH(xv0 && yv0, y0 * HW + x0,           w00)
            GATH(xv1 && yv0, y0 * HW + x0 + 1,       w01)
            GATH(xv0 && yv1, (y0 + 1) * HW + x0,     w10)
            GATH(xv1 && yv1, (y0 + 1) * HW + x0 + 1, w11)
#undef GATH
        }
    }
    float4 o = make_float4(a0, a1, a2, a3);
    *reinterpret_cast<float4*>(&outp[(size_t)m * D_MODEL + h * 32 + c]) = o;
}

// ---------------------------------------------------------------------------
// add+LN on pair-stored residual (4 rows/block, wave per row).
// TMODE 0: t fp32.  TMODE 1: t bf16 pair (th, tl).
// WRITEQ: also q = y + posf -> qh/ql.  WRITEF32: y -> f32out.
// ---------------------------------------------------------------------------
template<int TMODE, int WRITEQ, int WRITEF32>
__global__ __launch_bounds__(256) void add_ln_pair(
    const float* __restrict__ t, const u16* __restrict__ th,
    const u16* __restrict__ tl,
    const float* __restrict__ g, const float* __restrict__ beta,
    u16* __restrict__ oh, u16* __restrict__ ol,
    const float* __restrict__ posf, u16* __restrict__ qh, u16* __restrict__ ql,
    float* __restrict__ f32out)
{
    int row = blockIdx.x * 4 + (threadIdx.x >> 6);
    int lane = threadIdx.x & 63;
    size_t base = (size_t)row * D_MODEL + lane * 4;
    ushort4 hv = *reinterpret_cast<const ushort4*>(oh + base);
    ushort4 lv = *reinterpret_cast<const ushort4*>(ol + base);
    float t0, t1, t2, t3;
    if (TMODE == 0) {
        float4 tv = *reinterpret_cast<const float4*>(t + base);
        t0 = tv.x; t1 = tv.y; t2 = tv.z; t3 = tv.w;
    } else {
        ushort4 thv = *reinterpret_cast<const ushort4*>(th + base);
        ushort4 tlv = *reinterpret_cast<const ushort4*>(tl + base);
        t0 = bf2f(thv.x) + bf2f(tlv.x);
        t1 = bf2f(thv.y) + bf2f(tlv.y);
        t2 = bf2f(thv.z) + bf2f(tlv.z);
        t3 = bf2f(thv.w) + bf2f(tlv.w);
    }
    float v0 = bf2f(hv.x) + bf2f(lv.x) + t0;
    float v1 = bf2f(hv.y) + bf2f(lv.y) + t1;
    float v2 = bf2f(hv.z) + bf2f(lv.z) + t2;
    float v3 = bf2f(hv.w) + bf2f(lv.w) + t3;
    float s = v0 + v1 + v2 + v3;
#pragma unroll
    for (int o = 32; o > 0; o >>= 1) s += __shfl_xor(s, o);
    float mean = s * (1.f / D_MODEL);
    float d0 = v0 - mean, d1 = v1 - mean, d2 = v2 - mean, d3 = v3 - mean;
    float ss = d0 * d0 + d1 * d1 + d2 * d2 + d3 * d3;
#pragma unroll
    for (int o = 32; o > 0; o >>= 1) ss += __shfl_xor(ss, o);
    float rstd = rsqrtf(ss * (1.f / D_MODEL) + 1e-5f);
    float4 gv = *reinterpret_cast<const float4*>(&g[lane * 4]);
    float4 bv = *reinterpret_cast<const float4*>(&beta[lane * 4]);
    float y0 = d0 * rstd * gv.x + bv.x;
    float y1 = d1 * rstd * gv.y + bv.y;
    float y2 = d2 * rstd * gv.z + bv.z;
    float y3 = d3 * rstd * gv.w + bv.w;
    ushort4 nh, nl;
    nh.x = f2bf(y0); nl.x = f2bf(y0 - bf2f(nh.x));
    nh.y = f2bf(y1); nl.y = f2bf(y1 - bf2f(nh.y));
    nh.z = f2bf(y2); nl.z = f2bf(y2 - bf2f(nh.z));
    nh.w = f2bf(y3); nl.w = f2bf(y3 - bf2f(nh.w));
    *reinterpret_cast<ushort4*>(oh + base) = nh;
    *reinterpret_cast<ushort4*>(ol + base) = nl;
    if (WRITEQ) {
        float4 pv = *reinterpret_cast<const float4*>(posf + base);
        float q0 = y0 + pv.x, q1 = y1 + pv.y, q2 = y2 + pv.z, q3 = y3 + pv.w;
        ushort4 qhv, qlv;
        qhv.x = f2bf(q0); qlv.x = f2bf(q0 - bf2f(qhv.x));
        qhv.y = f2bf(q1); qlv.y = f2bf(q1 - bf2f(qhv.y));
        qhv.z = f2bf(q2); qlv.z = f2bf(q2 - bf2f(qhv.z));
        qhv.w = f2bf(q3); qlv.w = f2bf(q3 - bf2f(qhv.w));
        *reinterpret_cast<ushort4*>(qh + base) = qhv;
        *reinterpret_cast<ushort4*>(ql + base) = qlv;
    }
    if (WRITEF32) {
        *reinterpret_cast<float4*>(f32out + base) = make_float4(y0, y1, y2, y3);
    }
}

// old add_ln (fallback): in-place fp32
__global__ __launch_bounds__(64) void add_ln(
    const float* __restrict__ t, const float* __restrict__ g,
    const float* __restrict__ beta, float* __restrict__ x)
{
    int row = blockIdx.x;
    int lane = threadIdx.x;
    size_t base = (size_t)row * D_MODEL + lane * 4;
    float4 xv = *reinterpret_cast<const float4*>(&x[base]);
    float4 tv = *reinterpret_cast<const float4*>(&t[base]);
    float v0 = xv.x + tv.x, v1 = xv.y + tv.y, v2 = xv.z + tv.z, v3 = xv.w + tv.w;
    float s = v0 + v1 + v2 + v3;
#pragma unroll
    for (int o = 32; o > 0; o >>= 1) s += __shfl_xor(s, o);
    float mean = s * (1.f / D_MODEL);
    float d0 = v0 - mean, d1 = v1 - mean, d2 = v2 - mean, d3 = v3 - mean;
    float ss = d0 * d0 + d1 * d1 + d2 * d2 + d3 * d3;
#pragma unroll
    for (int o = 32; o > 0; o >>= 1) ss += __shfl_xor(ss, o);
    float rstd = rsqrtf(ss * (1.f / D_MODEL) + 1e-5f);
    float4 gv = *reinterpret_cast<const float4*>(&g[lane * 4]);
    float4 bv = *reinterpret_cast<const float4*>(&beta[lane * 4]);
    float4 ov = make_float4(d0 * rstd * gv.x + bv.x, d1 * rstd * gv.y + bv.y,
                            d2 * rstd * gv.z + bv.z, d3 * rstd * gv.w + bv.w);
    *reinterpret_cast<float4*>(&x[base]) = ov;
}

// ---------------------------------------------------------------------------
extern "C" void kernel_launch(void* const* d_in, const int* in_sizes, int n_in,
                              void* d_out, int out_size, void* d_ws, size_t ws_size,
                              hipStream_t stream)
{
    // dict order is INTERLEAVED: src0,pos0,src1,pos1,...
    const float* src[4] = {(const float*)d_in[0], (const float*)d_in[2],
                           (const float*)d_in[4], (const float*)d_in[6]};
    const float* pos[4] = {(const float*)d_in[1], (const float*)d_in[3],
                           (const float*)d_in[5], (const float*)d_in[7]};
    const float* lvl   = (const float*)d_in[8];
    const float* W_off = (const float*)d_in[9];
    const float* b_off = (const float*)d_in[10];
    const float* W_att = (const float*)d_in[11];
    const float* b_att = (const float*)d_in[12];
    const float* W_val = (const float*)d_in[13];
    const float* b_val = (const float*)d_in[14];
    const float* W_out = (const float*)d_in[15];
    const float* b_out = (const float*)d_in[16];
    const float* ln1g  = (const float*)d_in[17];
    const float* ln1b  = (const float*)d_in[18];
    const float* W_ff1 = (const float*)d_in[19];
    const float* b_ff1 = (const float*)d_in[20];
    const float* W_ff2 = (const float*)d_in[21];
    const float* b_ff2 = (const float*)d_in[22];
    const float* ln2g  = (const float*)d_in[23];
    const float* ln2b  = (const float*)d_in[24];

    float* ws = (float*)d_ws;
    const size_t MD = (size_t)MTOT * D_MODEL;    // 5,570,560

    const int hws[4]  = {4096, 1024, 256, 64};
    const int qoff[4] = {0, 4096, 5120, 5376};

    // ---- NEW path layout ----
    float* posf = ws;                                    // fp32 [M,256]
    u16* oh = (u16*)(ws + MD);
    u16* ol = oh + MD;
    u16* qh = ol + MD;                                   // q / e / ff2-out pair
    u16* ql = qh + MD;
    u16* eh = qh; u16* el = ql;
    float* val    = (float*)(ql + MD);                   // fp32 [M,256]
    float* offlog = val + MD;                            // fp32 [M,384]; tmp
    float* tmp    = offlog;
    u16* hid_h = (u16*)val;                              // FFN hid spans val+offlog
    u16* hid_l = hid_h + (size_t)MHALF * DFFN;
    u16* wb = (u16*)(offlog + (size_t)MTOT * 384);
    size_t o = 0;
    u16* wv_h = wb + o; o += 6 * 65536;  u16* wv_l = wb + o; o += 6 * 65536;
    u16* wc_h = wb + o; o += 6 * 98304;  u16* wc_l = wb + o; o += 6 * 98304;
    u16* wu_h = wb + o; o += 6 * 65536;  u16* wu_l = wb + o; o += 6 * 65536;
    u16* wf1_h = wb + o; o += 6 * 262144; u16* wf1_l = wb + o; o += 6 * 262144;
    u16* wf2_h = wb + o; o += 6 * 262144; u16* wf2_l = wb + o; o += 6 * 262144;
    const size_t NEED = (size_t)((char*)(wb + o) - (char*)ws);   // ~140.6 MB

    if (ws_size >= NEED) {
        dim3 cb(32, 8);
        // fused flatten: 1 dispatch (was 8)
        flatten_all<<<dim3(170, 8, BATCH), cb, 0, stream>>>(
            src[0], src[1], src[2], src[3], pos[0], pos[1], pos[2], pos[3],
            lvl, posf, oh, ol, qh, ql);
        // fused weight conversion: 1 dispatch (was 6)
        wconv_all<<<6 * 736, cb, 0, stream>>>(
            W_val, W_off, W_att, W_out, W_ff1, W_ff2,
            wv_h, wv_l, wc_h, wc_l, wu_h, wu_l, wf1_h, wf1_l, wf2_h, wf2_l);

        for (int i = 0; i < NLAYER; ++i) {
            gemm_vo<<<dim3(5, 170), 256, 0, stream>>>(
                oh, ol, qh, ql,
                wv_h + i * 65536, wv_l + i * 65536,
                wc_h + i * 98304, wc_l + i * 98304,
                b_val + i * 256, b_off + i * 256, b_att + i * 128,
                val, offlog);
            msda3<<<MTOT / 4, 256, 0, stream>>>(val, offlog, eh, el);
            gemm_pre<0><<<dim3(2, 170), 256, 0, stream>>>(
                eh, el, wu_h + i * 65536, wu_l + i * 65536,
                b_out + i * 256, b_out + i * 256, 256, tmp, nullptr, nullptr, 256, 256);
            add_ln_pair<0, 0, 0><<<MTOT / 4, 256, 0, stream>>>(
                tmp, nullptr, nullptr, ln1g + i * 256, ln1b + i * 256, oh, ol,
                nullptr, nullptr, nullptr, nullptr);
            // FFN: 2 chunks of 85 row-blocks; hid spans val+offlog (freed).
            for (int c = 0; c < 2; ++c) {
                size_t r0 = (size_t)c * MHALF * 256;
                gemm_pre<1><<<dim3(8, 85), 256, 0, stream>>>(
                    oh + r0, ol + r0, wf1_h + i * 262144, wf1_l + i * 262144,
                    b_ff1 + i * 1024, b_ff1 + i * 1024, 1024,
                    nullptr, hid_h, hid_l, 1024, 256);
                gemm_pre<2><<<dim3(2, 85), 256, 0, stream>>>(
                    hid_h, hid_l, wf2_h + i * 262144, wf2_l + i * 262144,
                    b_ff2 + i * 256, b_ff2 + i * 256, 256,
                    nullptr, eh + r0, el + r0, 256, 1024);
            }
            if (i < NLAYER - 1)
                add_ln_pair<1, 1, 0><<<MTOT / 4, 256, 0, stream>>>(
                    nullptr, eh, el, ln2g + i * 256, ln2b + i * 256, oh, ol,
                    posf, qh, ql, nullptr);
            else
                add_ln_pair<1, 0, 1><<<MTOT / 4, 256, 0, stream>>>(
                    nullptr, eh, el, ln2g + i * 256, ln2b + i * 256, oh, ol,
                    nullptr, nullptr, nullptr, (float*)d_out);
        }
    } else {
        // ---- FALLBACK: round-3 proven path (~118.4 MB) ----
        float* out = (float*)d_out;
        float* posf2  = ws;
        float* val2   = posf2 + MD;
        float* logits = val2 + MD;
        float* offb   = logits + (size_t)MTOT * 128;
        float* ebuf   = offb + MD;
        float* tmp2   = offb;
        float* hid2   = offb;
        short* wbase = (short*)(ebuf + MD);
        short* v_h = wbase;               short* v_l = v_h + 6 * 65536;
        short* o_h = v_l + 6 * 65536;     short* o_l = o_h + 6 * 65536;
        short* a_h = o_l + 6 * 65536;     short* a_l = a_h + 6 * 32768;
        short* u_h = a_l + 6 * 32768;     short* u_l = u_h + 6 * 65536;
        short* f1h = u_l + 6 * 65536;     short* f1l = f1h + 6 * 262144;
        short* f2h = f1l + 6 * 262144;    short* f2l = f2h + 6 * 262144;
        dim3 cb(32, 8);
        for (int l = 0; l < 4; ++l) {
            dim3 g(hws[l] / 32, D_MODEL / 32, BATCH);
            flatten_tr<<<g, cb, 0, stream>>>(src[l], nullptr, out, hws[l], qoff[l]);
            flatten_tr<<<g, cb, 0, stream>>>(pos[l], lvl + l * D_MODEL, posf2, hws[l], qoff[l]);
        }
        wconv<<<dim3(8, 8, 6),  cb, 0, stream>>>(W_val, (u16*)v_h, (u16*)v_l, 256, 256, 65536);
        wconv<<<dim3(8, 8, 6),  cb, 0, stream>>>(W_off, (u16*)o_h, (u16*)o_l, 256, 256, 65536);
        wconv<<<dim3(4, 8, 6),  cb, 0, stream>>>(W_att, (u16*)a_h, (u16*)a_l, 256, 128, 32768);
        wconv<<<dim3(8, 8, 6),  cb, 0, stream>>>(W_out, (u16*)u_h, (u16*)u_l, 256, 256, 65536);
        wconv<<<dim3(32, 8, 6), cb, 0, stream>>>(W_ff1, (u16*)f1h, (u16*)f1l, 256, 1024, 262144);
        wconv<<<dim3(8, 32, 6), cb, 0, stream>>>(W_ff2, (u16*)f2h, (u16*)f2l, 1024, 256, 262144);
        for (int i = 0; i < NLAYER; ++i) {
            gemm_mfma<0,0><<<dim3(4, 170), 256, 0, stream>>>(
                out, nullptr, v_h + i * 65536, v_l + i * 65536,
                b_val + i * 256, val2, 256, 256);
            gemm_mfma<0,1><<<dim3(4, 170), 256, 0, stream>>>(
                out, posf2, o_h + i * 65536, o_l + i * 65536,
                b_off + i * 256, offb, 256, 256);
            gemm_mfma<0,1><<<dim3(2, 170), 256, 0, stream>>>(
                out, posf2, a_h + i * 32768, a_l + i * 32768,
                b_att + i * 128, logits, 128, 256);
            msda2<<<MTOT / 4, 256, 0, stream>>>(val2, offb, logits, ebuf);
            gemm_mfma<0,0><<<dim3(4, 170), 256, 0, stream>>>(
                ebuf, nullptr, u_h + i * 65536, u_l + i * 65536,
                b_out + i * 256, tmp2, 256, 256);
            add_ln<<<MTOT, 64, 0, stream>>>(tmp2, ln1g + i * 256, ln1b + i * 256, out);
            for (int h = 0; h < 2; ++h) {
                gemm_mfma<1,0><<<dim3(16, 85), 256, 0, stream>>>(
                    out + (size_t)h * MHALF * 256, nullptr,
                    f1h + i * 262144, f1l + i * 262144,
                    b_ff1 + i * 1024, hid2, 1024, 256);
                gemm_mfma<0,0><<<dim3(4, 85), 256, 0, stream>>>(
                    hid2, nullptr, f2h + i * 262144, f2l + i * 262144,
                    b_ff2 + i * 256, val2 + (size_t)h * MHALF * 256, 256, 1024);
            }
            add_ln<<<MTOT, 64, 0, stream>>>(val2, ln2g + i * 256, ln2b + i * 256, out);
        }
    }
    (void)in_sizes; (void)n_in; (void)out_size;
}

// Round 11
// 1335.933 us; speedup vs baseline: 3.8612x; 1.2651x over previous
//
#include <hip/hip_runtime.h>
#include <cstddef>
#include <cstdint>

#define D_MODEL 256
#define NHEAD   8
#define NLAYER  6
#define BATCH   4
#define QTOT    5440
#define MTOT    (BATCH*QTOT)   // 21760 = 170*128
#define MHALF   (MTOT/2)
#define DFFN    1024

typedef short  bf16x8 __attribute__((ext_vector_type(8)));
typedef float  f32x4  __attribute__((ext_vector_type(4)));
typedef unsigned short u16;

typedef __attribute__((address_space(1))) const void g_as1;
typedef __attribute__((address_space(3))) void l_as3;

__device__ __forceinline__ u16 f2bf(float f) {
    uint32_t u = __float_as_uint(f);
    return (u16)((u + 0x7fffu + ((u >> 16) & 1u)) >> 16);
}
__device__ __forceinline__ float bf2f(u16 s) {
    return __uint_as_float(((uint32_t)s) << 16);
}

// ---------------------------------------------------------------------------
// Flatten + transpose (fp32): src [B,D,HW] -> dst [B,Q,D]  (fallback only)
// ---------------------------------------------------------------------------
__global__ __launch_bounds__(256) void flatten_tr(
    const float* __restrict__ src, const float* __restrict__ emb,
    float* __restrict__ dst, int HW, int qoff)
{
    __shared__ float tile[32][33];
    int tx = threadIdx.x, ty = threadIdx.y;
    int hw0 = blockIdx.x * 32, d0 = blockIdx.y * 32, b = blockIdx.z;
    const float* s = src + (size_t)b * D_MODEL * HW;
#pragma unroll
    for (int j = 0; j < 4; ++j)
        tile[ty + j * 8][tx] = s[(size_t)(d0 + ty + j * 8) * HW + hw0 + tx];
    __syncthreads();
#pragma unroll
    for (int j = 0; j < 4; ++j) {
        int hw = ty + j * 8;
        float v = tile[tx][hw];
        if (emb) v += emb[d0 + tx];
        dst[((size_t)b * QTOT + qoff + hw0 + hw) * D_MODEL + d0 + tx] = v;
    }
}

// ---------------------------------------------------------------------------
// FUSED flatten: all 4 levels, src+pos in one pass.
// ---------------------------------------------------------------------------
__global__ __launch_bounds__(256) void flatten_all(
    const float* __restrict__ s0, const float* __restrict__ s1,
    const float* __restrict__ s2, const float* __restrict__ s3,
    const float* __restrict__ p0, const float* __restrict__ p1,
    const float* __restrict__ p2, const float* __restrict__ p3,
    const float* __restrict__ lvl, float* __restrict__ posf,
    u16* __restrict__ oh, u16* __restrict__ ol,
    u16* __restrict__ qh, u16* __restrict__ ql)
{
    __shared__ float ts[32][33];
    __shared__ float tp[32][33];
    int bx = blockIdx.x;
    int l, hw0, qoff, HW;
    if (bx < 128)      { l = 0; hw0 = bx * 32;         qoff = 0;    HW = 4096; }
    else if (bx < 160) { l = 1; hw0 = (bx - 128) * 32; qoff = 4096; HW = 1024; }
    else if (bx < 168) { l = 2; hw0 = (bx - 160) * 32; qoff = 5120; HW = 256;  }
    else               { l = 3; hw0 = (bx - 168) * 32; qoff = 5376; HW = 64;   }
    const float* src = (l == 0) ? s0 : (l == 1) ? s1 : (l == 2) ? s2 : s3;
    const float* pos = (l == 0) ? p0 : (l == 1) ? p1 : (l == 2) ? p2 : p3;
    int tx = threadIdx.x, ty = threadIdx.y;
    int d0 = blockIdx.y * 32, b = blockIdx.z;
    const float* sp = src + (size_t)b * D_MODEL * HW;
    const float* pp = pos + (size_t)b * D_MODEL * HW;
#pragma unroll
    for (int j = 0; j < 4; ++j) {
        size_t off = (size_t)(d0 + ty + j * 8) * HW + hw0 + tx;
        ts[ty + j * 8][tx] = sp[off];
        tp[ty + j * 8][tx] = pp[off];
    }
    __syncthreads();
    float emb = lvl[l * D_MODEL + d0 + tx];
#pragma unroll
    for (int j = 0; j < 4; ++j) {
        int hw = ty + j * 8;
        float v = ts[tx][hw];
        float pv = tp[tx][hw] + emb;
        size_t idx = ((size_t)b * QTOT + qoff + hw0 + hw) * D_MODEL + d0 + tx;
        posf[idx] = pv;
        u16 h = f2bf(v);
        oh[idx] = h; ol[idx] = f2bf(v - bf2f(h));
        float q = v + pv;
        u16 qhv = f2bf(q);
        qh[idx] = qhv; ql[idx] = f2bf(q - bf2f(qhv));
    }
}

// ---------------------------------------------------------------------------
// Weight convert+transpose (fallback): W fp32 [L][K][N] -> hi/lo [L][N][K]
// ---------------------------------------------------------------------------
__global__ __launch_bounds__(256) void wconv(
    const float* __restrict__ W, u16* __restrict__ Whi,
    u16* __restrict__ Wlo, int K, int N, int lstride)
{
    __shared__ float t[32][33];
    int tx = threadIdx.x, ty = threadIdx.y;
    int n0 = blockIdx.x * 32, k0 = blockIdx.y * 32, l = blockIdx.z;
    const float* Wl = W + (size_t)l * K * N;
    u16* Hl = Whi + (size_t)l * lstride;
    u16* Ll = Wlo + (size_t)l * lstride;
#pragma unroll
    for (int j = 0; j < 4; ++j)
        t[ty + j * 8][tx] = Wl[(size_t)(k0 + ty + j * 8) * N + n0 + tx];
    __syncthreads();
#pragma unroll
    for (int j = 0; j < 4; ++j) {
        float v = t[tx][ty + j * 8];
        int n = n0 + ty + j * 8, k = k0 + tx;
        u16 h = f2bf(v);
        Hl[(size_t)n * K + k] = h;
        Ll[(size_t)n * K + k] = f2bf(v - bf2f(h));
    }
}

// ---------------------------------------------------------------------------
// FUSED weight convert: all 6 weight types x 6 layers in one dispatch.
// ---------------------------------------------------------------------------
__global__ __launch_bounds__(256) void wconv_all(
    const float* __restrict__ Wv, const float* __restrict__ Wo,
    const float* __restrict__ Wa, const float* __restrict__ Wu,
    const float* __restrict__ Wf1, const float* __restrict__ Wf2,
    u16* __restrict__ wv_h, u16* __restrict__ wv_l,
    u16* __restrict__ wc_h, u16* __restrict__ wc_l,
    u16* __restrict__ wu_h, u16* __restrict__ wu_l,
    u16* __restrict__ wf1_h, u16* __restrict__ wf1_l,
    u16* __restrict__ wf2_h, u16* __restrict__ wf2_l)
{
    __shared__ float t[32][33];
    int id = blockIdx.x;
    int layer = id / 736, r = id - layer * 736;
    const float* W; u16* Hl; u16* Ll; int K, N, n0, k0;
    if (r < 64) {
        W = Wv + (size_t)layer * 65536;
        Hl = wv_h + (size_t)layer * 65536; Ll = wv_l + (size_t)layer * 65536;
        K = 256; N = 256; n0 = (r & 7) * 32; k0 = (r >> 3) * 32;
    } else if (r < 128) {
        r -= 64;
        W = Wo + (size_t)layer * 65536;
        Hl = wc_h + (size_t)layer * 98304; Ll = wc_l + (size_t)layer * 98304;
        K = 256; N = 256; n0 = (r & 7) * 32; k0 = (r >> 3) * 32;
    } else if (r < 160) {
        r -= 128;
        W = Wa + (size_t)layer * 32768;
        Hl = wc_h + (size_t)layer * 98304 + 65536;
        Ll = wc_l + (size_t)layer * 98304 + 65536;
        K = 256; N = 128; n0 = (r & 3) * 32; k0 = (r >> 2) * 32;
    } else if (r < 224) {
        r -= 160;
        W = Wu + (size_t)layer * 65536;
        Hl = wu_h + (size_t)layer * 65536; Ll = wu_l + (size_t)layer * 65536;
        K = 256; N = 256; n0 = (r & 7) * 32; k0 = (r >> 3) * 32;
    } else if (r < 480) {
        r -= 224;
        W = Wf1 + (size_t)layer * 262144;
        Hl = wf1_h + (size_t)layer * 262144; Ll = wf1_l + (size_t)layer * 262144;
        K = 256; N = 1024; n0 = (r & 31) * 32; k0 = (r >> 5) * 32;
    } else {
        r -= 480;
        W = Wf2 + (size_t)layer * 262144;
        Hl = wf2_h + (size_t)layer * 262144; Ll = wf2_l + (size_t)layer * 262144;
        K = 1024; N = 256; n0 = (r & 7) * 32; k0 = (r >> 3) * 32;
    }
    int tx = threadIdx.x, ty = threadIdx.y;
#pragma unroll
    for (int j = 0; j < 4; ++j)
        t[ty + j * 8][tx] = W[(size_t)(k0 + ty + j * 8) * N + n0 + tx];
    __syncthreads();
#pragma unroll
    for (int j = 0; j < 4; ++j) {
        float v = t[tx][ty + j * 8];
        int n = n0 + ty + j * 8, k = k0 + tx;
        u16 h = f2bf(v);
        Hl[(size_t)n * K + k] = h;
        Ll[(size_t)n * K + k] = f2bf(v - bf2f(h));
    }
}

// ---------------------------------------------------------------------------
// Shared GEMM body: BM=128 BN=128 BK=32; global_load_lds staging
// (Ahi|Bhi|Blo LDS), A-lo in registers (only when HASAL=1 -> 3-pass).
// HASAL=0 -> 2-pass (single-bf16 A).
// ---------------------------------------------------------------------------
#define GEMM_BODY(AH, AL, BH, BL, KDIM, HASAL, BIAS_EXPR, STORE_STMT)          \
    __shared__ __align__(16) short lds[2 * 12288];  /* 2 x 24 KB */            \
    int tid  = threadIdx.x;                                                    \
    int lane = tid & 63, wid = tid >> 6;                                       \
    int wr = wid >> 1, wc = wid & 1;                                           \
    int row0 = blockIdx.y * 128;                                               \
    const u16* gsrc0 = (wid == 0) ? (AH) : (wid == 1) ? (BH) : (BL);           \
    int rbase = (wid == 0) ? row0 : col0;                                      \
    const u16* gsrc = gsrc0 + (size_t)(rbase + (lane >> 2)) * (KDIM)           \
                            + (((lane & 3) ^ ((lane >> 3) & 3)) * 8);          \
    auto issue = [&](int kt, short* buf) {                                     \
        if (wid < 3) {                                                         \
            char* lbase = (char*)buf + wid * 8192;                             \
            const u16* g = gsrc + kt * 32;                                     \
            _Pragma("unroll")                                                  \
            for (int j = 0; j < 8; ++j) {                                      \
                __builtin_amdgcn_global_load_lds(                              \
                    (g_as1*)(g + (size_t)j * 16 * (KDIM)),                     \
                    (l_as3*)(lbase + j * 1024), 16, 0, 0);                     \
            }                                                                  \
        }                                                                      \
    };                                                                         \
    int l15 = lane & 15, l4 = lane >> 4;                                       \
    const u16* alsrc = (HASAL) ? (AL) : (AH);                                  \
    const u16* alp0 = alsrc + (size_t)(row0 + wr * 64 + l15) * (KDIM) + l4 * 8;\
    const u16* alp1 = alp0 + (size_t)16 * (KDIM);                              \
    const u16* alp2 = alp0 + (size_t)32 * (KDIM);                              \
    const u16* alp3 = alp0 + (size_t)48 * (KDIM);                              \
    f32x4 acc[4][4];                                                           \
    _Pragma("unroll")                                                          \
    for (int i = 0; i < 4; ++i)                                                \
        _Pragma("unroll")                                                      \
        for (int j = 0; j < 4; ++j) acc[i][j] = (f32x4){0.f, 0.f, 0.f, 0.f};   \
    auto compute = [&](const short* buf,                                       \
                       bf16x8 al0, bf16x8 al1, bf16x8 al2, bf16x8 al3) {       \
        const char* Ahi = (const char*)buf;                                    \
        const char* Bhi = (const char*)(buf + 4096);                           \
        const char* Blo = (const char*)(buf + 8192);                           \
        bf16x8 bh[4], bl[4];                                                   \
        _Pragma("unroll")                                                      \
        for (int nc = 0; nc < 4; ++nc) {                                       \
            int col = wc * 64 + nc * 16 + l15;                                 \
            int byt = col * 64 + ((l4 ^ ((col >> 1) & 3)) * 16);               \
            bh[nc] = *(const bf16x8*)(Bhi + byt);                              \
            bl[nc] = *(const bf16x8*)(Blo + byt);                              \
        }                                                                      \
        _Pragma("unroll")                                                      \
        for (int mr = 0; mr < 4; ++mr) {                                       \
            int row = wr * 64 + mr * 16 + l15;                                 \
            int byt = row * 64 + ((l4 ^ ((row >> 1) & 3)) * 16);               \
            bf16x8 ah = *(const bf16x8*)(Ahi + byt);                           \
            bf16x8 al = (mr == 0) ? al0 : (mr == 1) ? al1                      \
                       : (mr == 2) ? al2 : al3;                                \
            _Pragma("unroll")                                                  \
            for (int nc = 0; nc < 4; ++nc) {                                   \
                acc[mr][nc] = __builtin_amdgcn_mfma_f32_16x16x32_bf16(ah, bh[nc], acc[mr][nc], 0, 0, 0); \
                acc[mr][nc] = __builtin_amdgcn_mfma_f32_16x16x32_bf16(ah, bl[nc], acc[mr][nc], 0, 0, 0); \
                if (HASAL)                                                     \
                    acc[mr][nc] = __builtin_amdgcn_mfma_f32_16x16x32_bf16(al, bh[nc], acc[mr][nc], 0, 0, 0); \
            }                                                                  \
        }                                                                      \
    };                                                                         \
    int nk = (KDIM) >> 5;                                                      \
    short* lds0 = lds;                                                         \
    short* lds1 = lds + 12288;                                                 \
    bf16x8 a0A{}, a1A{}, a2A{}, a3A{}, a0B{}, a1B{}, a2B{}, a3B{};             \
    issue(0, lds0);                                                            \
    if (HASAL) {                                                               \
        a0A = *(const bf16x8*)(alp0); a1A = *(const bf16x8*)(alp1);            \
        a2A = *(const bf16x8*)(alp2); a3A = *(const bf16x8*)(alp3);            \
    }                                                                          \
    __syncthreads();                                                           \
    for (int kt = 0; kt < nk; kt += 2) {                                       \
        if (kt + 1 < nk) {                                                     \
            issue(kt + 1, lds1);                                               \
            if (HASAL) {                                                       \
                const int o1 = (kt + 1) * 32;                                  \
                a0B = *(const bf16x8*)(alp0 + o1); a1B = *(const bf16x8*)(alp1 + o1); \
                a2B = *(const bf16x8*)(alp2 + o1); a3B = *(const bf16x8*)(alp3 + o1); \
            }                                                                  \
        }                                                                      \
        compute(lds0, a0A, a1A, a2A, a3A);                                     \
        __syncthreads();                                                       \
        if (kt + 1 < nk) {                                                     \
            if (kt + 2 < nk) {                                                 \
                issue(kt + 2, lds0);                                           \
                if (HASAL) {                                                   \
                    const int o2 = (kt + 2) * 32;                              \
                    a0A = *(const bf16x8*)(alp0 + o2); a1A = *(const bf16x8*)(alp1 + o2); \
                    a2A = *(const bf16x8*)(alp2 + o2); a3A = *(const bf16x8*)(alp3 + o2); \
                }                                                              \
            }                                                                  \
            compute(lds1, a0B, a1B, a2B, a3B);                                 \
            __syncthreads();                                                   \
        }                                                                      \
    }                                                                          \
    _Pragma("unroll")                                                          \
    for (int nc = 0; nc < 4; ++nc) {                                           \
        int col = col0 + wc * 64 + nc * 16 + l15;                              \
        float bv = (BIAS_EXPR);                                                \
        _Pragma("unroll")                                                      \
        for (int mr = 0; mr < 4; ++mr) {                                       \
            int row = row0 + wr * 64 + mr * 16 + l4 * 4;                       \
            _Pragma("unroll")                                                  \
            for (int r = 0; r < 4; ++r) {                                      \
                float v = acc[mr][nc][r] + bv;                                 \
                size_t idx = (size_t)(row + r) * N + col;                      \
                STORE_STMT;                                                    \
            }                                                                  \
        }                                                                      \
    }

// GEMM modes: 0 fp32 C; 1 pair+ReLU; 2 pair; 3 single bf16 + ReLU.
template<int CMODE, int HASAL>
__global__ __launch_bounds__(256, 3) void gemm_pre(
    const u16* __restrict__ Ah, const u16* __restrict__ Al,
    const u16* __restrict__ Bh, const u16* __restrict__ Bl,
    const float* __restrict__ bias, const float* __restrict__ bias2, int nsplit,
    float* __restrict__ Cf, u16* __restrict__ Ch, u16* __restrict__ Cl,
    int N, int K)
{
    int col0 = blockIdx.x * 128;
    GEMM_BODY(Ah, Al, Bh, Bl, K, HASAL,
        (col < nsplit) ? bias[col] : bias2[col - nsplit],
        {
            if (CMODE == 0) { Cf[idx] = v; }
            else if (CMODE == 3) {
                v = fmaxf(v, 0.f);
                Ch[idx] = f2bf(v);
            } else {
                if (CMODE == 1) v = fmaxf(v, 0.f);
                u16 h = f2bf(v);
                Ch[idx] = h;
                Cl[idx] = f2bf(v - bf2f(h));
            }
        })
}

// Fused val + offlog GEMM: bx<2 -> val = oh@Wv; bx>=2 -> offlog = qh@Wc.
__global__ __launch_bounds__(256, 3) void gemm_vo(
    const u16* __restrict__ oh, const u16* __restrict__ ol,
    const u16* __restrict__ qh, const u16* __restrict__ ql,
    const u16* __restrict__ wvh, const u16* __restrict__ wvl,
    const u16* __restrict__ wch, const u16* __restrict__ wcl,
    const float* __restrict__ b_val, const float* __restrict__ b_off,
    const float* __restrict__ b_att,
    float* __restrict__ val, float* __restrict__ offlog)
{
    int bx = blockIdx.x;
    bool isv = bx < 2;
    const u16* Ah = isv ? oh : qh;
    const u16* Al = isv ? ol : ql;
    const u16* Bh = isv ? wvh : wch;
    const u16* Bl = isv ? wvl : wcl;
    float* Cf = isv ? val : offlog;
    int N = isv ? 256 : 384;
    int col0 = isv ? bx * 128 : (bx - 2) * 128;
    GEMM_BODY(Ah, Al, Bh, Bl, 256, 1,
        isv ? b_val[col] : (col < 256 ? b_off[col] : b_att[col - 256]),
        { Cf[idx] = v; })
}

// ---------------------------------------------------------------------------
// OLD MFMA GEMM (fallback path, in-kernel fp32->bf16 split staging)
// ---------------------------------------------------------------------------
template<int RELU, int HASA2>
__global__ __launch_bounds__(256) void gemm_mfma(
    const float* __restrict__ A, const float* __restrict__ A2,
    const short* __restrict__ Whi, const short* __restrict__ Wlo,
    const float* __restrict__ bias, float* __restrict__ C, int N, int K)
{
    __shared__ __align__(16) short lds[2 * 12288];
    int tid  = threadIdx.x;
    int lane = tid & 63, wid = tid >> 6;
    int wr = wid >> 1, wc = wid & 1;
    int row0 = blockIdx.y * 128, col0 = blockIdx.x * 64;
    int srow = tid >> 1, shalf = tid & 1;
    int brow = tid >> 2, bseg = tid & 3;
    const float* Arow  = A + (size_t)(row0 + srow) * K + shalf * 16;
    const float* A2row = HASA2 ? A2 + (size_t)(row0 + srow) * K + shalf * 16 : nullptr;
    const short* Whirow = Whi + (size_t)(col0 + brow) * K + bseg * 8;
    const short* Wlorow = Wlo + (size_t)(col0 + brow) * K + bseg * 8;
    int aswz = (srow >> 1) & 3;
    int a_wb0 = srow * 64 + ((2 * shalf + 0) ^ aswz) * 16;
    int a_wb1 = srow * 64 + ((2 * shalf + 1) ^ aswz) * 16;
    int b_wb  = brow * 64 + ((bseg ^ ((brow >> 1) & 3)) * 16);
    f32x4 acc[4][2];
#pragma unroll
    for (int i = 0; i < 4; ++i)
#pragma unroll
        for (int j = 0; j < 2; ++j) acc[i][j] = (f32x4){0.f, 0.f, 0.f, 0.f};
    float av[16];
    uint4 bhv, blv;
    auto load_stage = [&](int kt) {
        const float4* ap = reinterpret_cast<const float4*>(Arow + kt * 32);
#pragma unroll
        for (int i = 0; i < 4; ++i) {
            float4 v = ap[i];
            av[4 * i + 0] = v.x; av[4 * i + 1] = v.y;
            av[4 * i + 2] = v.z; av[4 * i + 3] = v.w;
        }
        if (HASA2) {
            const float4* a2p = reinterpret_cast<const float4*>(A2row + kt * 32);
#pragma unroll
            for (int i = 0; i < 4; ++i) {
                float4 v = a2p[i];
                av[4 * i + 0] += v.x; av[4 * i + 1] += v.y;
                av[4 * i + 2] += v.z; av[4 * i + 3] += v.w;
            }
        }
        bhv = *reinterpret_cast<const uint4*>(Whirow + kt * 32);
        blv = *reinterpret_cast<const uint4*>(Wlorow + kt * 32);
    };
    auto write_stage = [&](short* buf) {
        unsigned int hw[8], lw[8];
#pragma unroll
        for (int i = 0; i < 8; ++i) {
            u16 h0 = f2bf(av[2 * i]), h1 = f2bf(av[2 * i + 1]);
            u16 l0 = f2bf(av[2 * i] - bf2f(h0));
            u16 l1 = f2bf(av[2 * i + 1] - bf2f(h1));
            hw[i] = (unsigned int)h0 | ((unsigned int)h1 << 16);
            lw[i] = (unsigned int)l0 | ((unsigned int)l1 << 16);
        }
        char* Ahi = (char*)buf;
        char* Alo = (char*)(buf + 4096);
        *(uint4*)(Ahi + a_wb0) = make_uint4(hw[0], hw[1], hw[2], hw[3]);
        *(uint4*)(Ahi + a_wb1) = make_uint4(hw[4], hw[5], hw[6], hw[7]);
        *(uint4*)(Alo + a_wb0) = make_uint4(lw[0], lw[1], lw[2], lw[3]);
        *(uint4*)(Alo + a_wb1) = make_uint4(lw[4], lw[5], lw[6], lw[7]);
        *(uint4*)((char*)(buf + 8192)  + b_wb) = bhv;
        *(uint4*)((char*)(buf + 10240) + b_wb) = blv;
    };
    int l15 = lane & 15, l4 = lane >> 4;
    auto compute = [&](const short* buf) {
        const char* Ahi = (const char*)buf;
        const char* Alo = (const char*)(buf + 4096);
        const char* Bhi = (const char*)(buf + 8192);
        const char* Blo = (const char*)(buf + 10240);
        bf16x8 bh[2], bl[2];
#pragma unroll
        for (int nc = 0; nc < 2; ++nc) {
            int col = wc * 32 + nc * 16 + l15;
            int byt = col * 64 + ((l4 ^ ((col >> 1) & 3)) * 16);
            bh[nc] = *(const bf16x8*)(Bhi + byt);
            bl[nc] = *(const bf16x8*)(Blo + byt);
        }
#pragma unroll
        for (int mr = 0; mr < 4; ++mr) {
            int row = wr * 64 + mr * 16 + l15;
            int byt = row * 64 + ((l4 ^ ((row >> 1) & 3)) * 16);
            bf16x8 ah = *(const bf16x8*)(Ahi + byt);
            bf16x8 al = *(const bf16x8*)(Alo + byt);
#pragma unroll
            for (int nc = 0; nc < 2; ++nc) {
                acc[mr][nc] = __builtin_amdgcn_mfma_f32_16x16x32_bf16(ah, bh[nc], acc[mr][nc], 0, 0, 0);
                acc[mr][nc] = __builtin_amdgcn_mfma_f32_16x16x32_bf16(ah, bl[nc], acc[mr][nc], 0, 0, 0);
                acc[mr][nc] = __builtin_amdgcn_mfma_f32_16x16x32_bf16(al, bh[nc], acc[mr][nc], 0, 0, 0);
            }
        }
    };
    int nk = K >> 5;
    load_stage(0);
    write_stage(lds);
    __syncthreads();
    for (int kt = 0; kt < nk; ++kt) {
        short* cur = lds + (kt & 1) * 12288;
        short* nxt = lds + ((kt & 1) ^ 1) * 12288;
        if (kt + 1 < nk) load_stage(kt + 1);
        compute(cur);
        if (kt + 1 < nk) write_stage(nxt);
        __syncthreads();
    }
#pragma unroll
    for (int nc = 0; nc < 2; ++nc) {
        int col = col0 + wc * 32 + nc * 16 + l15;
        float bv = bias[col];
#pragma unroll
        for (int mr = 0; mr < 4; ++mr) {
            int row = row0 + wr * 64 + mr * 16 + l4 * 4;
#pragma unroll
            for (int r = 0; r < 4; ++r) {
                float v = acc[mr][nc][r] + bv;
                if (RELU) v = fmaxf(v, 0.f);
                C[(size_t)(row + r) * N + col] = v;
            }
        }
    }
}

// ---------------------------------------------------------------------------
// MSDA v3b: LDS-shared weight precompute, gather phase with dual FMA chains.
// ---------------------------------------------------------------------------
__global__ __launch_bounds__(256) void msda3(
    const float* __restrict__ value, const float* __restrict__ offlog,
    u16* __restrict__ eh, u16* __restrict__ el)
{
    __shared__ float aw_lds[32][16];
    __shared__ __align__(16) float wts[32 * 17 * 4];
    __shared__ __align__(16) int   idxs[32 * 17 * 4];

    int tid = threadIdx.x;
    int m0 = blockIdx.x * 4;

    if (tid < 32) {
        int m = m0 + (tid >> 3);
        const float* lg = offlog + (size_t)m * 384 + 256 + (tid & 7) * 16;
        float w[16]; float mx = -1e30f;
#pragma unroll
        for (int i = 0; i < 4; ++i) {
            float4 v = reinterpret_cast<const float4*>(lg)[i];
            w[4 * i] = v.x; w[4 * i + 1] = v.y; w[4 * i + 2] = v.z; w[4 * i + 3] = v.w;
        }
#pragma unroll
        for (int j = 0; j < 16; ++j) mx = fmaxf(mx, w[j]);
        float s = 0.f;
#pragma unroll
        for (int j = 0; j < 16; ++j) { w[j] = __expf(w[j] - mx); s += w[j]; }
        float rs = 1.f / s;
#pragma unroll
        for (int j = 0; j < 16; ++j) aw_lds[tid][j] = w[j] * rs;
    }
    __syncthreads();

#pragma unroll
    for (int pp = 0; pp < 2; ++pp) {
        int pi = tid + 256 * pp;
        int qi = pi >> 7, rem = pi & 127;
        int h = rem >> 4, j = rem & 15;
        int l = j >> 2;
        int m = m0 + qi;
        int b = m / QTOT, q = m - b * QTOT;
        int lq = (q < 4096) ? 0 : (q < 5120) ? 1 : (q < 5376) ? 2 : 3;
        int qbase = (lq == 0) ? 0 : (lq == 1) ? 4096 : (lq == 2) ? 5120 : 5376;
        int qrem = q - qbase;
        int shq = 6 - lq;
        int Wq = 1 << shq;
        int yq = qrem >> shq, xq = qrem & (Wq - 1);
        float invq = 1.0f / (float)Wq;
        float ref_x = (xq + 0.5f) * invq;
        float ref_y = (yq + 0.5f) * invq;
        int HW = 64 >> l;
        float fHW = (float)HW;
        float invl = 1.0f / fHW;
        int loff = (l == 0) ? 0 : (l == 1) ? 4096 : (l == 2) ? 5120 : 5376;
        float ox = offlog[(size_t)m * 384 + h * 32 + j * 2 + 0];
        float oy = offlog[(size_t)m * 384 + h * 32 + j * 2 + 1];
        float aw = aw_lds[qi * 8 + h][j];
        float x = (ref_x + ox * invl) * fHW - 0.5f;
        float y = (ref_y + oy * invl) * fHW - 0.5f;
        float x0f = floorf(x), y0f = floorf(y);
        int x0 = (int)x0f, y0 = (int)y0f;
        float wx = x - x0f, wy = y - y0f;
        float vx0 = (x0 >= 0 && x0 < HW) ? 1.f : 0.f;
        float vx1 = (x0 + 1 >= 0 && x0 + 1 < HW) ? 1.f : 0.f;
        float vy0 = (y0 >= 0 && y0 < HW) ? 1.f : 0.f;
        float vy1 = (y0 + 1 >= 0 && y0 + 1 < HW) ? 1.f : 0.f;
        float w00 = (1.f - wx) * (1.f - wy) * aw * vx0 * vy0;
        float w01 = wx * (1.f - wy) * aw * vx1 * vy0;
        float w10 = (1.f - wx) * wy * aw * vx0 * vy1;
        float w11 = wx * wy * aw * vx1 * vy1;
        int xc0 = min(max(x0, 0), HW - 1);
        int xc1 = min(max(x0 + 1, 0), HW - 1);
        int yc0 = min(max(y0, 0), HW - 1);
        int yc1 = min(max(y0 + 1, 0), HW - 1);
        int rbase = b * QTOT + loff;
        int i00 = (rbase + yc0 * HW + xc0) << 10;
        int i01 = (rbase + yc0 * HW + xc1) << 10;
        int i10 = (rbase + yc1 * HW + xc0) << 10;
        int i11 = (rbase + yc1 * HW + xc1) << 10;
        int sl = (qi * 8 + h) * 17 + j;
        reinterpret_cast<float4*>(wts)[sl] = make_float4(w00, w01, w10, w11);
        reinterpret_cast<int4*>(idxs)[sl] = make_int4(i00, i01, i10, i11);
    }
    __syncthreads();

    int lane = tid & 63;
    int qi = tid >> 6, h = lane >> 3, c8 = lane & 7;
    int m = m0 + qi;
    const char* vb = (const char*)value + h * 128 + c8 * 16;
    int base = (qi * 8 + h) * 17;
    float a0 = 0.f, a1 = 0.f, a2 = 0.f, a3 = 0.f;
    float b0 = 0.f, b1 = 0.f, b2 = 0.f, b3 = 0.f;
#pragma unroll
    for (int j = 0; j < 16; j += 2) {
        float4 w0 = reinterpret_cast<const float4*>(wts)[base + j];
        int4  x0 = reinterpret_cast<const int4*>(idxs)[base + j];
        float4 w1 = reinterpret_cast<const float4*>(wts)[base + j + 1];
        int4  x1 = reinterpret_cast<const int4*>(idxs)[base + j + 1];
        float4 v00 = *reinterpret_cast<const float4*>(vb + x0.x);
        float4 v01 = *reinterpret_cast<const float4*>(vb + x0.y);
        float4 v10 = *reinterpret_cast<const float4*>(vb + x0.z);
        float4 v11 = *reinterpret_cast<const float4*>(vb + x0.w);
        float4 u00 = *reinterpret_cast<const float4*>(vb + x1.x);
        float4 u01 = *reinterpret_cast<const float4*>(vb + x1.y);
        float4 u10 = *reinterpret_cast<const float4*>(vb + x1.z);
        float4 u11 = *reinterpret_cast<const float4*>(vb + x1.w);
        a0 += w0.x * v00.x + w0.y * v01.x + w0.z * v10.x + w0.w * v11.x;
        a1 += w0.x * v00.y + w0.y * v01.y + w0.z * v10.y + w0.w * v11.y;
        a2 += w0.x * v00.z + w0.y * v01.z + w0.z * v10.z + w0.w * v11.z;
        a3 += w0.x * v00.w + w0.y * v01.w + w0.z * v10.w + w0.w * v11.w;
        b0 += w1.x * u00.x + w1.y * u01.x + w1.z * u10.x + w1.w * u11.x;
        b1 += w1.x * u00.y + w1.y * u01.y + w1.z * u10.y + w1.w * u11.y;
        b2 += w1.x * u00.z + w1.y * u01.z + w1.z * u10.z + w1.w * u11.z;
        b3 += w1.x * u00.w + w1.y * u01.w + w1.z * u10.w + w1.w * u11.w;
    }
    a0 += b0; a1 += b1; a2 += b2; a3 += b3;
    size_t oidx = (size_t)m * D_MODEL + h * 32 + c8 * 4;
    ushort4 hv, lv;
    hv.x = f2bf(a0); lv.x = f2bf(a0 - bf2f(hv.x));
    hv.y = f2bf(a1); lv.y = f2bf(a1 - bf2f(hv.y));
    hv.z = f2bf(a2); lv.z = f2bf(a2 - bf2f(hv.z));
    hv.w = f2bf(a3); lv.w = f2bf(a3 - bf2f(hv.w));
    *reinterpret_cast<ushort4*>(eh + oidx) = hv;
    *reinterpret_cast<ushort4*>(el + oidx) = lv;
}

// msda (old, fallback): separate off/logits, fp32 out
__global__ __launch_bounds__(256) void msda2(
    const float* __restrict__ value, const float* __restrict__ off,
    const float* __restrict__ logits, float* __restrict__ outp)
{
    const int lvl_off[4] = {0, 4096, 5120, 5376};
    const int lvl_hw[4]  = {64, 32, 16, 8};
    int m = blockIdx.x * 4 + (threadIdx.x >> 6);
    int lane = threadIdx.x & 63;
    int h = lane >> 3, c = (lane & 7) * 4;
    int b = m / QTOT, q = m - b * QTOT;
    int lq, rem;
    if      (q < 4096) { lq = 0; rem = q; }
    else if (q < 5120) { lq = 1; rem = q - 4096; }
    else if (q < 5376) { lq = 2; rem = q - 5120; }
    else               { lq = 3; rem = q - 5376; }
    int Wq = lvl_hw[lq];
    int yq = rem / Wq, xq = rem - yq * Wq;
    float ref_x = (xq + 0.5f) / (float)Wq;
    float ref_y = (yq + 0.5f) / (float)Wq;
    const float* lg = logits + (size_t)m * 128 + h * 16;
    float w[16];
    {
        float mx = -1e30f;
#pragma unroll
        for (int i = 0; i < 4; ++i) {
            float4 v = reinterpret_cast<const float4*>(lg)[i];
            w[4 * i] = v.x; w[4 * i + 1] = v.y; w[4 * i + 2] = v.z; w[4 * i + 3] = v.w;
        }
#pragma unroll
        for (int j = 0; j < 16; ++j) mx = fmaxf(mx, w[j]);
        float s = 0.f;
#pragma unroll
        for (int j = 0; j < 16; ++j) { w[j] = __expf(w[j] - mx); s += w[j]; }
        float rs = 1.f / s;
#pragma unroll
        for (int j = 0; j < 16; ++j) w[j] *= rs;
    }
    float ofv[32];
    const float* op = off + (size_t)m * 256 + h * 32;
#pragma unroll
    for (int i = 0; i < 8; ++i) {
        float4 v = reinterpret_cast<const float4*>(op)[i];
        ofv[4 * i] = v.x; ofv[4 * i + 1] = v.y; ofv[4 * i + 2] = v.z; ofv[4 * i + 3] = v.w;
    }
    float a0 = 0.f, a1 = 0.f, a2 = 0.f, a3 = 0.f;
#pragma unroll
    for (int l = 0; l < 4; ++l) {
        int HW = lvl_hw[l];
        float fHW = (float)HW;
        const float* vbase =
            value + ((size_t)(b * QTOT + lvl_off[l])) * D_MODEL + h * 32 + c;
#pragma unroll
        for (int p = 0; p < 4; ++p) {
            float ox = ofv[(l * 4 + p) * 2 + 0];
            float oy = ofv[(l * 4 + p) * 2 + 1];
            float aw = w[l * 4 + p];
            float x = (ref_x + ox / fHW) * fHW - 0.5f;
            float y = (ref_y + oy / fHW) * fHW - 0.5f;
            float x0f = floorf(x), y0f = floorf(y);
            int   x0 = (int)x0f,  y0 = (int)y0f;
            float wx = x - x0f,   wy = y - y0f;
            float w00 = (1.f - wx) * (1.f - wy) * aw, w01 = wx * (1.f - wy) * aw;
            float w10 = (1.f - wx) * wy * aw,         w11 = wx * wy * aw;
            bool xv0 = (x0 >= 0) && (x0 < HW);
            bool xv1 = (x0 + 1 >= 0) && (x0 + 1 < HW);
            bool yv0 = (y0 >= 0) && (y0 < HW);
            bool yv1 = (y0 + 1 >= 0) && (y0 + 1 < HW);
#define GATH(cond, idx, wgt)                                                  \
            if (cond) {                                                       \
                float4 v = *reinterpret_cast<const float4*>(                  \
                    vbase + (size_t)(idx) * D_MODEL);                         \
                a0 += (wgt) * v.x; a1 += (wgt) * v.y;                         \
                a2 += (wgt) * v.z; a3 += (wgt) * v.w;                         \
            }
            GATH(xv0 && yv0, y0 * HW + x0,           w00)
            GATH(xv1 && yv0, y0 * HW + x0 + 1,       w01)
            GATH(xv0 && yv1, (y0 + 1) * HW + x0,     w10)
            GATH(xv1 && yv1, (y0 + 1) * HW + x0 + 1, w11)
#undef GATH
        }
    }
    float4 o = make_float4(a0, a1, a2, a3);
    *reinterpret_cast<float4*>(&outp[(size_t)m * D_MODEL + h * 32 + c]) = o;
}

// ---------------------------------------------------------------------------
// add+LN on pair-stored residual (4 rows/block, wave per row).
// TMODE 0: t fp32.  TMODE 1: t bf16 pair (th, tl).
// WRITEQ: also q = y + posf -> qh/ql.  WRITEF32: y -> f32out.
// ---------------------------------------------------------------------------
template<int TMODE, int WRITEQ, int WRITEF32>
__global__ __launch_bounds__(256) void add_ln_pair(
    const float* __restrict__ t, const u16* __restrict__ th,
    const u16* __restrict__ tl,
    const float* __restrict__ g, const float* __restrict__ beta,
    u16* __restrict__ oh, u16* __restrict__ ol,
    const float* __restrict__ posf, u16* __restrict__ qh, u16* __restrict__ ql,
    float* __restrict__ f32out)
{
    int row = blockIdx.x * 4 + (threadIdx.x >> 6);
    int lane = threadIdx.x & 63;
    size_t base = (size_t)row * D_MODEL + lane * 4;
    ushort4 hv = *reinterpret_cast<const ushort4*>(oh + base);
    ushort4 lv = *reinterpret_cast<const ushort4*>(ol + base);
    float t0, t1, t2, t3;
    if (TMODE == 0) {
        float4 tv = *reinterpret_cast<const float4*>(t + base);
        t0 = tv.x; t1 = tv.y; t2 = tv.z; t3 = tv.w;
    } else {
        ushort4 thv = *reinterpret_cast<const ushort4*>(th + base);
        ushort4 tlv = *reinterpret_cast<const ushort4*>(tl + base);
        t0 = bf2f(thv.x) + bf2f(tlv.x);
        t1 = bf2f(thv.y) + bf2f(tlv.y);
        t2 = bf2f(thv.z) + bf2f(tlv.z);
        t3 = bf2f(thv.w) + bf2f(tlv.w);
    }
    float v0 = bf2f(hv.x) + bf2f(lv.x) + t0;
    float v1 = bf2f(hv.y) + bf2f(lv.y) + t1;
    float v2 = bf2f(hv.z) + bf2f(lv.z) + t2;
    float v3 = bf2f(hv.w) + bf2f(lv.w) + t3;
    float s = v0 + v1 + v2 + v3;
#pragma unroll
    for (int o = 32; o > 0; o >>= 1) s += __shfl_xor(s, o);
    float mean = s * (1.f / D_MODEL);
    float d0 = v0 - mean, d1 = v1 - mean, d2 = v2 - mean, d3 = v3 - mean;
    float ss = d0 * d0 + d1 * d1 + d2 * d2 + d3 * d3;
#pragma unroll
    for (int o = 32; o > 0; o >>= 1) ss += __shfl_xor(ss, o);
    float rstd = rsqrtf(ss * (1.f / D_MODEL) + 1e-5f);
    float4 gv = *reinterpret_cast<const float4*>(&g[lane * 4]);
    float4 bv = *reinterpret_cast<const float4*>(&beta[lane * 4]);
    float y0 = d0 * rstd * gv.x + bv.x;
    float y1 = d1 * rstd * gv.y + bv.y;
    float y2 = d2 * rstd * gv.z + bv.z;
    float y3 = d3 * rstd * gv.w + bv.w;
    ushort4 nh, nl;
    nh.x = f2bf(y0); nl.x = f2bf(y0 - bf2f(nh.x));
    nh.y = f2bf(y1); nl.y = f2bf(y1 - bf2f(nh.y));
    nh.z = f2bf(y2); nl.z = f2bf(y2 - bf2f(nh.z));
    nh.w = f2bf(y3); nl.w = f2bf(y3 - bf2f(nh.w));
    *reinterpret_cast<ushort4*>(oh + base) = nh;
    *reinterpret_cast<ushort4*>(ol + base) = nl;
    if (WRITEQ) {
        float4 pv = *reinterpret_cast<const float4*>(posf + base);
        float q0 = y0 + pv.x, q1 = y1 + pv.y, q2 = y2 + pv.z, q3 = y3 + pv.w;
        ushort4 qhv, qlv;
        qhv.x = f2bf(q0); qlv.x = f2bf(q0 - bf2f(qhv.x));
        qhv.y = f2bf(q1); qlv.y = f2bf(q1 - bf2f(qhv.y));
        qhv.z = f2bf(q2); qlv.z = f2bf(q2 - bf2f(qhv.z));
        qhv.w = f2bf(q3); qlv.w = f2bf(q3 - bf2f(qhv.w));
        *reinterpret_cast<ushort4*>(qh + base) = qhv;
        *reinterpret_cast<ushort4*>(ql + base) = qlv;
    }
    if (WRITEF32) {
        *reinterpret_cast<float4*>(f32out + base) = make_float4(y0, y1, y2, y3);
    }
}

// old add_ln (fallback): in-place fp32
__global__ __launch_bounds__(64) void add_ln(
    const float* __restrict__ t, const float* __restrict__ g,
    const float* __restrict__ beta, float* __restrict__ x)
{
    int row = blockIdx.x;
    int lane = threadIdx.x;
    size_t base = (size_t)row * D_MODEL + lane * 4;
    float4 xv = *reinterpret_cast<const float4*>(&x[base]);
    float4 tv = *reinterpret_cast<const float4*>(&t[base]);
    float v0 = xv.x + tv.x, v1 = xv.y + tv.y, v2 = xv.z + tv.z, v3 = xv.w + tv.w;
    float s = v0 + v1 + v2 + v3;
#pragma unroll
    for (int o = 32; o > 0; o >>= 1) s += __shfl_xor(s, o);
    float mean = s * (1.f / D_MODEL);
    float d0 = v0 - mean, d1 = v1 - mean, d2 = v2 - mean, d3 = v3 - mean;
    float ss = d0 * d0 + d1 * d1 + d2 * d2 + d3 * d3;
#pragma unroll
    for (int o = 32; o > 0; o >>= 1) ss += __shfl_xor(ss, o);
    float rstd = rsqrtf(ss * (1.f / D_MODEL) + 1e-5f);
    float4 gv = *reinterpret_cast<const float4*>(&g[lane * 4]);
    float4 bv = *reinterpret_cast<const float4*>(&beta[lane * 4]);
    float4 ov = make_float4(d0 * rstd * gv.x + bv.x, d1 * rstd * gv.y + bv.y,
                            d2 * rstd * gv.z + bv.z, d3 * rstd * gv.w + bv.w);
    *reinterpret_cast<float4*>(&x[base]) = ov;
}

// ---------------------------------------------------------------------------
extern "C" void kernel_launch(void* const* d_in, const int* in_sizes, int n_in,
                              void* d_out, int out_size, void* d_ws, size_t ws_size,
                              hipStream_t stream)
{
    // dict order is INTERLEAVED: src0,pos0,src1,pos1,...
    const float* src[4] = {(const float*)d_in[0], (const float*)d_in[2],
                           (const float*)d_in[4], (const float*)d_in[6]};
    const float* pos[4] = {(const float*)d_in[1], (const float*)d_in[3],
                           (const float*)d_in[5], (const float*)d_in[7]};
    const float* lvl   = (const float*)d_in[8];
    const float* W_off = (const float*)d_in[9];
    const float* b_off = (const float*)d_in[10];
    const float* W_att = (const float*)d_in[11];
    const float* b_att = (const float*)d_in[12];
    const float* W_val = (const float*)d_in[13];
    const float* b_val = (const float*)d_in[14];
    const float* W_out = (const float*)d_in[15];
    const float* b_out = (const float*)d_in[16];
    const float* ln1g  = (const float*)d_in[17];
    const float* ln1b  = (const float*)d_in[18];
    const float* W_ff1 = (const float*)d_in[19];
    const float* b_ff1 = (const float*)d_in[20];
    const float* W_ff2 = (const float*)d_in[21];
    const float* b_ff2 = (const float*)d_in[22];
    const float* ln2g  = (const float*)d_in[23];
    const float* ln2b  = (const float*)d_in[24];

    float* ws = (float*)d_ws;
    const size_t MD = (size_t)MTOT * D_MODEL;    // 5,570,560

    const int hws[4]  = {4096, 1024, 256, 64};
    const int qoff[4] = {0, 4096, 5120, 5376};

    // ---- NEW path layout ----
    float* posf = ws;                                    // fp32 [M,256]
    u16* oh = (u16*)(ws + MD);
    u16* ol = oh + MD;
    u16* qh = ol + MD;                                   // q / e / ff2-out pair
    u16* ql = qh + MD;
    u16* eh = qh; u16* el = ql;
    float* val    = (float*)(ql + MD);                   // fp32 [M,256]
    float* offlog = val + MD;                            // fp32 [M,384]; tmp
    float* tmp    = offlog;
    u16* hid = (u16*)val;   // FFN hidden, SINGLE bf16, full M: [M,1024]=44.6MB
                            // spans val(22.3MB)+offlog(33.4MB) region
    u16* wb = (u16*)(offlog + (size_t)MTOT * 384);
    size_t o = 0;
    u16* wv_h = wb + o; o += 6 * 65536;  u16* wv_l = wb + o; o += 6 * 65536;
    u16* wc_h = wb + o; o += 6 * 98304;  u16* wc_l = wb + o; o += 6 * 98304;
    u16* wu_h = wb + o; o += 6 * 65536;  u16* wu_l = wb + o; o += 6 * 65536;
    u16* wf1_h = wb + o; o += 6 * 262144; u16* wf1_l = wb + o; o += 6 * 262144;
    u16* wf2_h = wb + o; o += 6 * 262144; u16* wf2_l = wb + o; o += 6 * 262144;
    const size_t NEED = (size_t)((char*)(wb + o) - (char*)ws);   // ~140.6 MB

    if (ws_size >= NEED) {
        dim3 cb(32, 8);
        flatten_all<<<dim3(170, 8, BATCH), cb, 0, stream>>>(
            src[0], src[1], src[2], src[3], pos[0], pos[1], pos[2], pos[3],
            lvl, posf, oh, ol, qh, ql);
        wconv_all<<<6 * 736, cb, 0, stream>>>(
            W_val, W_off, W_att, W_out, W_ff1, W_ff2,
            wv_h, wv_l, wc_h, wc_l, wu_h, wu_l, wf1_h, wf1_l, wf2_h, wf2_l);

        for (int i = 0; i < NLAYER; ++i) {
            gemm_vo<<<dim3(5, 170), 256, 0, stream>>>(
                oh, ol, qh, ql,
                wv_h + i * 65536, wv_l + i * 65536,
                wc_h + i * 98304, wc_l + i * 98304,
                b_val + i * 256, b_off + i * 256, b_att + i * 128,
                val, offlog);
            msda3<<<MTOT / 4, 256, 0, stream>>>(val, offlog, eh, el);
            gemm_pre<0, 1><<<dim3(2, 170), 256, 0, stream>>>(
                eh, el, wu_h + i * 65536, wu_l + i * 65536,
                b_out + i * 256, b_out + i * 256, 256, tmp, nullptr, nullptr, 256, 256);
            add_ln_pair<0, 0, 0><<<MTOT / 4, 256, 0, stream>>>(
                tmp, nullptr, nullptr, ln1g + i * 256, ln1b + i * 256, oh, ol,
                nullptr, nullptr, nullptr, nullptr);
            // FFN full-M: ff1 -> single-bf16 hidden; ff2 2-pass (no A-lo).
            gemm_pre<3, 1><<<dim3(8, 170), 256, 0, stream>>>(
                oh, ol, wf1_h + i * 262144, wf1_l + i * 262144,
                b_ff1 + i * 1024, b_ff1 + i * 1024, 1024,
                nullptr, hid, nullptr, 1024, 256);
            gemm_pre<2, 0><<<dim3(2, 170), 256, 0, stream>>>(
                hid, nullptr, wf2_h + i * 262144, wf2_l + i * 262144,
                b_ff2 + i * 256, b_ff2 + i * 256, 256,
                nullptr, eh, el, 256, 1024);
            if (i < NLAYER - 1)
                add_ln_pair<1, 1, 0><<<MTOT / 4, 256, 0, stream>>>(
                    nullptr, eh, el, ln2g + i * 256, ln2b + i * 256, oh, ol,
                    posf, qh, ql, nullptr);
            else
                add_ln_pair<1, 0, 1><<<MTOT / 4, 256, 0, stream>>>(
                    nullptr, eh, el, ln2g + i * 256, ln2b + i * 256, oh, ol,
                    nullptr, nullptr, nullptr, (float*)d_out);
        }
    } else {
        // ---- FALLBACK: round-3 proven path (~118.4 MB) ----
        float* out = (float*)d_out;
        float* posf2  = ws;
        float* val2   = posf2 + MD;
        float* logits = val2 + MD;
        float* offb   = logits + (size_t)MTOT * 128;
        float* ebuf   = offb + MD;
        float* tmp2   = offb;
        float* hid2   = offb;
        short* wbase = (short*)(ebuf + MD);
        short* v_h = wbase;               short* v_l = v_h + 6 * 65536;
        short* o_h = v_l + 6 * 65536;     short* o_l = o_h + 6 * 65536;
        short* a_h = o_l + 6 * 65536;     short* a_l = a_h + 6 * 32768;
        short* u_h = a_l + 6 * 32768;     short* u_l = u_h + 6 * 65536;
        short* f1h = u_l + 6 * 65536;     short* f1l = f1h + 6 * 262144;
        short* f2h = f1l + 6 * 262144;    short* f2l = f2h + 6 * 262144;
        dim3 cb(32, 8);
        for (int l = 0; l < 4; ++l) {
            dim3 g(hws[l] / 32, D_MODEL / 32, BATCH);
            flatten_tr<<<g, cb, 0, stream>>>(src[l], nullptr, out, hws[l], qoff[l]);
            flatten_tr<<<g, cb, 0, stream>>>(pos[l], lvl + l * D_MODEL, posf2, hws[l], qoff[l]);
        }
        wconv<<<dim3(8, 8, 6),  cb, 0, stream>>>(W_val, (u16*)v_h, (u16*)v_l, 256, 256, 65536);
        wconv<<<dim3(8, 8, 6),  cb, 0, stream>>>(W_off, (u16*)o_h, (u16*)o_l, 256, 256, 65536);
        wconv<<<dim3(4, 8, 6),  cb, 0, stream>>>(W_att, (u16*)a_h, (u16*)a_l, 256, 128, 32768);
        wconv<<<dim3(8, 8, 6),  cb, 0, stream>>>(W_out, (u16*)u_h, (u16*)u_l, 256, 256, 65536);
        wconv<<<dim3(32, 8, 6), cb, 0, stream>>>(W_ff1, (u16*)f1h, (u16*)f1l, 256, 1024, 262144);
        wconv<<<dim3(8, 32, 6), cb, 0, stream>>>(W_ff2, (u16*)f2h, (u16*)f2l, 1024, 256, 262144);
        for (int i = 0; i < NLAYER; ++i) {
            gemm_mfma<0,0><<<dim3(4, 170), 256, 0, stream>>>(
                out, nullptr, v_h + i * 65536, v_l + i * 65536,
                b_val + i * 256, val2, 256, 256);
            gemm_mfma<0,1><<<dim3(4, 170), 256, 0, stream>>>(
                out, posf2, o_h + i * 65536, o_l + i * 65536,
                b_off + i * 256, offb, 256, 256);
            gemm_mfma<0,1><<<dim3(2, 170), 256, 0, stream>>>(
                out, posf2, a_h + i * 32768, a_l + i * 32768,
                b_att + i * 128, logits, 128, 256);
            msda2<<<MTOT / 4, 256, 0, stream>>>(val2, offb, logits, ebuf);
            gemm_mfma<0,0><<<dim3(4, 170), 256, 0, stream>>>(
                ebuf, nullptr, u_h + i * 65536, u_l + i * 65536,
                b_out + i * 256, tmp2, 256, 256);
            add_ln<<<MTOT, 64, 0, stream>>>(tmp2, ln1g + i * 256, ln1b + i * 256, out);
            for (int h = 0; h < 2; ++h) {
                gemm_mfma<1,0><<<dim3(16, 85), 256, 0, stream>>>(
                    out + (size_t)h * MHALF * 256, nullptr,
                    f1h + i * 262144, f1l + i * 262144,
                    b_ff1 + i * 1024, hid2, 1024, 256);
                gemm_mfma<0,0><<<dim3(4, 85), 256, 0, stream>>>(
                    hid2, nullptr, f2h + i * 262144, f2l + i * 262144,
                    b_ff2 + i * 256, val2 + (size_t)h * MHALF * 256, 256, 1024);
            }
            add_ln<<<MTOT, 64, 0, stream>>>(val2, ln2g + i * 256, ln2b + i * 256, out);
        }
    }
    (void)in_sizes; (void)n_in; (void)out_size;
}

// Round 14
// 1242.258 us; speedup vs baseline: 4.1524x; 1.0754x over previous
//
#include <hip/hip_runtime.h>
#include <cstddef>
#include <cstdint>

#define D_MODEL 256
#define NHEAD   8
#define NLAYER  6
#define BATCH   4
#define QTOT    5440
#define MTOT    (BATCH*QTOT)   // 21760 = 170*128
#define DFFN    1024

typedef short  bf16x8 __attribute__((ext_vector_type(8)));
typedef float  f32x4  __attribute__((ext_vector_type(4)));
typedef unsigned short u16;

typedef __attribute__((address_space(1))) const void g_as1;
typedef __attribute__((address_space(3))) void l_as3;

__device__ __forceinline__ u16 f2bf(float f) {
    uint32_t u = __float_as_uint(f);
    return (u16)((u + 0x7fffu + ((u >> 16) & 1u)) >> 16);
}
__device__ __forceinline__ float bf2f(u16 s) {
    return __uint_as_float(((uint32_t)s) << 16);
}

// Bijective XCD-aware swizzle (m204): maps linear bid -> tile id g so each
// XCD (bid%8) owns a contiguous chunk of g; with col-fastest tile decode,
// one row panel's col-blocks land on the same XCD's L2.
__device__ __forceinline__ int xcd_remap(int bid, int nwg) {
    int xcd = bid & 7, slot = bid >> 3;
    int q = nwg >> 3, r = nwg & 7;
    return (xcd < r ? xcd * (q + 1) : r * (q + 1) + (xcd - r) * q) + slot;
}

// ---------------------------------------------------------------------------
// FUSED flatten: all 4 levels, src+pos in one pass.
// Writes posf (fp32), oh/ol (out pair), qh/ql (q pair).
// ---------------------------------------------------------------------------
__global__ __launch_bounds__(256) void flatten_all(
    const float* __restrict__ s0, const float* __restrict__ s1,
    const float* __restrict__ s2, const float* __restrict__ s3,
    const float* __restrict__ p0, const float* __restrict__ p1,
    const float* __restrict__ p2, const float* __restrict__ p3,
    const float* __restrict__ lvl, float* __restrict__ posf,
    u16* __restrict__ oh, u16* __restrict__ ol,
    u16* __restrict__ qh, u16* __restrict__ ql)
{
    __shared__ float ts[32][33];
    __shared__ float tp[32][33];
    int bx = blockIdx.x;
    int l, hw0, qoff, HW;
    if (bx < 128)      { l = 0; hw0 = bx * 32;         qoff = 0;    HW = 4096; }
    else if (bx < 160) { l = 1; hw0 = (bx - 128) * 32; qoff = 4096; HW = 1024; }
    else if (bx < 168) { l = 2; hw0 = (bx - 160) * 32; qoff = 5120; HW = 256;  }
    else               { l = 3; hw0 = (bx - 168) * 32; qoff = 5376; HW = 64;   }
    const float* src = (l == 0) ? s0 : (l == 1) ? s1 : (l == 2) ? s2 : s3;
    const float* pos = (l == 0) ? p0 : (l == 1) ? p1 : (l == 2) ? p2 : p3;
    int tx = threadIdx.x, ty = threadIdx.y;
    int d0 = blockIdx.y * 32, b = blockIdx.z;
    const float* sp = src + (size_t)b * D_MODEL * HW;
    const float* pp = pos + (size_t)b * D_MODEL * HW;
#pragma unroll
    for (int j = 0; j < 4; ++j) {
        size_t off = (size_t)(d0 + ty + j * 8) * HW + hw0 + tx;
        ts[ty + j * 8][tx] = sp[off];
        tp[ty + j * 8][tx] = pp[off];
    }
    __syncthreads();
    float emb = lvl[l * D_MODEL + d0 + tx];
#pragma unroll
    for (int j = 0; j < 4; ++j) {
        int hw = ty + j * 8;
        float v = ts[tx][hw];
        float pv = tp[tx][hw] + emb;
        size_t idx = ((size_t)b * QTOT + qoff + hw0 + hw) * D_MODEL + d0 + tx;
        posf[idx] = pv;
        u16 h = f2bf(v);
        oh[idx] = h; ol[idx] = f2bf(v - bf2f(h));
        float q = v + pv;
        u16 qhv = f2bf(q);
        qh[idx] = qhv; ql[idx] = f2bf(q - bf2f(qhv));
    }
}

// ---------------------------------------------------------------------------
// FUSED weight convert: all 6 weight types x 6 layers in one dispatch.
// W fp32 [L][K][N] -> hi/lo bf16 [L][N][K].
// ---------------------------------------------------------------------------
__global__ __launch_bounds__(256) void wconv_all(
    const float* __restrict__ Wv, const float* __restrict__ Wo,
    const float* __restrict__ Wa, const float* __restrict__ Wu,
    const float* __restrict__ Wf1, const float* __restrict__ Wf2,
    u16* __restrict__ wv_h, u16* __restrict__ wv_l,
    u16* __restrict__ wc_h, u16* __restrict__ wc_l,
    u16* __restrict__ wu_h, u16* __restrict__ wu_l,
    u16* __restrict__ wf1_h, u16* __restrict__ wf1_l,
    u16* __restrict__ wf2_h, u16* __restrict__ wf2_l)
{
    __shared__ float t[32][33];
    int id = blockIdx.x;
    int layer = id / 736, r = id - layer * 736;
    const float* W; u16* Hl; u16* Ll; int K, N, n0, k0;
    if (r < 64) {
        W = Wv + (size_t)layer * 65536;
        Hl = wv_h + (size_t)layer * 65536; Ll = wv_l + (size_t)layer * 65536;
        K = 256; N = 256; n0 = (r & 7) * 32; k0 = (r >> 3) * 32;
    } else if (r < 128) {
        r -= 64;
        W = Wo + (size_t)layer * 65536;
        Hl = wc_h + (size_t)layer * 98304; Ll = wc_l + (size_t)layer * 98304;
        K = 256; N = 256; n0 = (r & 7) * 32; k0 = (r >> 3) * 32;
    } else if (r < 160) {
        r -= 128;
        W = Wa + (size_t)layer * 32768;
        Hl = wc_h + (size_t)layer * 98304 + 65536;
        Ll = wc_l + (size_t)layer * 98304 + 65536;
        K = 256; N = 128; n0 = (r & 3) * 32; k0 = (r >> 2) * 32;
    } else if (r < 224) {
        r -= 160;
        W = Wu + (size_t)layer * 65536;
        Hl = wu_h + (size_t)layer * 65536; Ll = wu_l + (size_t)layer * 65536;
        K = 256; N = 256; n0 = (r & 7) * 32; k0 = (r >> 3) * 32;
    } else if (r < 480) {
        r -= 224;
        W = Wf1 + (size_t)layer * 262144;
        Hl = wf1_h + (size_t)layer * 262144; Ll = wf1_l + (size_t)layer * 262144;
        K = 256; N = 1024; n0 = (r & 31) * 32; k0 = (r >> 5) * 32;
    } else {
        r -= 480;
        W = Wf2 + (size_t)layer * 262144;
        Hl = wf2_h + (size_t)layer * 262144; Ll = wf2_l + (size_t)layer * 262144;
        K = 1024; N = 256; n0 = (r & 7) * 32; k0 = (r >> 3) * 32;
    }
    int tx = threadIdx.x, ty = threadIdx.y;
#pragma unroll
    for (int j = 0; j < 4; ++j)
        t[ty + j * 8][tx] = W[(size_t)(k0 + ty + j * 8) * N + n0 + tx];
    __syncthreads();
#pragma unroll
    for (int j = 0; j < 4; ++j) {
        float v = t[tx][ty + j * 8];
        int n = n0 + ty + j * 8, k = k0 + tx;
        u16 h = f2bf(v);
        Hl[(size_t)n * K + k] = h;
        Ll[(size_t)n * K + k] = f2bf(v - bf2f(h));
    }
}

// ---------------------------------------------------------------------------
// Shared GEMM body: BM=128 BN=128 BK=32; global_load_lds staging
// (Ahi|Bhi|Blo LDS), A-lo in registers (HASAL=1 -> 3-pass; 0 -> 2-pass).
// Expects `row0` and `col0` already defined in enclosing scope.
// ---------------------------------------------------------------------------
#define GEMM_BODY(AH, AL, BH, BL, KDIM, HASAL, BIAS_EXPR, STORE_STMT)          \
    __shared__ __align__(16) short lds[2 * 12288];  /* 2 x 24 KB */            \
    int tid  = threadIdx.x;                                                    \
    int lane = tid & 63, wid = tid >> 6;                                       \
    int wr = wid >> 1, wc = wid & 1;                                           \
    const u16* gsrc0 = (wid == 0) ? (AH) : (wid == 1) ? (BH) : (BL);           \
    int rbase = (wid == 0) ? row0 : col0;                                      \
    const u16* gsrc = gsrc0 + (size_t)(rbase + (lane >> 2)) * (KDIM)           \
                            + (((lane & 3) ^ ((lane >> 3) & 3)) * 8);          \
    auto issue = [&](int kt, short* buf) {                                     \
        if (wid < 3) {                                                         \
            char* lbase = (char*)buf + wid * 8192;                             \
            const u16* g = gsrc + kt * 32;                                     \
            _Pragma("unroll")                                                  \
            for (int j = 0; j < 8; ++j) {                                      \
                __builtin_amdgcn_global_load_lds(                              \
                    (g_as1*)(g + (size_t)j * 16 * (KDIM)),                     \
                    (l_as3*)(lbase + j * 1024), 16, 0, 0);                     \
            }                                                                  \
        }                                                                      \
    };                                                                         \
    int l15 = lane & 15, l4 = lane >> 4;                                       \
    const u16* alsrc = (HASAL) ? (AL) : (AH);                                  \
    const u16* alp0 = alsrc + (size_t)(row0 + wr * 64 + l15) * (KDIM) + l4 * 8;\
    const u16* alp1 = alp0 + (size_t)16 * (KDIM);                              \
    const u16* alp2 = alp0 + (size_t)32 * (KDIM);                              \
    const u16* alp3 = alp0 + (size_t)48 * (KDIM);                              \
    f32x4 acc[4][4];                                                           \
    _Pragma("unroll")                                                          \
    for (int i = 0; i < 4; ++i)                                                \
        _Pragma("unroll")                                                      \
        for (int j = 0; j < 4; ++j) acc[i][j] = (f32x4){0.f, 0.f, 0.f, 0.f};   \
    auto compute = [&](const short* buf,                                       \
                       bf16x8 al0, bf16x8 al1, bf16x8 al2, bf16x8 al3) {       \
        const char* Ahi = (const char*)buf;                                    \
        const char* Bhi = (const char*)(buf + 4096);                           \
        const char* Blo = (const char*)(buf + 8192);                           \
        bf16x8 bh[4], bl[4];                                                   \
        _Pragma("unroll")                                                      \
        for (int nc = 0; nc < 4; ++nc) {                                       \
            int col = wc * 64 + nc * 16 + l15;                                 \
            int byt = col * 64 + ((l4 ^ ((col >> 1) & 3)) * 16);               \
            bh[nc] = *(const bf16x8*)(Bhi + byt);                              \
            bl[nc] = *(const bf16x8*)(Blo + byt);                              \
        }                                                                      \
        _Pragma("unroll")                                                      \
        for (int mr = 0; mr < 4; ++mr) {                                       \
            int row = wr * 64 + mr * 16 + l15;                                 \
            int byt = row * 64 + ((l4 ^ ((row >> 1) & 3)) * 16);               \
            bf16x8 ah = *(const bf16x8*)(Ahi + byt);                           \
            bf16x8 al = (mr == 0) ? al0 : (mr == 1) ? al1                      \
                       : (mr == 2) ? al2 : al3;                                \
            _Pragma("unroll")                                                  \
            for (int nc = 0; nc < 4; ++nc) {                                   \
                acc[mr][nc] = __builtin_amdgcn_mfma_f32_16x16x32_bf16(ah, bh[nc], acc[mr][nc], 0, 0, 0); \
                acc[mr][nc] = __builtin_amdgcn_mfma_f32_16x16x32_bf16(ah, bl[nc], acc[mr][nc], 0, 0, 0); \
                if (HASAL)                                                     \
                    acc[mr][nc] = __builtin_amdgcn_mfma_f32_16x16x32_bf16(al, bh[nc], acc[mr][nc], 0, 0, 0); \
            }                                                                  \
        }                                                                      \
    };                                                                         \
    int nk = (KDIM) >> 5;                                                      \
    short* lds0 = lds;                                                         \
    short* lds1 = lds + 12288;                                                 \
    bf16x8 a0A{}, a1A{}, a2A{}, a3A{}, a0B{}, a1B{}, a2B{}, a3B{};             \
    issue(0, lds0);                                                            \
    if (HASAL) {                                                               \
        a0A = *(const bf16x8*)(alp0); a1A = *(const bf16x8*)(alp1);            \
        a2A = *(const bf16x8*)(alp2); a3A = *(const bf16x8*)(alp3);            \
    }                                                                          \
    __syncthreads();                                                           \
    for (int kt = 0; kt < nk; kt += 2) {                                       \
        if (kt + 1 < nk) {                                                     \
            issue(kt + 1, lds1);                                               \
            if (HASAL) {                                                       \
                const int o1 = (kt + 1) * 32;                                  \
                a0B = *(const bf16x8*)(alp0 + o1); a1B = *(const bf16x8*)(alp1 + o1); \
                a2B = *(const bf16x8*)(alp2 + o1); a3B = *(const bf16x8*)(alp3 + o1); \
            }                                                                  \
        }                                                                      \
        compute(lds0, a0A, a1A, a2A, a3A);                                     \
        __syncthreads();                                                       \
        if (kt + 1 < nk) {                                                     \
            if (kt + 2 < nk) {                                                 \
                issue(kt + 2, lds0);                                           \
                if (HASAL) {                                                   \
                    const int o2 = (kt + 2) * 32;                              \
                    a0A = *(const bf16x8*)(alp0 + o2); a1A = *(const bf16x8*)(alp1 + o2); \
                    a2A = *(const bf16x8*)(alp2 + o2); a3A = *(const bf16x8*)(alp3 + o2); \
                }                                                              \
            }                                                                  \
            compute(lds1, a0B, a1B, a2B, a3B);                                 \
            __syncthreads();                                                   \
        }                                                                      \
    }                                                                          \
    _Pragma("unroll")                                                          \
    for (int nc = 0; nc < 4; ++nc) {                                           \
        int col = col0 + wc * 64 + nc * 16 + l15;                              \
        float bv = (BIAS_EXPR);                                                \
        _Pragma("unroll")                                                      \
        for (int mr = 0; mr < 4; ++mr) {                                       \
            int row = row0 + wr * 64 + mr * 16 + l4 * 4;                       \
            _Pragma("unroll")                                                  \
            for (int r = 0; r < 4; ++r) {                                      \
                float v = acc[mr][nc][r] + bv;                                 \
                size_t idx = (size_t)(row + r) * N + col;                      \
                STORE_STMT;                                                    \
            }                                                                  \
        }                                                                      \
    }

// GEMM modes: 0 fp32 C; 1 pair+ReLU; 2 pair; 3 single bf16 + ReLU.
// 1-D grid, XCD-swizzled; tile decode col-fastest (nCB col blocks).
template<int CMODE, int HASAL>
__global__ __launch_bounds__(256, 3) void gemm_pre(
    const u16* __restrict__ Ah, const u16* __restrict__ Al,
    const u16* __restrict__ Bh, const u16* __restrict__ Bl,
    const float* __restrict__ bias, const float* __restrict__ bias2, int nsplit,
    float* __restrict__ Cf, u16* __restrict__ Ch, u16* __restrict__ Cl,
    int N, int K, int nCB)
{
    int g = xcd_remap(blockIdx.x, gridDim.x);
    int col0 = (g % nCB) * 128;
    int row0 = (g / nCB) * 128;
    GEMM_BODY(Ah, Al, Bh, Bl, K, HASAL,
        (col < nsplit) ? bias[col] : bias2[col - nsplit],
        {
            if (CMODE == 0) { Cf[idx] = v; }
            else if (CMODE == 3) {
                v = fmaxf(v, 0.f);
                Ch[idx] = f2bf(v);
            } else {
                if (CMODE == 1) v = fmaxf(v, 0.f);
                u16 h = f2bf(v);
                Ch[idx] = h;
                Cl[idx] = f2bf(v - bf2f(h));
            }
        })
}

// Fused val + offlog GEMM, 1-D grid of 850 blocks, XCD-swizzled.
// Tile decode: cg = g%5 (cg<2 -> val cols, cg>=2 -> offlog cols), row = g/5.
__global__ __launch_bounds__(256, 3) void gemm_vo(
    const u16* __restrict__ oh, const u16* __restrict__ ol,
    const u16* __restrict__ qh, const u16* __restrict__ ql,
    const u16* __restrict__ wvh, const u16* __restrict__ wvl,
    const u16* __restrict__ wch, const u16* __restrict__ wcl,
    const float* __restrict__ b_val, const float* __restrict__ b_off,
    const float* __restrict__ b_att,
    float* __restrict__ val, float* __restrict__ offlog)
{
    int g = xcd_remap(blockIdx.x, gridDim.x);
    int cg = g % 5;
    int row0 = (g / 5) * 128;
    bool isv = cg < 2;
    const u16* Ah = isv ? oh : qh;
    const u16* Al = isv ? ol : ql;
    const u16* Bh = isv ? wvh : wch;
    const u16* Bl = isv ? wvl : wcl;
    float* Cf = isv ? val : offlog;
    int N = isv ? 256 : 384;
    int col0 = isv ? cg * 128 : (cg - 2) * 128;
    GEMM_BODY(Ah, Al, Bh, Bl, 256, 1,
        isv ? b_val[col] : (col < 256 ? b_off[col] : b_att[col - 256]),
        { Cf[idx] = v; })
}

// ---------------------------------------------------------------------------
// MSDA v3b: LDS-shared weight precompute, gather phase with dual FMA chains.
// One block = 4 queries (one wave each); fused softmax; bf16-pair output.
// ---------------------------------------------------------------------------
__global__ __launch_bounds__(256) void msda3(
    const float* __restrict__ value, const float* __restrict__ offlog,
    u16* __restrict__ eh, u16* __restrict__ el)
{
    __shared__ float aw_lds[32][16];
    __shared__ __align__(16) float wts[32 * 17 * 4];
    __shared__ __align__(16) int   idxs[32 * 17 * 4];

    int tid = threadIdx.x;
    int m0 = blockIdx.x * 4;

    if (tid < 32) {
        int m = m0 + (tid >> 3);
        const float* lg = offlog + (size_t)m * 384 + 256 + (tid & 7) * 16;
        float w[16]; float mx = -1e30f;
#pragma unroll
        for (int i = 0; i < 4; ++i) {
            float4 v = reinterpret_cast<const float4*>(lg)[i];
            w[4 * i] = v.x; w[4 * i + 1] = v.y; w[4 * i + 2] = v.z; w[4 * i + 3] = v.w;
        }
#pragma unroll
        for (int j = 0; j < 16; ++j) mx = fmaxf(mx, w[j]);
        float s = 0.f;
#pragma unroll
        for (int j = 0; j < 16; ++j) { w[j] = __expf(w[j] - mx); s += w[j]; }
        float rs = 1.f / s;
#pragma unroll
        for (int j = 0; j < 16; ++j) aw_lds[tid][j] = w[j] * rs;
    }
    __syncthreads();

#pragma unroll
    for (int pp = 0; pp < 2; ++pp) {
        int pi = tid + 256 * pp;
        int qi = pi >> 7, rem = pi & 127;
        int h = rem >> 4, j = rem & 15;
        int l = j >> 2;
        int m = m0 + qi;
        int b = m / QTOT, q = m - b * QTOT;
        int lq = (q < 4096) ? 0 : (q < 5120) ? 1 : (q < 5376) ? 2 : 3;
        int qbase = (lq == 0) ? 0 : (lq == 1) ? 4096 : (lq == 2) ? 5120 : 5376;
        int qrem = q - qbase;
        int shq = 6 - lq;
        int Wq = 1 << shq;
        int yq = qrem >> shq, xq = qrem & (Wq - 1);
        float invq = 1.0f / (float)Wq;
        float ref_x = (xq + 0.5f) * invq;
        float ref_y = (yq + 0.5f) * invq;
        int HW = 64 >> l;
        float fHW = (float)HW;
        float invl = 1.0f / fHW;
        int loff = (l == 0) ? 0 : (l == 1) ? 4096 : (l == 2) ? 5120 : 5376;
        float ox = offlog[(size_t)m * 384 + h * 32 + j * 2 + 0];
        float oy = offlog[(size_t)m * 384 + h * 32 + j * 2 + 1];
        float aw = aw_lds[qi * 8 + h][j];
        float x = (ref_x + ox * invl) * fHW - 0.5f;
        float y = (ref_y + oy * invl) * fHW - 0.5f;
        float x0f = floorf(x), y0f = floorf(y);
        int x0 = (int)x0f, y0 = (int)y0f;
        float wx = x - x0f, wy = y - y0f;
        float vx0 = (x0 >= 0 && x0 < HW) ? 1.f : 0.f;
        float vx1 = (x0 + 1 >= 0 && x0 + 1 < HW) ? 1.f : 0.f;
        float vy0 = (y0 >= 0 && y0 < HW) ? 1.f : 0.f;
        float vy1 = (y0 + 1 >= 0 && y0 + 1 < HW) ? 1.f : 0.f;
        float w00 = (1.f - wx) * (1.f - wy) * aw * vx0 * vy0;
        float w01 = wx * (1.f - wy) * aw * vx1 * vy0;
        float w10 = (1.f - wx) * wy * aw * vx0 * vy1;
        float w11 = wx * wy * aw * vx1 * vy1;
        int xc0 = min(max(x0, 0), HW - 1);
        int xc1 = min(max(x0 + 1, 0), HW - 1);
        int yc0 = min(max(y0, 0), HW - 1);
        int yc1 = min(max(y0 + 1, 0), HW - 1);
        int rbase = b * QTOT + loff;
        int i00 = (rbase + yc0 * HW + xc0) << 10;
        int i01 = (rbase + yc0 * HW + xc1) << 10;
        int i10 = (rbase + yc1 * HW + xc0) << 10;
        int i11 = (rbase + yc1 * HW + xc1) << 10;
        int sl = (qi * 8 + h) * 17 + j;
        reinterpret_cast<float4*>(wts)[sl] = make_float4(w00, w01, w10, w11);
        reinterpret_cast<int4*>(idxs)[sl] = make_int4(i00, i01, i10, i11);
    }
    __syncthreads();

    int lane = tid & 63;
    int qi = tid >> 6, h = lane >> 3, c8 = lane & 7;
    int m = m0 + qi;
    const char* vb = (const char*)value + h * 128 + c8 * 16;
    int base = (qi * 8 + h) * 17;
    float a0 = 0.f, a1 = 0.f, a2 = 0.f, a3 = 0.f;
    float b0 = 0.f, b1 = 0.f, b2 = 0.f, b3 = 0.f;
#pragma unroll
    for (int j = 0; j < 16; j += 2) {
        float4 w0 = reinterpret_cast<const float4*>(wts)[base + j];
        int4  x0 = reinterpret_cast<const int4*>(idxs)[base + j];
        float4 w1 = reinterpret_cast<const float4*>(wts)[base + j + 1];
        int4  x1 = reinterpret_cast<const int4*>(idxs)[base + j + 1];
        float4 v00 = *reinterpret_cast<const float4*>(vb + x0.x);
        float4 v01 = *reinterpret_cast<const float4*>(vb + x0.y);
        float4 v10 = *reinterpret_cast<const float4*>(vb + x0.z);
        float4 v11 = *reinterpret_cast<const float4*>(vb + x0.w);
        float4 u00 = *reinterpret_cast<const float4*>(vb + x1.x);
        float4 u01 = *reinterpret_cast<const float4*>(vb + x1.y);
        float4 u10 = *reinterpret_cast<const float4*>(vb + x1.z);
        float4 u11 = *reinterpret_cast<const float4*>(vb + x1.w);
        a0 += w0.x * v00.x + w0.y * v01.x + w0.z * v10.x + w0.w * v11.x;
        a1 += w0.x * v00.y + w0.y * v01.y + w0.z * v10.y + w0.w * v11.y;
        a2 += w0.x * v00.z + w0.y * v01.z + w0.z * v10.z + w0.w * v11.z;
        a3 += w0.x * v00.w + w0.y * v01.w + w0.z * v10.w + w0.w * v11.w;
        b0 += w1.x * u00.x + w1.y * u01.x + w1.z * u10.x + w1.w * u11.x;
        b1 += w1.x * u00.y + w1.y * u01.y + w1.z * u10.y + w1.w * u11.y;
        b2 += w1.x * u00.z + w1.y * u01.z + w1.z * u10.z + w1.w * u11.z;
        b3 += w1.x * u00.w + w1.y * u01.w + w1.z * u10.w + w1.w * u11.w;
    }
    a0 += b0; a1 += b1; a2 += b2; a3 += b3;
    size_t oidx = (size_t)m * D_MODEL + h * 32 + c8 * 4;
    ushort4 hv, lv;
    hv.x = f2bf(a0); lv.x = f2bf(a0 - bf2f(hv.x));
    hv.y = f2bf(a1); lv.y = f2bf(a1 - bf2f(hv.y));
    hv.z = f2bf(a2); lv.z = f2bf(a2 - bf2f(hv.z));
    hv.w = f2bf(a3); lv.w = f2bf(a3 - bf2f(hv.w));
    *reinterpret_cast<ushort4*>(eh + oidx) = hv;
    *reinterpret_cast<ushort4*>(el + oidx) = lv;
}

// ---------------------------------------------------------------------------
// add+LN on pair-stored residual (4 rows/block, wave per row).
// TMODE 0: t fp32.  TMODE 1: t bf16 pair (th, tl).
// WRITEQ: also q = y + posf -> qh/ql.  WRITEF32: y -> f32out.
// ---------------------------------------------------------------------------
template<int TMODE, int WRITEQ, int WRITEF32>
__global__ __launch_bounds__(256) void add_ln_pair(
    const float* __restrict__ t, const u16* __restrict__ th,
    const u16* __restrict__ tl,
    const float* __restrict__ g, const float* __restrict__ beta,
    u16* __restrict__ oh, u16* __restrict__ ol,
    const float* __restrict__ posf, u16* __restrict__ qh, u16* __restrict__ ql,
    float* __restrict__ f32out)
{
    int row = blockIdx.x * 4 + (threadIdx.x >> 6);
    int lane = threadIdx.x & 63;
    size_t base = (size_t)row * D_MODEL + lane * 4;
    ushort4 hv = *reinterpret_cast<const ushort4*>(oh + base);
    ushort4 lv = *reinterpret_cast<const ushort4*>(ol + base);
    float t0, t1, t2, t3;
    if (TMODE == 0) {
        float4 tv = *reinterpret_cast<const float4*>(t + base);
        t0 = tv.x; t1 = tv.y; t2 = tv.z; t3 = tv.w;
    } else {
        ushort4 thv = *reinterpret_cast<const ushort4*>(th + base);
        ushort4 tlv = *reinterpret_cast<const ushort4*>(tl + base);
        t0 = bf2f(thv.x) + bf2f(tlv.x);
        t1 = bf2f(thv.y) + bf2f(tlv.y);
        t2 = bf2f(thv.z) + bf2f(tlv.z);
        t3 = bf2f(thv.w) + bf2f(tlv.w);
    }
    float v0 = bf2f(hv.x) + bf2f(lv.x) + t0;
    float v1 = bf2f(hv.y) + bf2f(lv.y) + t1;
    float v2 = bf2f(hv.z) + bf2f(lv.z) + t2;
    float v3 = bf2f(hv.w) + bf2f(lv.w) + t3;
    float s = v0 + v1 + v2 + v3;
#pragma unroll
    for (int o = 32; o > 0; o >>= 1) s += __shfl_xor(s, o);
    float mean = s * (1.f / D_MODEL);
    float d0 = v0 - mean, d1 = v1 - mean, d2 = v2 - mean, d3 = v3 - mean;
    float ss = d0 * d0 + d1 * d1 + d2 * d2 + d3 * d3;
#pragma unroll
    for (int o = 32; o > 0; o >>= 1) ss += __shfl_xor(ss, o);
    float rstd = rsqrtf(ss * (1.f / D_MODEL) + 1e-5f);
    float4 gv = *reinterpret_cast<const float4*>(&g[lane * 4]);
    float4 bv = *reinterpret_cast<const float4*>(&beta[lane * 4]);
    float y0 = d0 * rstd * gv.x + bv.x;
    float y1 = d1 * rstd * gv.y + bv.y;
    float y2 = d2 * rstd * gv.z + bv.z;
    float y3 = d3 * rstd * gv.w + bv.w;
    ushort4 nh, nl;
    nh.x = f2bf(y0); nl.x = f2bf(y0 - bf2f(nh.x));
    nh.y = f2bf(y1); nl.y = f2bf(y1 - bf2f(nh.y));
    nh.z = f2bf(y2); nl.z = f2bf(y2 - bf2f(nh.z));
    nh.w = f2bf(y3); nl.w = f2bf(y3 - bf2f(nh.w));
    *reinterpret_cast<ushort4*>(oh + base) = nh;
    *reinterpret_cast<ushort4*>(ol + base) = nl;
    if (WRITEQ) {
        float4 pv = *reinterpret_cast<const float4*>(posf + base);
        float q0 = y0 + pv.x, q1 = y1 + pv.y, q2 = y2 + pv.z, q3 = y3 + pv.w;
        ushort4 qhv, qlv;
        qhv.x = f2bf(q0); qlv.x = f2bf(q0 - bf2f(qhv.x));
        qhv.y = f2bf(q1); qlv.y = f2bf(q1 - bf2f(qhv.y));
        qhv.z = f2bf(q2); qlv.z = f2bf(q2 - bf2f(qhv.z));
        qhv.w = f2bf(q3); qlv.w = f2bf(q3 - bf2f(qhv.w));
        *reinterpret_cast<ushort4*>(qh + base) = qhv;
        *reinterpret_cast<ushort4*>(ql + base) = qlv;
    }
    if (WRITEF32) {
        *reinterpret_cast<float4*>(f32out + base) = make_float4(y0, y1, y2, y3);
    }
}

// ---------------------------------------------------------------------------
extern "C" void kernel_launch(void* const* d_in, const int* in_sizes, int n_in,
                              void* d_out, int out_size, void* d_ws, size_t ws_size,
                              hipStream_t stream)
{
    // dict order is INTERLEAVED: src0,pos0,src1,pos1,...
    const float* src[4] = {(const float*)d_in[0], (const float*)d_in[2],
                           (const float*)d_in[4], (const float*)d_in[6]};
    const float* pos[4] = {(const float*)d_in[1], (const float*)d_in[3],
                           (const float*)d_in[5], (const float*)d_in[7]};
    const float* lvl   = (const float*)d_in[8];
    const float* W_off = (const float*)d_in[9];
    const float* b_off = (const float*)d_in[10];
    const float* W_att = (const float*)d_in[11];
    const float* b_att = (const float*)d_in[12];
    const float* W_val = (const float*)d_in[13];
    const float* b_val = (const float*)d_in[14];
    const float* W_out = (const float*)d_in[15];
    const float* b_out = (const float*)d_in[16];
    const float* ln1g  = (const float*)d_in[17];
    const float* ln1b  = (const float*)d_in[18];
    const float* W_ff1 = (const float*)d_in[19];
    const float* b_ff1 = (const float*)d_in[20];
    const float* W_ff2 = (const float*)d_in[21];
    const float* b_ff2 = (const float*)d_in[22];
    const float* ln2g  = (const float*)d_in[23];
    const float* ln2b  = (const float*)d_in[24];

    float* ws = (float*)d_ws;
    const size_t MD = (size_t)MTOT * D_MODEL;    // 5,570,560

    // Workspace layout (~140.6 MB; proven to fit in rounds 4-11):
    float* posf = ws;                                    // fp32 [M,256]
    u16* oh = (u16*)(ws + MD);
    u16* ol = oh + MD;
    u16* qh = ol + MD;                                   // q / e / ff2-out pair
    u16* ql = qh + MD;
    u16* eh = qh; u16* el = ql;
    float* val    = (float*)(ql + MD);                   // fp32 [M,256]
    float* offlog = val + MD;                            // fp32 [M,384]; tmp
    float* tmp    = offlog;
    u16* hid = (u16*)val;   // FFN hidden, SINGLE bf16, full M: [M,1024]=44.6MB
    u16* wb = (u16*)(offlog + (size_t)MTOT * 384);
    size_t o = 0;
    u16* wv_h = wb + o; o += 6 * 65536;  u16* wv_l = wb + o; o += 6 * 65536;
    u16* wc_h = wb + o; o += 6 * 98304;  u16* wc_l = wb + o; o += 6 * 98304;
    u16* wu_h = wb + o; o += 6 * 65536;  u16* wu_l = wb + o; o += 6 * 65536;
    u16* wf1_h = wb + o; o += 6 * 262144; u16* wf1_l = wb + o; o += 6 * 262144;
    u16* wf2_h = wb + o; o += 6 * 262144; u16* wf2_l = wb + o; o += 6 * 262144;

    dim3 cb(32, 8);
    flatten_all<<<dim3(170, 8, BATCH), cb, 0, stream>>>(
        src[0], src[1], src[2], src[3], pos[0], pos[1], pos[2], pos[3],
        lvl, posf, oh, ol, qh, ql);
    wconv_all<<<6 * 736, cb, 0, stream>>>(
        W_val, W_off, W_att, W_out, W_ff1, W_ff2,
        wv_h, wv_l, wc_h, wc_l, wu_h, wu_l, wf1_h, wf1_l, wf2_h, wf2_l);

    for (int i = 0; i < NLAYER; ++i) {
        gemm_vo<<<850, 256, 0, stream>>>(
            oh, ol, qh, ql,
            wv_h + i * 65536, wv_l + i * 65536,
            wc_h + i * 98304, wc_l + i * 98304,
            b_val + i * 256, b_off + i * 256, b_att + i * 128,
            val, offlog);
        msda3<<<MTOT / 4, 256, 0, stream>>>(val, offlog, eh, el);
        gemm_pre<0, 1><<<340, 256, 0, stream>>>(
            eh, el, wu_h + i * 65536, wu_l + i * 65536,
            b_out + i * 256, b_out + i * 256, 256,
            tmp, nullptr, nullptr, 256, 256, 2);
        add_ln_pair<0, 0, 0><<<MTOT / 4, 256, 0, stream>>>(
            tmp, nullptr, nullptr, ln1g + i * 256, ln1b + i * 256, oh, ol,
            nullptr, nullptr, nullptr, nullptr);
        // FFN full-M: ff1 -> single-bf16 hidden; ff2 2-pass (no A-lo).
        gemm_pre<3, 1><<<1360, 256, 0, stream>>>(
            oh, ol, wf1_h + i * 262144, wf1_l + i * 262144,
            b_ff1 + i * 1024, b_ff1 + i * 1024, 1024,
            nullptr, hid, nullptr, 1024, 256, 8);
        gemm_pre<2, 0><<<340, 256, 0, stream>>>(
            hid, nullptr, wf2_h + i * 262144, wf2_l + i * 262144,
            b_ff2 + i * 256, b_ff2 + i * 256, 256,
            nullptr, eh, el, 256, 1024, 2);
        if (i < NLAYER - 1)
            add_ln_pair<1, 1, 0><<<MTOT / 4, 256, 0, stream>>>(
                nullptr, eh, el, ln2g + i * 256, ln2b + i * 256, oh, ol,
                posf, qh, ql, nullptr);
        else
            add_ln_pair<1, 0, 1><<<MTOT / 4, 256, 0, stream>>>(
                nullptr, eh, el, ln2g + i * 256, ln2b + i * 256, oh, ol,
                nullptr, nullptr, nullptr, (float*)d_out);
    }
    (void)in_sizes; (void)n_in; (void)out_size; (void)ws_size;
}